// Round 6
// baseline (3152.692 us; speedup 1.0000x reference)
//
#include <hip/hip_runtime.h>
#include <hip/hip_bf16.h>
#include <math.h>

#define VOCAB 50257
#define CTX 2048
#define DMODEL 1024
#define NHEAD 16
#define NLAYER 8
#define DHEAD 64
#define BATCH 2
#define SEQ 2048
#define NTOK (BATCH * SEQ)   // 4096

typedef __bf16 bf16x8 __attribute__((ext_vector_type(8)));
typedef float  f32x4  __attribute__((ext_vector_type(4)));
typedef unsigned short ushort4v __attribute__((ext_vector_type(4)));
typedef unsigned short ushort8v __attribute__((ext_vector_type(8)));

__device__ inline void gl_lds16(const void* g, void* l) {
    __builtin_amdgcn_global_load_lds(
        (const __attribute__((address_space(1))) unsigned int*)g,
        (__attribute__((address_space(3))) unsigned int*)l, 16, 0, 0);
}

__device__ inline unsigned short f2bs(float v) {
    __hip_bfloat16 t = __float2bfloat16(v);
    return *(unsigned short*)&t;
}
__device__ inline float bs2f(unsigned short u) {
    return __uint_as_float(((unsigned)u) << 16);
}

// ---------------- embedding: h(bf16) = wte[x] + wpe[pos] ----------------
__global__ void embed_kernel(const int* __restrict__ x,
                             const float* __restrict__ wte,
                             const float* __restrict__ wpe,
                             unsigned short* __restrict__ h) {
    int t = blockIdx.x;
    int s = t & (SEQ - 1);
    int tok = x[t];
    const float* pe = wpe + (long)s * DMODEL;
    const float* te = wte + (long)tok * DMODEL;
    unsigned short* ph = h + (long)t * DMODEL;
    int d = threadIdx.x * 4;
    f32x4 t4 = *(const f32x4*)&te[d];
    f32x4 p4 = *(const f32x4*)&pe[d];
    ushort4v o;
    #pragma unroll
    for (int j = 0; j < 4; ++j) o[j] = f2bs(t4[j] + p4[j]);
    *(ushort4v*)&ph[d] = o;
}

// ---------------- layernorm: bf16 in, 1 wave per row ----------------
__device__ inline float wave_sum(float v) {
    for (int off = 32; off; off >>= 1) v += __shfl_xor(v, off);
    return v;
}

template<typename OT>
__global__ void ln_kernel(const unsigned short* __restrict__ in, OT* __restrict__ out,
                          const float* __restrict__ g, const float* __restrict__ b,
                          long row_stride, int nrows) {
    const int w = threadIdx.x >> 6, lane = threadIdx.x & 63;
    const int row = blockIdx.x * 4 + w;
    if (row >= nrows) return;
    const unsigned short* px = in + (long)row * row_stride;
    ushort8v u[2];
    u[0] = *(const ushort8v*)&px[lane * 16];
    u[1] = *(const ushort8v*)&px[lane * 16 + 8];
    float x[16];
    float s = 0.f;
    #pragma unroll
    for (int i = 0; i < 16; ++i) { x[i] = bs2f(u[i >> 3][i & 7]); s += x[i]; }
    s = wave_sum(s);
    const float mean = s * (1.0f / DMODEL);
    float s2 = 0.f;
    #pragma unroll
    for (int i = 0; i < 16; ++i) { float d = x[i] - mean; s2 += d * d; }
    s2 = wave_sum(s2);
    const float r = 1.0f / sqrtf(s2 * (1.0f / DMODEL) + 1e-5f);
    const int d0 = lane * 16;
    if constexpr (sizeof(OT) == 2) {
        #pragma unroll
        for (int p = 0; p < 2; ++p) {
            ushort8v pk;
            #pragma unroll
            for (int j = 0; j < 8; ++j) {
                int d = d0 + p * 8 + j;
                pk[j] = f2bs((x[p * 8 + j] - mean) * r * g[d] + b[d]);
            }
            *(ushort8v*)((unsigned short*)out + (long)row * DMODEL + d0 + p * 8) = pk;
        }
    } else {
        #pragma unroll
        for (int p = 0; p < 4; ++p) {
            f32x4 ov;
            #pragma unroll
            for (int j = 0; j < 4; ++j) {
                int d = d0 + p * 4 + j;
                ov[j] = (x[p * 4 + j] - mean) * r * g[d] + b[d];
            }
            *(f32x4*)((float*)out + (long)row * DMODEL + d0 + p * 4) = ov;
        }
    }
}

// ------------- batched vectorized transpose+convert: all layer weights -------------
// arena per layer (ushort elems): qkvT@0 (3072x1024), projT@3145728 (1024x1024),
// fcT@4194304 (4096x1024), cpT@8388608 (1024x4096). layer stride 12582912.
// 64x64 tiles, k-fastest block order (adjacent blocks write adjacent k-chunks).
#define LWOFF 12582912L
__global__ void convT_all(const float* __restrict__ wq, const float* __restrict__ wp,
                          const float* __restrict__ wf, const float* __restrict__ wc,
                          unsigned short* __restrict__ arena) {
    __shared__ float t[64][65];
    const int bid = blockIdx.x;
    const int l = bid / 3072;
    int r = bid % 3072;
    const float* W; unsigned short* WT; int K, N, bx, by;
    if (r < 768)       {            W = wq + l * 3145728L; WT = arena + l * LWOFF;           K = 1024; N = 3072; by = r % 16; bx = r / 16; }
    else if (r < 1024) { r -= 768;  W = wp + l * 1048576L; WT = arena + l * LWOFF + 3145728; K = 1024; N = 1024; by = r % 16; bx = r / 16; }
    else if (r < 2048) { r -= 1024; W = wf + l * 4194304L; WT = arena + l * LWOFF + 4194304; K = 1024; N = 4096; by = r % 16; bx = r / 16; }
    else               { r -= 2048; W = wc + l * 4194304L; WT = arena + l * LWOFF + 8388608; K = 4096; N = 1024; by = r % 64; bx = r / 64; }
    const int n0 = bx * 64, k0 = by * 64;
    const int tid = threadIdx.x;
    {
        const int krow = tid >> 4, c4 = (tid & 15) * 4;
        #pragma unroll
        for (int p = 0; p < 4; ++p) {
            f32x4 gv = *(const f32x4*)&W[(long)(k0 + p * 16 + krow) * N + n0 + c4];
            #pragma unroll
            for (int j = 0; j < 4; ++j) t[p * 16 + krow][c4 + j] = gv[j];
        }
    }
    __syncthreads();
    {
        const int n = tid >> 3, kl = (tid & 7) * 8;
        #pragma unroll
        for (int p = 0; p < 2; ++p) {
            ushort8v pk;
            #pragma unroll
            for (int j = 0; j < 8; ++j) pk[j] = f2bs(t[kl + j][p * 32 + n]);
            *(ushort8v*)&WT[(long)(n0 + p * 32 + n) * K + k0 + kl] = pk;
        }
    }
}

// ---------------- 128^2 bf16 MFMA GEMM (proven m97 structure) ----------------
// A [M][K] bf16, BT [N][K] bf16. 128x128 tile, BK=32, 4 waves.
// EPI: 1 = bf16 +bias+R(bf16); 2 = bf16 gelu(x+bias); 3 = qkv scatter
template<int EPI>
__global__ __launch_bounds__(256)
void mm_mfma(const unsigned short* __restrict__ A,
             const unsigned short* __restrict__ BT,
             const float* __restrict__ bias, const unsigned short* __restrict__ R,
             void* __restrict__ Cout, int M, int N, int K) {
    __shared__ unsigned short As[128 * 32];
    __shared__ unsigned short Bs[128 * 32];
    const int tid = threadIdx.x;
    const int w = tid >> 6, lane = tid & 63;
    const int bm = blockIdx.y * 128, bn = blockIdx.x * 128;
    const int wr = (w >> 1) * 64, wc = (w & 1) * 64;

    f32x4 acc[4][4];
    #pragma unroll
    for (int m = 0; m < 4; ++m)
        #pragma unroll
        for (int n = 0; n < 4; ++n)
            acc[m][n] = (f32x4){0.f, 0.f, 0.f, 0.f};

    const int lrow = lane >> 2;
    const int lcol = (lane & 3) * 8;
    const unsigned short* gA = A + (long)(bm + w * 32 + lrow) * K + lcol;
    const unsigned short* gB = BT + (long)(bn + w * 32 + lrow) * K + lcol;
    unsigned short* lA = &As[(w * 32) * 32];
    unsigned short* lB = &Bs[(w * 32) * 32];

    for (int k0 = 0; k0 < K; k0 += 32) {
        gl_lds16(gA + k0,          lA);
        gl_lds16(gA + k0 + 16 * K, lA + 16 * 32);
        gl_lds16(gB + k0,          lB);
        gl_lds16(gB + k0 + 16 * K, lB + 16 * 32);
        __syncthreads();

        bf16x8 a[4], b[4];
        #pragma unroll
        for (int m = 0; m < 4; ++m)
            a[m] = *(const bf16x8*)&As[(wr + m * 16 + (lane & 15)) * 32 + (lane >> 4) * 8];
        #pragma unroll
        for (int n = 0; n < 4; ++n)
            b[n] = *(const bf16x8*)&Bs[(wc + n * 16 + (lane & 15)) * 32 + (lane >> 4) * 8];
        #pragma unroll
        for (int m = 0; m < 4; ++m)
            #pragma unroll
            for (int n = 0; n < 4; ++n)
                acc[m][n] = __builtin_amdgcn_mfma_f32_16x16x32_bf16(a[m], b[n], acc[m][n], 0, 0, 0);
        __syncthreads();
    }

    const int r0 = (lane >> 4) * 4, cc = lane & 15;
    #pragma unroll
    for (int n = 0; n < 4; ++n) {
        int colb = bn + wc + n * 16;
        float bv = bias[colb + cc];
        #pragma unroll
        for (int m = 0; m < 4; ++m) {
            int rowb = bm + wr + m * 16 + r0;
            if (EPI == 3) {
                unsigned short* qkvB = (unsigned short*)Cout;
                int which = colb >> 10, hh = (colb & 1023) >> 6, dbase = colb & 63;
                int b_ = rowb >> 11, s_ = rowb & 2047;
                long bh2 = b_ * 16 + hh;
                float v[4];
                #pragma unroll
                for (int r = 0; r < 4; ++r) v[r] = acc[m][n][r] + bv;
                if (which == 2) {
                    ushort4v pk;
                    #pragma unroll
                    for (int r = 0; r < 4; ++r) pk[r] = f2bs(v[r]);
                    *(ushort4v*)&qkvB[8388608L + (bh2 * 64 + dbase + cc) * 2048 + s_] = pk;
                } else {
                    unsigned short* dst = qkvB + (long)which * 4194304L +
                                          (bh2 * 2048 + s_) * 64 + dbase + cc;
                    #pragma unroll
                    for (int r = 0; r < 4; ++r) dst[r * 64] = f2bs(v[r]);
                }
            } else {
                #pragma unroll
                for (int r = 0; r < 4; ++r) {
                    long row = rowb + r, col = colb + cc;
                    float v = acc[m][n][r] + bv;
                    if (EPI == 1) {
                        v += bs2f(R[row * N + col]);
                        ((unsigned short*)Cout)[row * N + col] = f2bs(v);
                    } else {
                        v = 0.5f * v * (1.0f + erff(v * 0.70710678118f));
                        ((unsigned short*)Cout)[row * N + col] = f2bs(v);
                    }
                }
            }
        }
    }
}

// ---------------- MFMA flash attention (R3 proven version) ----------------
// qB,kB: [bh][s][64] bf16. vT: [bh][64][s] bf16. z: [b][s][1024] bf16.
__global__ __launch_bounds__(256)
void attn_mfma(const unsigned short* __restrict__ qB,
               const unsigned short* __restrict__ kB,
               const unsigned short* __restrict__ vT,
               unsigned short* __restrict__ z) {
    const int bh = blockIdx.x;
    const int qb = blockIdx.y * 64;
    const int tid = threadIdx.x, w = tid >> 6, lane = tid & 63;
    const int arow = lane & 15, kg = lane >> 4;
    __shared__ unsigned short Ks[64 * 64];
    __shared__ unsigned short Vs[64 * 64];
    __shared__ unsigned short Ps[4][16 * 64];

    const long kvbase = (long)bh * (2048 * 64);

    bf16x8 qa[2];
    {
        const unsigned short* q0 = qB + kvbase + (long)(qb + w * 16 + arow) * 64 + kg * 8;
        qa[0] = *(const bf16x8*)(q0);
        qa[1] = *(const bf16x8*)(q0 + 32);
    }

    f32x4 po[4];
    float mrow[4], lrow[4];
    #pragma unroll
    for (int i = 0; i < 4; ++i) {
        po[i] = (f32x4){0.f, 0.f, 0.f, 0.f};
        mrow[i] = -1e30f; lrow[i] = 0.f;
    }

    const int srow = lane >> 3;
    const int schunk = (lane & 7) ^ srow;          // pre-swizzled source (rule #21)
    const int cmax = qb >> 6;

    for (int c = 0; c <= cmax; ++c) {
        {
            const unsigned short* ks0 = kB + kvbase + (long)(c * 64 + w * 16 + srow) * 64 + schunk * 8;
            const unsigned short* vs0 = vT + kvbase + (long)(w * 16 + srow) * 2048 + c * 64 + schunk * 8;
            gl_lds16(ks0,            &Ks[(w * 16) * 64]);
            gl_lds16(ks0 + 8 * 64,   &Ks[(w * 16 + 8) * 64]);
            gl_lds16(vs0,            &Vs[(w * 16) * 64]);
            gl_lds16(vs0 + 8 * 2048, &Vs[(w * 16 + 8) * 64]);
        }
        __syncthreads();

        f32x4 s[4];
        #pragma unroll
        for (int n = 0; n < 4; ++n) {
            s[n] = (f32x4){0.f, 0.f, 0.f, 0.f};
            int row = n * 16 + arow, sw = row & 7;
            bf16x8 kb0 = *(const bf16x8*)&Ks[row * 64 + (kg ^ sw) * 8];
            bf16x8 kb1 = *(const bf16x8*)&Ks[row * 64 + ((4 + kg) ^ sw) * 8];
            s[n] = __builtin_amdgcn_mfma_f32_16x16x32_bf16(qa[0], kb0, s[n], 0, 0, 0);
            s[n] = __builtin_amdgcn_mfma_f32_16x16x32_bf16(qa[1], kb1, s[n], 0, 0, 0);
        }

        const bool diag = (c == cmax);
        #pragma unroll
        for (int n = 0; n < 4; ++n)
            #pragma unroll
            for (int r = 0; r < 4; ++r) {
                float v = s[n][r] * 0.125f;
                if (diag) {
                    int key = c * 64 + n * 16 + arow;
                    int qrow = qb + w * 16 + kg * 4 + r;
                    if (key > qrow) v = -1e30f;
                }
                s[n][r] = v;
            }

        #pragma unroll
        for (int r = 0; r < 4; ++r) {
            float rm = fmaxf(fmaxf(s[0][r], s[1][r]), fmaxf(s[2][r], s[3][r]));
            #pragma unroll
            for (int off = 1; off < 16; off <<= 1)
                rm = fmaxf(rm, __shfl_xor(rm, off));
            float mnew = fmaxf(mrow[r], rm);
            float esc = expf(mrow[r] - mnew);
            float rs = 0.f;
            #pragma unroll
            for (int n = 0; n < 4; ++n) {
                float p = expf(s[n][r] - mnew);
                s[n][r] = p;
                rs += p;
            }
            #pragma unroll
            for (int off = 1; off < 16; off <<= 1)
                rs += __shfl_xor(rs, off);
            lrow[r] = lrow[r] * esc + rs;
            #pragma unroll
            for (int dt = 0; dt < 4; ++dt) po[dt][r] *= esc;
            mrow[r] = mnew;
        }

        #pragma unroll
        for (int n = 0; n < 4; ++n) {
            int col = n * 16 + arow;
            int chunk = col >> 3, cw = col & 7;
            #pragma unroll
            for (int r = 0; r < 4; ++r) {
                int row = kg * 4 + r;
                Ps[w][row * 64 + ((chunk ^ (row & 7)) * 8 + cw)] = f2bs(s[n][r]);
            }
        }

        bf16x8 pa[2];
        #pragma unroll
        for (int ks = 0; ks < 2; ++ks)
            pa[ks] = *(const bf16x8*)&Ps[w][arow * 64 + (((ks * 4 + kg) ^ (arow & 7)) * 8)];
        #pragma unroll
        for (int dt = 0; dt < 4; ++dt) {
            int vrow = dt * 16 + arow, sw = vrow & 7;
            bf16x8 vb0 = *(const bf16x8*)&Vs[vrow * 64 + ((kg ^ sw) * 8)];
            bf16x8 vb1 = *(const bf16x8*)&Vs[vrow * 64 + (((4 + kg) ^ sw) * 8)];
            po[dt] = __builtin_amdgcn_mfma_f32_16x16x32_bf16(pa[0], vb0, po[dt], 0, 0, 0);
            po[dt] = __builtin_amdgcn_mfma_f32_16x16x32_bf16(pa[1], vb1, po[dt], 0, 0, 0);
        }
        __syncthreads();
    }

    const int b_ = bh >> 4, hofs = (bh & 15) * 64;
    #pragma unroll
    for (int dt = 0; dt < 4; ++dt)
        #pragma unroll
        for (int r = 0; r < 4; ++r) {
            long row = (long)b_ * 2048 + qb + w * 16 + kg * 4 + r;
            z[row * 1024 + hofs + dt * 16 + arow] = f2bs(po[dt][r] / lrow[r]);
        }
}

// ---------------- head ----------------
__global__ void head_kernel(const float* __restrict__ hl, const float* __restrict__ W,
                            float* __restrict__ out) {
    __shared__ float hs[2 * DMODEL];
    int tid = threadIdx.x;
    #pragma unroll
    for (int i = 0; i < 8; ++i) hs[tid + i * 256] = hl[tid + i * 256];
    __syncthreads();
    int v = blockIdx.x * 256 + tid;
    if (v >= VOCAB) return;
    float a0 = 0.f, a1 = 0.f;
    for (int d = 0; d < DMODEL; ++d) {
        float wv = W[(long)d * VOCAB + v];
        a0 += hs[d] * wv;
        a1 += hs[DMODEL + d] * wv;
    }
    out[v] = a0;
    out[VOCAB + v] = a1;
}

extern "C" void kernel_launch(void* const* d_in, const int* in_sizes, int n_in,
                              void* d_out, int out_size, void* d_ws, size_t ws_size,
                              hipStream_t stream) {
    const int*   x      = (const int*)  d_in[0];
    const float* wte    = (const float*)d_in[1];
    const float* wpe    = (const float*)d_in[2];
    const float* ln1_g  = (const float*)d_in[3];
    const float* ln1_b  = (const float*)d_in[4];
    const float* w_qkv  = (const float*)d_in[5];
    const float* b_qkv  = (const float*)d_in[6];
    const float* w_proj = (const float*)d_in[7];
    const float* b_proj = (const float*)d_in[8];
    const float* ln2_g  = (const float*)d_in[9];
    const float* ln2_b  = (const float*)d_in[10];
    const float* w_fc   = (const float*)d_in[11];
    const float* b_fc   = (const float*)d_in[12];
    const float* w_cp   = (const float*)d_in[13];
    const float* b_cp   = (const float*)d_in[14];
    const float* lnf_g  = (const float*)d_in[15];
    const float* lnf_b  = (const float*)d_in[16];
    const float* w_head = (const float*)d_in[17];
    float* out = (float*)d_out;

    char* ws = (char*)d_ws;
    unsigned short* h     = (unsigned short*)ws;                    // 8 MB (bf16)
    unsigned short* qkvB  = (unsigned short*)(ws + (8L << 20));     // 24 MB
    unsigned short* y_bf  = (unsigned short*)(ws + (32L << 20));    // 8 MB
    unsigned short* z_bf  = (unsigned short*)(ws + (40L << 20));    // 8 MB
    unsigned short* fc_bf = (unsigned short*)(ws + (48L << 20));    // 32 MB
    float*          hl    = (float*)(ws + (80L << 20));             // 8 KB
    unsigned short* wsT   = (unsigned short*)(ws + (96L << 20));    // 202 MB arena

    convT_all<<<24576, 256, 0, stream>>>(w_qkv, w_proj, w_fc, w_cp, wsT);
    embed_kernel<<<NTOK, 256, 0, stream>>>(x, wte, wpe, h);

    for (int l = 0; l < NLAYER; ++l) {
        unsigned short* wl = wsT + l * LWOFF;
        ln_kernel<unsigned short><<<NTOK / 4, 256, 0, stream>>>(
            h, y_bf, ln1_g + l * DMODEL, ln1_b + l * DMODEL, DMODEL, NTOK);

        mm_mfma<3><<<dim3(24, 32), 256, 0, stream>>>(
            y_bf, wl, b_qkv + l * 3072, nullptr, qkvB, NTOK, 3072, 1024);

        attn_mfma<<<dim3(BATCH * NHEAD, SEQ / 64), 256, 0, stream>>>(
            qkvB, qkvB + 4194304L, qkvB + 8388608L, z_bf);

        mm_mfma<1><<<dim3(8, 32), 256, 0, stream>>>(
            z_bf, wl + 3145728, b_proj + l * DMODEL, h, h, NTOK, 1024, 1024);

        ln_kernel<unsigned short><<<NTOK / 4, 256, 0, stream>>>(
            h, y_bf, ln2_g + l * DMODEL, ln2_b + l * DMODEL, DMODEL, NTOK);

        mm_mfma<2><<<dim3(32, 32), 256, 0, stream>>>(
            y_bf, wl + 4194304, b_fc + l * 4096, nullptr, fc_bf, NTOK, 4096, 1024);

        mm_mfma<1><<<dim3(8, 32), 256, 0, stream>>>(
            fc_bf, wl + 8388608, b_cp + l * DMODEL, h, h, NTOK, 1024, 4096);
    }

    ln_kernel<float><<<1, 256, 0, stream>>>(h + (long)(SEQ - 1) * DMODEL, hl,
                                            lnf_g, lnf_b, (long)SEQ * DMODEL, 2);
    head_kernel<<<(VOCAB + 255) / 256, 256, 0, stream>>>(hl, w_head, out);
}

// Round 7
// 2927.768 us; speedup vs baseline: 1.0768x; 1.0768x over previous
//
#include <hip/hip_runtime.h>
#include <hip/hip_bf16.h>
#include <math.h>

#define VOCAB 50257
#define CTX 2048
#define DMODEL 1024
#define NHEAD 16
#define NLAYER 8
#define DHEAD 64
#define BATCH 2
#define SEQ 2048
#define NTOK (BATCH * SEQ)   // 4096

typedef __bf16 bf16x8 __attribute__((ext_vector_type(8)));
typedef float  f32x4  __attribute__((ext_vector_type(4)));
typedef unsigned short ushort4v __attribute__((ext_vector_type(4)));
typedef unsigned short ushort8v __attribute__((ext_vector_type(8)));

__device__ inline void gl_lds16(const void* g, void* l) {
    __builtin_amdgcn_global_load_lds(
        (const __attribute__((address_space(1))) unsigned int*)g,
        (__attribute__((address_space(3))) unsigned int*)l, 16, 0, 0);
}

__device__ inline unsigned short f2bs(float v) {
    __hip_bfloat16 t = __float2bfloat16(v);
    return *(unsigned short*)&t;
}

// ---------------- embedding ----------------
__global__ void embed_kernel(const int* __restrict__ x,
                             const float* __restrict__ wte,
                             const float* __restrict__ wpe,
                             float* __restrict__ h) {
    int t = blockIdx.x;
    int s = t & (SEQ - 1);
    int tok = x[t];
    const float* pe = wpe + (long)s * DMODEL;
    const float* te = wte + (long)tok * DMODEL;
    float* ph = h + (long)t * DMODEL;
    for (int d = threadIdx.x; d < DMODEL; d += 256)
        ph[d] = te[d] + pe[d];
}

// ---------------- layernorm ----------------
__device__ inline float wave_sum(float v) {
    for (int off = 32; off; off >>= 1) v += __shfl_xor(v, off);
    return v;
}
__device__ inline void st_val(float* p, float v) { *p = v; }
__device__ inline void st_val(__hip_bfloat16* p, float v) { *p = __float2bfloat16(v); }

template<typename OT>
__global__ void ln_kernel(const float* __restrict__ in, OT* __restrict__ out,
                          const float* __restrict__ g, const float* __restrict__ b,
                          long row_stride) {
    int row = blockIdx.x;
    const float* px = in + (long)row * row_stride;
    OT* po = out + (long)row * DMODEL;
    int tid = threadIdx.x;
    int wid = tid >> 6, lane = tid & 63;

    float x[4];
    float s = 0.f;
    #pragma unroll
    for (int i = 0; i < 4; ++i) { x[i] = px[tid + i * 256]; s += x[i]; }
    s = wave_sum(s);
    __shared__ float red[4], red2[4];
    if (lane == 0) red[wid] = s;
    __syncthreads();
    float mean = (red[0] + red[1] + red[2] + red[3]) * (1.0f / DMODEL);

    float s2 = 0.f;
    #pragma unroll
    for (int i = 0; i < 4; ++i) { float d = x[i] - mean; s2 += d * d; }
    s2 = wave_sum(s2);
    if (lane == 0) red2[wid] = s2;
    __syncthreads();
    float var = (red2[0] + red2[1] + red2[2] + red2[3]) * (1.0f / DMODEL);
    float r = 1.0f / sqrtf(var + 1e-5f);
    #pragma unroll
    for (int i = 0; i < 4; ++i) {
        int d = tid + i * 256;
        st_val(po + d, (x[i] - mean) * r * g[d] + b[d]);
    }
}

// ------------- transpose+convert: W f32 [K][N] -> WT bf16 [N][K] -------------
// 64x64 tile, f32x4 reads, ushort8 (16B) writes, LDS [64][65] (2-way only).
// grid: (K/64, N/64) — k-fastest so adjacent blocks write adjacent 128B chunks.
__global__ void convT64(const float* __restrict__ W,
                        unsigned short* __restrict__ WT, int K, int N) {
    __shared__ float t[64][65];
    const int k0 = blockIdx.x * 64, n0 = blockIdx.y * 64;
    const int tid = threadIdx.x;
    {
        const int krow = tid >> 4, c4 = (tid & 15) * 4;
        #pragma unroll
        for (int p = 0; p < 4; ++p) {
            f32x4 gv = *(const f32x4*)&W[(long)(k0 + p * 16 + krow) * N + n0 + c4];
            #pragma unroll
            for (int j = 0; j < 4; ++j) t[p * 16 + krow][c4 + j] = gv[j];
        }
    }
    __syncthreads();
    {
        const int n = tid >> 3, kl = (tid & 7) * 8;
        #pragma unroll
        for (int p = 0; p < 2; ++p) {
            ushort8v pk;
            #pragma unroll
            for (int j = 0; j < 8; ++j) pk[j] = f2bs(t[kl + j][p * 32 + n]);
            *(ushort8v*)&WT[(long)(n0 + p * 32 + n) * K + k0 + kl] = pk;
        }
    }
}

// ---------------- bf16 MFMA GEMM ----------------
// A [M][K] bf16, BT [N][K] bf16. 128x128 tile, BK=32, 4 waves.
// EPI: 1 = f32 +bias+R; 2 = bf16 gelu(x+bias); 3 = qkv scatter to qB|kB|vT
template<int EPI>
__global__ __launch_bounds__(256)
void mm_mfma(const unsigned short* __restrict__ A,
             const unsigned short* __restrict__ BT,
             const float* __restrict__ bias, const float* __restrict__ R,
             void* __restrict__ Cout, int M, int N, int K) {
    __shared__ unsigned short As[128 * 32];
    __shared__ unsigned short Bs[128 * 32];
    const int tid = threadIdx.x;
    const int w = tid >> 6, lane = tid & 63;
    const int bm = blockIdx.y * 128, bn = blockIdx.x * 128;
    const int wr = (w >> 1) * 64, wc = (w & 1) * 64;

    f32x4 acc[4][4];
    #pragma unroll
    for (int m = 0; m < 4; ++m)
        #pragma unroll
        for (int n = 0; n < 4; ++n)
            acc[m][n] = (f32x4){0.f, 0.f, 0.f, 0.f};

    const int lrow = lane >> 2;
    const int lcol = (lane & 3) * 8;
    const unsigned short* gA = A + (long)(bm + w * 32 + lrow) * K + lcol;
    const unsigned short* gB = BT + (long)(bn + w * 32 + lrow) * K + lcol;
    unsigned short* lA = &As[(w * 32) * 32];
    unsigned short* lB = &Bs[(w * 32) * 32];

    for (int k0 = 0; k0 < K; k0 += 32) {
        gl_lds16(gA + k0,          lA);
        gl_lds16(gA + k0 + 16 * K, lA + 16 * 32);
        gl_lds16(gB + k0,          lB);
        gl_lds16(gB + k0 + 16 * K, lB + 16 * 32);
        __syncthreads();

        bf16x8 a[4], b[4];
        #pragma unroll
        for (int m = 0; m < 4; ++m)
            a[m] = *(const bf16x8*)&As[(wr + m * 16 + (lane & 15)) * 32 + (lane >> 4) * 8];
        #pragma unroll
        for (int n = 0; n < 4; ++n)
            b[n] = *(const bf16x8*)&Bs[(wc + n * 16 + (lane & 15)) * 32 + (lane >> 4) * 8];
        #pragma unroll
        for (int m = 0; m < 4; ++m)
            #pragma unroll
            for (int n = 0; n < 4; ++n)
                acc[m][n] = __builtin_amdgcn_mfma_f32_16x16x32_bf16(a[m], b[n], acc[m][n], 0, 0, 0);
        __syncthreads();
    }

    const int r0 = (lane >> 4) * 4, cc = lane & 15;
    #pragma unroll
    for (int n = 0; n < 4; ++n) {
        int colb = bn + wc + n * 16;
        float bv = bias[colb + cc];
        #pragma unroll
        for (int m = 0; m < 4; ++m) {
            int rowb = bm + wr + m * 16 + r0;
            if (EPI == 3) {
                // qkv scatter: Cout = qB base; kB at +4M elems, vT at +8M elems
                unsigned short* qkvB = (unsigned short*)Cout;
                int which = colb >> 10, hh = (colb & 1023) >> 6, dbase = colb & 63;
                int b_ = rowb >> 11, s_ = rowb & 2047;
                long bh2 = b_ * 16 + hh;
                float v[4];
                #pragma unroll
                for (int r = 0; r < 4; ++r) v[r] = acc[m][n][r] + bv;
                if (which == 2) {
                    ushort4v pk;
                    #pragma unroll
                    for (int r = 0; r < 4; ++r) pk[r] = f2bs(v[r]);
                    *(ushort4v*)&qkvB[8388608L + (bh2 * 64 + dbase + cc) * 2048 + s_] = pk;
                } else {
                    unsigned short* dst = qkvB + (long)which * 4194304L +
                                          (bh2 * 2048 + s_) * 64 + dbase + cc;
                    #pragma unroll
                    for (int r = 0; r < 4; ++r) dst[r * 64] = f2bs(v[r]);
                }
            } else {
                #pragma unroll
                for (int r = 0; r < 4; ++r) {
                    long row = rowb + r, col = colb + cc;
                    float v = acc[m][n][r] + bv;
                    if (EPI == 1) {
                        v += R[row * N + col];
                        ((float*)Cout)[row * N + col] = v;
                    } else {
                        v = 0.5f * v * (1.0f + erff(v * 0.70710678118f));
                        ((__hip_bfloat16*)Cout)[row * N + col] = __float2bfloat16(v);
                    }
                }
            }
        }
    }
}

// ---------------- MFMA flash attention ----------------
// qB,kB: [bh][s][64] bf16. vT: [bh][64][s] bf16. z: [b][s][1024] bf16.
__global__ __launch_bounds__(256)
void attn_mfma(const unsigned short* __restrict__ qB,
               const unsigned short* __restrict__ kB,
               const unsigned short* __restrict__ vT,
               __hip_bfloat16* __restrict__ z) {
    const int bh = blockIdx.x;
    const int qb = blockIdx.y * 64;
    const int tid = threadIdx.x, w = tid >> 6, lane = tid & 63;
    const int arow = lane & 15, kg = lane >> 4;
    __shared__ unsigned short Ks[64 * 64];
    __shared__ unsigned short Vs[64 * 64];
    __shared__ unsigned short Ps[4][16 * 64];

    const long kvbase = (long)bh * (2048 * 64);

    bf16x8 qa[2];
    {
        const unsigned short* q0 = qB + kvbase + (long)(qb + w * 16 + arow) * 64 + kg * 8;
        qa[0] = *(const bf16x8*)(q0);
        qa[1] = *(const bf16x8*)(q0 + 32);
    }

    f32x4 po[4];
    float mrow[4], lrow[4];
    #pragma unroll
    for (int i = 0; i < 4; ++i) {
        po[i] = (f32x4){0.f, 0.f, 0.f, 0.f};
        mrow[i] = -1e30f; lrow[i] = 0.f;
    }

    const int srow = lane >> 3;
    const int schunk = (lane & 7) ^ srow;          // pre-swizzled source (rule #21)
    const int cmax = qb >> 6;

    for (int c = 0; c <= cmax; ++c) {
        {
            const unsigned short* ks0 = kB + kvbase + (long)(c * 64 + w * 16 + srow) * 64 + schunk * 8;
            const unsigned short* vs0 = vT + kvbase + (long)(w * 16 + srow) * 2048 + c * 64 + schunk * 8;
            gl_lds16(ks0,            &Ks[(w * 16) * 64]);
            gl_lds16(ks0 + 8 * 64,   &Ks[(w * 16 + 8) * 64]);
            gl_lds16(vs0,            &Vs[(w * 16) * 64]);
            gl_lds16(vs0 + 8 * 2048, &Vs[(w * 16 + 8) * 64]);
        }
        __syncthreads();

        f32x4 s[4];
        #pragma unroll
        for (int n = 0; n < 4; ++n) {
            s[n] = (f32x4){0.f, 0.f, 0.f, 0.f};
            int row = n * 16 + arow, sw = row & 7;
            bf16x8 kb0 = *(const bf16x8*)&Ks[row * 64 + (kg ^ sw) * 8];
            bf16x8 kb1 = *(const bf16x8*)&Ks[row * 64 + ((4 + kg) ^ sw) * 8];
            s[n] = __builtin_amdgcn_mfma_f32_16x16x32_bf16(qa[0], kb0, s[n], 0, 0, 0);
            s[n] = __builtin_amdgcn_mfma_f32_16x16x32_bf16(qa[1], kb1, s[n], 0, 0, 0);
        }

        const bool diag = (c == cmax);
        #pragma unroll
        for (int n = 0; n < 4; ++n)
            #pragma unroll
            for (int r = 0; r < 4; ++r) {
                float v = s[n][r] * 0.125f;
                if (diag) {
                    int key = c * 64 + n * 16 + arow;
                    int qrow = qb + w * 16 + kg * 4 + r;
                    if (key > qrow) v = -1e30f;
                }
                s[n][r] = v;
            }

        #pragma unroll
        for (int r = 0; r < 4; ++r) {
            float rm = fmaxf(fmaxf(s[0][r], s[1][r]), fmaxf(s[2][r], s[3][r]));
            #pragma unroll
            for (int off = 1; off < 16; off <<= 1)
                rm = fmaxf(rm, __shfl_xor(rm, off));
            float mnew = fmaxf(mrow[r], rm);
            float esc = expf(mrow[r] - mnew);
            float rs = 0.f;
            #pragma unroll
            for (int n = 0; n < 4; ++n) {
                float p = expf(s[n][r] - mnew);
                s[n][r] = p;
                rs += p;
            }
            #pragma unroll
            for (int off = 1; off < 16; off <<= 1)
                rs += __shfl_xor(rs, off);
            lrow[r] = lrow[r] * esc + rs;
            #pragma unroll
            for (int dt = 0; dt < 4; ++dt) po[dt][r] *= esc;
            mrow[r] = mnew;
        }

        #pragma unroll
        for (int n = 0; n < 4; ++n) {
            int col = n * 16 + arow;
            int chunk = col >> 3, cw = col & 7;
            #pragma unroll
            for (int r = 0; r < 4; ++r) {
                int row = kg * 4 + r;
                Ps[w][row * 64 + ((chunk ^ (row & 7)) * 8 + cw)] = f2bs(s[n][r]);
            }
        }

        bf16x8 pa[2];
        #pragma unroll
        for (int ks = 0; ks < 2; ++ks)
            pa[ks] = *(const bf16x8*)&Ps[w][arow * 64 + (((ks * 4 + kg) ^ (arow & 7)) * 8)];
        #pragma unroll
        for (int dt = 0; dt < 4; ++dt) {
            int vrow = dt * 16 + arow, sw = vrow & 7;
            bf16x8 vb0 = *(const bf16x8*)&Vs[vrow * 64 + ((kg ^ sw) * 8)];
            bf16x8 vb1 = *(const bf16x8*)&Vs[vrow * 64 + (((4 + kg) ^ sw) * 8)];
            po[dt] = __builtin_amdgcn_mfma_f32_16x16x32_bf16(pa[0], vb0, po[dt], 0, 0, 0);
            po[dt] = __builtin_amdgcn_mfma_f32_16x16x32_bf16(pa[1], vb1, po[dt], 0, 0, 0);
        }
        __syncthreads();
    }

    const int b_ = bh >> 4, hofs = (bh & 15) * 64;
    #pragma unroll
    for (int dt = 0; dt < 4; ++dt)
        #pragma unroll
        for (int r = 0; r < 4; ++r) {
            long row = (long)b_ * 2048 + qb + w * 16 + kg * 4 + r;
            z[row * 1024 + hofs + dt * 16 + arow] = __float2bfloat16(po[dt][r] / lrow[r]);
        }
}

// ---------------- head ----------------
__global__ void head_kernel(const float* __restrict__ hl, const float* __restrict__ W,
                            float* __restrict__ out) {
    __shared__ float hs[2 * DMODEL];
    int tid = threadIdx.x;
    #pragma unroll
    for (int i = 0; i < 8; ++i) hs[tid + i * 256] = hl[tid + i * 256];
    __syncthreads();
    int v = blockIdx.x * 256 + tid;
    if (v >= VOCAB) return;
    float a0 = 0.f, a1 = 0.f;
    for (int d = 0; d < DMODEL; ++d) {
        float wv = W[(long)d * VOCAB + v];
        a0 += hs[d] * wv;
        a1 += hs[DMODEL + d] * wv;
    }
    out[v] = a0;
    out[VOCAB + v] = a1;
}

extern "C" void kernel_launch(void* const* d_in, const int* in_sizes, int n_in,
                              void* d_out, int out_size, void* d_ws, size_t ws_size,
                              hipStream_t stream) {
    const int*   x      = (const int*)  d_in[0];
    const float* wte    = (const float*)d_in[1];
    const float* wpe    = (const float*)d_in[2];
    const float* ln1_g  = (const float*)d_in[3];
    const float* ln1_b  = (const float*)d_in[4];
    const float* w_qkv  = (const float*)d_in[5];
    const float* b_qkv  = (const float*)d_in[6];
    const float* w_proj = (const float*)d_in[7];
    const float* b_proj = (const float*)d_in[8];
    const float* ln2_g  = (const float*)d_in[9];
    const float* ln2_b  = (const float*)d_in[10];
    const float* w_fc   = (const float*)d_in[11];
    const float* b_fc   = (const float*)d_in[12];
    const float* w_cp   = (const float*)d_in[13];
    const float* b_cp   = (const float*)d_in[14];
    const float* lnf_g  = (const float*)d_in[15];
    const float* lnf_b  = (const float*)d_in[16];
    const float* w_head = (const float*)d_in[17];
    float* out = (float*)d_out;

    char* ws = (char*)d_ws;
    float*          h     = (float*)ws;                             // 16 MB
    unsigned short* qkvB  = (unsigned short*)(ws + (16L << 20));    // 24 MB
    __hip_bfloat16* y_bf  = (__hip_bfloat16*)(ws + (40L << 20));    // 8 MB
    __hip_bfloat16* z_bf  = (__hip_bfloat16*)(ws + (48L << 20));    // 8 MB
    __hip_bfloat16* fc_bf = (__hip_bfloat16*)(ws + (56L << 20));    // 32 MB
    unsigned short* wT    = (unsigned short*)(ws + (88L << 20));    // 8.5 MB rotating
    float*          hl    = (float*)(ws + (97L << 20));             // 8 KB

    embed_kernel<<<NTOK, 256, 0, stream>>>(x, wte, wpe, h);

    for (int l = 0; l < NLAYER; ++l) {
        ln_kernel<__hip_bfloat16><<<NTOK, 256, 0, stream>>>(
            h, y_bf, ln1_g + l * DMODEL, ln1_b + l * DMODEL, DMODEL);

        convT64<<<dim3(1024 / 64, 3072 / 64), 256, 0, stream>>>(
            w_qkv + (long)l * DMODEL * 3072, wT, 1024, 3072);
        mm_mfma<3><<<dim3(24, 32), 256, 0, stream>>>(
            (const unsigned short*)y_bf, wT, b_qkv + l * 3072, nullptr, qkvB,
            NTOK, 3072, 1024);

        attn_mfma<<<dim3(BATCH * NHEAD, SEQ / 64), 256, 0, stream>>>(
            qkvB, qkvB + 4194304L, qkvB + 8388608L, z_bf);

        convT64<<<dim3(1024 / 64, 1024 / 64), 256, 0, stream>>>(
            w_proj + (long)l * DMODEL * DMODEL, wT, 1024, 1024);
        mm_mfma<1><<<dim3(8, 32), 256, 0, stream>>>(
            (const unsigned short*)z_bf, wT, b_proj + l * DMODEL, h, h,
            NTOK, 1024, 1024);

        ln_kernel<__hip_bfloat16><<<NTOK, 256, 0, stream>>>(
            h, y_bf, ln2_g + l * DMODEL, ln2_b + l * DMODEL, DMODEL);

        convT64<<<dim3(1024 / 64, 4096 / 64), 256, 0, stream>>>(
            w_fc + (long)l * DMODEL * 4096, wT, 1024, 4096);
        mm_mfma<2><<<dim3(32, 32), 256, 0, stream>>>(
            (const unsigned short*)y_bf, wT, b_fc + l * 4096, nullptr, fc_bf,
            NTOK, 4096, 1024);

        convT64<<<dim3(4096 / 64, 1024 / 64), 256, 0, stream>>>(
            w_cp + (long)l * 4096 * DMODEL, wT, 4096, 1024);
        mm_mfma<1><<<dim3(8, 32), 256, 0, stream>>>(
            (const unsigned short*)fc_bf, wT, b_cp + l * DMODEL, h, h,
            NTOK, 1024, 4096);
    }

    ln_kernel<float><<<BATCH, 256, 0, stream>>>(h + (long)(SEQ - 1) * DMODEL, hl,
                                                lnf_g, lnf_b, (long)SEQ * DMODEL);
    head_kernel<<<(VOCAB + 255) / 256, 256, 0, stream>>>(hl, w_head, out);
}

// Round 8
// 2786.983 us; speedup vs baseline: 1.1312x; 1.0505x over previous
//
#include <hip/hip_runtime.h>
#include <hip/hip_bf16.h>
#include <math.h>

#define VOCAB 50257
#define CTX 2048
#define DMODEL 1024
#define NHEAD 16
#define NLAYER 8
#define DHEAD 64
#define BATCH 2
#define SEQ 2048
#define NTOK (BATCH * SEQ)   // 4096

typedef __bf16 bf16x8 __attribute__((ext_vector_type(8)));
typedef float  f32x4  __attribute__((ext_vector_type(4)));
typedef unsigned short ushort4v __attribute__((ext_vector_type(4)));
typedef unsigned short ushort8v __attribute__((ext_vector_type(8)));

__device__ inline void gl_lds16(const void* g, void* l) {
    __builtin_amdgcn_global_load_lds(
        (const __attribute__((address_space(1))) unsigned int*)g,
        (__attribute__((address_space(3))) unsigned int*)l, 16, 0, 0);
}

__device__ inline unsigned short f2bs(float v) {
    __hip_bfloat16 t = __float2bfloat16(v);
    return *(unsigned short*)&t;
}

// ---------------- embedding ----------------
__global__ void embed_kernel(const int* __restrict__ x,
                             const float* __restrict__ wte,
                             const float* __restrict__ wpe,
                             float* __restrict__ h) {
    int t = blockIdx.x;
    int s = t & (SEQ - 1);
    int tok = x[t];
    const float* pe = wpe + (long)s * DMODEL;
    const float* te = wte + (long)tok * DMODEL;
    float* ph = h + (long)t * DMODEL;
    for (int d = threadIdx.x; d < DMODEL; d += 256)
        ph[d] = te[d] + pe[d];
}

// ---------------- layernorm ----------------
__device__ inline float wave_sum(float v) {
    for (int off = 32; off; off >>= 1) v += __shfl_xor(v, off);
    return v;
}
__device__ inline void st_val(float* p, float v) { *p = v; }
__device__ inline void st_val(__hip_bfloat16* p, float v) { *p = __float2bfloat16(v); }

template<typename OT>
__global__ void ln_kernel(const float* __restrict__ in, OT* __restrict__ out,
                          const float* __restrict__ g, const float* __restrict__ b,
                          long row_stride) {
    int row = blockIdx.x;
    const float* px = in + (long)row * row_stride;
    OT* po = out + (long)row * DMODEL;
    int tid = threadIdx.x;
    int wid = tid >> 6, lane = tid & 63;

    float x[4];
    float s = 0.f;
    #pragma unroll
    for (int i = 0; i < 4; ++i) { x[i] = px[tid + i * 256]; s += x[i]; }
    s = wave_sum(s);
    __shared__ float red[4], red2[4];
    if (lane == 0) red[wid] = s;
    __syncthreads();
    float mean = (red[0] + red[1] + red[2] + red[3]) * (1.0f / DMODEL);

    float s2 = 0.f;
    #pragma unroll
    for (int i = 0; i < 4; ++i) { float d = x[i] - mean; s2 += d * d; }
    s2 = wave_sum(s2);
    if (lane == 0) red2[wid] = s2;
    __syncthreads();
    float var = (red2[0] + red2[1] + red2[2] + red2[3]) * (1.0f / DMODEL);
    float r = 1.0f / sqrtf(var + 1e-5f);
    #pragma unroll
    for (int i = 0; i < 4; ++i) {
        int d = tid + i * 256;
        st_val(po + d, (x[i] - mean) * r * g[d] + b[d]);
    }
}

// ------------- transpose+convert: W f32 [K][N] -> WT bf16 [N][K] -------------
__global__ void convT64(const float* __restrict__ W,
                        unsigned short* __restrict__ WT, int K, int N) {
    __shared__ float t[64][65];
    const int k0 = blockIdx.x * 64, n0 = blockIdx.y * 64;
    const int tid = threadIdx.x;
    {
        const int krow = tid >> 4, c4 = (tid & 15) * 4;
        #pragma unroll
        for (int p = 0; p < 4; ++p) {
            f32x4 gv = *(const f32x4*)&W[(long)(k0 + p * 16 + krow) * N + n0 + c4];
            #pragma unroll
            for (int j = 0; j < 4; ++j) t[p * 16 + krow][c4 + j] = gv[j];
        }
    }
    __syncthreads();
    {
        const int n = tid >> 3, kl = (tid & 7) * 8;
        #pragma unroll
        for (int p = 0; p < 2; ++p) {
            ushort8v pk;
            #pragma unroll
            for (int j = 0; j < 8; ++j) pk[j] = f2bs(t[kl + j][p * 32 + n]);
            *(ushort8v*)&WT[(long)(n0 + p * 32 + n) * K + k0 + kl] = pk;
        }
    }
}

// ---------------- bf16 MFMA GEMM, 128x128 tile ----------------
// EPI: 1 = f32 +bias+R; 2 = bf16 gelu(x+bias); 3 = qkv scatter to qB|kB|vT
template<int EPI>
__global__ __launch_bounds__(256)
void mm_mfma(const unsigned short* __restrict__ A,
             const unsigned short* __restrict__ BT,
             const float* __restrict__ bias, const float* __restrict__ R,
             void* __restrict__ Cout, int M, int N, int K) {
    __shared__ unsigned short As[128 * 32];
    __shared__ unsigned short Bs[128 * 32];
    const int tid = threadIdx.x;
    const int w = tid >> 6, lane = tid & 63;
    const int bm = blockIdx.y * 128, bn = blockIdx.x * 128;
    const int wr = (w >> 1) * 64, wc = (w & 1) * 64;

    f32x4 acc[4][4];
    #pragma unroll
    for (int m = 0; m < 4; ++m)
        #pragma unroll
        for (int n = 0; n < 4; ++n)
            acc[m][n] = (f32x4){0.f, 0.f, 0.f, 0.f};

    const int lrow = lane >> 2;
    const int lcol = (lane & 3) * 8;
    const unsigned short* gA = A + (long)(bm + w * 32 + lrow) * K + lcol;
    const unsigned short* gB = BT + (long)(bn + w * 32 + lrow) * K + lcol;
    unsigned short* lA = &As[(w * 32) * 32];
    unsigned short* lB = &Bs[(w * 32) * 32];

    for (int k0 = 0; k0 < K; k0 += 32) {
        gl_lds16(gA + k0,          lA);
        gl_lds16(gA + k0 + 16 * K, lA + 16 * 32);
        gl_lds16(gB + k0,          lB);
        gl_lds16(gB + k0 + 16 * K, lB + 16 * 32);
        __syncthreads();

        bf16x8 a[4], b[4];
        #pragma unroll
        for (int m = 0; m < 4; ++m)
            a[m] = *(const bf16x8*)&As[(wr + m * 16 + (lane & 15)) * 32 + (lane >> 4) * 8];
        #pragma unroll
        for (int n = 0; n < 4; ++n)
            b[n] = *(const bf16x8*)&Bs[(wc + n * 16 + (lane & 15)) * 32 + (lane >> 4) * 8];
        #pragma unroll
        for (int m = 0; m < 4; ++m)
            #pragma unroll
            for (int n = 0; n < 4; ++n)
                acc[m][n] = __builtin_amdgcn_mfma_f32_16x16x32_bf16(a[m], b[n], acc[m][n], 0, 0, 0);
        __syncthreads();
    }

    const int r0 = (lane >> 4) * 4, cc = lane & 15;
    #pragma unroll
    for (int n = 0; n < 4; ++n) {
        int colb = bn + wc + n * 16;
        float bv = bias[colb + cc];
        #pragma unroll
        for (int m = 0; m < 4; ++m) {
            int rowb = bm + wr + m * 16 + r0;
            if (EPI == 3) {
                unsigned short* qkvB = (unsigned short*)Cout;
                int which = colb >> 10, hh = (colb & 1023) >> 6, dbase = colb & 63;
                int b_ = rowb >> 11, s_ = rowb & 2047;
                long bh2 = b_ * 16 + hh;
                float v[4];
                #pragma unroll
                for (int r = 0; r < 4; ++r) v[r] = acc[m][n][r] + bv;
                if (which == 2) {
                    ushort4v pk;
                    #pragma unroll
                    for (int r = 0; r < 4; ++r) pk[r] = f2bs(v[r]);
                    *(ushort4v*)&qkvB[8388608L + (bh2 * 64 + dbase + cc) * 2048 + s_] = pk;
                } else {
                    unsigned short* dst = qkvB + (long)which * 4194304L +
                                          (bh2 * 2048 + s_) * 64 + dbase + cc;
                    #pragma unroll
                    for (int r = 0; r < 4; ++r) dst[r * 64] = f2bs(v[r]);
                }
            } else {
                #pragma unroll
                for (int r = 0; r < 4; ++r) {
                    long row = rowb + r, col = colb + cc;
                    float v = acc[m][n][r] + bv;
                    if (EPI == 1) {
                        v += R[row * N + col];
                        ((float*)Cout)[row * N + col] = v;
                    } else {
                        v = 0.5f * v * (1.0f + erff(v * 0.70710678118f));
                        ((__hip_bfloat16*)Cout)[row * N + col] = __float2bfloat16(v);
                    }
                }
            }
        }
    }
}

// ---------------- bf16 MFMA GEMM, 128x64 tile (small-N: 2 blocks/CU) ----------------
// EPI 1 only: f32 +bias+R. Grid (N/64, M/128).
__global__ __launch_bounds__(256)
void mm_mfma_n64(const unsigned short* __restrict__ A,
                 const unsigned short* __restrict__ BT,
                 const float* __restrict__ bias, const float* __restrict__ R,
                 float* __restrict__ Cout, int M, int N, int K) {
    __shared__ unsigned short As[128 * 32];
    __shared__ unsigned short Bs[64 * 32];
    const int tid = threadIdx.x;
    const int w = tid >> 6, lane = tid & 63;
    const int bm = blockIdx.y * 128, bn = blockIdx.x * 64;
    const int wr = (w >> 1) * 64, wc = (w & 1) * 32;

    f32x4 acc[4][2];
    #pragma unroll
    for (int m = 0; m < 4; ++m)
        #pragma unroll
        for (int n = 0; n < 2; ++n)
            acc[m][n] = (f32x4){0.f, 0.f, 0.f, 0.f};

    const int lrow = lane >> 2;
    const int lcol = (lane & 3) * 8;
    const unsigned short* gA = A + (long)(bm + w * 32 + lrow) * K + lcol;
    const unsigned short* gB = BT + (long)(bn + w * 16 + lrow) * K + lcol;
    unsigned short* lA = &As[(w * 32) * 32];
    unsigned short* lB = &Bs[(w * 16) * 32];

    for (int k0 = 0; k0 < K; k0 += 32) {
        gl_lds16(gA + k0,          lA);
        gl_lds16(gA + k0 + 16 * K, lA + 16 * 32);
        gl_lds16(gB + k0,          lB);
        __syncthreads();

        bf16x8 a[4], b[2];
        #pragma unroll
        for (int m = 0; m < 4; ++m)
            a[m] = *(const bf16x8*)&As[(wr + m * 16 + (lane & 15)) * 32 + (lane >> 4) * 8];
        #pragma unroll
        for (int n = 0; n < 2; ++n)
            b[n] = *(const bf16x8*)&Bs[(wc + n * 16 + (lane & 15)) * 32 + (lane >> 4) * 8];
        #pragma unroll
        for (int m = 0; m < 4; ++m)
            #pragma unroll
            for (int n = 0; n < 2; ++n)
                acc[m][n] = __builtin_amdgcn_mfma_f32_16x16x32_bf16(a[m], b[n], acc[m][n], 0, 0, 0);
        __syncthreads();
    }

    const int r0 = (lane >> 4) * 4, cc = lane & 15;
    #pragma unroll
    for (int n = 0; n < 2; ++n) {
        int colb = bn + wc + n * 16;
        float bv = bias[colb + cc];
        #pragma unroll
        for (int m = 0; m < 4; ++m) {
            int rowb = bm + wr + m * 16 + r0;
            #pragma unroll
            for (int r = 0; r < 4; ++r) {
                long row = rowb + r, col = colb + cc;
                float v = acc[m][n][r] + bv + R[row * N + col];
                Cout[row * N + col] = v;
            }
        }
    }
}

// ---------------- MFMA flash attention ----------------
__global__ __launch_bounds__(256)
void attn_mfma(const unsigned short* __restrict__ qB,
               const unsigned short* __restrict__ kB,
               const unsigned short* __restrict__ vT,
               __hip_bfloat16* __restrict__ z) {
    const int bh = blockIdx.x;
    const int qb = blockIdx.y * 64;
    const int tid = threadIdx.x, w = tid >> 6, lane = tid & 63;
    const int arow = lane & 15, kg = lane >> 4;
    __shared__ unsigned short Ks[64 * 64];
    __shared__ unsigned short Vs[64 * 64];
    __shared__ unsigned short Ps[4][16 * 64];

    const long kvbase = (long)bh * (2048 * 64);

    bf16x8 qa[2];
    {
        const unsigned short* q0 = qB + kvbase + (long)(qb + w * 16 + arow) * 64 + kg * 8;
        qa[0] = *(const bf16x8*)(q0);
        qa[1] = *(const bf16x8*)(q0 + 32);
    }

    f32x4 po[4];
    float mrow[4], lrow[4];
    #pragma unroll
    for (int i = 0; i < 4; ++i) {
        po[i] = (f32x4){0.f, 0.f, 0.f, 0.f};
        mrow[i] = -1e30f; lrow[i] = 0.f;
    }

    const int srow = lane >> 3;
    const int schunk = (lane & 7) ^ srow;
    const int cmax = qb >> 6;

    for (int c = 0; c <= cmax; ++c) {
        {
            const unsigned short* ks0 = kB + kvbase + (long)(c * 64 + w * 16 + srow) * 64 + schunk * 8;
            const unsigned short* vs0 = vT + kvbase + (long)(w * 16 + srow) * 2048 + c * 64 + schunk * 8;
            gl_lds16(ks0,            &Ks[(w * 16) * 64]);
            gl_lds16(ks0 + 8 * 64,   &Ks[(w * 16 + 8) * 64]);
            gl_lds16(vs0,            &Vs[(w * 16) * 64]);
            gl_lds16(vs0 + 8 * 2048, &Vs[(w * 16 + 8) * 64]);
        }
        __syncthreads();

        f32x4 s[4];
        #pragma unroll
        for (int n = 0; n < 4; ++n) {
            s[n] = (f32x4){0.f, 0.f, 0.f, 0.f};
            int row = n * 16 + arow, sw = row & 7;
            bf16x8 kb0 = *(const bf16x8*)&Ks[row * 64 + (kg ^ sw) * 8];
            bf16x8 kb1 = *(const bf16x8*)&Ks[row * 64 + ((4 + kg) ^ sw) * 8];
            s[n] = __builtin_amdgcn_mfma_f32_16x16x32_bf16(qa[0], kb0, s[n], 0, 0, 0);
            s[n] = __builtin_amdgcn_mfma_f32_16x16x32_bf16(qa[1], kb1, s[n], 0, 0, 0);
        }

        const bool diag = (c == cmax);
        #pragma unroll
        for (int n = 0; n < 4; ++n)
            #pragma unroll
            for (int r = 0; r < 4; ++r) {
                float v = s[n][r] * 0.125f;
                if (diag) {
                    int key = c * 64 + n * 16 + arow;
                    int qrow = qb + w * 16 + kg * 4 + r;
                    if (key > qrow) v = -1e30f;
                }
                s[n][r] = v;
            }

        #pragma unroll
        for (int r = 0; r < 4; ++r) {
            float rm = fmaxf(fmaxf(s[0][r], s[1][r]), fmaxf(s[2][r], s[3][r]));
            #pragma unroll
            for (int off = 1; off < 16; off <<= 1)
                rm = fmaxf(rm, __shfl_xor(rm, off));
            float mnew = fmaxf(mrow[r], rm);
            float esc = expf(mrow[r] - mnew);
            float rs = 0.f;
            #pragma unroll
            for (int n = 0; n < 4; ++n) {
                float p = expf(s[n][r] - mnew);
                s[n][r] = p;
                rs += p;
            }
            #pragma unroll
            for (int off = 1; off < 16; off <<= 1)
                rs += __shfl_xor(rs, off);
            lrow[r] = lrow[r] * esc + rs;
            #pragma unroll
            for (int dt = 0; dt < 4; ++dt) po[dt][r] *= esc;
            mrow[r] = mnew;
        }

        #pragma unroll
        for (int n = 0; n < 4; ++n) {
            int col = n * 16 + arow;
            int chunk = col >> 3, cw = col & 7;
            #pragma unroll
            for (int r = 0; r < 4; ++r) {
                int row = kg * 4 + r;
                Ps[w][row * 64 + ((chunk ^ (row & 7)) * 8 + cw)] = f2bs(s[n][r]);
            }
        }

        bf16x8 pa[2];
        #pragma unroll
        for (int ks = 0; ks < 2; ++ks)
            pa[ks] = *(const bf16x8*)&Ps[w][arow * 64 + (((ks * 4 + kg) ^ (arow & 7)) * 8)];
        #pragma unroll
        for (int dt = 0; dt < 4; ++dt) {
            int vrow = dt * 16 + arow, sw = vrow & 7;
            bf16x8 vb0 = *(const bf16x8*)&Vs[vrow * 64 + ((kg ^ sw) * 8)];
            bf16x8 vb1 = *(const bf16x8*)&Vs[vrow * 64 + (((4 + kg) ^ sw) * 8)];
            po[dt] = __builtin_amdgcn_mfma_f32_16x16x32_bf16(pa[0], vb0, po[dt], 0, 0, 0);
            po[dt] = __builtin_amdgcn_mfma_f32_16x16x32_bf16(pa[1], vb1, po[dt], 0, 0, 0);
        }
        __syncthreads();
    }

    const int b_ = bh >> 4, hofs = (bh & 15) * 64;
    #pragma unroll
    for (int dt = 0; dt < 4; ++dt)
        #pragma unroll
        for (int r = 0; r < 4; ++r) {
            long row = (long)b_ * 2048 + qb + w * 16 + kg * 4 + r;
            z[row * 1024 + hofs + dt * 16 + arow] = __float2bfloat16(po[dt][r] / lrow[r]);
        }
}

// ---------------- head ----------------
__global__ void head_kernel(const float* __restrict__ hl, const float* __restrict__ W,
                            float* __restrict__ out) {
    __shared__ float hs[2 * DMODEL];
    int tid = threadIdx.x;
    #pragma unroll
    for (int i = 0; i < 8; ++i) hs[tid + i * 256] = hl[tid + i * 256];
    __syncthreads();
    int v = blockIdx.x * 256 + tid;
    if (v >= VOCAB) return;
    float a0 = 0.f, a1 = 0.f;
    for (int d = 0; d < DMODEL; ++d) {
        float wv = W[(long)d * VOCAB + v];
        a0 += hs[d] * wv;
        a1 += hs[DMODEL + d] * wv;
    }
    out[v] = a0;
    out[VOCAB + v] = a1;
}

extern "C" void kernel_launch(void* const* d_in, const int* in_sizes, int n_in,
                              void* d_out, int out_size, void* d_ws, size_t ws_size,
                              hipStream_t stream) {
    const int*   x      = (const int*)  d_in[0];
    const float* wte    = (const float*)d_in[1];
    const float* wpe    = (const float*)d_in[2];
    const float* ln1_g  = (const float*)d_in[3];
    const float* ln1_b  = (const float*)d_in[4];
    const float* w_qkv  = (const float*)d_in[5];
    const float* b_qkv  = (const float*)d_in[6];
    const float* w_proj = (const float*)d_in[7];
    const float* b_proj = (const float*)d_in[8];
    const float* ln2_g  = (const float*)d_in[9];
    const float* ln2_b  = (const float*)d_in[10];
    const float* w_fc   = (const float*)d_in[11];
    const float* b_fc   = (const float*)d_in[12];
    const float* w_cp   = (const float*)d_in[13];
    const float* b_cp   = (const float*)d_in[14];
    const float* lnf_g  = (const float*)d_in[15];
    const float* lnf_b  = (const float*)d_in[16];
    const float* w_head = (const float*)d_in[17];
    float* out = (float*)d_out;

    char* ws = (char*)d_ws;
    float*          h     = (float*)ws;                             // 16 MB
    unsigned short* qkvB  = (unsigned short*)(ws + (16L << 20));    // 24 MB
    __hip_bfloat16* y_bf  = (__hip_bfloat16*)(ws + (40L << 20));    // 8 MB
    __hip_bfloat16* z_bf  = (__hip_bfloat16*)(ws + (48L << 20));    // 8 MB
    __hip_bfloat16* fc_bf = (__hip_bfloat16*)(ws + (56L << 20));    // 32 MB
    unsigned short* wT    = (unsigned short*)(ws + (88L << 20));    // 8.5 MB rotating
    float*          hl    = (float*)(ws + (97L << 20));             // 8 KB

    embed_kernel<<<NTOK, 256, 0, stream>>>(x, wte, wpe, h);

    for (int l = 0; l < NLAYER; ++l) {
        ln_kernel<__hip_bfloat16><<<NTOK, 256, 0, stream>>>(
            h, y_bf, ln1_g + l * DMODEL, ln1_b + l * DMODEL, DMODEL);

        convT64<<<dim3(1024 / 64, 3072 / 64), 256, 0, stream>>>(
            w_qkv + (long)l * DMODEL * 3072, wT, 1024, 3072);
        mm_mfma<3><<<dim3(24, 32), 256, 0, stream>>>(
            (const unsigned short*)y_bf, wT, b_qkv + l * 3072, nullptr, qkvB,
            NTOK, 3072, 1024);

        attn_mfma<<<dim3(BATCH * NHEAD, SEQ / 64), 256, 0, stream>>>(
            qkvB, qkvB + 4194304L, qkvB + 8388608L, z_bf);

        convT64<<<dim3(1024 / 64, 1024 / 64), 256, 0, stream>>>(
            w_proj + (long)l * DMODEL * DMODEL, wT, 1024, 1024);
        mm_mfma_n64<<<dim3(16, 32), 256, 0, stream>>>(
            (const unsigned short*)z_bf, wT, b_proj + l * DMODEL, h, h,
            NTOK, 1024, 1024);

        ln_kernel<__hip_bfloat16><<<NTOK, 256, 0, stream>>>(
            h, y_bf, ln2_g + l * DMODEL, ln2_b + l * DMODEL, DMODEL);

        convT64<<<dim3(1024 / 64, 4096 / 64), 256, 0, stream>>>(
            w_fc + (long)l * DMODEL * 4096, wT, 1024, 4096);
        mm_mfma<2><<<dim3(32, 32), 256, 0, stream>>>(
            (const unsigned short*)y_bf, wT, b_fc + l * 4096, nullptr, fc_bf,
            NTOK, 4096, 1024);

        convT64<<<dim3(4096 / 64, 1024 / 64), 256, 0, stream>>>(
            w_cp + (long)l * 4096 * DMODEL, wT, 4096, 1024);
        mm_mfma_n64<<<dim3(16, 32), 256, 0, stream>>>(
            (const unsigned short*)fc_bf, wT, b_cp + l * DMODEL, h, h,
            NTOK, 1024, 4096);
    }

    ln_kernel<float><<<BATCH, 256, 0, stream>>>(h + (long)(SEQ - 1) * DMODEL, hl,
                                                lnf_g, lnf_b, (long)SEQ * DMODEL);
    head_kernel<<<(VOCAB + 255) / 256, 256, 0, stream>>>(hl, w_head, out);
}

// Round 9
// 2726.922 us; speedup vs baseline: 1.1561x; 1.0220x over previous
//
#include <hip/hip_runtime.h>
#include <hip/hip_bf16.h>
#include <math.h>

#define VOCAB 50257
#define CTX 2048
#define DMODEL 1024
#define NHEAD 16
#define NLAYER 8
#define DHEAD 64
#define BATCH 2
#define SEQ 2048
#define NTOK (BATCH * SEQ)   // 4096

typedef __bf16 bf16x8 __attribute__((ext_vector_type(8)));
typedef float  f32x4  __attribute__((ext_vector_type(4)));
typedef unsigned short ushort4v __attribute__((ext_vector_type(4)));
typedef unsigned short ushort8v __attribute__((ext_vector_type(8)));

__device__ inline void gl_lds16(const void* g, void* l) {
    __builtin_amdgcn_global_load_lds(
        (const __attribute__((address_space(1))) unsigned int*)g,
        (__attribute__((address_space(3))) unsigned int*)l, 16, 0, 0);
}

__device__ inline unsigned short f2bs(float v) {
    __hip_bfloat16 t = __float2bfloat16(v);
    return *(unsigned short*)&t;
}

// ---------------- embedding ----------------
__global__ void embed_kernel(const int* __restrict__ x,
                             const float* __restrict__ wte,
                             const float* __restrict__ wpe,
                             float* __restrict__ h) {
    int t = blockIdx.x;
    int s = t & (SEQ - 1);
    int tok = x[t];
    const float* pe = wpe + (long)s * DMODEL;
    const float* te = wte + (long)tok * DMODEL;
    float* ph = h + (long)t * DMODEL;
    for (int d = threadIdx.x; d < DMODEL; d += 256)
        ph[d] = te[d] + pe[d];
}

// ---------------- layernorm ----------------
__device__ inline float wave_sum(float v) {
    for (int off = 32; off; off >>= 1) v += __shfl_xor(v, off);
    return v;
}
__device__ inline void st_val(float* p, float v) { *p = v; }
__device__ inline void st_val(__hip_bfloat16* p, float v) { *p = __float2bfloat16(v); }

template<typename OT>
__global__ void ln_kernel(const float* __restrict__ in, OT* __restrict__ out,
                          const float* __restrict__ g, const float* __restrict__ b,
                          long row_stride) {
    int row = blockIdx.x;
    const float* px = in + (long)row * row_stride;
    OT* po = out + (long)row * DMODEL;
    int tid = threadIdx.x;
    int wid = tid >> 6, lane = tid & 63;

    float x[4];
    float s = 0.f;
    #pragma unroll
    for (int i = 0; i < 4; ++i) { x[i] = px[tid + i * 256]; s += x[i]; }
    s = wave_sum(s);
    __shared__ float red[4], red2[4];
    if (lane == 0) red[wid] = s;
    __syncthreads();
    float mean = (red[0] + red[1] + red[2] + red[3]) * (1.0f / DMODEL);

    float s2 = 0.f;
    #pragma unroll
    for (int i = 0; i < 4; ++i) { float d = x[i] - mean; s2 += d * d; }
    s2 = wave_sum(s2);
    if (lane == 0) red2[wid] = s2;
    __syncthreads();
    float var = (red2[0] + red2[1] + red2[2] + red2[3]) * (1.0f / DMODEL);
    float r = 1.0f / sqrtf(var + 1e-5f);
    #pragma unroll
    for (int i = 0; i < 4; ++i) {
        int d = tid + i * 256;
        st_val(po + d, (x[i] - mean) * r * g[d] + b[d]);
    }
}

// ------------- transpose+convert: W f32 [K][N] -> WT bf16 [N][K] -------------
__global__ void convT64(const float* __restrict__ W,
                        unsigned short* __restrict__ WT, int K, int N) {
    __shared__ float t[64][65];
    const int k0 = blockIdx.x * 64, n0 = blockIdx.y * 64;
    const int tid = threadIdx.x;
    {
        const int krow = tid >> 4, c4 = (tid & 15) * 4;
        #pragma unroll
        for (int p = 0; p < 4; ++p) {
            f32x4 gv = *(const f32x4*)&W[(long)(k0 + p * 16 + krow) * N + n0 + c4];
            #pragma unroll
            for (int j = 0; j < 4; ++j) t[p * 16 + krow][c4 + j] = gv[j];
        }
    }
    __syncthreads();
    {
        const int n = tid >> 3, kl = (tid & 7) * 8;
        #pragma unroll
        for (int p = 0; p < 2; ++p) {
            ushort8v pk;
            #pragma unroll
            for (int j = 0; j < 8; ++j) pk[j] = f2bs(t[kl + j][p * 32 + n]);
            *(ushort8v*)&WT[(long)(n0 + p * 32 + n) * K + k0 + kl] = pk;
        }
    }
}

// ---------------- bf16 MFMA GEMM, 128x128 tile ----------------
// EPI: 2 = bf16 gelu(x+bias); 3 = qkv scatter to qB|kB|vT
template<int EPI>
__global__ __launch_bounds__(256)
void mm_mfma(const unsigned short* __restrict__ A,
             const unsigned short* __restrict__ BT,
             const float* __restrict__ bias, const float* __restrict__ R,
             void* __restrict__ Cout, int M, int N, int K) {
    __shared__ unsigned short As[128 * 32];
    __shared__ unsigned short Bs[128 * 32];
    const int tid = threadIdx.x;
    const int w = tid >> 6, lane = tid & 63;
    const int bm = blockIdx.y * 128, bn = blockIdx.x * 128;
    const int wr = (w >> 1) * 64, wc = (w & 1) * 64;

    f32x4 acc[4][4];
    #pragma unroll
    for (int m = 0; m < 4; ++m)
        #pragma unroll
        for (int n = 0; n < 4; ++n)
            acc[m][n] = (f32x4){0.f, 0.f, 0.f, 0.f};

    const int lrow = lane >> 2;
    const int lcol = (lane & 3) * 8;
    const unsigned short* gA = A + (long)(bm + w * 32 + lrow) * K + lcol;
    const unsigned short* gB = BT + (long)(bn + w * 32 + lrow) * K + lcol;
    unsigned short* lA = &As[(w * 32) * 32];
    unsigned short* lB = &Bs[(w * 32) * 32];

    for (int k0 = 0; k0 < K; k0 += 32) {
        gl_lds16(gA + k0,          lA);
        gl_lds16(gA + k0 + 16 * K, lA + 16 * 32);
        gl_lds16(gB + k0,          lB);
        gl_lds16(gB + k0 + 16 * K, lB + 16 * 32);
        __syncthreads();

        bf16x8 a[4], b[4];
        #pragma unroll
        for (int m = 0; m < 4; ++m)
            a[m] = *(const bf16x8*)&As[(wr + m * 16 + (lane & 15)) * 32 + (lane >> 4) * 8];
        #pragma unroll
        for (int n = 0; n < 4; ++n)
            b[n] = *(const bf16x8*)&Bs[(wc + n * 16 + (lane & 15)) * 32 + (lane >> 4) * 8];
        #pragma unroll
        for (int m = 0; m < 4; ++m)
            #pragma unroll
            for (int n = 0; n < 4; ++n)
                acc[m][n] = __builtin_amdgcn_mfma_f32_16x16x32_bf16(a[m], b[n], acc[m][n], 0, 0, 0);
        __syncthreads();
    }

    const int r0 = (lane >> 4) * 4, cc = lane & 15;
    #pragma unroll
    for (int n = 0; n < 4; ++n) {
        int colb = bn + wc + n * 16;
        float bv = bias[colb + cc];
        #pragma unroll
        for (int m = 0; m < 4; ++m) {
            int rowb = bm + wr + m * 16 + r0;
            if (EPI == 3) {
                unsigned short* qkvB = (unsigned short*)Cout;
                int which = colb >> 10, hh = (colb & 1023) >> 6, dbase = colb & 63;
                int b_ = rowb >> 11, s_ = rowb & 2047;
                long bh2 = b_ * 16 + hh;
                float v[4];
                #pragma unroll
                for (int r = 0; r < 4; ++r) v[r] = acc[m][n][r] + bv;
                if (which == 2) {
                    ushort4v pk;
                    #pragma unroll
                    for (int r = 0; r < 4; ++r) pk[r] = f2bs(v[r]);
                    *(ushort4v*)&qkvB[8388608L + (bh2 * 64 + dbase + cc) * 2048 + s_] = pk;
                } else {
                    unsigned short* dst = qkvB + (long)which * 4194304L +
                                          (bh2 * 2048 + s_) * 64 + dbase + cc;
                    #pragma unroll
                    for (int r = 0; r < 4; ++r) dst[r * 64] = f2bs(v[r]);
                }
            } else {
                #pragma unroll
                for (int r = 0; r < 4; ++r) {
                    long row = rowb + r, col = colb + cc;
                    float v = acc[m][n][r] + bv;
                    v = 0.5f * v * (1.0f + erff(v * 0.70710678118f));
                    ((__hip_bfloat16*)Cout)[row * N + col] = __float2bfloat16(v);
                }
            }
        }
    }
}

// ---------------- bf16 MFMA GEMM, 128x64 tile (small-N: 2 blocks/CU) ----------------
__global__ __launch_bounds__(256)
void mm_mfma_n64(const unsigned short* __restrict__ A,
                 const unsigned short* __restrict__ BT,
                 const float* __restrict__ bias, const float* __restrict__ R,
                 float* __restrict__ Cout, int M, int N, int K) {
    __shared__ unsigned short As[128 * 32];
    __shared__ unsigned short Bs[64 * 32];
    const int tid = threadIdx.x;
    const int w = tid >> 6, lane = tid & 63;
    const int bm = blockIdx.y * 128, bn = blockIdx.x * 64;
    const int wr = (w >> 1) * 64, wc = (w & 1) * 32;

    f32x4 acc[4][2];
    #pragma unroll
    for (int m = 0; m < 4; ++m)
        #pragma unroll
        for (int n = 0; n < 2; ++n)
            acc[m][n] = (f32x4){0.f, 0.f, 0.f, 0.f};

    const int lrow = lane >> 2;
    const int lcol = (lane & 3) * 8;
    const unsigned short* gA = A + (long)(bm + w * 32 + lrow) * K + lcol;
    const unsigned short* gB = BT + (long)(bn + w * 16 + lrow) * K + lcol;
    unsigned short* lA = &As[(w * 32) * 32];
    unsigned short* lB = &Bs[(w * 16) * 32];

    for (int k0 = 0; k0 < K; k0 += 32) {
        gl_lds16(gA + k0,          lA);
        gl_lds16(gA + k0 + 16 * K, lA + 16 * 32);
        gl_lds16(gB + k0,          lB);
        __syncthreads();

        bf16x8 a[4], b[2];
        #pragma unroll
        for (int m = 0; m < 4; ++m)
            a[m] = *(const bf16x8*)&As[(wr + m * 16 + (lane & 15)) * 32 + (lane >> 4) * 8];
        #pragma unroll
        for (int n = 0; n < 2; ++n)
            b[n] = *(const bf16x8*)&Bs[(wc + n * 16 + (lane & 15)) * 32 + (lane >> 4) * 8];
        #pragma unroll
        for (int m = 0; m < 4; ++m)
            #pragma unroll
            for (int n = 0; n < 2; ++n)
                acc[m][n] = __builtin_amdgcn_mfma_f32_16x16x32_bf16(a[m], b[n], acc[m][n], 0, 0, 0);
        __syncthreads();
    }

    const int r0 = (lane >> 4) * 4, cc = lane & 15;
    #pragma unroll
    for (int n = 0; n < 2; ++n) {
        int colb = bn + wc + n * 16;
        float bv = bias[colb + cc];
        #pragma unroll
        for (int m = 0; m < 4; ++m) {
            int rowb = bm + wr + m * 16 + r0;
            #pragma unroll
            for (int r = 0; r < 4; ++r) {
                long row = rowb + r, col = colb + cc;
                float v = acc[m][n][r] + bv + R[row * N + col];
                Cout[row * N + col] = v;
            }
        }
    }
}

// ---------------- MFMA flash attention, KVBLK=128 ----------------
// qB,kB: [bh][s][64] bf16. vT: [bh][64][s] bf16. z: [b][s][1024] bf16.
// 4 waves; 64 q-rows/block (16/wave); KV chunks of 128.
__global__ __launch_bounds__(256)
void attn_mfma(const unsigned short* __restrict__ qB,
               const unsigned short* __restrict__ kB,
               const unsigned short* __restrict__ vT,
               __hip_bfloat16* __restrict__ z) {
    const int bh = blockIdx.x;
    const int qb = blockIdx.y * 64;
    const int tid = threadIdx.x, w = tid >> 6, lane = tid & 63;
    const int arow = lane & 15, kg = lane >> 4;
    __shared__ unsigned short Ks[128 * 64];      // [key][d], chunk-swizzled
    __shared__ unsigned short Vs[64 * 128];      // [d][key], chunk-swizzled
    __shared__ unsigned short Ps[4][16 * 128];   // per-wave P, chunk-swizzled

    const long kvbase = (long)bh * (2048 * 64);

    bf16x8 qa[2];
    {
        const unsigned short* q0 = qB + kvbase + (long)(qb + w * 16 + arow) * 64 + kg * 8;
        qa[0] = *(const bf16x8*)(q0);
        qa[1] = *(const bf16x8*)(q0 + 32);
    }

    f32x4 po[4];
    float mrow[4], lrow[4];
    #pragma unroll
    for (int i = 0; i < 4; ++i) {
        po[i] = (f32x4){0.f, 0.f, 0.f, 0.f};
        mrow[i] = -1e30f; lrow[i] = 0.f;
    }

    // K staging: 8 rows/instr, 8 lanes/row; source pre-swizzled (rule #21)
    const int ksrow = lane >> 3;                  // 0..7
    const int kschunk = (lane & 7) ^ ksrow;       // chunk ^ (row&7)
    // V staging: 4 rows/instr, 16 lanes/row
    const int vsr = lane >> 4;                    // 0..3
    const int cmax = qb >> 7;

    for (int c = 0; c <= cmax; ++c) {
        {
            const unsigned short* ks0 = kB + kvbase +
                (long)(c * 128 + w * 32 + ksrow) * 64 + kschunk * 8;
            #pragma unroll
            for (int i = 0; i < 4; ++i)
                gl_lds16(ks0 + (long)i * 8 * 64, &Ks[(w * 32 + i * 8) * 64]);
            #pragma unroll
            for (int i = 0; i < 4; ++i) {
                int d = w * 16 + i * 4 + vsr;
                int sch = (lane & 15) ^ (d & 7);
                gl_lds16(vT + kvbase + (long)d * 2048 + c * 128 + sch * 8,
                         &Vs[(w * 16 + i * 4) * 128]);
            }
        }
        __syncthreads();

        // S = Q @ K^T  (per wave: 16 rows x 128 keys)
        f32x4 s[8];
        #pragma unroll
        for (int n = 0; n < 8; ++n) {
            s[n] = (f32x4){0.f, 0.f, 0.f, 0.f};
            int row = n * 16 + arow, sw = row & 7;
            bf16x8 kb0 = *(const bf16x8*)&Ks[row * 64 + (kg ^ sw) * 8];
            bf16x8 kb1 = *(const bf16x8*)&Ks[row * 64 + ((4 + kg) ^ sw) * 8];
            s[n] = __builtin_amdgcn_mfma_f32_16x16x32_bf16(qa[0], kb0, s[n], 0, 0, 0);
            s[n] = __builtin_amdgcn_mfma_f32_16x16x32_bf16(qa[1], kb1, s[n], 0, 0, 0);
        }

        // scale + causal mask (final chunk only)
        const bool diag = (c == cmax);
        #pragma unroll
        for (int n = 0; n < 8; ++n)
            #pragma unroll
            for (int r = 0; r < 4; ++r) {
                float v = s[n][r] * 0.125f;
                if (diag) {
                    int key = c * 128 + n * 16 + arow;
                    int qrow = qb + w * 16 + kg * 4 + r;
                    if (key > qrow) v = -1e30f;
                }
                s[n][r] = v;
            }

        // online softmax (16-lane butterfly per row)
        #pragma unroll
        for (int r = 0; r < 4; ++r) {
            float rm = s[0][r];
            #pragma unroll
            for (int n = 1; n < 8; ++n) rm = fmaxf(rm, s[n][r]);
            #pragma unroll
            for (int off = 1; off < 16; off <<= 1)
                rm = fmaxf(rm, __shfl_xor(rm, off));
            float mnew = fmaxf(mrow[r], rm);
            float esc = expf(mrow[r] - mnew);
            float rs = 0.f;
            #pragma unroll
            for (int n = 0; n < 8; ++n) {
                float p = expf(s[n][r] - mnew);
                s[n][r] = p;
                rs += p;
            }
            #pragma unroll
            for (int off = 1; off < 16; off <<= 1)
                rs += __shfl_xor(rs, off);
            lrow[r] = lrow[r] * esc + rs;
            #pragma unroll
            for (int dt = 0; dt < 4; ++dt) po[dt][r] *= esc;
            mrow[r] = mnew;
        }

        // write P (bf16) to wave-private LDS tile, swizzled
        #pragma unroll
        for (int n = 0; n < 8; ++n) {
            int col = n * 16 + arow;
            int chunk = col >> 3, cw = col & 7;
            #pragma unroll
            for (int r = 0; r < 4; ++r) {
                int row = kg * 4 + r;
                Ps[w][row * 128 + ((chunk ^ (row & 7)) * 8 + cw)] = f2bs(s[n][r]);
            }
        }

        // O += P @ V
        bf16x8 pa[4];
        #pragma unroll
        for (int ks = 0; ks < 4; ++ks)
            pa[ks] = *(const bf16x8*)&Ps[w][arow * 128 + (((ks * 4 + kg) ^ (arow & 7)) * 8)];
        #pragma unroll
        for (int dt = 0; dt < 4; ++dt) {
            int vrow = dt * 16 + arow, sw = vrow & 7;
            #pragma unroll
            for (int ks = 0; ks < 4; ++ks) {
                bf16x8 vb = *(const bf16x8*)&Vs[vrow * 128 + (((ks * 4 + kg) ^ sw) * 8)];
                po[dt] = __builtin_amdgcn_mfma_f32_16x16x32_bf16(pa[ks], vb, po[dt], 0, 0, 0);
            }
        }
        __syncthreads();
    }

    const int b_ = bh >> 4, hofs = (bh & 15) * 64;
    #pragma unroll
    for (int dt = 0; dt < 4; ++dt)
        #pragma unroll
        for (int r = 0; r < 4; ++r) {
            long row = (long)b_ * 2048 + qb + w * 16 + kg * 4 + r;
            z[row * 1024 + hofs + dt * 16 + arow] = __float2bfloat16(po[dt][r] / lrow[r]);
        }
}

// ---------------- head ----------------
__global__ void head_kernel(const float* __restrict__ hl, const float* __restrict__ W,
                            float* __restrict__ out) {
    __shared__ float hs[2 * DMODEL];
    int tid = threadIdx.x;
    #pragma unroll
    for (int i = 0; i < 8; ++i) hs[tid + i * 256] = hl[tid + i * 256];
    __syncthreads();
    int v = blockIdx.x * 256 + tid;
    if (v >= VOCAB) return;
    float a0 = 0.f, a1 = 0.f;
    for (int d = 0; d < DMODEL; ++d) {
        float wv = W[(long)d * VOCAB + v];
        a0 += hs[d] * wv;
        a1 += hs[DMODEL + d] * wv;
    }
    out[v] = a0;
    out[VOCAB + v] = a1;
}

extern "C" void kernel_launch(void* const* d_in, const int* in_sizes, int n_in,
                              void* d_out, int out_size, void* d_ws, size_t ws_size,
                              hipStream_t stream) {
    const int*   x      = (const int*)  d_in[0];
    const float* wte    = (const float*)d_in[1];
    const float* wpe    = (const float*)d_in[2];
    const float* ln1_g  = (const float*)d_in[3];
    const float* ln1_b  = (const float*)d_in[4];
    const float* w_qkv  = (const float*)d_in[5];
    const float* b_qkv  = (const float*)d_in[6];
    const float* w_proj = (const float*)d_in[7];
    const float* b_proj = (const float*)d_in[8];
    const float* ln2_g  = (const float*)d_in[9];
    const float* ln2_b  = (const float*)d_in[10];
    const float* w_fc   = (const float*)d_in[11];
    const float* b_fc   = (const float*)d_in[12];
    const float* w_cp   = (const float*)d_in[13];
    const float* b_cp   = (const float*)d_in[14];
    const float* lnf_g  = (const float*)d_in[15];
    const float* lnf_b  = (const float*)d_in[16];
    const float* w_head = (const float*)d_in[17];
    float* out = (float*)d_out;

    char* ws = (char*)d_ws;
    float*          h     = (float*)ws;                             // 16 MB
    unsigned short* qkvB  = (unsigned short*)(ws + (16L << 20));    // 24 MB
    __hip_bfloat16* y_bf  = (__hip_bfloat16*)(ws + (40L << 20));    // 8 MB
    __hip_bfloat16* z_bf  = (__hip_bfloat16*)(ws + (48L << 20));    // 8 MB
    __hip_bfloat16* fc_bf = (__hip_bfloat16*)(ws + (56L << 20));    // 32 MB
    unsigned short* wT    = (unsigned short*)(ws + (88L << 20));    // 8.5 MB rotating
    float*          hl    = (float*)(ws + (97L << 20));             // 8 KB

    embed_kernel<<<NTOK, 256, 0, stream>>>(x, wte, wpe, h);

    for (int l = 0; l < NLAYER; ++l) {
        ln_kernel<__hip_bfloat16><<<NTOK, 256, 0, stream>>>(
            h, y_bf, ln1_g + l * DMODEL, ln1_b + l * DMODEL, DMODEL);

        convT64<<<dim3(1024 / 64, 3072 / 64), 256, 0, stream>>>(
            w_qkv + (long)l * DMODEL * 3072, wT, 1024, 3072);
        mm_mfma<3><<<dim3(24, 32), 256, 0, stream>>>(
            (const unsigned short*)y_bf, wT, b_qkv + l * 3072, nullptr, qkvB,
            NTOK, 3072, 1024);

        attn_mfma<<<dim3(BATCH * NHEAD, SEQ / 64), 256, 0, stream>>>(
            qkvB, qkvB + 4194304L, qkvB + 8388608L, z_bf);

        convT64<<<dim3(1024 / 64, 1024 / 64), 256, 0, stream>>>(
            w_proj + (long)l * DMODEL * DMODEL, wT, 1024, 1024);
        mm_mfma_n64<<<dim3(16, 32), 256, 0, stream>>>(
            (const unsigned short*)z_bf, wT, b_proj + l * DMODEL, h, h,
            NTOK, 1024, 1024);

        ln_kernel<__hip_bfloat16><<<NTOK, 256, 0, stream>>>(
            h, y_bf, ln2_g + l * DMODEL, ln2_b + l * DMODEL, DMODEL);

        convT64<<<dim3(1024 / 64, 4096 / 64), 256, 0, stream>>>(
            w_fc + (long)l * DMODEL * 4096, wT, 1024, 4096);
        mm_mfma<2><<<dim3(32, 32), 256, 0, stream>>>(
            (const unsigned short*)y_bf, wT, b_fc + l * 4096, nullptr, fc_bf,
            NTOK, 4096, 1024);

        convT64<<<dim3(4096 / 64, 1024 / 64), 256, 0, stream>>>(
            w_cp + (long)l * 4096 * DMODEL, wT, 4096, 1024);
        mm_mfma_n64<<<dim3(16, 32), 256, 0, stream>>>(
            (const unsigned short*)fc_bf, wT, b_cp + l * DMODEL, h, h,
            NTOK, 1024, 4096);
    }

    ln_kernel<float><<<BATCH, 256, 0, stream>>>(h + (long)(SEQ - 1) * DMODEL, hl,
                                                lnf_g, lnf_b, (long)SEQ * DMODEL);
    head_kernel<<<(VOCAB + 255) / 256, 256, 0, stream>>>(hl, w_head, out);
}

// Round 10
// 2666.925 us; speedup vs baseline: 1.1821x; 1.0225x over previous
//
#include <hip/hip_runtime.h>
#include <hip/hip_bf16.h>
#include <math.h>

#define VOCAB 50257
#define CTX 2048
#define DMODEL 1024
#define NHEAD 16
#define NLAYER 8
#define DHEAD 64
#define BATCH 2
#define SEQ 2048
#define NTOK (BATCH * SEQ)   // 4096

typedef __bf16 bf16x8 __attribute__((ext_vector_type(8)));
typedef float  f32x4  __attribute__((ext_vector_type(4)));
typedef unsigned short ushort4v __attribute__((ext_vector_type(4)));
typedef unsigned short ushort8v __attribute__((ext_vector_type(8)));

__device__ inline void gl_lds16(const void* g, void* l) {
    __builtin_amdgcn_global_load_lds(
        (const __attribute__((address_space(1))) unsigned int*)g,
        (__attribute__((address_space(3))) unsigned int*)l, 16, 0, 0);
}

__device__ inline unsigned short f2bs(float v) {
    __hip_bfloat16 t = __float2bfloat16(v);
    return *(unsigned short*)&t;
}

// ---------------- embedding ----------------
__global__ void embed_kernel(const int* __restrict__ x,
                             const float* __restrict__ wte,
                             const float* __restrict__ wpe,
                             float* __restrict__ h) {
    int t = blockIdx.x;
    int s = t & (SEQ - 1);
    int tok = x[t];
    const float* pe = wpe + (long)s * DMODEL;
    const float* te = wte + (long)tok * DMODEL;
    float* ph = h + (long)t * DMODEL;
    for (int d = threadIdx.x; d < DMODEL; d += 256)
        ph[d] = te[d] + pe[d];
}

// ---------------- layernorm bodies ----------------
__device__ inline float wave_sum(float v) {
    for (int off = 32; off; off >>= 1) v += __shfl_xor(v, off);
    return v;
}

// bf16-out LN body (used in fused kernels); smem: first 32 B for reductions
__device__ void ln_body(char* smem, int row, const float* __restrict__ in,
                        unsigned short* __restrict__ out,
                        const float* __restrict__ g, const float* __restrict__ b) {
    float* red  = (float*)smem;
    float* red2 = red + 4;
    const float* px = in + (long)row * DMODEL;
    unsigned short* po = out + (long)row * DMODEL;
    int tid = threadIdx.x;
    int wid = tid >> 6, lane = tid & 63;

    float x[4];
    float s = 0.f;
    #pragma unroll
    for (int i = 0; i < 4; ++i) { x[i] = px[tid + i * 256]; s += x[i]; }
    s = wave_sum(s);
    if (lane == 0) red[wid] = s;
    __syncthreads();
    float mean = (red[0] + red[1] + red[2] + red[3]) * (1.0f / DMODEL);

    float s2 = 0.f;
    #pragma unroll
    for (int i = 0; i < 4; ++i) { float d = x[i] - mean; s2 += d * d; }
    s2 = wave_sum(s2);
    if (lane == 0) red2[wid] = s2;
    __syncthreads();
    float var = (red2[0] + red2[1] + red2[2] + red2[3]) * (1.0f / DMODEL);
    float r = 1.0f / sqrtf(var + 1e-5f);
    #pragma unroll
    for (int i = 0; i < 4; ++i) {
        int d = tid + i * 256;
        po[d] = f2bs((x[i] - mean) * r * g[d] + b[d]);
    }
}

// standalone final LN (float out)
__global__ void ln_final(const float* __restrict__ in, float* __restrict__ out,
                         const float* __restrict__ g, const float* __restrict__ b,
                         long row_stride) {
    __shared__ float red[4], red2[4];
    int row = blockIdx.x;
    const float* px = in + (long)row * row_stride;
    float* po = out + (long)row * DMODEL;
    int tid = threadIdx.x;
    int wid = tid >> 6, lane = tid & 63;
    float x[4];
    float s = 0.f;
    #pragma unroll
    for (int i = 0; i < 4; ++i) { x[i] = px[tid + i * 256]; s += x[i]; }
    s = wave_sum(s);
    if (lane == 0) red[wid] = s;
    __syncthreads();
    float mean = (red[0] + red[1] + red[2] + red[3]) * (1.0f / DMODEL);
    float s2 = 0.f;
    #pragma unroll
    for (int i = 0; i < 4; ++i) { float d = x[i] - mean; s2 += d * d; }
    s2 = wave_sum(s2);
    if (lane == 0) red2[wid] = s2;
    __syncthreads();
    float var = (red2[0] + red2[1] + red2[2] + red2[3]) * (1.0f / DMODEL);
    float r = 1.0f / sqrtf(var + 1e-5f);
    #pragma unroll
    for (int i = 0; i < 4; ++i) {
        int d = tid + i * 256;
        po[d] = (x[i] - mean) * r * g[d] + b[d];
    }
}

// ------------- transpose+convert body: W f32 [K][N] -> WT bf16 [N][K] -------------
__device__ void convT_body(char* smem, int kx, int ny, const float* __restrict__ W,
                           unsigned short* __restrict__ WT, int K, int N) {
    float (*t)[65] = (float(*)[65])smem;
    const int k0 = kx * 64, n0 = ny * 64;
    const int tid = threadIdx.x;
    {
        const int krow = tid >> 4, c4 = (tid & 15) * 4;
        #pragma unroll
        for (int p = 0; p < 4; ++p) {
            f32x4 gv = *(const f32x4*)&W[(long)(k0 + p * 16 + krow) * N + n0 + c4];
            #pragma unroll
            for (int j = 0; j < 4; ++j) t[p * 16 + krow][c4 + j] = gv[j];
        }
    }
    __syncthreads();
    {
        const int n = tid >> 3, kl = (tid & 7) * 8;
        #pragma unroll
        for (int p = 0; p < 2; ++p) {
            ushort8v pk;
            #pragma unroll
            for (int j = 0; j < 8; ++j) pk[j] = f2bs(t[kl + j][p * 32 + n]);
            *(ushort8v*)&WT[(long)(n0 + p * 32 + n) * K + k0 + kl] = pk;
        }
    }
}

// ---------------- bf16 MFMA GEMM, 128x128 tile, qkv-scatter epilogue ----------------
__global__ __launch_bounds__(256)
void mm_qkv(const unsigned short* __restrict__ A,
            const unsigned short* __restrict__ BT,
            const float* __restrict__ bias,
            unsigned short* __restrict__ qkvB, int M, int N, int K) {
    __shared__ unsigned short As[128 * 32];
    __shared__ unsigned short Bs[128 * 32];
    const int tid = threadIdx.x;
    const int w = tid >> 6, lane = tid & 63;
    const int bm = blockIdx.y * 128, bn = blockIdx.x * 128;
    const int wr = (w >> 1) * 64, wc = (w & 1) * 64;

    f32x4 acc[4][4];
    #pragma unroll
    for (int m = 0; m < 4; ++m)
        #pragma unroll
        for (int n = 0; n < 4; ++n)
            acc[m][n] = (f32x4){0.f, 0.f, 0.f, 0.f};

    const int lrow = lane >> 2;
    const int lcol = (lane & 3) * 8;
    const unsigned short* gA = A + (long)(bm + w * 32 + lrow) * K + lcol;
    const unsigned short* gB = BT + (long)(bn + w * 32 + lrow) * K + lcol;
    unsigned short* lA = &As[(w * 32) * 32];
    unsigned short* lB = &Bs[(w * 32) * 32];

    for (int k0 = 0; k0 < K; k0 += 32) {
        gl_lds16(gA + k0,          lA);
        gl_lds16(gA + k0 + 16 * K, lA + 16 * 32);
        gl_lds16(gB + k0,          lB);
        gl_lds16(gB + k0 + 16 * K, lB + 16 * 32);
        __syncthreads();

        bf16x8 a[4], b[4];
        #pragma unroll
        for (int m = 0; m < 4; ++m)
            a[m] = *(const bf16x8*)&As[(wr + m * 16 + (lane & 15)) * 32 + (lane >> 4) * 8];
        #pragma unroll
        for (int n = 0; n < 4; ++n)
            b[n] = *(const bf16x8*)&Bs[(wc + n * 16 + (lane & 15)) * 32 + (lane >> 4) * 8];
        #pragma unroll
        for (int m = 0; m < 4; ++m)
            #pragma unroll
            for (int n = 0; n < 4; ++n)
                acc[m][n] = __builtin_amdgcn_mfma_f32_16x16x32_bf16(a[m], b[n], acc[m][n], 0, 0, 0);
        __syncthreads();
    }

    const int r0 = (lane >> 4) * 4, cc = lane & 15;
    #pragma unroll
    for (int n = 0; n < 4; ++n) {
        int colb = bn + wc + n * 16;
        float bv = bias[colb + cc];
        #pragma unroll
        for (int m = 0; m < 4; ++m) {
            int rowb = bm + wr + m * 16 + r0;
            int which = colb >> 10, hh = (colb & 1023) >> 6, dbase = colb & 63;
            int b_ = rowb >> 11, s_ = rowb & 2047;
            long bh2 = b_ * 16 + hh;
            float v[4];
            #pragma unroll
            for (int r = 0; r < 4; ++r) v[r] = acc[m][n][r] + bv;
            if (which == 2) {
                ushort4v pk;
                #pragma unroll
                for (int r = 0; r < 4; ++r) pk[r] = f2bs(v[r]);
                *(ushort4v*)&qkvB[8388608L + (bh2 * 64 + dbase + cc) * 2048 + s_] = pk;
            } else {
                unsigned short* dst = qkvB + (long)which * 4194304L +
                                      (bh2 * 2048 + s_) * 64 + dbase + cc;
                #pragma unroll
                for (int r = 0; r < 4; ++r) dst[r * 64] = f2bs(v[r]);
            }
        }
    }
}

// ---------------- 128x128 GEMM body, gelu bf16 epilogue (dynamic smem) ----------------
__device__ void mm128_gelu_body(char* smem, int bx, int by,
                                const unsigned short* __restrict__ A,
                                const unsigned short* __restrict__ BT,
                                const float* __restrict__ bias,
                                unsigned short* __restrict__ Cout, int M, int N, int K) {
    unsigned short* As = (unsigned short*)smem;
    unsigned short* Bs = As + 128 * 32;
    const int tid = threadIdx.x;
    const int w = tid >> 6, lane = tid & 63;
    const int bm = by * 128, bn = bx * 128;
    const int wr = (w >> 1) * 64, wc = (w & 1) * 64;

    f32x4 acc[4][4];
    #pragma unroll
    for (int m = 0; m < 4; ++m)
        #pragma unroll
        for (int n = 0; n < 4; ++n)
            acc[m][n] = (f32x4){0.f, 0.f, 0.f, 0.f};

    const int lrow = lane >> 2;
    const int lcol = (lane & 3) * 8;
    const unsigned short* gA = A + (long)(bm + w * 32 + lrow) * K + lcol;
    const unsigned short* gB = BT + (long)(bn + w * 32 + lrow) * K + lcol;
    unsigned short* lA = &As[(w * 32) * 32];
    unsigned short* lB = &Bs[(w * 32) * 32];

    for (int k0 = 0; k0 < K; k0 += 32) {
        gl_lds16(gA + k0,          lA);
        gl_lds16(gA + k0 + 16 * K, lA + 16 * 32);
        gl_lds16(gB + k0,          lB);
        gl_lds16(gB + k0 + 16 * K, lB + 16 * 32);
        __syncthreads();

        bf16x8 a[4], b[4];
        #pragma unroll
        for (int m = 0; m < 4; ++m)
            a[m] = *(const bf16x8*)&As[(wr + m * 16 + (lane & 15)) * 32 + (lane >> 4) * 8];
        #pragma unroll
        for (int n = 0; n < 4; ++n)
            b[n] = *(const bf16x8*)&Bs[(wc + n * 16 + (lane & 15)) * 32 + (lane >> 4) * 8];
        #pragma unroll
        for (int m = 0; m < 4; ++m)
            #pragma unroll
            for (int n = 0; n < 4; ++n)
                acc[m][n] = __builtin_amdgcn_mfma_f32_16x16x32_bf16(a[m], b[n], acc[m][n], 0, 0, 0);
        __syncthreads();
    }

    const int r0 = (lane >> 4) * 4, cc = lane & 15;
    #pragma unroll
    for (int n = 0; n < 4; ++n) {
        int colb = bn + wc + n * 16;
        float bv = bias[colb + cc];
        #pragma unroll
        for (int m = 0; m < 4; ++m) {
            int rowb = bm + wr + m * 16 + r0;
            #pragma unroll
            for (int r = 0; r < 4; ++r) {
                long row = rowb + r, col = colb + cc;
                float v = acc[m][n][r] + bv;
                v = 0.5f * v * (1.0f + erff(v * 0.70710678118f));
                Cout[row * N + col] = f2bs(v);
            }
        }
    }
}

// ---------------- bf16 MFMA GEMM, 128x64 tile (small-N) ----------------
__global__ __launch_bounds__(256)
void mm_mfma_n64(const unsigned short* __restrict__ A,
                 const unsigned short* __restrict__ BT,
                 const float* __restrict__ bias, const float* __restrict__ R,
                 float* __restrict__ Cout, int M, int N, int K) {
    __shared__ unsigned short As[128 * 32];
    __shared__ unsigned short Bs[64 * 32];
    const int tid = threadIdx.x;
    const int w = tid >> 6, lane = tid & 63;
    const int bm = blockIdx.y * 128, bn = blockIdx.x * 64;
    const int wr = (w >> 1) * 64, wc = (w & 1) * 32;

    f32x4 acc[4][2];
    #pragma unroll
    for (int m = 0; m < 4; ++m)
        #pragma unroll
        for (int n = 0; n < 2; ++n)
            acc[m][n] = (f32x4){0.f, 0.f, 0.f, 0.f};

    const int lrow = lane >> 2;
    const int lcol = (lane & 3) * 8;
    const unsigned short* gA = A + (long)(bm + w * 32 + lrow) * K + lcol;
    const unsigned short* gB = BT + (long)(bn + w * 16 + lrow) * K + lcol;
    unsigned short* lA = &As[(w * 32) * 32];
    unsigned short* lB = &Bs[(w * 16) * 32];

    for (int k0 = 0; k0 < K; k0 += 32) {
        gl_lds16(gA + k0,          lA);
        gl_lds16(gA + k0 + 16 * K, lA + 16 * 32);
        gl_lds16(gB + k0,          lB);
        __syncthreads();

        bf16x8 a[4], b[2];
        #pragma unroll
        for (int m = 0; m < 4; ++m)
            a[m] = *(const bf16x8*)&As[(wr + m * 16 + (lane & 15)) * 32 + (lane >> 4) * 8];
        #pragma unroll
        for (int n = 0; n < 2; ++n)
            b[n] = *(const bf16x8*)&Bs[(wc + n * 16 + (lane & 15)) * 32 + (lane >> 4) * 8];
        #pragma unroll
        for (int m = 0; m < 4; ++m)
            #pragma unroll
            for (int n = 0; n < 2; ++n)
                acc[m][n] = __builtin_amdgcn_mfma_f32_16x16x32_bf16(a[m], b[n], acc[m][n], 0, 0, 0);
        __syncthreads();
    }

    const int r0 = (lane >> 4) * 4, cc = lane & 15;
    #pragma unroll
    for (int n = 0; n < 2; ++n) {
        int colb = bn + wc + n * 16;
        float bv = bias[colb + cc];
        #pragma unroll
        for (int m = 0; m < 4; ++m) {
            int rowb = bm + wr + m * 16 + r0;
            #pragma unroll
            for (int r = 0; r < 4; ++r) {
                long row = rowb + r, col = colb + cc;
                float v = acc[m][n][r] + bv + R[row * N + col];
                Cout[row * N + col] = v;
            }
        }
    }
}

// ---------------- MFMA flash attention body, KVBLK=128 (dynamic smem 48K) ----------------
__device__ void attn_body(char* smem, int bh, int qb,
                          const unsigned short* __restrict__ qB,
                          const unsigned short* __restrict__ kB,
                          const unsigned short* __restrict__ vT,
                          __hip_bfloat16* __restrict__ z) {
    const int tid = threadIdx.x, w = tid >> 6, lane = tid & 63;
    const int arow = lane & 15, kg = lane >> 4;
    unsigned short* Ks = (unsigned short*)smem;          // [128][64]
    unsigned short* Vs = Ks + 128 * 64;                  // [64][128]
    unsigned short* Ps = Vs + 64 * 128 + w * 16 * 128;   // wave-private [16][128]

    const long kvbase = (long)bh * (2048 * 64);

    bf16x8 qa[2];
    {
        const unsigned short* q0 = qB + kvbase + (long)(qb + w * 16 + arow) * 64 + kg * 8;
        qa[0] = *(const bf16x8*)(q0);
        qa[1] = *(const bf16x8*)(q0 + 32);
    }

    f32x4 po[4];
    float mrow[4], lrow[4];
    #pragma unroll
    for (int i = 0; i < 4; ++i) {
        po[i] = (f32x4){0.f, 0.f, 0.f, 0.f};
        mrow[i] = -1e30f; lrow[i] = 0.f;
    }

    const int ksrow = lane >> 3;
    const int kschunk = (lane & 7) ^ ksrow;
    const int vsr = lane >> 4;
    const int cmax = qb >> 7;

    for (int c = 0; c <= cmax; ++c) {
        {
            const unsigned short* ks0 = kB + kvbase +
                (long)(c * 128 + w * 32 + ksrow) * 64 + kschunk * 8;
            #pragma unroll
            for (int i = 0; i < 4; ++i)
                gl_lds16(ks0 + (long)i * 8 * 64, &Ks[(w * 32 + i * 8) * 64]);
            #pragma unroll
            for (int i = 0; i < 4; ++i) {
                int d = w * 16 + i * 4 + vsr;
                int sch = (lane & 15) ^ (d & 7);
                gl_lds16(vT + kvbase + (long)d * 2048 + c * 128 + sch * 8,
                         &Vs[(w * 16 + i * 4) * 128]);
            }
        }
        __syncthreads();

        f32x4 s[8];
        #pragma unroll
        for (int n = 0; n < 8; ++n) {
            s[n] = (f32x4){0.f, 0.f, 0.f, 0.f};
            int row = n * 16 + arow, sw = row & 7;
            bf16x8 kb0 = *(const bf16x8*)&Ks[row * 64 + (kg ^ sw) * 8];
            bf16x8 kb1 = *(const bf16x8*)&Ks[row * 64 + ((4 + kg) ^ sw) * 8];
            s[n] = __builtin_amdgcn_mfma_f32_16x16x32_bf16(qa[0], kb0, s[n], 0, 0, 0);
            s[n] = __builtin_amdgcn_mfma_f32_16x16x32_bf16(qa[1], kb1, s[n], 0, 0, 0);
        }

        const bool diag = (c == cmax);
        #pragma unroll
        for (int n = 0; n < 8; ++n)
            #pragma unroll
            for (int r = 0; r < 4; ++r) {
                float v = s[n][r] * 0.125f;
                if (diag) {
                    int key = c * 128 + n * 16 + arow;
                    int qrow = qb + w * 16 + kg * 4 + r;
                    if (key > qrow) v = -1e30f;
                }
                s[n][r] = v;
            }

        #pragma unroll
        for (int r = 0; r < 4; ++r) {
            float rm = s[0][r];
            #pragma unroll
            for (int n = 1; n < 8; ++n) rm = fmaxf(rm, s[n][r]);
            #pragma unroll
            for (int off = 1; off < 16; off <<= 1)
                rm = fmaxf(rm, __shfl_xor(rm, off));
            float mnew = fmaxf(mrow[r], rm);
            float esc = expf(mrow[r] - mnew);
            float rs = 0.f;
            #pragma unroll
            for (int n = 0; n < 8; ++n) {
                float p = expf(s[n][r] - mnew);
                s[n][r] = p;
                rs += p;
            }
            #pragma unroll
            for (int off = 1; off < 16; off <<= 1)
                rs += __shfl_xor(rs, off);
            lrow[r] = lrow[r] * esc + rs;
            #pragma unroll
            for (int dt = 0; dt < 4; ++dt) po[dt][r] *= esc;
            mrow[r] = mnew;
        }

        #pragma unroll
        for (int n = 0; n < 8; ++n) {
            int col = n * 16 + arow;
            int chunk = col >> 3, cw = col & 7;
            #pragma unroll
            for (int r = 0; r < 4; ++r) {
                int row = kg * 4 + r;
                Ps[row * 128 + ((chunk ^ (row & 7)) * 8 + cw)] = f2bs(s[n][r]);
            }
        }

        bf16x8 pa[4];
        #pragma unroll
        for (int ks = 0; ks < 4; ++ks)
            pa[ks] = *(const bf16x8*)&Ps[arow * 128 + (((ks * 4 + kg) ^ (arow & 7)) * 8)];
        #pragma unroll
        for (int dt = 0; dt < 4; ++dt) {
            int vrow = dt * 16 + arow, sw = vrow & 7;
            #pragma unroll
            for (int ks = 0; ks < 4; ++ks) {
                bf16x8 vb = *(const bf16x8*)&Vs[vrow * 128 + (((ks * 4 + kg) ^ sw) * 8)];
                po[dt] = __builtin_amdgcn_mfma_f32_16x16x32_bf16(pa[ks], vb, po[dt], 0, 0, 0);
            }
        }
        __syncthreads();
    }

    const int b_ = bh >> 4, hofs = (bh & 15) * 64;
    #pragma unroll
    for (int dt = 0; dt < 4; ++dt)
        #pragma unroll
        for (int r = 0; r < 4; ++r) {
            long row = (long)b_ * 2048 + qb + w * 16 + kg * 4 + r;
            z[row * 1024 + hofs + dt * 16 + arow] = __float2bfloat16(po[dt][r] / lrow[r]);
        }
}

// ---------------- fused kernels ----------------
__global__ __launch_bounds__(256)
void fused_ln_convT(const float* __restrict__ h, unsigned short* __restrict__ y,
                    const float* __restrict__ g, const float* __restrict__ b,
                    const float* __restrict__ W, unsigned short* __restrict__ WT,
                    int K, int N, int nLN) {
    extern __shared__ char smem[];
    int bid = blockIdx.x;
    if (bid < nLN) {
        ln_body(smem, bid, h, y, g, b);
    } else {
        int r = bid - nLN, kt = K >> 6;
        convT_body(smem, r % kt, r / kt, W, WT, K, N);
    }
}

__global__ __launch_bounds__(256)
void fused_attn_convT(const unsigned short* __restrict__ qB,
                      const unsigned short* __restrict__ kB,
                      const unsigned short* __restrict__ vT,
                      __hip_bfloat16* __restrict__ z,
                      const float* __restrict__ W, unsigned short* __restrict__ WT,
                      int K, int N, int nAttn) {
    extern __shared__ char smem[];
    int bid = blockIdx.x;
    if (bid < nAttn) {
        attn_body(smem, bid & 31, (bid >> 5) * 64, qB, kB, vT, z);
    } else {
        int r = bid - nAttn, kt = K >> 6;
        convT_body(smem, r % kt, r / kt, W, WT, K, N);
    }
}

__global__ __launch_bounds__(256)
void fused_fc_convT(const unsigned short* __restrict__ A,
                    const unsigned short* __restrict__ BT,
                    const float* __restrict__ bias, unsigned short* __restrict__ Cout,
                    int M, int N, int K,
                    const float* __restrict__ W2, unsigned short* __restrict__ WT2,
                    int K2, int N2, int nMM) {
    extern __shared__ char smem[];
    int bid = blockIdx.x;
    if (bid < nMM) {
        mm128_gelu_body(smem, bid & 31, bid >> 5, A, BT, bias, Cout, M, N, K);
    } else {
        int r = bid - nMM, kt = K2 >> 6;
        convT_body(smem, r % kt, r / kt, W2, WT2, K2, N2);
    }
}

// ---------------- head ----------------
__global__ void head_kernel(const float* __restrict__ hl, const float* __restrict__ W,
                            float* __restrict__ out) {
    __shared__ float hs[2 * DMODEL];
    int tid = threadIdx.x;
    #pragma unroll
    for (int i = 0; i < 8; ++i) hs[tid + i * 256] = hl[tid + i * 256];
    __syncthreads();
    int v = blockIdx.x * 256 + tid;
    if (v >= VOCAB) return;
    float a0 = 0.f, a1 = 0.f;
    for (int d = 0; d < DMODEL; ++d) {
        float wv = W[(long)d * VOCAB + v];
        a0 += hs[d] * wv;
        a1 += hs[DMODEL + d] * wv;
    }
    out[v] = a0;
    out[VOCAB + v] = a1;
}

extern "C" void kernel_launch(void* const* d_in, const int* in_sizes, int n_in,
                              void* d_out, int out_size, void* d_ws, size_t ws_size,
                              hipStream_t stream) {
    const int*   x      = (const int*)  d_in[0];
    const float* wte    = (const float*)d_in[1];
    const float* wpe    = (const float*)d_in[2];
    const float* ln1_g  = (const float*)d_in[3];
    const float* ln1_b  = (const float*)d_in[4];
    const float* w_qkv  = (const float*)d_in[5];
    const float* b_qkv  = (const float*)d_in[6];
    const float* w_proj = (const float*)d_in[7];
    const float* b_proj = (const float*)d_in[8];
    const float* ln2_g  = (const float*)d_in[9];
    const float* ln2_b  = (const float*)d_in[10];
    const float* w_fc   = (const float*)d_in[11];
    const float* b_fc   = (const float*)d_in[12];
    const float* w_cp   = (const float*)d_in[13];
    const float* b_cp   = (const float*)d_in[14];
    const float* lnf_g  = (const float*)d_in[15];
    const float* lnf_b  = (const float*)d_in[16];
    const float* w_head = (const float*)d_in[17];
    float* out = (float*)d_out;

    char* ws = (char*)d_ws;
    float*          h     = (float*)ws;                             // 16 MB
    unsigned short* qkvB  = (unsigned short*)(ws + (16L << 20));    // 24 MB
    unsigned short* y_bf  = (unsigned short*)(ws + (40L << 20));    // 8 MB
    __hip_bfloat16* z_bf  = (__hip_bfloat16*)(ws + (48L << 20));    // 8 MB
    unsigned short* fc_bf = (unsigned short*)(ws + (56L << 20));    // 32 MB
    unsigned short* wT_a  = (unsigned short*)(ws + (88L << 20));    // 8 MB
    unsigned short* wT_b  = (unsigned short*)(ws + (97L << 20));    // 8 MB
    float*          hl    = (float*)(ws + (106L << 20));            // 8 KB

    const int SM_CONV = 16640;   // 64*65*4
    const int SM_ATTN = 49152;   // Ks+Vs+Ps

    embed_kernel<<<NTOK, 256, 0, stream>>>(x, wte, wpe, h);

    for (int l = 0; l < NLAYER; ++l) {
        // A: LN1 (4096) + convT qkv (768) -> wT_a
        fused_ln_convT<<<4096 + 768, 256, SM_CONV, stream>>>(
            h, y_bf, ln1_g + l * DMODEL, ln1_b + l * DMODEL,
            w_qkv + (long)l * DMODEL * 3072, wT_a, 1024, 3072, 4096);

        // B: qkv GEMM
        mm_qkv<<<dim3(24, 32), 256, 0, stream>>>(
            y_bf, wT_a, b_qkv + l * 3072, qkvB, NTOK, 3072, 1024);

        // C: attn (1024) + convT proj (256) -> wT_b
        fused_attn_convT<<<1024 + 256, 256, SM_ATTN, stream>>>(
            qkvB, qkvB + 4194304L, qkvB + 8388608L, z_bf,
            w_proj + (long)l * DMODEL * DMODEL, wT_b, 1024, 1024, 1024);

        // D: proj GEMM (+residual)
        mm_mfma_n64<<<dim3(16, 32), 256, 0, stream>>>(
            (const unsigned short*)z_bf, wT_b, b_proj + l * DMODEL, h, h,
            NTOK, 1024, 1024);

        // E: LN2 (4096) + convT fc (1024) -> wT_a
        fused_ln_convT<<<4096 + 1024, 256, SM_CONV, stream>>>(
            h, y_bf, ln2_g + l * DMODEL, ln2_b + l * DMODEL,
            w_fc + (long)l * DMODEL * 4096, wT_a, 1024, 4096, 4096);

        // F: fc GEMM (1024) + convT cp (1024) -> wT_b
        fused_fc_convT<<<1024 + 1024, 256, SM_CONV, stream>>>(
            y_bf, wT_a, b_fc + l * 4096, fc_bf, NTOK, 4096, 1024,
            w_cp + (long)l * 4096 * DMODEL, wT_b, 4096, 1024, 1024);

        // G: cp GEMM (+residual)
        mm_mfma_n64<<<dim3(16, 32), 256, 0, stream>>>(
            fc_bf, wT_b, b_cp + l * DMODEL, h, h, NTOK, 1024, 4096);
    }

    ln_final<<<BATCH, 256, 0, stream>>>(h + (long)(SEQ - 1) * DMODEL, hl,
                                        lnf_g, lnf_b, (long)SEQ * DMODEL);
    head_kernel<<<(VOCAB + 255) / 256, 256, 0, stream>>>(hl, w_head, out);
}

// Round 11
// 2520.881 us; speedup vs baseline: 1.2506x; 1.0579x over previous
//
#include <hip/hip_runtime.h>
#include <hip/hip_bf16.h>
#include <math.h>

#define VOCAB 50257
#define CTX 2048
#define DMODEL 1024
#define NHEAD 16
#define NLAYER 8
#define DHEAD 64
#define BATCH 2
#define SEQ 2048
#define NTOK (BATCH * SEQ)   // 4096

typedef __bf16 bf16x8 __attribute__((ext_vector_type(8)));
typedef float  f32x4  __attribute__((ext_vector_type(4)));
typedef unsigned short ushort4v __attribute__((ext_vector_type(4)));
typedef unsigned short ushort8v __attribute__((ext_vector_type(8)));

__device__ inline void gl_lds16(const void* g, void* l) {
    __builtin_amdgcn_global_load_lds(
        (const __attribute__((address_space(1))) unsigned int*)g,
        (__attribute__((address_space(3))) unsigned int*)l, 16, 0, 0);
}

__device__ inline unsigned short f2bs(float v) {
    __hip_bfloat16 t = __float2bfloat16(v);
    return *(unsigned short*)&t;
}

// ---------------- embedding ----------------
__global__ void embed_kernel(const int* __restrict__ x,
                             const float* __restrict__ wte,
                             const float* __restrict__ wpe,
                             float* __restrict__ h) {
    int t = blockIdx.x;
    int s = t & (SEQ - 1);
    int tok = x[t];
    const float* pe = wpe + (long)s * DMODEL;
    const float* te = wte + (long)tok * DMODEL;
    float* ph = h + (long)t * DMODEL;
    for (int d = threadIdx.x; d < DMODEL; d += 256)
        ph[d] = te[d] + pe[d];
}

// ---------------- layernorm bodies ----------------
__device__ inline float wave_sum(float v) {
    for (int off = 32; off; off >>= 1) v += __shfl_xor(v, off);
    return v;
}

__device__ void ln_body(char* smem, int row, const float* __restrict__ in,
                        unsigned short* __restrict__ out,
                        const float* __restrict__ g, const float* __restrict__ b) {
    float* red  = (float*)smem;
    float* red2 = red + 4;
    const float* px = in + (long)row * DMODEL;
    unsigned short* po = out + (long)row * DMODEL;
    int tid = threadIdx.x;
    int wid = tid >> 6, lane = tid & 63;

    float x[4];
    float s = 0.f;
    #pragma unroll
    for (int i = 0; i < 4; ++i) { x[i] = px[tid + i * 256]; s += x[i]; }
    s = wave_sum(s);
    if (lane == 0) red[wid] = s;
    __syncthreads();
    float mean = (red[0] + red[1] + red[2] + red[3]) * (1.0f / DMODEL);

    float s2 = 0.f;
    #pragma unroll
    for (int i = 0; i < 4; ++i) { float d = x[i] - mean; s2 += d * d; }
    s2 = wave_sum(s2);
    if (lane == 0) red2[wid] = s2;
    __syncthreads();
    float var = (red2[0] + red2[1] + red2[2] + red2[3]) * (1.0f / DMODEL);
    float r = 1.0f / sqrtf(var + 1e-5f);
    #pragma unroll
    for (int i = 0; i < 4; ++i) {
        int d = tid + i * 256;
        po[d] = f2bs((x[i] - mean) * r * g[d] + b[d]);
    }
}

__global__ void ln_final(const float* __restrict__ in, float* __restrict__ out,
                         const float* __restrict__ g, const float* __restrict__ b,
                         long row_stride) {
    __shared__ float red[4], red2[4];
    int row = blockIdx.x;
    const float* px = in + (long)row * row_stride;
    float* po = out + (long)row * DMODEL;
    int tid = threadIdx.x;
    int wid = tid >> 6, lane = tid & 63;
    float x[4];
    float s = 0.f;
    #pragma unroll
    for (int i = 0; i < 4; ++i) { x[i] = px[tid + i * 256]; s += x[i]; }
    s = wave_sum(s);
    if (lane == 0) red[wid] = s;
    __syncthreads();
    float mean = (red[0] + red[1] + red[2] + red[3]) * (1.0f / DMODEL);
    float s2 = 0.f;
    #pragma unroll
    for (int i = 0; i < 4; ++i) { float d = x[i] - mean; s2 += d * d; }
    s2 = wave_sum(s2);
    if (lane == 0) red2[wid] = s2;
    __syncthreads();
    float var = (red2[0] + red2[1] + red2[2] + red2[3]) * (1.0f / DMODEL);
    float r = 1.0f / sqrtf(var + 1e-5f);
    #pragma unroll
    for (int i = 0; i < 4; ++i) {
        int d = tid + i * 256;
        po[d] = (x[i] - mean) * r * g[d] + b[d];
    }
}

// ------------- transpose+convert body: W f32 [K][N] -> WT bf16 [N][K] -------------
__device__ void convT_body(char* smem, int kx, int ny, const float* __restrict__ W,
                           unsigned short* __restrict__ WT, int K, int N) {
    float (*t)[65] = (float(*)[65])smem;
    const int k0 = kx * 64, n0 = ny * 64;
    const int tid = threadIdx.x;
    {
        const int krow = tid >> 4, c4 = (tid & 15) * 4;
        #pragma unroll
        for (int p = 0; p < 4; ++p) {
            f32x4 gv = *(const f32x4*)&W[(long)(k0 + p * 16 + krow) * N + n0 + c4];
            #pragma unroll
            for (int j = 0; j < 4; ++j) t[p * 16 + krow][c4 + j] = gv[j];
        }
    }
    __syncthreads();
    {
        const int n = tid >> 3, kl = (tid & 7) * 8;
        #pragma unroll
        for (int p = 0; p < 2; ++p) {
            ushort8v pk;
            #pragma unroll
            for (int j = 0; j < 8; ++j) pk[j] = f2bs(t[kl + j][p * 32 + n]);
            *(ushort8v*)&WT[(long)(n0 + p * 32 + n) * K + k0 + kl] = pk;
        }
    }
}

// ---------------- 256^2 8-phase bf16 MFMA GEMM (R4-verified) ----------------
// BM=BN=256, BK=64, 512 thr (8 waves 2Mx4N), per-wave 128x64 out.
// LDS 128KB dynamic. EPI: 2 = bf16 gelu(x+bias); 3 = qkv scatter.
#define STG_A(KS, H) do { \
    const unsigned short* g_ = A + (long)(bm + (H) * 128 + srow) * K + (KS) * 64 + stgch; \
    unsigned short* s_ = LDS + (((KS) & 1) * 2 + (H)) * 8192 + (w * 8) * 64; \
    gl_lds16(g_, s_); gl_lds16(g_ + 64L * K, s_ + 4096); \
} while (0)
#define STG_B(KS, H) do { \
    const unsigned short* g_ = BT + (long)(bn + (H) * 128 + srow) * K + (KS) * 64 + stgch; \
    unsigned short* s_ = LDS + 32768 + (((KS) & 1) * 2 + (H)) * 8192 + (w * 8) * 64; \
    gl_lds16(g_, s_); gl_lds16(g_ + 64L * K, s_ + 4096); \
} while (0)
#define MM2(M_, x0, x1) do { \
    acc[M_][0] = __builtin_amdgcn_mfma_f32_16x16x32_bf16(x0, bfr[0], acc[M_][0], 0, 0, 0); \
    acc[M_][0] = __builtin_amdgcn_mfma_f32_16x16x32_bf16(x1, bfr[1], acc[M_][0], 0, 0, 0); \
    acc[M_][1] = __builtin_amdgcn_mfma_f32_16x16x32_bf16(x0, bfr[2], acc[M_][1], 0, 0, 0); \
    acc[M_][1] = __builtin_amdgcn_mfma_f32_16x16x32_bf16(x1, bfr[3], acc[M_][1], 0, 0, 0); \
    acc[M_][2] = __builtin_amdgcn_mfma_f32_16x16x32_bf16(x0, bfr[4], acc[M_][2], 0, 0, 0); \
    acc[M_][2] = __builtin_amdgcn_mfma_f32_16x16x32_bf16(x1, bfr[5], acc[M_][2], 0, 0, 0); \
    acc[M_][3] = __builtin_amdgcn_mfma_f32_16x16x32_bf16(x0, bfr[6], acc[M_][3], 0, 0, 0); \
    acc[M_][3] = __builtin_amdgcn_mfma_f32_16x16x32_bf16(x1, bfr[7], acc[M_][3], 0, 0, 0); \
} while (0)
#define PHASE(Q, SPAR, STAGE_STMT, TAIL_STMT) do { \
    bf16x8 a00, a01, a10, a11; \
    if (((Q) & 3) == 0) { \
        const unsigned short* Bb_ = lBp[SPAR] + ((wc & 1) * 64 + fr) * 64; \
        bfr[0] = *(const bf16x8*)(Bb_ + rd0);        bfr[1] = *(const bf16x8*)(Bb_ + rd1); \
        bfr[2] = *(const bf16x8*)(Bb_ + 1024 + rd0); bfr[3] = *(const bf16x8*)(Bb_ + 1024 + rd1); \
        bfr[4] = *(const bf16x8*)(Bb_ + 2048 + rd0); bfr[5] = *(const bf16x8*)(Bb_ + 2048 + rd1); \
        bfr[6] = *(const bf16x8*)(Bb_ + 3072 + rd0); bfr[7] = *(const bf16x8*)(Bb_ + 3072 + rd1); \
    } \
    { const unsigned short* Ab_ = lAp[SPAR] + fr * 64; \
      a00 = *(const bf16x8*)(Ab_ + (((Q) & 3) * 2) * 1024 + rd0); \
      a01 = *(const bf16x8*)(Ab_ + (((Q) & 3) * 2) * 1024 + rd1); \
      a10 = *(const bf16x8*)(Ab_ + (((Q) & 3) * 2 + 1) * 1024 + rd0); \
      a11 = *(const bf16x8*)(Ab_ + (((Q) & 3) * 2 + 1) * 1024 + rd1); } \
    STAGE_STMT; \
    __builtin_amdgcn_s_barrier(); \
    asm volatile("s_waitcnt lgkmcnt(0)" ::: "memory"); \
    __builtin_amdgcn_sched_barrier(0); \
    __builtin_amdgcn_s_setprio(1); \
    MM2(((Q) & 3) * 2, a00, a01); \
    MM2(((Q) & 3) * 2 + 1, a10, a11); \
    __builtin_amdgcn_s_setprio(0); \
    TAIL_STMT; \
    __builtin_amdgcn_s_barrier(); \
} while (0)

template<int EPI>
__global__ __launch_bounds__(512, 1)
void mm_mfma256(const unsigned short* __restrict__ A,
                const unsigned short* __restrict__ BT,
                const float* __restrict__ bias,
                void* __restrict__ Cout, int M, int N, int K, int nbx) {
    extern __shared__ unsigned short LDS[];
    const int tid = threadIdx.x;
    const int w = tid >> 6, lane = tid & 63;
    const int wr = w >> 2, wc = w & 3;
    const int nwg = gridDim.x, bid = blockIdx.x;
    const int swz = (bid & 7) * (nwg >> 3) + (bid >> 3);
    const int bm = (swz / nbx) * 256, bn = (swz % nbx) * 256;

    f32x4 acc[8][4];
    #pragma unroll
    for (int m = 0; m < 8; ++m)
        #pragma unroll
        for (int n = 0; n < 4; ++n)
            acc[m][n] = (f32x4){0.f, 0.f, 0.f, 0.f};

    const int fr = lane & 15, kg = lane >> 4;
    const int rd0 = 8 * (kg ^ (lane & 7)), rd1 = 8 * ((kg + 4) ^ (lane & 7));
    const int stgch = 8 * ((lane & 7) ^ (lane >> 3));
    const int srow = w * 8 + (lane >> 3);
    unsigned short* const lAp[2] = { LDS + wr * 8192, LDS + (2 + wr) * 8192 };
    unsigned short* const lBp[2] = { LDS + 32768 + (wc >> 1) * 8192,
                                     LDS + 32768 + (2 + (wc >> 1)) * 8192 };
    bf16x8 bfr[8];

    STG_B(0, 0); STG_B(0, 1); STG_A(0, 0); STG_A(0, 1); STG_B(1, 0); STG_B(1, 1);
    asm volatile("s_waitcnt vmcnt(4)" ::: "memory");
    __builtin_amdgcn_sched_barrier(0);
    __builtin_amdgcn_s_barrier();

    const int T = K >> 7;
    for (int t = 0; t < T; ++t) {
        const int s = 2 * t;
        const bool nl = (t < T - 1);
        PHASE(0, 0, STG_A(s + 1, 0), );
        PHASE(1, 0, STG_A(s + 1, 1), );
        PHASE(2, 0, if (nl) STG_B(s + 2, 0), );
        PHASE(3, 0, if (nl) STG_B(s + 2, 1),
              if (nl) { asm volatile("s_waitcnt vmcnt(4)" ::: "memory"); } else { asm volatile("s_waitcnt vmcnt(0)" ::: "memory"); } __builtin_amdgcn_sched_barrier(0); );
        PHASE(4, 1, if (nl) STG_A(s + 2, 0), );
        PHASE(5, 1, if (nl) STG_A(s + 2, 1), );
        PHASE(6, 1, if (nl) STG_B(s + 3, 0), );
        PHASE(7, 1, if (nl) STG_B(s + 3, 1),
              if (nl) { asm volatile("s_waitcnt vmcnt(4)" ::: "memory"); __builtin_amdgcn_sched_barrier(0); } );
    }

    const int r0 = (lane >> 4) * 4;
    #pragma unroll
    for (int n = 0; n < 4; ++n) {
        int colb = bn + wc * 64 + n * 16;
        float bv = bias[colb + fr];
        #pragma unroll
        for (int m = 0; m < 8; ++m) {
            int rowb = bm + wr * 128 + m * 16 + r0;
            if (EPI == 3) {
                unsigned short* qkvB = (unsigned short*)Cout;
                int which = colb >> 10, hh = (colb & 1023) >> 6, dbase = colb & 63;
                int b_ = rowb >> 11, s_ = rowb & 2047;
                long bh2 = b_ * 16 + hh;
                float v[4];
                #pragma unroll
                for (int r = 0; r < 4; ++r) v[r] = acc[m][n][r] + bv;
                if (which == 2) {
                    ushort4v pk;
                    #pragma unroll
                    for (int r = 0; r < 4; ++r) pk[r] = f2bs(v[r]);
                    *(ushort4v*)&qkvB[8388608L + (bh2 * 64 + dbase + fr) * 2048 + s_] = pk;
                } else {
                    unsigned short* dst = qkvB + (long)which * 4194304L +
                                          (bh2 * 2048 + s_) * 64 + dbase + fr;
                    #pragma unroll
                    for (int r = 0; r < 4; ++r) dst[r * 64] = f2bs(v[r]);
                }
            } else {
                #pragma unroll
                for (int r = 0; r < 4; ++r) {
                    long row = rowb + r, col = colb + fr;
                    float v = acc[m][n][r] + bv;
                    v = 0.5f * v * (1.0f + erff(v * 0.70710678118f));
                    ((__hip_bfloat16*)Cout)[row * N + col] = __float2bfloat16(v);
                }
            }
        }
    }
}

// ---------------- bf16 MFMA GEMM, 128x64 tile (small-N) ----------------
__global__ __launch_bounds__(256)
void mm_mfma_n64(const unsigned short* __restrict__ A,
                 const unsigned short* __restrict__ BT,
                 const float* __restrict__ bias, const float* __restrict__ R,
                 float* __restrict__ Cout, int M, int N, int K) {
    __shared__ unsigned short As[128 * 32];
    __shared__ unsigned short Bs[64 * 32];
    const int tid = threadIdx.x;
    const int w = tid >> 6, lane = tid & 63;
    const int bm = blockIdx.y * 128, bn = blockIdx.x * 64;
    const int wr = (w >> 1) * 64, wc = (w & 1) * 32;

    f32x4 acc[4][2];
    #pragma unroll
    for (int m = 0; m < 4; ++m)
        #pragma unroll
        for (int n = 0; n < 2; ++n)
            acc[m][n] = (f32x4){0.f, 0.f, 0.f, 0.f};

    const int lrow = lane >> 2;
    const int lcol = (lane & 3) * 8;
    const unsigned short* gA = A + (long)(bm + w * 32 + lrow) * K + lcol;
    const unsigned short* gB = BT + (long)(bn + w * 16 + lrow) * K + lcol;
    unsigned short* lA = &As[(w * 32) * 32];
    unsigned short* lB = &Bs[(w * 16) * 32];

    for (int k0 = 0; k0 < K; k0 += 32) {
        gl_lds16(gA + k0,          lA);
        gl_lds16(gA + k0 + 16 * K, lA + 16 * 32);
        gl_lds16(gB + k0,          lB);
        __syncthreads();

        bf16x8 a[4], b[2];
        #pragma unroll
        for (int m = 0; m < 4; ++m)
            a[m] = *(const bf16x8*)&As[(wr + m * 16 + (lane & 15)) * 32 + (lane >> 4) * 8];
        #pragma unroll
        for (int n = 0; n < 2; ++n)
            b[n] = *(const bf16x8*)&Bs[(wc + n * 16 + (lane & 15)) * 32 + (lane >> 4) * 8];
        #pragma unroll
        for (int m = 0; m < 4; ++m)
            #pragma unroll
            for (int n = 0; n < 2; ++n)
                acc[m][n] = __builtin_amdgcn_mfma_f32_16x16x32_bf16(a[m], b[n], acc[m][n], 0, 0, 0);
        __syncthreads();
    }

    const int r0 = (lane >> 4) * 4, cc = lane & 15;
    #pragma unroll
    for (int n = 0; n < 2; ++n) {
        int colb = bn + wc + n * 16;
        float bv = bias[colb + cc];
        #pragma unroll
        for (int m = 0; m < 4; ++m) {
            int rowb = bm + wr + m * 16 + r0;
            #pragma unroll
            for (int r = 0; r < 4; ++r) {
                long row = rowb + r, col = colb + cc;
                float v = acc[m][n][r] + bv + R[row * N + col];
                Cout[row * N + col] = v;
            }
        }
    }
}

// ---------------- MFMA flash attention body, KVBLK=128 (dynamic smem 48K) ----------------
__device__ void attn_body(char* smem, int bh, int qb,
                          const unsigned short* __restrict__ qB,
                          const unsigned short* __restrict__ kB,
                          const unsigned short* __restrict__ vT,
                          __hip_bfloat16* __restrict__ z) {
    const int tid = threadIdx.x, w = tid >> 6, lane = tid & 63;
    const int arow = lane & 15, kg = lane >> 4;
    unsigned short* Ks = (unsigned short*)smem;
    unsigned short* Vs = Ks + 128 * 64;
    unsigned short* Ps = Vs + 64 * 128 + w * 16 * 128;

    const long kvbase = (long)bh * (2048 * 64);

    bf16x8 qa[2];
    {
        const unsigned short* q0 = qB + kvbase + (long)(qb + w * 16 + arow) * 64 + kg * 8;
        qa[0] = *(const bf16x8*)(q0);
        qa[1] = *(const bf16x8*)(q0 + 32);
    }

    f32x4 po[4];
    float mrow[4], lrow[4];
    #pragma unroll
    for (int i = 0; i < 4; ++i) {
        po[i] = (f32x4){0.f, 0.f, 0.f, 0.f};
        mrow[i] = -1e30f; lrow[i] = 0.f;
    }

    const int ksrow = lane >> 3;
    const int kschunk = (lane & 7) ^ ksrow;
    const int vsr = lane >> 4;
    const int cmax = qb >> 7;

    for (int c = 0; c <= cmax; ++c) {
        {
            const unsigned short* ks0 = kB + kvbase +
                (long)(c * 128 + w * 32 + ksrow) * 64 + kschunk * 8;
            #pragma unroll
            for (int i = 0; i < 4; ++i)
                gl_lds16(ks0 + (long)i * 8 * 64, &Ks[(w * 32 + i * 8) * 64]);
            #pragma unroll
            for (int i = 0; i < 4; ++i) {
                int d = w * 16 + i * 4 + vsr;
                int sch = (lane & 15) ^ (d & 7);
                gl_lds16(vT + kvbase + (long)d * 2048 + c * 128 + sch * 8,
                         &Vs[(w * 16 + i * 4) * 128]);
            }
        }
        __syncthreads();

        f32x4 s[8];
        #pragma unroll
        for (int n = 0; n < 8; ++n) {
            s[n] = (f32x4){0.f, 0.f, 0.f, 0.f};
            int row = n * 16 + arow, sw = row & 7;
            bf16x8 kb0 = *(const bf16x8*)&Ks[row * 64 + (kg ^ sw) * 8];
            bf16x8 kb1 = *(const bf16x8*)&Ks[row * 64 + ((4 + kg) ^ sw) * 8];
            s[n] = __builtin_amdgcn_mfma_f32_16x16x32_bf16(qa[0], kb0, s[n], 0, 0, 0);
            s[n] = __builtin_amdgcn_mfma_f32_16x16x32_bf16(qa[1], kb1, s[n], 0, 0, 0);
        }

        const bool diag = (c == cmax);
        #pragma unroll
        for (int n = 0; n < 8; ++n)
            #pragma unroll
            for (int r = 0; r < 4; ++r) {
                float v = s[n][r] * 0.125f;
                if (diag) {
                    int key = c * 128 + n * 16 + arow;
                    int qrow = qb + w * 16 + kg * 4 + r;
                    if (key > qrow) v = -1e30f;
                }
                s[n][r] = v;
            }

        #pragma unroll
        for (int r = 0; r < 4; ++r) {
            float rm = s[0][r];
            #pragma unroll
            for (int n = 1; n < 8; ++n) rm = fmaxf(rm, s[n][r]);
            #pragma unroll
            for (int off = 1; off < 16; off <<= 1)
                rm = fmaxf(rm, __shfl_xor(rm, off));
            float mnew = fmaxf(mrow[r], rm);
            float esc = expf(mrow[r] - mnew);
            float rs = 0.f;
            #pragma unroll
            for (int n = 0; n < 8; ++n) {
                float p = expf(s[n][r] - mnew);
                s[n][r] = p;
                rs += p;
            }
            #pragma unroll
            for (int off = 1; off < 16; off <<= 1)
                rs += __shfl_xor(rs, off);
            lrow[r] = lrow[r] * esc + rs;
            #pragma unroll
            for (int dt = 0; dt < 4; ++dt) po[dt][r] *= esc;
            mrow[r] = mnew;
        }

        #pragma unroll
        for (int n = 0; n < 8; ++n) {
            int col = n * 16 + arow;
            int chunk = col >> 3, cw = col & 7;
            #pragma unroll
            for (int r = 0; r < 4; ++r) {
                int row = kg * 4 + r;
                Ps[row * 128 + ((chunk ^ (row & 7)) * 8 + cw)] = f2bs(s[n][r]);
            }
        }

        bf16x8 pa[4];
        #pragma unroll
        for (int ks = 0; ks < 4; ++ks)
            pa[ks] = *(const bf16x8*)&Ps[arow * 128 + (((ks * 4 + kg) ^ (arow & 7)) * 8)];
        #pragma unroll
        for (int dt = 0; dt < 4; ++dt) {
            int vrow = dt * 16 + arow, sw = vrow & 7;
            #pragma unroll
            for (int ks = 0; ks < 4; ++ks) {
                bf16x8 vb = *(const bf16x8*)&Vs[vrow * 128 + (((ks * 4 + kg) ^ sw) * 8)];
                po[dt] = __builtin_amdgcn_mfma_f32_16x16x32_bf16(pa[ks], vb, po[dt], 0, 0, 0);
            }
        }
        __syncthreads();
    }

    const int b_ = bh >> 4, hofs = (bh & 15) * 64;
    #pragma unroll
    for (int dt = 0; dt < 4; ++dt)
        #pragma unroll
        for (int r = 0; r < 4; ++r) {
            long row = (long)b_ * 2048 + qb + w * 16 + kg * 4 + r;
            z[row * 1024 + hofs + dt * 16 + arow] = __float2bfloat16(po[dt][r] / lrow[r]);
        }
}

// ---------------- fused kernels ----------------
__global__ __launch_bounds__(256)
void fused_ln_convT(const float* __restrict__ h, unsigned short* __restrict__ y,
                    const float* __restrict__ g, const float* __restrict__ b,
                    const float* __restrict__ W, unsigned short* __restrict__ WT,
                    int K, int N, int nLN) {
    extern __shared__ char smem[];
    int bid = blockIdx.x;
    if (bid < nLN) {
        ln_body(smem, bid, h, y, g, b);
    } else {
        int r = bid - nLN, kt = K >> 6;
        convT_body(smem, r % kt, r / kt, W, WT, K, N);
    }
}

// attn (nAttn) + convT proj -> WT1 (n1) + convT cp -> WT2
__global__ __launch_bounds__(256)
void fused_attn_convT2(const unsigned short* __restrict__ qB,
                       const unsigned short* __restrict__ kB,
                       const unsigned short* __restrict__ vT,
                       __hip_bfloat16* __restrict__ z,
                       const float* __restrict__ W1, unsigned short* __restrict__ WT1,
                       int K1, int N1, int n1,
                       const float* __restrict__ W2, unsigned short* __restrict__ WT2,
                       int K2, int N2, int nAttn) {
    extern __shared__ char smem[];
    int bid = blockIdx.x;
    if (bid < nAttn) {
        attn_body(smem, bid & 31, (bid >> 5) * 64, qB, kB, vT, z);
    } else if (bid < nAttn + n1) {
        int r = bid - nAttn, kt = K1 >> 6;
        convT_body(smem, r % kt, r / kt, W1, WT1, K1, N1);
    } else {
        int r = bid - nAttn - n1, kt = K2 >> 6;
        convT_body(smem, r % kt, r / kt, W2, WT2, K2, N2);
    }
}

// ---------------- head ----------------
__global__ void head_kernel(const float* __restrict__ hl, const float* __restrict__ W,
                            float* __restrict__ out) {
    __shared__ float hs[2 * DMODEL];
    int tid = threadIdx.x;
    #pragma unroll
    for (int i = 0; i < 8; ++i) hs[tid + i * 256] = hl[tid + i * 256];
    __syncthreads();
    int v = blockIdx.x * 256 + tid;
    if (v >= VOCAB) return;
    float a0 = 0.f, a1 = 0.f;
    for (int d = 0; d < DMODEL; ++d) {
        float wv = W[(long)d * VOCAB + v];
        a0 += hs[d] * wv;
        a1 += hs[DMODEL + d] * wv;
    }
    out[v] = a0;
    out[VOCAB + v] = a1;
}

extern "C" void kernel_launch(void* const* d_in, const int* in_sizes, int n_in,
                              void* d_out, int out_size, void* d_ws, size_t ws_size,
                              hipStream_t stream) {
    const int*   x      = (const int*)  d_in[0];
    const float* wte    = (const float*)d_in[1];
    const float* wpe    = (const float*)d_in[2];
    const float* ln1_g  = (const float*)d_in[3];
    const float* ln1_b  = (const float*)d_in[4];
    const float* w_qkv  = (const float*)d_in[5];
    const float* b_qkv  = (const float*)d_in[6];
    const float* w_proj = (const float*)d_in[7];
    const float* b_proj = (const float*)d_in[8];
    const float* ln2_g  = (const float*)d_in[9];
    const float* ln2_b  = (const float*)d_in[10];
    const float* w_fc   = (const float*)d_in[11];
    const float* b_fc   = (const float*)d_in[12];
    const float* w_cp   = (const float*)d_in[13];
    const float* b_cp   = (const float*)d_in[14];
    const float* lnf_g  = (const float*)d_in[15];
    const float* lnf_b  = (const float*)d_in[16];
    const float* w_head = (const float*)d_in[17];
    float* out = (float*)d_out;

    char* ws = (char*)d_ws;
    float*          h     = (float*)ws;                             // 16 MB
    unsigned short* qkvB  = (unsigned short*)(ws + (16L << 20));    // 24 MB
    unsigned short* y_bf  = (unsigned short*)(ws + (40L << 20));    // 8 MB
    __hip_bfloat16* z_bf  = (__hip_bfloat16*)(ws + (48L << 20));    // 8 MB
    unsigned short* fc_bf = (unsigned short*)(ws + (56L << 20));    // 32 MB
    unsigned short* wT_a  = (unsigned short*)(ws + (88L << 20));    // 8 MB
    unsigned short* wT_b  = (unsigned short*)(ws + (97L << 20));    // 8 MB (proj)
    unsigned short* wT_c  = (unsigned short*)(ws + (106L << 20));   // 8 MB (cp)
    float*          hl    = (float*)(ws + (115L << 20));            // 8 KB

    const int SM_CONV = 16640;   // 64*65*4
    const int SM_ATTN = 49152;   // Ks+Vs+Ps

    embed_kernel<<<NTOK, 256, 0, stream>>>(x, wte, wpe, h);

    for (int l = 0; l < NLAYER; ++l) {
        // A: LN1 (4096) + convT qkv (768) -> wT_a
        fused_ln_convT<<<4096 + 768, 256, SM_CONV, stream>>>(
            h, y_bf, ln1_g + l * DMODEL, ln1_b + l * DMODEL,
            w_qkv + (long)l * DMODEL * 3072, wT_a, 1024, 3072, 4096);

        // B: qkv GEMM (256^2 8-phase)
        mm_mfma256<3><<<192, 512, 131072, stream>>>(
            y_bf, wT_a, b_qkv + l * 3072, qkvB, NTOK, 3072, 1024, 12);

        // C: attn (1024) + convT proj (256) -> wT_b + convT cp (1024) -> wT_c
        fused_attn_convT2<<<1024 + 256 + 1024, 256, SM_ATTN, stream>>>(
            qkvB, qkvB + 4194304L, qkvB + 8388608L, z_bf,
            w_proj + (long)l * DMODEL * DMODEL, wT_b, 1024, 1024, 256,
            w_cp + (long)l * 4096 * DMODEL, wT_c, 4096, 1024, 1024);

        // D: proj GEMM (+residual)
        mm_mfma_n64<<<dim3(16, 32), 256, 0, stream>>>(
            (const unsigned short*)z_bf, wT_b, b_proj + l * DMODEL, h, h,
            NTOK, 1024, 1024);

        // E: LN2 (4096) + convT fc (1024) -> wT_a
        fused_ln_convT<<<4096 + 1024, 256, SM_CONV, stream>>>(
            h, y_bf, ln2_g + l * DMODEL, ln2_b + l * DMODEL,
            w_fc + (long)l * DMODEL * 4096, wT_a, 1024, 4096, 4096);

        // F: fc GEMM (256^2 8-phase, gelu)
        mm_mfma256<2><<<256, 512, 131072, stream>>>(
            y_bf, wT_a, b_fc + l * 4096, fc_bf, NTOK, 4096, 1024, 16);

        // G: cp GEMM (+residual)
        mm_mfma_n64<<<dim3(16, 32), 256, 0, stream>>>(
            fc_bf, wT_c, b_cp + l * DMODEL, h, h, NTOK, 1024, 4096);
    }

    ln_final<<<BATCH, 256, 0, stream>>>(h + (long)(SEQ - 1) * DMODEL, hl,
                                        lnf_g, lnf_b, (long)SEQ * DMODEL);
    head_kernel<<<(VOCAB + 255) / 256, 256, 0, stream>>>(hl, w_head, out);
}

// Round 12
// 2501.328 us; speedup vs baseline: 1.2604x; 1.0078x over previous
//
#include <hip/hip_runtime.h>
#include <hip/hip_bf16.h>
#include <math.h>

#define VOCAB 50257
#define CTX 2048
#define DMODEL 1024
#define NHEAD 16
#define NLAYER 8
#define DHEAD 64
#define BATCH 2
#define SEQ 2048
#define NTOK (BATCH * SEQ)   // 4096

typedef __bf16 bf16x8 __attribute__((ext_vector_type(8)));
typedef float  f32x4  __attribute__((ext_vector_type(4)));
typedef unsigned short ushort4v __attribute__((ext_vector_type(4)));
typedef unsigned short ushort8v __attribute__((ext_vector_type(8)));

__device__ inline void gl_lds16(const void* g, void* l) {
    __builtin_amdgcn_global_load_lds(
        (const __attribute__((address_space(1))) unsigned int*)g,
        (__attribute__((address_space(3))) unsigned int*)l, 16, 0, 0);
}

__device__ inline unsigned short f2bs(float v) {
    __hip_bfloat16 t = __float2bfloat16(v);
    return *(unsigned short*)&t;
}

// ---------------- embedding ----------------
__global__ void embed_kernel(const int* __restrict__ x,
                             const float* __restrict__ wte,
                             const float* __restrict__ wpe,
                             float* __restrict__ h) {
    int t = blockIdx.x;
    int s = t & (SEQ - 1);
    int tok = x[t];
    const float* pe = wpe + (long)s * DMODEL;
    const float* te = wte + (long)tok * DMODEL;
    float* ph = h + (long)t * DMODEL;
    for (int d = threadIdx.x; d < DMODEL; d += 256)
        ph[d] = te[d] + pe[d];
}

// ---------------- layernorm bodies ----------------
__device__ inline float wave_sum(float v) {
    for (int off = 32; off; off >>= 1) v += __shfl_xor(v, off);
    return v;
}

__device__ void ln_body(char* smem, int row, const float* __restrict__ in,
                        unsigned short* __restrict__ out,
                        const float* __restrict__ g, const float* __restrict__ b) {
    float* red  = (float*)smem;
    float* red2 = red + 4;
    const float* px = in + (long)row * DMODEL;
    unsigned short* po = out + (long)row * DMODEL;
    int tid = threadIdx.x;
    int wid = tid >> 6, lane = tid & 63;

    float x[4];
    float s = 0.f;
    #pragma unroll
    for (int i = 0; i < 4; ++i) { x[i] = px[tid + i * 256]; s += x[i]; }
    s = wave_sum(s);
    if (lane == 0) red[wid] = s;
    __syncthreads();
    float mean = (red[0] + red[1] + red[2] + red[3]) * (1.0f / DMODEL);

    float s2 = 0.f;
    #pragma unroll
    for (int i = 0; i < 4; ++i) { float d = x[i] - mean; s2 += d * d; }
    s2 = wave_sum(s2);
    if (lane == 0) red2[wid] = s2;
    __syncthreads();
    float var = (red2[0] + red2[1] + red2[2] + red2[3]) * (1.0f / DMODEL);
    float r = 1.0f / sqrtf(var + 1e-5f);
    #pragma unroll
    for (int i = 0; i < 4; ++i) {
        int d = tid + i * 256;
        po[d] = f2bs((x[i] - mean) * r * g[d] + b[d]);
    }
}

__global__ void ln_final(const float* __restrict__ in, float* __restrict__ out,
                         const float* __restrict__ g, const float* __restrict__ b,
                         long row_stride) {
    __shared__ float red[4], red2[4];
    int row = blockIdx.x;
    const float* px = in + (long)row * row_stride;
    float* po = out + (long)row * DMODEL;
    int tid = threadIdx.x;
    int wid = tid >> 6, lane = tid & 63;
    float x[4];
    float s = 0.f;
    #pragma unroll
    for (int i = 0; i < 4; ++i) { x[i] = px[tid + i * 256]; s += x[i]; }
    s = wave_sum(s);
    if (lane == 0) red[wid] = s;
    __syncthreads();
    float mean = (red[0] + red[1] + red[2] + red[3]) * (1.0f / DMODEL);
    float s2 = 0.f;
    #pragma unroll
    for (int i = 0; i < 4; ++i) { float d = x[i] - mean; s2 += d * d; }
    s2 = wave_sum(s2);
    if (lane == 0) red2[wid] = s2;
    __syncthreads();
    float var = (red2[0] + red2[1] + red2[2] + red2[3]) * (1.0f / DMODEL);
    float r = 1.0f / sqrtf(var + 1e-5f);
    #pragma unroll
    for (int i = 0; i < 4; ++i) {
        int d = tid + i * 256;
        po[d] = (x[i] - mean) * r * g[d] + b[d];
    }
}

// ------------- transpose+convert body: W f32 [K][N] -> WT bf16 [N][K] -------------
__device__ void convT_body(char* smem, int kx, int ny, const float* __restrict__ W,
                           unsigned short* __restrict__ WT, int K, int N) {
    float (*t)[65] = (float(*)[65])smem;
    const int k0 = kx * 64, n0 = ny * 64;
    const int tid = threadIdx.x;
    {
        const int krow = tid >> 4, c4 = (tid & 15) * 4;
        #pragma unroll
        for (int p = 0; p < 4; ++p) {
            f32x4 gv = *(const f32x4*)&W[(long)(k0 + p * 16 + krow) * N + n0 + c4];
            #pragma unroll
            for (int j = 0; j < 4; ++j) t[p * 16 + krow][c4 + j] = gv[j];
        }
    }
    __syncthreads();
    {
        const int n = tid >> 3, kl = (tid & 7) * 8;
        #pragma unroll
        for (int p = 0; p < 2; ++p) {
            ushort8v pk;
            #pragma unroll
            for (int j = 0; j < 8; ++j) pk[j] = f2bs(t[kl + j][p * 32 + n]);
            *(ushort8v*)&WT[(long)(n0 + p * 32 + n) * K + k0 + kl] = pk;
        }
    }
}

// ---------------- 256^2 8-phase bf16 MFMA GEMM ----------------
#define STG_A(KS, H) do { \
    const unsigned short* g_ = A + (long)(bm + (H) * 128 + srow) * K + (KS) * 64 + stgch; \
    unsigned short* s_ = LDS + (((KS) & 1) * 2 + (H)) * 8192 + (w * 8) * 64; \
    gl_lds16(g_, s_); gl_lds16(g_ + 64L * K, s_ + 4096); \
} while (0)
#define STG_B(KS, H) do { \
    const unsigned short* g_ = BT + (long)(bn + (H) * 128 + srow) * K + (KS) * 64 + stgch; \
    unsigned short* s_ = LDS + 32768 + (((KS) & 1) * 2 + (H)) * 8192 + (w * 8) * 64; \
    gl_lds16(g_, s_); gl_lds16(g_ + 64L * K, s_ + 4096); \
} while (0)
#define MM2(M_, x0, x1) do { \
    acc[M_][0] = __builtin_amdgcn_mfma_f32_16x16x32_bf16(x0, bfr[0], acc[M_][0], 0, 0, 0); \
    acc[M_][0] = __builtin_amdgcn_mfma_f32_16x16x32_bf16(x1, bfr[1], acc[M_][0], 0, 0, 0); \
    acc[M_][1] = __builtin_amdgcn_mfma_f32_16x16x32_bf16(x0, bfr[2], acc[M_][1], 0, 0, 0); \
    acc[M_][1] = __builtin_amdgcn_mfma_f32_16x16x32_bf16(x1, bfr[3], acc[M_][1], 0, 0, 0); \
    acc[M_][2] = __builtin_amdgcn_mfma_f32_16x16x32_bf16(x0, bfr[4], acc[M_][2], 0, 0, 0); \
    acc[M_][2] = __builtin_amdgcn_mfma_f32_16x16x32_bf16(x1, bfr[5], acc[M_][2], 0, 0, 0); \
    acc[M_][3] = __builtin_amdgcn_mfma_f32_16x16x32_bf16(x0, bfr[6], acc[M_][3], 0, 0, 0); \
    acc[M_][3] = __builtin_amdgcn_mfma_f32_16x16x32_bf16(x1, bfr[7], acc[M_][3], 0, 0, 0); \
} while (0)
#define PHASE(Q, SPAR, STAGE_STMT, TAIL_STMT) do { \
    bf16x8 a00, a01, a10, a11; \
    if (((Q) & 3) == 0) { \
        const unsigned short* Bb_ = lBp[SPAR] + ((wc & 1) * 64 + fr) * 64; \
        bfr[0] = *(const bf16x8*)(Bb_ + rd0);        bfr[1] = *(const bf16x8*)(Bb_ + rd1); \
        bfr[2] = *(const bf16x8*)(Bb_ + 1024 + rd0); bfr[3] = *(const bf16x8*)(Bb_ + 1024 + rd1); \
        bfr[4] = *(const bf16x8*)(Bb_ + 2048 + rd0); bfr[5] = *(const bf16x8*)(Bb_ + 2048 + rd1); \
        bfr[6] = *(const bf16x8*)(Bb_ + 3072 + rd0); bfr[7] = *(const bf16x8*)(Bb_ + 3072 + rd1); \
    } \
    { const unsigned short* Ab_ = lAp[SPAR] + fr * 64; \
      a00 = *(const bf16x8*)(Ab_ + (((Q) & 3) * 2) * 1024 + rd0); \
      a01 = *(const bf16x8*)(Ab_ + (((Q) & 3) * 2) * 1024 + rd1); \
      a10 = *(const bf16x8*)(Ab_ + (((Q) & 3) * 2 + 1) * 1024 + rd0); \
      a11 = *(const bf16x8*)(Ab_ + (((Q) & 3) * 2 + 1) * 1024 + rd1); } \
    STAGE_STMT; \
    __builtin_amdgcn_s_barrier(); \
    asm volatile("s_waitcnt lgkmcnt(0)" ::: "memory"); \
    __builtin_amdgcn_sched_barrier(0); \
    __builtin_amdgcn_s_setprio(1); \
    MM2(((Q) & 3) * 2, a00, a01); \
    MM2(((Q) & 3) * 2 + 1, a10, a11); \
    __builtin_amdgcn_s_setprio(0); \
    TAIL_STMT; \
    __builtin_amdgcn_s_barrier(); \
} while (0)

template<int EPI>
__global__ __launch_bounds__(512, 1)
void mm_mfma256(const unsigned short* __restrict__ A,
                const unsigned short* __restrict__ BT,
                const float* __restrict__ bias,
                void* __restrict__ Cout, int M, int N, int K, int nbx) {
    extern __shared__ unsigned short LDS[];
    const int tid = threadIdx.x;
    const int w = tid >> 6, lane = tid & 63;
    const int wr = w >> 2, wc = w & 3;
    const int nwg = gridDim.x, bid = blockIdx.x;
    const int swz = (bid & 7) * (nwg >> 3) + (bid >> 3);
    const int bm = (swz / nbx) * 256, bn = (swz % nbx) * 256;

    f32x4 acc[8][4];
    #pragma unroll
    for (int m = 0; m < 8; ++m)
        #pragma unroll
        for (int n = 0; n < 4; ++n)
            acc[m][n] = (f32x4){0.f, 0.f, 0.f, 0.f};

    const int fr = lane & 15, kg = lane >> 4;
    const int rd0 = 8 * (kg ^ (lane & 7)), rd1 = 8 * ((kg + 4) ^ (lane & 7));
    const int stgch = 8 * ((lane & 7) ^ (lane >> 3));
    const int srow = w * 8 + (lane >> 3);
    unsigned short* const lAp[2] = { LDS + wr * 8192, LDS + (2 + wr) * 8192 };
    unsigned short* const lBp[2] = { LDS + 32768 + (wc >> 1) * 8192,
                                     LDS + 32768 + (2 + (wc >> 1)) * 8192 };
    bf16x8 bfr[8];

    STG_B(0, 0); STG_B(0, 1); STG_A(0, 0); STG_A(0, 1); STG_B(1, 0); STG_B(1, 1);
    asm volatile("s_waitcnt vmcnt(4)" ::: "memory");
    __builtin_amdgcn_sched_barrier(0);
    __builtin_amdgcn_s_barrier();

    const int T = K >> 7;
    for (int t = 0; t < T; ++t) {
        const int s = 2 * t;
        const bool nl = (t < T - 1);
        PHASE(0, 0, STG_A(s + 1, 0), );
        PHASE(1, 0, STG_A(s + 1, 1), );
        PHASE(2, 0, if (nl) STG_B(s + 2, 0), );
        PHASE(3, 0, if (nl) STG_B(s + 2, 1),
              if (nl) { asm volatile("s_waitcnt vmcnt(4)" ::: "memory"); } else { asm volatile("s_waitcnt vmcnt(0)" ::: "memory"); } __builtin_amdgcn_sched_barrier(0); );
        PHASE(4, 1, if (nl) STG_A(s + 2, 0), );
        PHASE(5, 1, if (nl) STG_A(s + 2, 1), );
        PHASE(6, 1, if (nl) STG_B(s + 3, 0), );
        PHASE(7, 1, if (nl) STG_B(s + 3, 1),
              if (nl) { asm volatile("s_waitcnt vmcnt(4)" ::: "memory"); __builtin_amdgcn_sched_barrier(0); } );
    }

    const int r0 = (lane >> 4) * 4;
    #pragma unroll
    for (int n = 0; n < 4; ++n) {
        int colb = bn + wc * 64 + n * 16;
        float bv = bias[colb + fr];
        #pragma unroll
        for (int m = 0; m < 8; ++m) {
            int rowb = bm + wr * 128 + m * 16 + r0;
            if (EPI == 3) {
                unsigned short* qkvB = (unsigned short*)Cout;
                int which = colb >> 10, hh = (colb & 1023) >> 6, dbase = colb & 63;
                int b_ = rowb >> 11, s_ = rowb & 2047;
                long bh2 = b_ * 16 + hh;
                float v[4];
                #pragma unroll
                for (int r = 0; r < 4; ++r) v[r] = acc[m][n][r] + bv;
                if (which == 2) {
                    ushort4v pk;
                    #pragma unroll
                    for (int r = 0; r < 4; ++r) pk[r] = f2bs(v[r]);
                    *(ushort4v*)&qkvB[8388608L + (bh2 * 64 + dbase + fr) * 2048 + s_] = pk;
                } else {
                    unsigned short* dst = qkvB + (long)which * 4194304L +
                                          (bh2 * 2048 + s_) * 64 + dbase + fr;
                    #pragma unroll
                    for (int r = 0; r < 4; ++r) dst[r * 64] = f2bs(v[r]);
                }
            } else {
                #pragma unroll
                for (int r = 0; r < 4; ++r) {
                    long row = rowb + r, col = colb + fr;
                    float v = acc[m][n][r] + bv;
                    v = 0.5f * v * (1.0f + erff(v * 0.70710678118f));
                    ((__hip_bfloat16*)Cout)[row * N + col] = __float2bfloat16(v);
                }
            }
        }
    }
}

// ---------------- bf16 MFMA GEMM, 128x64 tile, 2-phase double-buffered ----------------
// T3-minimum schedule: stage(t+1 -> buf^1) issued BEFORE reads of buf; one
// vmcnt(0)+barrier per K-step (load latency hides under ds_read+MFMA).
__global__ __launch_bounds__(256)
void mm_mfma_n64(const unsigned short* __restrict__ A,
                 const unsigned short* __restrict__ BT,
                 const float* __restrict__ bias, const float* __restrict__ R,
                 float* __restrict__ Cout, int M, int N, int K) {
    __shared__ unsigned short As[2][128 * 32];
    __shared__ unsigned short Bs[2][64 * 32];
    const int tid = threadIdx.x;
    const int w = tid >> 6, lane = tid & 63;
    const int bm = blockIdx.y * 128, bn = blockIdx.x * 64;
    const int wr = (w >> 1) * 64, wc = (w & 1) * 32;

    f32x4 acc[4][2];
    #pragma unroll
    for (int m = 0; m < 4; ++m)
        #pragma unroll
        for (int n = 0; n < 2; ++n)
            acc[m][n] = (f32x4){0.f, 0.f, 0.f, 0.f};

    const int lrow = lane >> 2;
    const int lcol = (lane & 3) * 8;
    const unsigned short* gA = A + (long)(bm + w * 32 + lrow) * K + lcol;
    const unsigned short* gB = BT + (long)(bn + w * 16 + lrow) * K + lcol;

#define N64_STAGE(K0, BB) do { \
    gl_lds16(gA + (K0),          &As[BB][(w * 32) * 32]); \
    gl_lds16(gA + (K0) + 16 * K, &As[BB][(w * 32 + 16) * 32]); \
    gl_lds16(gB + (K0),          &Bs[BB][(w * 16) * 32]); \
} while (0)

    N64_STAGE(0, 0);
    asm volatile("s_waitcnt vmcnt(0)" ::: "memory");
    __builtin_amdgcn_sched_barrier(0);
    __builtin_amdgcn_s_barrier();

    const int T = K >> 5;
    for (int t = 0; t < T; ++t) {
        const int buf = t & 1;
        if (t + 1 < T) N64_STAGE((t + 1) * 32, buf ^ 1);

        bf16x8 a[4], b[2];
        #pragma unroll
        for (int m = 0; m < 4; ++m)
            a[m] = *(const bf16x8*)&As[buf][(wr + m * 16 + (lane & 15)) * 32 + (lane >> 4) * 8];
        #pragma unroll
        for (int n = 0; n < 2; ++n)
            b[n] = *(const bf16x8*)&Bs[buf][(wc + n * 16 + (lane & 15)) * 32 + (lane >> 4) * 8];
        #pragma unroll
        for (int m = 0; m < 4; ++m)
            #pragma unroll
            for (int n = 0; n < 2; ++n)
                acc[m][n] = __builtin_amdgcn_mfma_f32_16x16x32_bf16(a[m], b[n], acc[m][n], 0, 0, 0);

        asm volatile("s_waitcnt vmcnt(0)" ::: "memory");
        __builtin_amdgcn_sched_barrier(0);
        __builtin_amdgcn_s_barrier();
    }
#undef N64_STAGE

    const int r0 = (lane >> 4) * 4, cc = lane & 15;
    #pragma unroll
    for (int n = 0; n < 2; ++n) {
        int colb = bn + wc + n * 16;
        float bv = bias[colb + cc];
        #pragma unroll
        for (int m = 0; m < 4; ++m) {
            int rowb = bm + wr + m * 16 + r0;
            #pragma unroll
            for (int r = 0; r < 4; ++r) {
                long row = rowb + r, col = colb + cc;
                float v = acc[m][n][r] + bv + R[row * N + col];
                Cout[row * N + col] = v;
            }
        }
    }
}

// ---------------- MFMA flash attention body, KVBLK=128 (dynamic smem 48K) ----------------
__device__ void attn_body(char* smem, int bh, int qb,
                          const unsigned short* __restrict__ qB,
                          const unsigned short* __restrict__ kB,
                          const unsigned short* __restrict__ vT,
                          __hip_bfloat16* __restrict__ z) {
    const int tid = threadIdx.x, w = tid >> 6, lane = tid & 63;
    const int arow = lane & 15, kg = lane >> 4;
    unsigned short* Ks = (unsigned short*)smem;
    unsigned short* Vs = Ks + 128 * 64;
    unsigned short* Ps = Vs + 64 * 128 + w * 16 * 128;

    const long kvbase = (long)bh * (2048 * 64);

    bf16x8 qa[2];
    {
        const unsigned short* q0 = qB + kvbase + (long)(qb + w * 16 + arow) * 64 + kg * 8;
        qa[0] = *(const bf16x8*)(q0);
        qa[1] = *(const bf16x8*)(q0 + 32);
    }

    f32x4 po[4];
    float mrow[4], lrow[4];
    #pragma unroll
    for (int i = 0; i < 4; ++i) {
        po[i] = (f32x4){0.f, 0.f, 0.f, 0.f};
        mrow[i] = -1e30f; lrow[i] = 0.f;
    }

    const int ksrow = lane >> 3;
    const int kschunk = (lane & 7) ^ ksrow;
    const int vsr = lane >> 4;
    const int cmax = qb >> 7;

    for (int c = 0; c <= cmax; ++c) {
        {
            const unsigned short* ks0 = kB + kvbase +
                (long)(c * 128 + w * 32 + ksrow) * 64 + kschunk * 8;
            #pragma unroll
            for (int i = 0; i < 4; ++i)
                gl_lds16(ks0 + (long)i * 8 * 64, &Ks[(w * 32 + i * 8) * 64]);
            #pragma unroll
            for (int i = 0; i < 4; ++i) {
                int d = w * 16 + i * 4 + vsr;
                int sch = (lane & 15) ^ (d & 7);
                gl_lds16(vT + kvbase + (long)d * 2048 + c * 128 + sch * 8,
                         &Vs[(w * 16 + i * 4) * 128]);
            }
        }
        __syncthreads();

        f32x4 s[8];
        #pragma unroll
        for (int n = 0; n < 8; ++n) {
            s[n] = (f32x4){0.f, 0.f, 0.f, 0.f};
            int row = n * 16 + arow, sw = row & 7;
            bf16x8 kb0 = *(const bf16x8*)&Ks[row * 64 + (kg ^ sw) * 8];
            bf16x8 kb1 = *(const bf16x8*)&Ks[row * 64 + ((4 + kg) ^ sw) * 8];
            s[n] = __builtin_amdgcn_mfma_f32_16x16x32_bf16(qa[0], kb0, s[n], 0, 0, 0);
            s[n] = __builtin_amdgcn_mfma_f32_16x16x32_bf16(qa[1], kb1, s[n], 0, 0, 0);
        }

        const bool diag = (c == cmax);
        #pragma unroll
        for (int n = 0; n < 8; ++n)
            #pragma unroll
            for (int r = 0; r < 4; ++r) {
                float v = s[n][r] * 0.125f;
                if (diag) {
                    int key = c * 128 + n * 16 + arow;
                    int qrow = qb + w * 16 + kg * 4 + r;
                    if (key > qrow) v = -1e30f;
                }
                s[n][r] = v;
            }

        #pragma unroll
        for (int r = 0; r < 4; ++r) {
            float rm = s[0][r];
            #pragma unroll
            for (int n = 1; n < 8; ++n) rm = fmaxf(rm, s[n][r]);
            #pragma unroll
            for (int off = 1; off < 16; off <<= 1)
                rm = fmaxf(rm, __shfl_xor(rm, off));
            float mnew = fmaxf(mrow[r], rm);
            float esc = expf(mrow[r] - mnew);
            float rs = 0.f;
            #pragma unroll
            for (int n = 0; n < 8; ++n) {
                float p = expf(s[n][r] - mnew);
                s[n][r] = p;
                rs += p;
            }
            #pragma unroll
            for (int off = 1; off < 16; off <<= 1)
                rs += __shfl_xor(rs, off);
            lrow[r] = lrow[r] * esc + rs;
            #pragma unroll
            for (int dt = 0; dt < 4; ++dt) po[dt][r] *= esc;
            mrow[r] = mnew;
        }

        #pragma unroll
        for (int n = 0; n < 8; ++n) {
            int col = n * 16 + arow;
            int chunk = col >> 3, cw = col & 7;
            #pragma unroll
            for (int r = 0; r < 4; ++r) {
                int row = kg * 4 + r;
                Ps[row * 128 + ((chunk ^ (row & 7)) * 8 + cw)] = f2bs(s[n][r]);
            }
        }

        bf16x8 pa[4];
        #pragma unroll
        for (int ks = 0; ks < 4; ++ks)
            pa[ks] = *(const bf16x8*)&Ps[arow * 128 + (((ks * 4 + kg) ^ (arow & 7)) * 8)];
        #pragma unroll
        for (int dt = 0; dt < 4; ++dt) {
            int vrow = dt * 16 + arow, sw = vrow & 7;
            #pragma unroll
            for (int ks = 0; ks < 4; ++ks) {
                bf16x8 vb = *(const bf16x8*)&Vs[vrow * 128 + (((ks * 4 + kg) ^ sw) * 8)];
                po[dt] = __builtin_amdgcn_mfma_f32_16x16x32_bf16(pa[ks], vb, po[dt], 0, 0, 0);
            }
        }
        __syncthreads();
    }

    const int b_ = bh >> 4, hofs = (bh & 15) * 64;
    #pragma unroll
    for (int dt = 0; dt < 4; ++dt)
        #pragma unroll
        for (int r = 0; r < 4; ++r) {
            long row = (long)b_ * 2048 + qb + w * 16 + kg * 4 + r;
            z[row * 1024 + hofs + dt * 16 + arow] = __float2bfloat16(po[dt][r] / lrow[r]);
        }
}

// ---------------- fused kernels ----------------
__global__ __launch_bounds__(256)
void fused_ln_convT(const float* __restrict__ h, unsigned short* __restrict__ y,
                    const float* __restrict__ g, const float* __restrict__ b,
                    const float* __restrict__ W, unsigned short* __restrict__ WT,
                    int K, int N, int nLN) {
    extern __shared__ char smem[];
    int bid = blockIdx.x;
    if (bid < nLN) {
        ln_body(smem, bid, h, y, g, b);
    } else {
        int r = bid - nLN, kt = K >> 6;
        convT_body(smem, r % kt, r / kt, W, WT, K, N);
    }
}

__global__ __launch_bounds__(256)
void fused_attn_convT2(const unsigned short* __restrict__ qB,
                       const unsigned short* __restrict__ kB,
                       const unsigned short* __restrict__ vT,
                       __hip_bfloat16* __restrict__ z,
                       const float* __restrict__ W1, unsigned short* __restrict__ WT1,
                       int K1, int N1, int n1,
                       const float* __restrict__ W2, unsigned short* __restrict__ WT2,
                       int K2, int N2, int nAttn) {
    extern __shared__ char smem[];
    int bid = blockIdx.x;
    if (bid < nAttn) {
        attn_body(smem, bid & 31, (bid >> 5) * 64, qB, kB, vT, z);
    } else if (bid < nAttn + n1) {
        int r = bid - nAttn, kt = K1 >> 6;
        convT_body(smem, r % kt, r / kt, W1, WT1, K1, N1);
    } else {
        int r = bid - nAttn - n1, kt = K2 >> 6;
        convT_body(smem, r % kt, r / kt, W2, WT2, K2, N2);
    }
}

// ---------------- head ----------------
__global__ void head_kernel(const float* __restrict__ hl, const float* __restrict__ W,
                            float* __restrict__ out) {
    __shared__ float hs[2 * DMODEL];
    int tid = threadIdx.x;
    #pragma unroll
    for (int i = 0; i < 8; ++i) hs[tid + i * 256] = hl[tid + i * 256];
    __syncthreads();
    int v = blockIdx.x * 256 + tid;
    if (v >= VOCAB) return;
    float a0 = 0.f, a1 = 0.f;
    for (int d = 0; d < DMODEL; ++d) {
        float wv = W[(long)d * VOCAB + v];
        a0 += hs[d] * wv;
        a1 += hs[DMODEL + d] * wv;
    }
    out[v] = a0;
    out[VOCAB + v] = a1;
}

extern "C" void kernel_launch(void* const* d_in, const int* in_sizes, int n_in,
                              void* d_out, int out_size, void* d_ws, size_t ws_size,
                              hipStream_t stream) {
    const int*   x      = (const int*)  d_in[0];
    const float* wte    = (const float*)d_in[1];
    const float* wpe    = (const float*)d_in[2];
    const float* ln1_g  = (const float*)d_in[3];
    const float* ln1_b  = (const float*)d_in[4];
    const float* w_qkv  = (const float*)d_in[5];
    const float* b_qkv  = (const float*)d_in[6];
    const float* w_proj = (const float*)d_in[7];
    const float* b_proj = (const float*)d_in[8];
    const float* ln2_g  = (const float*)d_in[9];
    const float* ln2_b  = (const float*)d_in[10];
    const float* w_fc   = (const float*)d_in[11];
    const float* b_fc   = (const float*)d_in[12];
    const float* w_cp   = (const float*)d_in[13];
    const float* b_cp   = (const float*)d_in[14];
    const float* lnf_g  = (const float*)d_in[15];
    const float* lnf_b  = (const float*)d_in[16];
    const float* w_head = (const float*)d_in[17];
    float* out = (float*)d_out;

    char* ws = (char*)d_ws;
    float*          h     = (float*)ws;                             // 16 MB
    unsigned short* qkvB  = (unsigned short*)(ws + (16L << 20));    // 24 MB
    unsigned short* y_bf  = (unsigned short*)(ws + (40L << 20));    // 8 MB
    __hip_bfloat16* z_bf  = (__hip_bfloat16*)(ws + (48L << 20));    // 8 MB
    unsigned short* fc_bf = (unsigned short*)(ws + (56L << 20));    // 32 MB
    unsigned short* wT_a  = (unsigned short*)(ws + (88L << 20));    // 8 MB
    unsigned short* wT_b  = (unsigned short*)(ws + (97L << 20));    // 8 MB (proj)
    unsigned short* wT_c  = (unsigned short*)(ws + (106L << 20));   // 8 MB (cp)
    float*          hl    = (float*)(ws + (115L << 20));            // 8 KB

    const int SM_CONV = 16640;   // 64*65*4
    const int SM_ATTN = 49152;   // Ks+Vs+Ps

    embed_kernel<<<NTOK, 256, 0, stream>>>(x, wte, wpe, h);

    for (int l = 0; l < NLAYER; ++l) {
        // A: LN1 (4096) + convT qkv (768) -> wT_a
        fused_ln_convT<<<4096 + 768, 256, SM_CONV, stream>>>(
            h, y_bf, ln1_g + l * DMODEL, ln1_b + l * DMODEL,
            w_qkv + (long)l * DMODEL * 3072, wT_a, 1024, 3072, 4096);

        // B: qkv GEMM (256^2 8-phase)
        mm_mfma256<3><<<192, 512, 131072, stream>>>(
            y_bf, wT_a, b_qkv + l * 3072, qkvB, NTOK, 3072, 1024, 12);

        // C: attn (1024) + convT proj (256) -> wT_b + convT cp (1024) -> wT_c
        fused_attn_convT2<<<1024 + 256 + 1024, 256, SM_ATTN, stream>>>(
            qkvB, qkvB + 4194304L, qkvB + 8388608L, z_bf,
            w_proj + (long)l * DMODEL * DMODEL, wT_b, 1024, 1024, 256,
            w_cp + (long)l * 4096 * DMODEL, wT_c, 4096, 1024, 1024);

        // D: proj GEMM (+residual)
        mm_mfma_n64<<<dim3(16, 32), 256, 0, stream>>>(
            (const unsigned short*)z_bf, wT_b, b_proj + l * DMODEL, h, h,
            NTOK, 1024, 1024);

        // E: LN2 (4096) + convT fc (1024) -> wT_a
        fused_ln_convT<<<4096 + 1024, 256, SM_CONV, stream>>>(
            h, y_bf, ln2_g + l * DMODEL, ln2_b + l * DMODEL,
            w_fc + (long)l * DMODEL * 4096, wT_a, 1024, 4096, 4096);

        // F: fc GEMM (256^2 8-phase, gelu)
        mm_mfma256<2><<<256, 512, 131072, stream>>>(
            y_bf, wT_a, b_fc + l * 4096, fc_bf, NTOK, 4096, 1024, 16);

        // G: cp GEMM (+residual)
        mm_mfma_n64<<<dim3(16, 32), 256, 0, stream>>>(
            fc_bf, wT_c, b_cp + l * DMODEL, h, h, NTOK, 1024, 4096);
    }

    ln_final<<<BATCH, 256, 0, stream>>>(h + (long)(SEQ - 1) * DMODEL, hl,
                                        lnf_g, lnf_b, (long)SEQ * DMODEL);
    head_kernel<<<(VOCAB + 255) / 256, 256, 0, stream>>>(hl, w_head, out);
}

// Round 13
// 2426.104 us; speedup vs baseline: 1.2995x; 1.0310x over previous
//
#include <hip/hip_runtime.h>
#include <hip/hip_bf16.h>
#include <math.h>

#define VOCAB 50257
#define CTX 2048
#define DMODEL 1024
#define NHEAD 16
#define NLAYER 8
#define DHEAD 64
#define BATCH 2
#define SEQ 2048
#define NTOK (BATCH * SEQ)   // 4096

typedef __bf16 bf16x8 __attribute__((ext_vector_type(8)));
typedef float  f32x4  __attribute__((ext_vector_type(4)));
typedef unsigned short ushort4v __attribute__((ext_vector_type(4)));
typedef unsigned short ushort8v __attribute__((ext_vector_type(8)));

__device__ inline void gl_lds16(const void* g, void* l) {
    __builtin_amdgcn_global_load_lds(
        (const __attribute__((address_space(1))) unsigned int*)g,
        (__attribute__((address_space(3))) unsigned int*)l, 16, 0, 0);
}

__device__ inline unsigned short f2bs(float v) {
    __hip_bfloat16 t = __float2bfloat16(v);
    return *(unsigned short*)&t;
}

// ---------------- embedding body ----------------
__device__ void embed_body(int t, const int* __restrict__ x,
                           const float* __restrict__ wte,
                           const float* __restrict__ wpe,
                           float* __restrict__ h) {
    int s = t & (SEQ - 1);
    int tok = x[t];
    const float* pe = wpe + (long)s * DMODEL;
    const float* te = wte + (long)tok * DMODEL;
    float* ph = h + (long)t * DMODEL;
    for (int d = threadIdx.x; d < DMODEL; d += 256)
        ph[d] = te[d] + pe[d];
}

// ---------------- layernorm ----------------
__device__ inline float wave_sum(float v) {
    for (int off = 32; off; off >>= 1) v += __shfl_xor(v, off);
    return v;
}

// standalone LN (f32 in -> bf16 out), static smem
__global__ void ln_std(const float* __restrict__ in, unsigned short* __restrict__ out,
                       const float* __restrict__ g, const float* __restrict__ b) {
    __shared__ float red[4], red2[4];
    int row = blockIdx.x;
    const float* px = in + (long)row * DMODEL;
    unsigned short* po = out + (long)row * DMODEL;
    int tid = threadIdx.x;
    int wid = tid >> 6, lane = tid & 63;

    float x[4];
    float s = 0.f;
    #pragma unroll
    for (int i = 0; i < 4; ++i) { x[i] = px[tid + i * 256]; s += x[i]; }
    s = wave_sum(s);
    if (lane == 0) red[wid] = s;
    __syncthreads();
    float mean = (red[0] + red[1] + red[2] + red[3]) * (1.0f / DMODEL);

    float s2 = 0.f;
    #pragma unroll
    for (int i = 0; i < 4; ++i) { float d = x[i] - mean; s2 += d * d; }
    s2 = wave_sum(s2);
    if (lane == 0) red2[wid] = s2;
    __syncthreads();
    float var = (red2[0] + red2[1] + red2[2] + red2[3]) * (1.0f / DMODEL);
    float r = 1.0f / sqrtf(var + 1e-5f);
    #pragma unroll
    for (int i = 0; i < 4; ++i) {
        int d = tid + i * 256;
        po[d] = f2bs((x[i] - mean) * r * g[d] + b[d]);
    }
}

__global__ void ln_final(const float* __restrict__ in, float* __restrict__ out,
                         const float* __restrict__ g, const float* __restrict__ b,
                         long row_stride) {
    __shared__ float red[4], red2[4];
    int row = blockIdx.x;
    const float* px = in + (long)row * row_stride;
    float* po = out + (long)row * DMODEL;
    int tid = threadIdx.x;
    int wid = tid >> 6, lane = tid & 63;
    float x[4];
    float s = 0.f;
    #pragma unroll
    for (int i = 0; i < 4; ++i) { x[i] = px[tid + i * 256]; s += x[i]; }
    s = wave_sum(s);
    if (lane == 0) red[wid] = s;
    __syncthreads();
    float mean = (red[0] + red[1] + red[2] + red[3]) * (1.0f / DMODEL);
    float s2 = 0.f;
    #pragma unroll
    for (int i = 0; i < 4; ++i) { float d = x[i] - mean; s2 += d * d; }
    s2 = wave_sum(s2);
    if (lane == 0) red2[wid] = s2;
    __syncthreads();
    float var = (red2[0] + red2[1] + red2[2] + red2[3]) * (1.0f / DMODEL);
    float r = 1.0f / sqrtf(var + 1e-5f);
    #pragma unroll
    for (int i = 0; i < 4; ++i) {
        int d = tid + i * 256;
        po[d] = (x[i] - mean) * r * g[d] + b[d];
    }
}

// ------------- transpose+convert body: W f32 [K][N] -> WT bf16 [N][K] -------------
__device__ void convT_body(char* smem, int kx, int ny, const float* __restrict__ W,
                           unsigned short* __restrict__ WT, int K, int N) {
    float (*t)[65] = (float(*)[65])smem;
    const int k0 = kx * 64, n0 = ny * 64;
    const int tid = threadIdx.x;
    {
        const int krow = tid >> 4, c4 = (tid & 15) * 4;
        #pragma unroll
        for (int p = 0; p < 4; ++p) {
            f32x4 gv = *(const f32x4*)&W[(long)(k0 + p * 16 + krow) * N + n0 + c4];
            #pragma unroll
            for (int j = 0; j < 4; ++j) t[p * 16 + krow][c4 + j] = gv[j];
        }
    }
    __syncthreads();
    {
        const int n = tid >> 3, kl = (tid & 7) * 8;
        #pragma unroll
        for (int p = 0; p < 2; ++p) {
            ushort8v pk;
            #pragma unroll
            for (int j = 0; j < 8; ++j) pk[j] = f2bs(t[kl + j][p * 32 + n]);
            *(ushort8v*)&WT[(long)(n0 + p * 32 + n) * K + k0 + kl] = pk;
        }
    }
}

// ---------------- 256^2 8-phase bf16 MFMA GEMM ----------------
#define STG_A(KS, H) do { \
    const unsigned short* g_ = A + (long)(bm + (H) * 128 + srow) * K + (KS) * 64 + stgch; \
    unsigned short* s_ = LDS + (((KS) & 1) * 2 + (H)) * 8192 + (w * 8) * 64; \
    gl_lds16(g_, s_); gl_lds16(g_ + 64L * K, s_ + 4096); \
} while (0)
#define STG_B(KS, H) do { \
    const unsigned short* g_ = BT + (long)(bn + (H) * 128 + srow) * K + (KS) * 64 + stgch; \
    unsigned short* s_ = LDS + 32768 + (((KS) & 1) * 2 + (H)) * 8192 + (w * 8) * 64; \
    gl_lds16(g_, s_); gl_lds16(g_ + 64L * K, s_ + 4096); \
} while (0)
#define MM2(M_, x0, x1) do { \
    acc[M_][0] = __builtin_amdgcn_mfma_f32_16x16x32_bf16(x0, bfr[0], acc[M_][0], 0, 0, 0); \
    acc[M_][0] = __builtin_amdgcn_mfma_f32_16x16x32_bf16(x1, bfr[1], acc[M_][0], 0, 0, 0); \
    acc[M_][1] = __builtin_amdgcn_mfma_f32_16x16x32_bf16(x0, bfr[2], acc[M_][1], 0, 0, 0); \
    acc[M_][1] = __builtin_amdgcn_mfma_f32_16x16x32_bf16(x1, bfr[3], acc[M_][1], 0, 0, 0); \
    acc[M_][2] = __builtin_amdgcn_mfma_f32_16x16x32_bf16(x0, bfr[4], acc[M_][2], 0, 0, 0); \
    acc[M_][2] = __builtin_amdgcn_mfma_f32_16x16x32_bf16(x1, bfr[5], acc[M_][2], 0, 0, 0); \
    acc[M_][3] = __builtin_amdgcn_mfma_f32_16x16x32_bf16(x0, bfr[6], acc[M_][3], 0, 0, 0); \
    acc[M_][3] = __builtin_amdgcn_mfma_f32_16x16x32_bf16(x1, bfr[7], acc[M_][3], 0, 0, 0); \
} while (0)
#define PHASE(Q, SPAR, STAGE_STMT, TAIL_STMT) do { \
    bf16x8 a00, a01, a10, a11; \
    if (((Q) & 3) == 0) { \
        const unsigned short* Bb_ = lBp[SPAR] + ((wc & 1) * 64 + fr) * 64; \
        bfr[0] = *(const bf16x8*)(Bb_ + rd0);        bfr[1] = *(const bf16x8*)(Bb_ + rd1); \
        bfr[2] = *(const bf16x8*)(Bb_ + 1024 + rd0); bfr[3] = *(const bf16x8*)(Bb_ + 1024 + rd1); \
        bfr[4] = *(const bf16x8*)(Bb_ + 2048 + rd0); bfr[5] = *(const bf16x8*)(Bb_ + 2048 + rd1); \
        bfr[6] = *(const bf16x8*)(Bb_ + 3072 + rd0); bfr[7] = *(const bf16x8*)(Bb_ + 3072 + rd1); \
    } \
    { const unsigned short* Ab_ = lAp[SPAR] + fr * 64; \
      a00 = *(const bf16x8*)(Ab_ + (((Q) & 3) * 2) * 1024 + rd0); \
      a01 = *(const bf16x8*)(Ab_ + (((Q) & 3) * 2) * 1024 + rd1); \
      a10 = *(const bf16x8*)(Ab_ + (((Q) & 3) * 2 + 1) * 1024 + rd0); \
      a11 = *(const bf16x8*)(Ab_ + (((Q) & 3) * 2 + 1) * 1024 + rd1); } \
    STAGE_STMT; \
    __builtin_amdgcn_s_barrier(); \
    asm volatile("s_waitcnt lgkmcnt(0)" ::: "memory"); \
    __builtin_amdgcn_sched_barrier(0); \
    __builtin_amdgcn_s_setprio(1); \
    MM2(((Q) & 3) * 2, a00, a01); \
    MM2(((Q) & 3) * 2 + 1, a10, a11); \
    __builtin_amdgcn_s_setprio(0); \
    TAIL_STMT; \
    __builtin_amdgcn_s_barrier(); \
} while (0)

template<int EPI>
__global__ __launch_bounds__(512, 1)
void mm_mfma256(const unsigned short* __restrict__ A,
                const unsigned short* __restrict__ BT,
                const float* __restrict__ bias,
                void* __restrict__ Cout, int M, int N, int K, int nbx) {
    extern __shared__ unsigned short LDS[];
    const int tid = threadIdx.x;
    const int w = tid >> 6, lane = tid & 63;
    const int wr = w >> 2, wc = w & 3;
    const int nwg = gridDim.x, bid = blockIdx.x;
    const int swz = (bid & 7) * (nwg >> 3) + (bid >> 3);
    const int bm = (swz / nbx) * 256, bn = (swz % nbx) * 256;

    f32x4 acc[8][4];
    #pragma unroll
    for (int m = 0; m < 8; ++m)
        #pragma unroll
        for (int n = 0; n < 4; ++n)
            acc[m][n] = (f32x4){0.f, 0.f, 0.f, 0.f};

    const int fr = lane & 15, kg = lane >> 4;
    const int rd0 = 8 * (kg ^ (lane & 7)), rd1 = 8 * ((kg + 4) ^ (lane & 7));
    const int stgch = 8 * ((lane & 7) ^ (lane >> 3));
    const int srow = w * 8 + (lane >> 3);
    unsigned short* const lAp[2] = { LDS + wr * 8192, LDS + (2 + wr) * 8192 };
    unsigned short* const lBp[2] = { LDS + 32768 + (wc >> 1) * 8192,
                                     LDS + 32768 + (2 + (wc >> 1)) * 8192 };
    bf16x8 bfr[8];

    STG_B(0, 0); STG_B(0, 1); STG_A(0, 0); STG_A(0, 1); STG_B(1, 0); STG_B(1, 1);
    asm volatile("s_waitcnt vmcnt(4)" ::: "memory");
    __builtin_amdgcn_sched_barrier(0);
    __builtin_amdgcn_s_barrier();

    const int T = K >> 7;
    for (int t = 0; t < T; ++t) {
        const int s = 2 * t;
        const bool nl = (t < T - 1);
        PHASE(0, 0, STG_A(s + 1, 0), );
        PHASE(1, 0, STG_A(s + 1, 1), );
        PHASE(2, 0, if (nl) STG_B(s + 2, 0), );
        PHASE(3, 0, if (nl) STG_B(s + 2, 1),
              if (nl) { asm volatile("s_waitcnt vmcnt(4)" ::: "memory"); } else { asm volatile("s_waitcnt vmcnt(0)" ::: "memory"); } __builtin_amdgcn_sched_barrier(0); );
        PHASE(4, 1, if (nl) STG_A(s + 2, 0), );
        PHASE(5, 1, if (nl) STG_A(s + 2, 1), );
        PHASE(6, 1, if (nl) STG_B(s + 3, 0), );
        PHASE(7, 1, if (nl) STG_B(s + 3, 1),
              if (nl) { asm volatile("s_waitcnt vmcnt(4)" ::: "memory"); __builtin_amdgcn_sched_barrier(0); } );
    }

    const int r0 = (lane >> 4) * 4;
    #pragma unroll
    for (int n = 0; n < 4; ++n) {
        int colb = bn + wc * 64 + n * 16;
        float bv = bias[colb + fr];
        #pragma unroll
        for (int m = 0; m < 8; ++m) {
            int rowb = bm + wr * 128 + m * 16 + r0;
            if (EPI == 3) {
                unsigned short* qkvB = (unsigned short*)Cout;
                int which = colb >> 10, hh = (colb & 1023) >> 6, dbase = colb & 63;
                int b_ = rowb >> 11, s_ = rowb & 2047;
                long bh2 = b_ * 16 + hh;
                float v[4];
                #pragma unroll
                for (int r = 0; r < 4; ++r) v[r] = acc[m][n][r] + bv;
                if (which == 2) {
                    ushort4v pk;
                    #pragma unroll
                    for (int r = 0; r < 4; ++r) pk[r] = f2bs(v[r]);
                    *(ushort4v*)&qkvB[8388608L + (bh2 * 64 + dbase + fr) * 2048 + s_] = pk;
                } else {
                    unsigned short* dst = qkvB + (long)which * 4194304L +
                                          (bh2 * 2048 + s_) * 64 + dbase + fr;
                    #pragma unroll
                    for (int r = 0; r < 4; ++r) dst[r * 64] = f2bs(v[r]);
                }
            } else {
                #pragma unroll
                for (int r = 0; r < 4; ++r) {
                    long row = rowb + r, col = colb + fr;
                    float v = acc[m][n][r] + bv;
                    v = 0.5f * v * (1.0f + erff(v * 0.70710678118f));
                    ((__hip_bfloat16*)Cout)[row * N + col] = __float2bfloat16(v);
                }
            }
        }
    }
}

// ---------------- n64 GEMM body (2-phase dbuf), dynamic smem 24KB ----------------
__device__ void n64_body(char* smem, int bx, int by,
                         const unsigned short* __restrict__ A,
                         const unsigned short* __restrict__ BT,
                         const float* __restrict__ bias, const float* __restrict__ R,
                         float* __restrict__ Cout, int M, int N, int K) {
    unsigned short* As = (unsigned short*)smem;          // [2][128*32]
    unsigned short* Bs = As + 2 * 128 * 32;              // [2][64*32]
    const int tid = threadIdx.x;
    const int w = tid >> 6, lane = tid & 63;
    const int bm = by * 128, bn = bx * 64;
    const int wr = (w >> 1) * 64, wc = (w & 1) * 32;

    f32x4 acc[4][2];
    #pragma unroll
    for (int m = 0; m < 4; ++m)
        #pragma unroll
        for (int n = 0; n < 2; ++n)
            acc[m][n] = (f32x4){0.f, 0.f, 0.f, 0.f};

    const int lrow = lane >> 2;
    const int lcol = (lane & 3) * 8;
    const unsigned short* gA = A + (long)(bm + w * 32 + lrow) * K + lcol;
    const unsigned short* gB = BT + (long)(bn + w * 16 + lrow) * K + lcol;

#define N64_STAGE(K0, BB) do { \
    gl_lds16(gA + (K0),          &As[(BB) * 4096 + (w * 32) * 32]); \
    gl_lds16(gA + (K0) + 16 * K, &As[(BB) * 4096 + (w * 32 + 16) * 32]); \
    gl_lds16(gB + (K0),          &Bs[(BB) * 2048 + (w * 16) * 32]); \
} while (0)

    N64_STAGE(0, 0);
    asm volatile("s_waitcnt vmcnt(0)" ::: "memory");
    __builtin_amdgcn_sched_barrier(0);
    __builtin_amdgcn_s_barrier();

    const int T = K >> 5;
    for (int t = 0; t < T; ++t) {
        const int buf = t & 1;
        if (t + 1 < T) N64_STAGE((t + 1) * 32, buf ^ 1);

        bf16x8 a[4], b[2];
        #pragma unroll
        for (int m = 0; m < 4; ++m)
            a[m] = *(const bf16x8*)&As[buf * 4096 + (wr + m * 16 + (lane & 15)) * 32 + (lane >> 4) * 8];
        #pragma unroll
        for (int n = 0; n < 2; ++n)
            b[n] = *(const bf16x8*)&Bs[buf * 2048 + (wc + n * 16 + (lane & 15)) * 32 + (lane >> 4) * 8];
        #pragma unroll
        for (int m = 0; m < 4; ++m)
            #pragma unroll
            for (int n = 0; n < 2; ++n)
                acc[m][n] = __builtin_amdgcn_mfma_f32_16x16x32_bf16(a[m], b[n], acc[m][n], 0, 0, 0);

        asm volatile("s_waitcnt vmcnt(0)" ::: "memory");
        __builtin_amdgcn_sched_barrier(0);
        __builtin_amdgcn_s_barrier();
    }
#undef N64_STAGE

    const int r0 = (lane >> 4) * 4, cc = lane & 15;
    #pragma unroll
    for (int n = 0; n < 2; ++n) {
        int colb = bn + wc + n * 16;
        float bv = bias[colb + cc];
        #pragma unroll
        for (int m = 0; m < 4; ++m) {
            int rowb = bm + wr + m * 16 + r0;
            #pragma unroll
            for (int r = 0; r < 4; ++r) {
                long row = rowb + r, col = colb + cc;
                float v = acc[m][n][r] + bv + R[row * N + col];
                Cout[row * N + col] = v;
            }
        }
    }
}

// ---------------- MFMA flash attention body, KVBLK=128 (dynamic smem 48K) ----------------
__device__ void attn_body(char* smem, int bh, int qb,
                          const unsigned short* __restrict__ qB,
                          const unsigned short* __restrict__ kB,
                          const unsigned short* __restrict__ vT,
                          __hip_bfloat16* __restrict__ z) {
    const int tid = threadIdx.x, w = tid >> 6, lane = tid & 63;
    const int arow = lane & 15, kg = lane >> 4;
    unsigned short* Ks = (unsigned short*)smem;
    unsigned short* Vs = Ks + 128 * 64;
    unsigned short* Ps = Vs + 64 * 128 + w * 16 * 128;

    const long kvbase = (long)bh * (2048 * 64);

    bf16x8 qa[2];
    {
        const unsigned short* q0 = qB + kvbase + (long)(qb + w * 16 + arow) * 64 + kg * 8;
        qa[0] = *(const bf16x8*)(q0);
        qa[1] = *(const bf16x8*)(q0 + 32);
    }

    f32x4 po[4];
    float mrow[4], lrow[4];
    #pragma unroll
    for (int i = 0; i < 4; ++i) {
        po[i] = (f32x4){0.f, 0.f, 0.f, 0.f};
        mrow[i] = -1e30f; lrow[i] = 0.f;
    }

    const int ksrow = lane >> 3;
    const int kschunk = (lane & 7) ^ ksrow;
    const int vsr = lane >> 4;
    const int cmax = qb >> 7;

    for (int c = 0; c <= cmax; ++c) {
        {
            const unsigned short* ks0 = kB + kvbase +
                (long)(c * 128 + w * 32 + ksrow) * 64 + kschunk * 8;
            #pragma unroll
            for (int i = 0; i < 4; ++i)
                gl_lds16(ks0 + (long)i * 8 * 64, &Ks[(w * 32 + i * 8) * 64]);
            #pragma unroll
            for (int i = 0; i < 4; ++i) {
                int d = w * 16 + i * 4 + vsr;
                int sch = (lane & 15) ^ (d & 7);
                gl_lds16(vT + kvbase + (long)d * 2048 + c * 128 + sch * 8,
                         &Vs[(w * 16 + i * 4) * 128]);
            }
        }
        __syncthreads();

        f32x4 s[8];
        #pragma unroll
        for (int n = 0; n < 8; ++n) {
            s[n] = (f32x4){0.f, 0.f, 0.f, 0.f};
            int row = n * 16 + arow, sw = row & 7;
            bf16x8 kb0 = *(const bf16x8*)&Ks[row * 64 + (kg ^ sw) * 8];
            bf16x8 kb1 = *(const bf16x8*)&Ks[row * 64 + ((4 + kg) ^ sw) * 8];
            s[n] = __builtin_amdgcn_mfma_f32_16x16x32_bf16(qa[0], kb0, s[n], 0, 0, 0);
            s[n] = __builtin_amdgcn_mfma_f32_16x16x32_bf16(qa[1], kb1, s[n], 0, 0, 0);
        }

        const bool diag = (c == cmax);
        #pragma unroll
        for (int n = 0; n < 8; ++n)
            #pragma unroll
            for (int r = 0; r < 4; ++r) {
                float v = s[n][r] * 0.125f;
                if (diag) {
                    int key = c * 128 + n * 16 + arow;
                    int qrow = qb + w * 16 + kg * 4 + r;
                    if (key > qrow) v = -1e30f;
                }
                s[n][r] = v;
            }

        #pragma unroll
        for (int r = 0; r < 4; ++r) {
            float rm = s[0][r];
            #pragma unroll
            for (int n = 1; n < 8; ++n) rm = fmaxf(rm, s[n][r]);
            #pragma unroll
            for (int off = 1; off < 16; off <<= 1)
                rm = fmaxf(rm, __shfl_xor(rm, off));
            float mnew = fmaxf(mrow[r], rm);
            float esc = expf(mrow[r] - mnew);
            float rs = 0.f;
            #pragma unroll
            for (int n = 0; n < 8; ++n) {
                float p = expf(s[n][r] - mnew);
                s[n][r] = p;
                rs += p;
            }
            #pragma unroll
            for (int off = 1; off < 16; off <<= 1)
                rs += __shfl_xor(rs, off);
            lrow[r] = lrow[r] * esc + rs;
            #pragma unroll
            for (int dt = 0; dt < 4; ++dt) po[dt][r] *= esc;
            mrow[r] = mnew;
        }

        #pragma unroll
        for (int n = 0; n < 8; ++n) {
            int col = n * 16 + arow;
            int chunk = col >> 3, cw = col & 7;
            #pragma unroll
            for (int r = 0; r < 4; ++r) {
                int row = kg * 4 + r;
                Ps[row * 128 + ((chunk ^ (row & 7)) * 8 + cw)] = f2bs(s[n][r]);
            }
        }

        bf16x8 pa[4];
        #pragma unroll
        for (int ks = 0; ks < 4; ++ks)
            pa[ks] = *(const bf16x8*)&Ps[arow * 128 + (((ks * 4 + kg) ^ (arow & 7)) * 8)];
        #pragma unroll
        for (int dt = 0; dt < 4; ++dt) {
            int vrow = dt * 16 + arow, sw = vrow & 7;
            #pragma unroll
            for (int ks = 0; ks < 4; ++ks) {
                bf16x8 vb = *(const bf16x8*)&Vs[vrow * 128 + (((ks * 4 + kg) ^ sw) * 8)];
                po[dt] = __builtin_amdgcn_mfma_f32_16x16x32_bf16(pa[ks], vb, po[dt], 0, 0, 0);
            }
        }
        __syncthreads();
    }

    const int b_ = bh >> 4, hofs = (bh & 15) * 64;
    #pragma unroll
    for (int dt = 0; dt < 4; ++dt)
        #pragma unroll
        for (int r = 0; r < 4; ++r) {
            long row = (long)b_ * 2048 + qb + w * 16 + kg * 4 + r;
            z[row * 1024 + hofs + dt * 16 + arow] = __float2bfloat16(po[dt][r] / lrow[r]);
        }
}

// ---------------- fused kernels ----------------
// embed (nEmb) + convT qkv(0)
__global__ __launch_bounds__(256)
void fused_embed_convT(const int* __restrict__ x, const float* __restrict__ wte,
                       const float* __restrict__ wpe, float* __restrict__ h,
                       const float* __restrict__ W, unsigned short* __restrict__ WT,
                       int K, int N, int nEmb) {
    extern __shared__ char smem[];
    int bid = blockIdx.x;
    if (bid < nEmb) {
        embed_body(bid, x, wte, wpe, h);
    } else {
        int r = bid - nEmb, kt = K >> 6;
        convT_body(smem, r % kt, r / kt, W, WT, K, N);
    }
}

// attn (nAttn) + convT proj -> WT1 (n1) + convT cp -> WT2
__global__ __launch_bounds__(256)
void fused_attn_convT2(const unsigned short* __restrict__ qB,
                       const unsigned short* __restrict__ kB,
                       const unsigned short* __restrict__ vT,
                       __hip_bfloat16* __restrict__ z,
                       const float* __restrict__ W1, unsigned short* __restrict__ WT1,
                       int K1, int N1, int n1,
                       const float* __restrict__ W2, unsigned short* __restrict__ WT2,
                       int K2, int N2, int nAttn) {
    extern __shared__ char smem[];
    int bid = blockIdx.x;
    if (bid < nAttn) {
        attn_body(smem, bid & 31, (bid >> 5) * 64, qB, kB, vT, z);
    } else if (bid < nAttn + n1) {
        int r = bid - nAttn, kt = K1 >> 6;
        convT_body(smem, r % kt, r / kt, W1, WT1, K1, N1);
    } else {
        int r = bid - nAttn - n1, kt = K2 >> 6;
        convT_body(smem, r % kt, r / kt, W2, WT2, K2, N2);
    }
}

// n64 GEMM (nMM, bx=bid%nbx) + optional convT -> WT2 (nConv blocks)
__global__ __launch_bounds__(256)
void fused_n64_convT(const unsigned short* __restrict__ A,
                     const unsigned short* __restrict__ BT,
                     const float* __restrict__ bias, const float* __restrict__ R,
                     float* __restrict__ Cout, int M, int N, int K, int nbx,
                     const float* __restrict__ W2, unsigned short* __restrict__ WT2,
                     int K2, int N2, int nMM) {
    extern __shared__ char smem[];
    int bid = blockIdx.x;
    if (bid < nMM) {
        n64_body(smem, bid % nbx, bid / nbx, A, BT, bias, R, Cout, M, N, K);
    } else {
        int r = bid - nMM, kt = K2 >> 6;
        convT_body(smem, r % kt, r / kt, W2, WT2, K2, N2);
    }
}

// ---------------- head ----------------
__global__ void head_kernel(const float* __restrict__ hl, const float* __restrict__ W,
                            float* __restrict__ out) {
    __shared__ float hs[2 * DMODEL];
    int tid = threadIdx.x;
    #pragma unroll
    for (int i = 0; i < 8; ++i) hs[tid + i * 256] = hl[tid + i * 256];
    __syncthreads();
    int v = blockIdx.x * 256 + tid;
    if (v >= VOCAB) return;
    float a0 = 0.f, a1 = 0.f;
    for (int d = 0; d < DMODEL; ++d) {
        float wv = W[(long)d * VOCAB + v];
        a0 += hs[d] * wv;
        a1 += hs[DMODEL + d] * wv;
    }
    out[v] = a0;
    out[VOCAB + v] = a1;
}

extern "C" void kernel_launch(void* const* d_in, const int* in_sizes, int n_in,
                              void* d_out, int out_size, void* d_ws, size_t ws_size,
                              hipStream_t stream) {
    const int*   x      = (const int*)  d_in[0];
    const float* wte    = (const float*)d_in[1];
    const float* wpe    = (const float*)d_in[2];
    const float* ln1_g  = (const float*)d_in[3];
    const float* ln1_b  = (const float*)d_in[4];
    const float* w_qkv  = (const float*)d_in[5];
    const float* b_qkv  = (const float*)d_in[6];
    const float* w_proj = (const float*)d_in[7];
    const float* b_proj = (const float*)d_in[8];
    const float* ln2_g  = (const float*)d_in[9];
    const float* ln2_b  = (const float*)d_in[10];
    const float* w_fc   = (const float*)d_in[11];
    const float* b_fc   = (const float*)d_in[12];
    const float* w_cp   = (const float*)d_in[13];
    const float* b_cp   = (const float*)d_in[14];
    const float* lnf_g  = (const float*)d_in[15];
    const float* lnf_b  = (const float*)d_in[16];
    const float* w_head = (const float*)d_in[17];
    float* out = (float*)d_out;

    char* ws = (char*)d_ws;
    float*          h     = (float*)ws;                             // 16 MB
    unsigned short* qkvB  = (unsigned short*)(ws + (16L << 20));    // 24 MB
    unsigned short* y_bf  = (unsigned short*)(ws + (40L << 20));    // 8 MB
    __hip_bfloat16* z_bf  = (__hip_bfloat16*)(ws + (48L << 20));    // 8 MB
    unsigned short* fc_bf = (unsigned short*)(ws + (56L << 20));    // 32 MB
    unsigned short* wT_a  = (unsigned short*)(ws + (88L << 20));    // 8 MB (fc)
    unsigned short* wT_b  = (unsigned short*)(ws + (97L << 20));    // 8 MB (proj)
    unsigned short* wT_c  = (unsigned short*)(ws + (106L << 20));   // 8 MB (cp)
    unsigned short* wT_q  = (unsigned short*)(ws + (115L << 20));   // 8 MB (qkv)
    float*          hl    = (float*)(ws + (124L << 20));            // 8 KB

    const int SM_CONV = 16640;   // 64*65*4
    const int SM_ATTN = 49152;   // Ks+Vs+Ps
    const int SM_N64  = 24576;   // As(16K)+Bs(8K), >= SM_CONV

    // P: embed (4096) + convT qkv layer 0 (768) -> wT_q
    fused_embed_convT<<<4096 + 768, 256, SM_CONV, stream>>>(
        x, wte, wpe, h, w_qkv, wT_q, 1024, 3072, 4096);

    for (int l = 0; l < NLAYER; ++l) {
        // A: pure LN1
        ln_std<<<NTOK, 256, 0, stream>>>(h, y_bf, ln1_g + l * DMODEL, ln1_b + l * DMODEL);

        // B: qkv GEMM (reads wT_q produced by P or previous G)
        mm_mfma256<3><<<192, 512, 131072, stream>>>(
            y_bf, wT_q, b_qkv + l * 3072, qkvB, NTOK, 3072, 1024, 12);

        // C: attn (1024) + convT proj -> wT_b (256) + convT cp -> wT_c (1024)
        fused_attn_convT2<<<1024 + 256 + 1024, 256, SM_ATTN, stream>>>(
            qkvB, qkvB + 4194304L, qkvB + 8388608L, z_bf,
            w_proj + (long)l * DMODEL * DMODEL, wT_b, 1024, 1024, 256,
            w_cp + (long)l * 4096 * DMODEL, wT_c, 4096, 1024, 1024);

        // D: proj GEMM (+residual) + convT fc -> wT_a (1024)
        fused_n64_convT<<<512 + 1024, 256, SM_N64, stream>>>(
            (const unsigned short*)z_bf, wT_b, b_proj + l * DMODEL, h, h,
            NTOK, 1024, 1024, 16,
            w_fc + (long)l * DMODEL * 4096, wT_a, 1024, 4096, 512);

        // E: pure LN2
        ln_std<<<NTOK, 256, 0, stream>>>(h, y_bf, ln2_g + l * DMODEL, ln2_b + l * DMODEL);

        // F: fc GEMM (256^2 8-phase, gelu; reads wT_a)
        mm_mfma256<2><<<256, 512, 131072, stream>>>(
            y_bf, wT_a, b_fc + l * 4096, fc_bf, NTOK, 4096, 1024, 16);

        // G: cp GEMM (+residual) + convT qkv(l+1) -> wT_q (768; none on last layer)
        int nConv = (l + 1 < NLAYER) ? 768 : 0;
        fused_n64_convT<<<512 + nConv, 256, SM_N64, stream>>>(
            fc_bf, wT_c, b_cp + l * DMODEL, h, h, NTOK, 1024, 4096, 16,
            w_qkv + (long)(l + 1) * DMODEL * 3072, wT_q, 1024, 3072, 512);
    }

    ln_final<<<BATCH, 256, 0, stream>>>(h + (long)(SEQ - 1) * DMODEL, hl,
                                        lnf_g, lnf_b, (long)SEQ * DMODEL);
    head_kernel<<<(VOCAB + 255) / 256, 256, 0, stream>>>(hl, w_head, out);
}

// Round 14
// 2358.457 us; speedup vs baseline: 1.3368x; 1.0287x over previous
//
#include <hip/hip_runtime.h>
#include <hip/hip_bf16.h>
#include <math.h>

#define VOCAB 50257
#define CTX 2048
#define DMODEL 1024
#define NHEAD 16
#define NLAYER 8
#define DHEAD 64
#define BATCH 2
#define SEQ 2048
#define NTOK (BATCH * SEQ)   // 4096

typedef __bf16 bf16x8 __attribute__((ext_vector_type(8)));
typedef float  f32x4  __attribute__((ext_vector_type(4)));
typedef unsigned short ushort4v __attribute__((ext_vector_type(4)));
typedef unsigned short ushort8v __attribute__((ext_vector_type(8)));

__device__ inline void gl_lds16(const void* g, void* l) {
    __builtin_amdgcn_global_load_lds(
        (const __attribute__((address_space(1))) unsigned int*)g,
        (__attribute__((address_space(3))) unsigned int*)l, 16, 0, 0);
}

__device__ inline unsigned short f2bs(float v) {
    __hip_bfloat16 t = __float2bfloat16(v);
    return *(unsigned short*)&t;
}

// ---------------- embedding body ----------------
__device__ void embed_body(int t, const int* __restrict__ x,
                           const float* __restrict__ wte,
                           const float* __restrict__ wpe,
                           float* __restrict__ h) {
    int s = t & (SEQ - 1);
    int tok = x[t];
    const float* pe = wpe + (long)s * DMODEL;
    const float* te = wte + (long)tok * DMODEL;
    float* ph = h + (long)t * DMODEL;
    for (int d = threadIdx.x; d < DMODEL; d += 256)
        ph[d] = te[d] + pe[d];
}

// ---------------- layernorm ----------------
__device__ inline float wave_sum(float v) {
    for (int off = 32; off; off >>= 1) v += __shfl_xor(v, off);
    return v;
}

__global__ void ln_std(const float* __restrict__ in, unsigned short* __restrict__ out,
                       const float* __restrict__ g, const float* __restrict__ b) {
    __shared__ float red[4], red2[4];
    int row = blockIdx.x;
    const float* px = in + (long)row * DMODEL;
    unsigned short* po = out + (long)row * DMODEL;
    int tid = threadIdx.x;
    int wid = tid >> 6, lane = tid & 63;

    float x[4];
    float s = 0.f;
    #pragma unroll
    for (int i = 0; i < 4; ++i) { x[i] = px[tid + i * 256]; s += x[i]; }
    s = wave_sum(s);
    if (lane == 0) red[wid] = s;
    __syncthreads();
    float mean = (red[0] + red[1] + red[2] + red[3]) * (1.0f / DMODEL);

    float s2 = 0.f;
    #pragma unroll
    for (int i = 0; i < 4; ++i) { float d = x[i] - mean; s2 += d * d; }
    s2 = wave_sum(s2);
    if (lane == 0) red2[wid] = s2;
    __syncthreads();
    float var = (red2[0] + red2[1] + red2[2] + red2[3]) * (1.0f / DMODEL);
    float r = 1.0f / sqrtf(var + 1e-5f);
    #pragma unroll
    for (int i = 0; i < 4; ++i) {
        int d = tid + i * 256;
        po[d] = f2bs((x[i] - mean) * r * g[d] + b[d]);
    }
}

__global__ void ln_final(const float* __restrict__ in, float* __restrict__ out,
                         const float* __restrict__ g, const float* __restrict__ b,
                         long row_stride) {
    __shared__ float red[4], red2[4];
    int row = blockIdx.x;
    const float* px = in + (long)row * row_stride;
    float* po = out + (long)row * DMODEL;
    int tid = threadIdx.x;
    int wid = tid >> 6, lane = tid & 63;
    float x[4];
    float s = 0.f;
    #pragma unroll
    for (int i = 0; i < 4; ++i) { x[i] = px[tid + i * 256]; s += x[i]; }
    s = wave_sum(s);
    if (lane == 0) red[wid] = s;
    __syncthreads();
    float mean = (red[0] + red[1] + red[2] + red[3]) * (1.0f / DMODEL);
    float s2 = 0.f;
    #pragma unroll
    for (int i = 0; i < 4; ++i) { float d = x[i] - mean; s2 += d * d; }
    s2 = wave_sum(s2);
    if (lane == 0) red2[wid] = s2;
    __syncthreads();
    float var = (red2[0] + red2[1] + red2[2] + red2[3]) * (1.0f / DMODEL);
    float r = 1.0f / sqrtf(var + 1e-5f);
    #pragma unroll
    for (int i = 0; i < 4; ++i) {
        int d = tid + i * 256;
        po[d] = (x[i] - mean) * r * g[d] + b[d];
    }
}

// ------------- transpose+convert bodies: W f32 [K][N] -> WT bf16 [N][K] -------------
__device__ void convT_body(char* smem, int kx, int ny, const float* __restrict__ W,
                           unsigned short* __restrict__ WT, int K, int N) {
    float (*t)[65] = (float(*)[65])smem;
    const int k0 = kx * 64, n0 = ny * 64;
    const int tid = threadIdx.x;
    {
        const int krow = tid >> 4, c4 = (tid & 15) * 4;
        #pragma unroll
        for (int p = 0; p < 4; ++p) {
            f32x4 gv = *(const f32x4*)&W[(long)(k0 + p * 16 + krow) * N + n0 + c4];
            #pragma unroll
            for (int j = 0; j < 4; ++j) t[p * 16 + krow][c4 + j] = gv[j];
        }
    }
    __syncthreads();
    {
        const int n = tid >> 3, kl = (tid & 7) * 8;
        #pragma unroll
        for (int p = 0; p < 2; ++p) {
            ushort8v pk;
            #pragma unroll
            for (int j = 0; j < 8; ++j) pk[j] = f2bs(t[kl + j][p * 32 + n]);
            *(ushort8v*)&WT[(long)(n0 + p * 32 + n) * K + k0 + kl] = pk;
        }
    }
}

// 512-thread variant (for the 512-thread fused attention kernel)
__device__ void convT_body512(char* smem, int kx, int ny, const float* __restrict__ W,
                              unsigned short* __restrict__ WT, int K, int N) {
    float (*t)[65] = (float(*)[65])smem;
    const int k0 = kx * 64, n0 = ny * 64;
    const int tid = threadIdx.x;
    {
        const int krow = tid >> 4, c4 = (tid & 15) * 4;   // krow 0..31
        #pragma unroll
        for (int p = 0; p < 2; ++p) {
            f32x4 gv = *(const f32x4*)&W[(long)(k0 + p * 32 + krow) * N + n0 + c4];
            #pragma unroll
            for (int j = 0; j < 4; ++j) t[p * 32 + krow][c4 + j] = gv[j];
        }
    }
    __syncthreads();
    {
        const int n = tid >> 3, kl = (tid & 7) * 8;       // n 0..63
        ushort8v pk;
        #pragma unroll
        for (int j = 0; j < 8; ++j) pk[j] = f2bs(t[kl + j][n]);
        *(ushort8v*)&WT[(long)(n0 + n) * K + k0 + kl] = pk;
    }
}

// ---------------- 256^2 8-phase bf16 MFMA GEMM ----------------
#define STG_A(KS, H) do { \
    const unsigned short* g_ = A + (long)(bm + (H) * 128 + srow) * K + (KS) * 64 + stgch; \
    unsigned short* s_ = LDS + (((KS) & 1) * 2 + (H)) * 8192 + (w * 8) * 64; \
    gl_lds16(g_, s_); gl_lds16(g_ + 64L * K, s_ + 4096); \
} while (0)
#define STG_B(KS, H) do { \
    const unsigned short* g_ = BT + (long)(bn + (H) * 128 + srow) * K + (KS) * 64 + stgch; \
    unsigned short* s_ = LDS + 32768 + (((KS) & 1) * 2 + (H)) * 8192 + (w * 8) * 64; \
    gl_lds16(g_, s_); gl_lds16(g_ + 64L * K, s_ + 4096); \
} while (0)
#define MM2(M_, x0, x1) do { \
    acc[M_][0] = __builtin_amdgcn_mfma_f32_16x16x32_bf16(x0, bfr[0], acc[M_][0], 0, 0, 0); \
    acc[M_][0] = __builtin_amdgcn_mfma_f32_16x16x32_bf16(x1, bfr[1], acc[M_][0], 0, 0, 0); \
    acc[M_][1] = __builtin_amdgcn_mfma_f32_16x16x32_bf16(x0, bfr[2], acc[M_][1], 0, 0, 0); \
    acc[M_][1] = __builtin_amdgcn_mfma_f32_16x16x32_bf16(x1, bfr[3], acc[M_][1], 0, 0, 0); \
    acc[M_][2] = __builtin_amdgcn_mfma_f32_16x16x32_bf16(x0, bfr[4], acc[M_][2], 0, 0, 0); \
    acc[M_][2] = __builtin_amdgcn_mfma_f32_16x16x32_bf16(x1, bfr[5], acc[M_][2], 0, 0, 0); \
    acc[M_][3] = __builtin_amdgcn_mfma_f32_16x16x32_bf16(x0, bfr[6], acc[M_][3], 0, 0, 0); \
    acc[M_][3] = __builtin_amdgcn_mfma_f32_16x16x32_bf16(x1, bfr[7], acc[M_][3], 0, 0, 0); \
} while (0)
#define PHASE(Q, SPAR, STAGE_STMT, TAIL_STMT) do { \
    bf16x8 a00, a01, a10, a11; \
    if (((Q) & 3) == 0) { \
        const unsigned short* Bb_ = lBp[SPAR] + ((wc & 1) * 64 + fr) * 64; \
        bfr[0] = *(const bf16x8*)(Bb_ + rd0);        bfr[1] = *(const bf16x8*)(Bb_ + rd1); \
        bfr[2] = *(const bf16x8*)(Bb_ + 1024 + rd0); bfr[3] = *(const bf16x8*)(Bb_ + 1024 + rd1); \
        bfr[4] = *(const bf16x8*)(Bb_ + 2048 + rd0); bfr[5] = *(const bf16x8*)(Bb_ + 2048 + rd1); \
        bfr[6] = *(const bf16x8*)(Bb_ + 3072 + rd0); bfr[7] = *(const bf16x8*)(Bb_ + 3072 + rd1); \
    } \
    { const unsigned short* Ab_ = lAp[SPAR] + fr * 64; \
      a00 = *(const bf16x8*)(Ab_ + (((Q) & 3) * 2) * 1024 + rd0); \
      a01 = *(const bf16x8*)(Ab_ + (((Q) & 3) * 2) * 1024 + rd1); \
      a10 = *(const bf16x8*)(Ab_ + (((Q) & 3) * 2 + 1) * 1024 + rd0); \
      a11 = *(const bf16x8*)(Ab_ + (((Q) & 3) * 2 + 1) * 1024 + rd1); } \
    STAGE_STMT; \
    __builtin_amdgcn_s_barrier(); \
    asm volatile("s_waitcnt lgkmcnt(0)" ::: "memory"); \
    __builtin_amdgcn_sched_barrier(0); \
    __builtin_amdgcn_s_setprio(1); \
    MM2(((Q) & 3) * 2, a00, a01); \
    MM2(((Q) & 3) * 2 + 1, a10, a11); \
    __builtin_amdgcn_s_setprio(0); \
    TAIL_STMT; \
    __builtin_amdgcn_s_barrier(); \
} while (0)

template<int EPI>
__global__ __launch_bounds__(512, 1)
void mm_mfma256(const unsigned short* __restrict__ A,
                const unsigned short* __restrict__ BT,
                const float* __restrict__ bias,
                void* __restrict__ Cout, int M, int N, int K, int nbx) {
    extern __shared__ unsigned short LDS[];
    const int tid = threadIdx.x;
    const int w = tid >> 6, lane = tid & 63;
    const int wr = w >> 2, wc = w & 3;
    const int nwg = gridDim.x, bid = blockIdx.x;
    const int swz = (bid & 7) * (nwg >> 3) + (bid >> 3);
    const int bm = (swz / nbx) * 256, bn = (swz % nbx) * 256;

    f32x4 acc[8][4];
    #pragma unroll
    for (int m = 0; m < 8; ++m)
        #pragma unroll
        for (int n = 0; n < 4; ++n)
            acc[m][n] = (f32x4){0.f, 0.f, 0.f, 0.f};

    const int fr = lane & 15, kg = lane >> 4;
    const int rd0 = 8 * (kg ^ (lane & 7)), rd1 = 8 * ((kg + 4) ^ (lane & 7));
    const int stgch = 8 * ((lane & 7) ^ (lane >> 3));
    const int srow = w * 8 + (lane >> 3);
    unsigned short* const lAp[2] = { LDS + wr * 8192, LDS + (2 + wr) * 8192 };
    unsigned short* const lBp[2] = { LDS + 32768 + (wc >> 1) * 8192,
                                     LDS + 32768 + (2 + (wc >> 1)) * 8192 };
    bf16x8 bfr[8];

    STG_B(0, 0); STG_B(0, 1); STG_A(0, 0); STG_A(0, 1); STG_B(1, 0); STG_B(1, 1);
    asm volatile("s_waitcnt vmcnt(4)" ::: "memory");
    __builtin_amdgcn_sched_barrier(0);
    __builtin_amdgcn_s_barrier();

    const int T = K >> 7;
    for (int t = 0; t < T; ++t) {
        const int s = 2 * t;
        const bool nl = (t < T - 1);
        PHASE(0, 0, STG_A(s + 1, 0), );
        PHASE(1, 0, STG_A(s + 1, 1), );
        PHASE(2, 0, if (nl) STG_B(s + 2, 0), );
        PHASE(3, 0, if (nl) STG_B(s + 2, 1),
              if (nl) { asm volatile("s_waitcnt vmcnt(4)" ::: "memory"); } else { asm volatile("s_waitcnt vmcnt(0)" ::: "memory"); } __builtin_amdgcn_sched_barrier(0); );
        PHASE(4, 1, if (nl) STG_A(s + 2, 0), );
        PHASE(5, 1, if (nl) STG_A(s + 2, 1), );
        PHASE(6, 1, if (nl) STG_B(s + 3, 0), );
        PHASE(7, 1, if (nl) STG_B(s + 3, 1),
              if (nl) { asm volatile("s_waitcnt vmcnt(4)" ::: "memory"); __builtin_amdgcn_sched_barrier(0); } );
    }

    const int r0 = (lane >> 4) * 4;
    #pragma unroll
    for (int n = 0; n < 4; ++n) {
        int colb = bn + wc * 64 + n * 16;
        float bv = bias[colb + fr];
        #pragma unroll
        for (int m = 0; m < 8; ++m) {
            int rowb = bm + wr * 128 + m * 16 + r0;
            if (EPI == 3) {
                unsigned short* qkvB = (unsigned short*)Cout;
                int which = colb >> 10, hh = (colb & 1023) >> 6, dbase = colb & 63;
                int b_ = rowb >> 11, s_ = rowb & 2047;
                long bh2 = b_ * 16 + hh;
                float v[4];
                #pragma unroll
                for (int r = 0; r < 4; ++r) v[r] = acc[m][n][r] + bv;
                if (which == 2) {
                    ushort4v pk;
                    #pragma unroll
                    for (int r = 0; r < 4; ++r) pk[r] = f2bs(v[r]);
                    *(ushort4v*)&qkvB[8388608L + (bh2 * 64 + dbase + fr) * 2048 + s_] = pk;
                } else {
                    unsigned short* dst = qkvB + (long)which * 4194304L +
                                          (bh2 * 2048 + s_) * 64 + dbase + fr;
                    #pragma unroll
                    for (int r = 0; r < 4; ++r) dst[r * 64] = f2bs(v[r]);
                }
            } else {
                #pragma unroll
                for (int r = 0; r < 4; ++r) {
                    long row = rowb + r, col = colb + fr;
                    float v = acc[m][n][r] + bv;
                    v = 0.5f * v * (1.0f + erff(v * 0.70710678118f));
                    ((__hip_bfloat16*)Cout)[row * N + col] = __float2bfloat16(v);
                }
            }
        }
    }
}

// ---------------- n64 GEMM body (2-phase dbuf), dynamic smem 24KB ----------------
__device__ void n64_body(char* smem, int bx, int by,
                         const unsigned short* __restrict__ A,
                         const unsigned short* __restrict__ BT,
                         const float* __restrict__ bias, const float* __restrict__ R,
                         float* __restrict__ Cout, int M, int N, int K) {
    unsigned short* As = (unsigned short*)smem;          // [2][128*32]
    unsigned short* Bs = As + 2 * 128 * 32;              // [2][64*32]
    const int tid = threadIdx.x;
    const int w = tid >> 6, lane = tid & 63;
    const int bm = by * 128, bn = bx * 64;
    const int wr = (w >> 1) * 64, wc = (w & 1) * 32;

    f32x4 acc[4][2];
    #pragma unroll
    for (int m = 0; m < 4; ++m)
        #pragma unroll
        for (int n = 0; n < 2; ++n)
            acc[m][n] = (f32x4){0.f, 0.f, 0.f, 0.f};

    const int lrow = lane >> 2;
    const int lcol = (lane & 3) * 8;
    const unsigned short* gA = A + (long)(bm + w * 32 + lrow) * K + lcol;
    const unsigned short* gB = BT + (long)(bn + w * 16 + lrow) * K + lcol;

#define N64_STAGE(K0, BB) do { \
    gl_lds16(gA + (K0),          &As[(BB) * 4096 + (w * 32) * 32]); \
    gl_lds16(gA + (K0) + 16 * K, &As[(BB) * 4096 + (w * 32 + 16) * 32]); \
    gl_lds16(gB + (K0),          &Bs[(BB) * 2048 + (w * 16) * 32]); \
} while (0)

    N64_STAGE(0, 0);
    asm volatile("s_waitcnt vmcnt(0)" ::: "memory");
    __builtin_amdgcn_sched_barrier(0);
    __builtin_amdgcn_s_barrier();

    const int T = K >> 5;
    for (int t = 0; t < T; ++t) {
        const int buf = t & 1;
        if (t + 1 < T) N64_STAGE((t + 1) * 32, buf ^ 1);

        bf16x8 a[4], b[2];
        #pragma unroll
        for (int m = 0; m < 4; ++m)
            a[m] = *(const bf16x8*)&As[buf * 4096 + (wr + m * 16 + (lane & 15)) * 32 + (lane >> 4) * 8];
        #pragma unroll
        for (int n = 0; n < 2; ++n)
            b[n] = *(const bf16x8*)&Bs[buf * 2048 + (wc + n * 16 + (lane & 15)) * 32 + (lane >> 4) * 8];
        #pragma unroll
        for (int m = 0; m < 4; ++m)
            #pragma unroll
            for (int n = 0; n < 2; ++n)
                acc[m][n] = __builtin_amdgcn_mfma_f32_16x16x32_bf16(a[m], b[n], acc[m][n], 0, 0, 0);

        asm volatile("s_waitcnt vmcnt(0)" ::: "memory");
        __builtin_amdgcn_sched_barrier(0);
        __builtin_amdgcn_s_barrier();
    }
#undef N64_STAGE

    const int r0 = (lane >> 4) * 4, cc = lane & 15;
    #pragma unroll
    for (int n = 0; n < 2; ++n) {
        int colb = bn + wc + n * 16;
        float bv = bias[colb + cc];
        #pragma unroll
        for (int m = 0; m < 4; ++m) {
            int rowb = bm + wr + m * 16 + r0;
            #pragma unroll
            for (int r = 0; r < 4; ++r) {
                long row = rowb + r, col = colb + cc;
                float v = acc[m][n][r] + bv + R[row * N + col];
                Cout[row * N + col] = v;
            }
        }
    }
}

// ---------------- MFMA flash attention body, QBLK=128, KVBLK=128, 8 waves ----------------
// smem: Ks[128][64] 16K | Vs[64][128] 16K | Ps 8x[16][128] 32K = 64K
__device__ void attn_body(char* smem, int bh, int qb,
                          const unsigned short* __restrict__ qB,
                          const unsigned short* __restrict__ kB,
                          const unsigned short* __restrict__ vT,
                          __hip_bfloat16* __restrict__ z) {
    const int tid = threadIdx.x, w = tid >> 6, lane = tid & 63;
    const int arow = lane & 15, kg = lane >> 4;
    unsigned short* Ks = (unsigned short*)smem;
    unsigned short* Vs = Ks + 128 * 64;
    unsigned short* Ps = Vs + 64 * 128 + w * 16 * 128;

    const long kvbase = (long)bh * (2048 * 64);

    bf16x8 qa[2];
    {
        const unsigned short* q0 = qB + kvbase + (long)(qb + w * 16 + arow) * 64 + kg * 8;
        qa[0] = *(const bf16x8*)(q0);
        qa[1] = *(const bf16x8*)(q0 + 32);
    }

    f32x4 po[4];
    float mrow[4], lrow[4];
    #pragma unroll
    for (int i = 0; i < 4; ++i) {
        po[i] = (f32x4){0.f, 0.f, 0.f, 0.f};
        mrow[i] = -1e30f; lrow[i] = 0.f;
    }

    const int ksrow = lane >> 3;                  // 0..7
    const int kschunk = (lane & 7) ^ ksrow;       // pre-swizzled source (rule #21)
    const int vsr = lane >> 4;                    // 0..3
    const int cmax = qb >> 7;

    for (int c = 0; c <= cmax; ++c) {
        {
            // K: 8 waves x 16 rows (2 instrs/wave)
            const unsigned short* ks0 = kB + kvbase +
                (long)(c * 128 + w * 16 + ksrow) * 64 + kschunk * 8;
            #pragma unroll
            for (int i = 0; i < 2; ++i)
                gl_lds16(ks0 + (long)i * 8 * 64, &Ks[(w * 16 + i * 8) * 64]);
            // V: 8 waves x 8 d-rows (2 instrs/wave)
            #pragma unroll
            for (int i = 0; i < 2; ++i) {
                int d = w * 8 + i * 4 + vsr;
                int sch = (lane & 15) ^ (d & 7);
                gl_lds16(vT + kvbase + (long)d * 2048 + c * 128 + sch * 8,
                         &Vs[(w * 8 + i * 4) * 128]);
            }
        }
        __syncthreads();

        f32x4 s[8];
        #pragma unroll
        for (int n = 0; n < 8; ++n) {
            s[n] = (f32x4){0.f, 0.f, 0.f, 0.f};
            int row = n * 16 + arow, sw = row & 7;
            bf16x8 kb0 = *(const bf16x8*)&Ks[row * 64 + (kg ^ sw) * 8];
            bf16x8 kb1 = *(const bf16x8*)&Ks[row * 64 + ((4 + kg) ^ sw) * 8];
            s[n] = __builtin_amdgcn_mfma_f32_16x16x32_bf16(qa[0], kb0, s[n], 0, 0, 0);
            s[n] = __builtin_amdgcn_mfma_f32_16x16x32_bf16(qa[1], kb1, s[n], 0, 0, 0);
        }

        const bool diag = (c == cmax);
        #pragma unroll
        for (int n = 0; n < 8; ++n)
            #pragma unroll
            for (int r = 0; r < 4; ++r) {
                float v = s[n][r] * 0.125f;
                if (diag) {
                    int key = c * 128 + n * 16 + arow;
                    int qrow = qb + w * 16 + kg * 4 + r;
                    if (key > qrow) v = -1e30f;
                }
                s[n][r] = v;
            }

        #pragma unroll
        for (int r = 0; r < 4; ++r) {
            float rm = s[0][r];
            #pragma unroll
            for (int n = 1; n < 8; ++n) rm = fmaxf(rm, s[n][r]);
            #pragma unroll
            for (int off = 1; off < 16; off <<= 1)
                rm = fmaxf(rm, __shfl_xor(rm, off));
            float mnew = fmaxf(mrow[r], rm);
            float esc = expf(mrow[r] - mnew);
            float rs = 0.f;
            #pragma unroll
            for (int n = 0; n < 8; ++n) {
                float p = expf(s[n][r] - mnew);
                s[n][r] = p;
                rs += p;
            }
            #pragma unroll
            for (int off = 1; off < 16; off <<= 1)
                rs += __shfl_xor(rs, off);
            lrow[r] = lrow[r] * esc + rs;
            #pragma unroll
            for (int dt = 0; dt < 4; ++dt) po[dt][r] *= esc;
            mrow[r] = mnew;
        }

        #pragma unroll
        for (int n = 0; n < 8; ++n) {
            int col = n * 16 + arow;
            int chunk = col >> 3, cw = col & 7;
            #pragma unroll
            for (int r = 0; r < 4; ++r) {
                int row = kg * 4 + r;
                Ps[row * 128 + ((chunk ^ (row & 7)) * 8 + cw)] = f2bs(s[n][r]);
            }
        }

        bf16x8 pa[4];
        #pragma unroll
        for (int ks = 0; ks < 4; ++ks)
            pa[ks] = *(const bf16x8*)&Ps[arow * 128 + (((ks * 4 + kg) ^ (arow & 7)) * 8)];
        #pragma unroll
        for (int dt = 0; dt < 4; ++dt) {
            int vrow = dt * 16 + arow, sw = vrow & 7;
            #pragma unroll
            for (int ks = 0; ks < 4; ++ks) {
                bf16x8 vb = *(const bf16x8*)&Vs[vrow * 128 + (((ks * 4 + kg) ^ sw) * 8)];
                po[dt] = __builtin_amdgcn_mfma_f32_16x16x32_bf16(pa[ks], vb, po[dt], 0, 0, 0);
            }
        }
        __syncthreads();
    }

    const int b_ = bh >> 4, hofs = (bh & 15) * 64;
    #pragma unroll
    for (int dt = 0; dt < 4; ++dt)
        #pragma unroll
        for (int r = 0; r < 4; ++r) {
            long row = (long)b_ * 2048 + qb + w * 16 + kg * 4 + r;
            z[row * 1024 + hofs + dt * 16 + arow] = __float2bfloat16(po[dt][r] / lrow[r]);
        }
}

// ---------------- fused kernels ----------------
__global__ __launch_bounds__(256)
void fused_embed_convT(const int* __restrict__ x, const float* __restrict__ wte,
                       const float* __restrict__ wpe, float* __restrict__ h,
                       const float* __restrict__ W, unsigned short* __restrict__ WT,
                       int K, int N, int nEmb) {
    extern __shared__ char smem[];
    int bid = blockIdx.x;
    if (bid < nEmb) {
        embed_body(bid, x, wte, wpe, h);
    } else {
        int r = bid - nEmb, kt = K >> 6;
        convT_body(smem, r % kt, r / kt, W, WT, K, N);
    }
}

// attn QBLK=128 heavy-first (nAttn) + convT proj -> WT1 (n1) + convT cp -> WT2; 512 thr
__global__ __launch_bounds__(512)
void fused_attn_convT2(const unsigned short* __restrict__ qB,
                       const unsigned short* __restrict__ kB,
                       const unsigned short* __restrict__ vT,
                       __hip_bfloat16* __restrict__ z,
                       const float* __restrict__ W1, unsigned short* __restrict__ WT1,
                       int K1, int N1, int n1,
                       const float* __restrict__ W2, unsigned short* __restrict__ WT2,
                       int K2, int N2, int nAttn) {
    extern __shared__ char smem[];
    int bid = blockIdx.x;
    if (bid < nAttn) {
        int bh = bid & 31;
        int qblk = 15 - (bid >> 5);           // heavy-first: big qb launches first
        attn_body(smem, bh, qblk * 128, qB, kB, vT, z);
    } else if (bid < nAttn + n1) {
        int r = bid - nAttn, kt = K1 >> 6;
        convT_body512(smem, r % kt, r / kt, W1, WT1, K1, N1);
    } else {
        int r = bid - nAttn - n1, kt = K2 >> 6;
        convT_body512(smem, r % kt, r / kt, W2, WT2, K2, N2);
    }
}

// n64 GEMM (nMM, bx=bid%nbx) + optional convT -> WT2 (nConv blocks)
__global__ __launch_bounds__(256)
void fused_n64_convT(const unsigned short* __restrict__ A,
                     const unsigned short* __restrict__ BT,
                     const float* __restrict__ bias, const float* __restrict__ R,
                     float* __restrict__ Cout, int M, int N, int K, int nbx,
                     const float* __restrict__ W2, unsigned short* __restrict__ WT2,
                     int K2, int N2, int nMM) {
    extern __shared__ char smem[];
    int bid = blockIdx.x;
    if (bid < nMM) {
        n64_body(smem, bid % nbx, bid / nbx, A, BT, bias, R, Cout, M, N, K);
    } else {
        int r = bid - nMM, kt = K2 >> 6;
        convT_body(smem, r % kt, r / kt, W2, WT2, K2, N2);
    }
}

// ---------------- head ----------------
__global__ void head_kernel(const float* __restrict__ hl, const float* __restrict__ W,
                            float* __restrict__ out) {
    __shared__ float hs[2 * DMODEL];
    int tid = threadIdx.x;
    #pragma unroll
    for (int i = 0; i < 8; ++i) hs[tid + i * 256] = hl[tid + i * 256];
    __syncthreads();
    int v = blockIdx.x * 256 + tid;
    if (v >= VOCAB) return;
    float a0 = 0.f, a1 = 0.f;
    for (int d = 0; d < DMODEL; ++d) {
        float wv = W[(long)d * VOCAB + v];
        a0 += hs[d] * wv;
        a1 += hs[DMODEL + d] * wv;
    }
    out[v] = a0;
    out[VOCAB + v] = a1;
}

extern "C" void kernel_launch(void* const* d_in, const int* in_sizes, int n_in,
                              void* d_out, int out_size, void* d_ws, size_t ws_size,
                              hipStream_t stream) {
    const int*   x      = (const int*)  d_in[0];
    const float* wte    = (const float*)d_in[1];
    const float* wpe    = (const float*)d_in[2];
    const float* ln1_g  = (const float*)d_in[3];
    const float* ln1_b  = (const float*)d_in[4];
    const float* w_qkv  = (const float*)d_in[5];
    const float* b_qkv  = (const float*)d_in[6];
    const float* w_proj = (const float*)d_in[7];
    const float* b_proj = (const float*)d_in[8];
    const float* ln2_g  = (const float*)d_in[9];
    const float* ln2_b  = (const float*)d_in[10];
    const float* w_fc   = (const float*)d_in[11];
    const float* b_fc   = (const float*)d_in[12];
    const float* w_cp   = (const float*)d_in[13];
    const float* b_cp   = (const float*)d_in[14];
    const float* lnf_g  = (const float*)d_in[15];
    const float* lnf_b  = (const float*)d_in[16];
    const float* w_head = (const float*)d_in[17];
    float* out = (float*)d_out;

    char* ws = (char*)d_ws;
    float*          h     = (float*)ws;                             // 16 MB
    unsigned short* qkvB  = (unsigned short*)(ws + (16L << 20));    // 24 MB
    unsigned short* y_bf  = (unsigned short*)(ws + (40L << 20));    // 8 MB
    __hip_bfloat16* z_bf  = (__hip_bfloat16*)(ws + (48L << 20));    // 8 MB
    unsigned short* fc_bf = (unsigned short*)(ws + (56L << 20));    // 32 MB
    unsigned short* wT_a  = (unsigned short*)(ws + (88L << 20));    // 8 MB (fc)
    unsigned short* wT_b  = (unsigned short*)(ws + (97L << 20));    // 8 MB (proj)
    unsigned short* wT_c  = (unsigned short*)(ws + (106L << 20));   // 8 MB (cp)
    unsigned short* wT_q  = (unsigned short*)(ws + (115L << 20));   // 8 MB (qkv)
    float*          hl    = (float*)(ws + (124L << 20));            // 8 KB

    const int SM_CONV = 16640;   // 64*65*4
    const int SM_ATTN = 65536;   // Ks 16K + Vs 16K + Ps 32K
    const int SM_N64  = 24576;   // As(16K)+Bs(8K), >= SM_CONV

    // P: embed (4096) + convT qkv layer 0 (768) -> wT_q
    fused_embed_convT<<<4096 + 768, 256, SM_CONV, stream>>>(
        x, wte, wpe, h, w_qkv, wT_q, 1024, 3072, 4096);

    for (int l = 0; l < NLAYER; ++l) {
        // A: pure LN1
        ln_std<<<NTOK, 256, 0, stream>>>(h, y_bf, ln1_g + l * DMODEL, ln1_b + l * DMODEL);

        // B: qkv GEMM (reads wT_q produced by P or previous G)
        mm_mfma256<3><<<192, 512, 131072, stream>>>(
            y_bf, wT_q, b_qkv + l * 3072, qkvB, NTOK, 3072, 1024, 12);

        // C: attn QBLK=128 (512) + convT proj -> wT_b (256) + convT cp -> wT_c (1024)
        fused_attn_convT2<<<512 + 256 + 1024, 512, SM_ATTN, stream>>>(
            qkvB, qkvB + 4194304L, qkvB + 8388608L, z_bf,
            w_proj + (long)l * DMODEL * DMODEL, wT_b, 1024, 1024, 256,
            w_cp + (long)l * 4096 * DMODEL, wT_c, 4096, 1024, 512);

        // D: proj GEMM (+residual) + convT fc -> wT_a (1024)
        fused_n64_convT<<<512 + 1024, 256, SM_N64, stream>>>(
            (const unsigned short*)z_bf, wT_b, b_proj + l * DMODEL, h, h,
            NTOK, 1024, 1024, 16,
            w_fc + (long)l * DMODEL * 4096, wT_a, 1024, 4096, 512);

        // E: pure LN2
        ln_std<<<NTOK, 256, 0, stream>>>(h, y_bf, ln2_g + l * DMODEL, ln2_b + l * DMODEL);

        // F: fc GEMM (256^2 8-phase, gelu; reads wT_a)
        mm_mfma256<2><<<256, 512, 131072, stream>>>(
            y_bf, wT_a, b_fc + l * 4096, fc_bf, NTOK, 4096, 1024, 16);

        // G: cp GEMM (+residual) + convT qkv(l+1) -> wT_q (768; none on last layer)
        int nConv = (l + 1 < NLAYER) ? 768 : 0;
        fused_n64_convT<<<512 + nConv, 256, SM_N64, stream>>>(
            fc_bf, wT_c, b_cp + l * DMODEL, h, h, NTOK, 1024, 4096, 16,
            w_qkv + (long)(l + 1) * DMODEL * 3072, wT_q, 1024, 3072, 512);
    }

    ln_final<<<BATCH, 256, 0, stream>>>(h + (long)(SEQ - 1) * DMODEL, hl,
                                        lnf_g, lnf_b, (long)SEQ * DMODEL);
    head_kernel<<<(VOCAB + 255) / 256, 256, 0, stream>>>(hl, w_head, out);
}

// Round 15
// 2352.006 us; speedup vs baseline: 1.3404x; 1.0027x over previous
//
#include <hip/hip_runtime.h>
#include <hip/hip_bf16.h>
#include <math.h>

#define VOCAB 50257
#define CTX 2048
#define DMODEL 1024
#define NHEAD 16
#define NLAYER 8
#define DHEAD 64
#define BATCH 2
#define SEQ 2048
#define NTOK (BATCH * SEQ)   // 4096

typedef __bf16 bf16x8 __attribute__((ext_vector_type(8)));
typedef float  f32x4  __attribute__((ext_vector_type(4)));
typedef unsigned short ushort4v __attribute__((ext_vector_type(4)));
typedef unsigned short ushort8v __attribute__((ext_vector_type(8)));

__device__ inline void gl_lds16(const void* g, void* l) {
    __builtin_amdgcn_global_load_lds(
        (const __attribute__((address_space(1))) unsigned int*)g,
        (__attribute__((address_space(3))) unsigned int*)l, 16, 0, 0);
}

__device__ inline unsigned short f2bs(float v) {
    __hip_bfloat16 t = __float2bfloat16(v);
    return *(unsigned short*)&t;
}

// ---------------- embedding body ----------------
__device__ void embed_body(int t, const int* __restrict__ x,
                           const float* __restrict__ wte,
                           const float* __restrict__ wpe,
                           float* __restrict__ h) {
    int s = t & (SEQ - 1);
    int tok = x[t];
    const float* pe = wpe + (long)s * DMODEL;
    const float* te = wte + (long)tok * DMODEL;
    float* ph = h + (long)t * DMODEL;
    for (int d = threadIdx.x; d < DMODEL; d += 256)
        ph[d] = te[d] + pe[d];
}

// ---------------- layernorm ----------------
__device__ inline float wave_sum(float v) {
    for (int off = 32; off; off >>= 1) v += __shfl_xor(v, off);
    return v;
}

// wave-per-row LN: 4 waves/block, each owns one row; no barriers, vector loads
__global__ void ln_wave(const float* __restrict__ in, unsigned short* __restrict__ out,
                        const float* __restrict__ g, const float* __restrict__ b) {
    const int w = threadIdx.x >> 6, lane = threadIdx.x & 63;
    const int row = blockIdx.x * 4 + w;
    const float* px = in + (long)row * DMODEL;
    f32x4 x[4];
    float s = 0.f;
    #pragma unroll
    for (int i = 0; i < 4; ++i) {
        x[i] = *(const f32x4*)&px[i * 256 + lane * 4];
        s += x[i][0] + x[i][1] + x[i][2] + x[i][3];
    }
    s = wave_sum(s);
    const float mean = s * (1.0f / DMODEL);
    float s2 = 0.f;
    #pragma unroll
    for (int i = 0; i < 4; ++i)
        #pragma unroll
        for (int j = 0; j < 4; ++j) { float d = x[i][j] - mean; s2 += d * d; }
    s2 = wave_sum(s2);
    const float r = 1.0f / sqrtf(s2 * (1.0f / DMODEL) + 1e-5f);
    unsigned short* po = out + (long)row * DMODEL;
    #pragma unroll
    for (int i = 0; i < 4; ++i) {
        const int d0 = i * 256 + lane * 4;
        f32x4 gv = *(const f32x4*)&g[d0];
        f32x4 bv = *(const f32x4*)&b[d0];
        ushort4v pk;
        #pragma unroll
        for (int j = 0; j < 4; ++j)
            pk[j] = f2bs((x[i][j] - mean) * r * gv[j] + bv[j]);
        *(ushort4v*)&po[d0] = pk;
    }
}

__global__ void ln_final(const float* __restrict__ in, float* __restrict__ out,
                         const float* __restrict__ g, const float* __restrict__ b,
                         long row_stride) {
    __shared__ float red[4], red2[4];
    int row = blockIdx.x;
    const float* px = in + (long)row * row_stride;
    float* po = out + (long)row * DMODEL;
    int tid = threadIdx.x;
    int wid = tid >> 6, lane = tid & 63;
    float x[4];
    float s = 0.f;
    #pragma unroll
    for (int i = 0; i < 4; ++i) { x[i] = px[tid + i * 256]; s += x[i]; }
    s = wave_sum(s);
    if (lane == 0) red[wid] = s;
    __syncthreads();
    float mean = (red[0] + red[1] + red[2] + red[3]) * (1.0f / DMODEL);
    float s2 = 0.f;
    #pragma unroll
    for (int i = 0; i < 4; ++i) { float d = x[i] - mean; s2 += d * d; }
    s2 = wave_sum(s2);
    if (lane == 0) red2[wid] = s2;
    __syncthreads();
    float var = (red2[0] + red2[1] + red2[2] + red2[3]) * (1.0f / DMODEL);
    float r = 1.0f / sqrtf(var + 1e-5f);
    #pragma unroll
    for (int i = 0; i < 4; ++i) {
        int d = tid + i * 256;
        po[d] = (x[i] - mean) * r * g[d] + b[d];
    }
}

// ------------- transpose+convert bodies: W f32 [K][N] -> WT bf16 [N][K] -------------
__device__ void convT_body(char* smem, int kx, int ny, const float* __restrict__ W,
                           unsigned short* __restrict__ WT, int K, int N) {
    float (*t)[65] = (float(*)[65])smem;
    const int k0 = kx * 64, n0 = ny * 64;
    const int tid = threadIdx.x;
    {
        const int krow = tid >> 4, c4 = (tid & 15) * 4;
        #pragma unroll
        for (int p = 0; p < 4; ++p) {
            f32x4 gv = *(const f32x4*)&W[(long)(k0 + p * 16 + krow) * N + n0 + c4];
            #pragma unroll
            for (int j = 0; j < 4; ++j) t[p * 16 + krow][c4 + j] = gv[j];
        }
    }
    __syncthreads();
    {
        const int n = tid >> 3, kl = (tid & 7) * 8;
        #pragma unroll
        for (int p = 0; p < 2; ++p) {
            ushort8v pk;
            #pragma unroll
            for (int j = 0; j < 8; ++j) pk[j] = f2bs(t[kl + j][p * 32 + n]);
            *(ushort8v*)&WT[(long)(n0 + p * 32 + n) * K + k0 + kl] = pk;
        }
    }
}

// 512-thread variant (for the 512-thread fused attention kernel)
__device__ void convT_body512(char* smem, int kx, int ny, const float* __restrict__ W,
                              unsigned short* __restrict__ WT, int K, int N) {
    float (*t)[65] = (float(*)[65])smem;
    const int k0 = kx * 64, n0 = ny * 64;
    const int tid = threadIdx.x;
    {
        const int krow = tid >> 4, c4 = (tid & 15) * 4;   // krow 0..31
        #pragma unroll
        for (int p = 0; p < 2; ++p) {
            f32x4 gv = *(const f32x4*)&W[(long)(k0 + p * 32 + krow) * N + n0 + c4];
            #pragma unroll
            for (int j = 0; j < 4; ++j) t[p * 32 + krow][c4 + j] = gv[j];
        }
    }
    __syncthreads();
    {
        const int n = tid >> 3, kl = (tid & 7) * 8;       // n 0..63
        ushort8v pk;
        #pragma unroll
        for (int j = 0; j < 8; ++j) pk[j] = f2bs(t[kl + j][n]);
        *(ushort8v*)&WT[(long)(n0 + n) * K + k0 + kl] = pk;
    }
}

// ---------------- 256^2 8-phase bf16 MFMA GEMM ----------------
#define STG_A(KS, H) do { \
    const unsigned short* g_ = A + (long)(bm + (H) * 128 + srow) * K + (KS) * 64 + stgch; \
    unsigned short* s_ = LDS + (((KS) & 1) * 2 + (H)) * 8192 + (w * 8) * 64; \
    gl_lds16(g_, s_); gl_lds16(g_ + 64L * K, s_ + 4096); \
} while (0)
#define STG_B(KS, H) do { \
    const unsigned short* g_ = BT + (long)(bn + (H) * 128 + srow) * K + (KS) * 64 + stgch; \
    unsigned short* s_ = LDS + 32768 + (((KS) & 1) * 2 + (H)) * 8192 + (w * 8) * 64; \
    gl_lds16(g_, s_); gl_lds16(g_ + 64L * K, s_ + 4096); \
} while (0)
#define MM2(M_, x0, x1) do { \
    acc[M_][0] = __builtin_amdgcn_mfma_f32_16x16x32_bf16(x0, bfr[0], acc[M_][0], 0, 0, 0); \
    acc[M_][0] = __builtin_amdgcn_mfma_f32_16x16x32_bf16(x1, bfr[1], acc[M_][0], 0, 0, 0); \
    acc[M_][1] = __builtin_amdgcn_mfma_f32_16x16x32_bf16(x0, bfr[2], acc[M_][1], 0, 0, 0); \
    acc[M_][1] = __builtin_amdgcn_mfma_f32_16x16x32_bf16(x1, bfr[3], acc[M_][1], 0, 0, 0); \
    acc[M_][2] = __builtin_amdgcn_mfma_f32_16x16x32_bf16(x0, bfr[4], acc[M_][2], 0, 0, 0); \
    acc[M_][2] = __builtin_amdgcn_mfma_f32_16x16x32_bf16(x1, bfr[5], acc[M_][2], 0, 0, 0); \
    acc[M_][3] = __builtin_amdgcn_mfma_f32_16x16x32_bf16(x0, bfr[6], acc[M_][3], 0, 0, 0); \
    acc[M_][3] = __builtin_amdgcn_mfma_f32_16x16x32_bf16(x1, bfr[7], acc[M_][3], 0, 0, 0); \
} while (0)
#define PHASE(Q, SPAR, STAGE_STMT, TAIL_STMT) do { \
    bf16x8 a00, a01, a10, a11; \
    if (((Q) & 3) == 0) { \
        const unsigned short* Bb_ = lBp[SPAR] + ((wc & 1) * 64 + fr) * 64; \
        bfr[0] = *(const bf16x8*)(Bb_ + rd0);        bfr[1] = *(const bf16x8*)(Bb_ + rd1); \
        bfr[2] = *(const bf16x8*)(Bb_ + 1024 + rd0); bfr[3] = *(const bf16x8*)(Bb_ + 1024 + rd1); \
        bfr[4] = *(const bf16x8*)(Bb_ + 2048 + rd0); bfr[5] = *(const bf16x8*)(Bb_ + 2048 + rd1); \
        bfr[6] = *(const bf16x8*)(Bb_ + 3072 + rd0); bfr[7] = *(const bf16x8*)(Bb_ + 3072 + rd1); \
    } \
    { const unsigned short* Ab_ = lAp[SPAR] + fr * 64; \
      a00 = *(const bf16x8*)(Ab_ + (((Q) & 3) * 2) * 1024 + rd0); \
      a01 = *(const bf16x8*)(Ab_ + (((Q) & 3) * 2) * 1024 + rd1); \
      a10 = *(const bf16x8*)(Ab_ + (((Q) & 3) * 2 + 1) * 1024 + rd0); \
      a11 = *(const bf16x8*)(Ab_ + (((Q) & 3) * 2 + 1) * 1024 + rd1); } \
    STAGE_STMT; \
    __builtin_amdgcn_s_barrier(); \
    asm volatile("s_waitcnt lgkmcnt(0)" ::: "memory"); \
    __builtin_amdgcn_sched_barrier(0); \
    __builtin_amdgcn_s_setprio(1); \
    MM2(((Q) & 3) * 2, a00, a01); \
    MM2(((Q) & 3) * 2 + 1, a10, a11); \
    __builtin_amdgcn_s_setprio(0); \
    TAIL_STMT; \
    __builtin_amdgcn_s_barrier(); \
} while (0)

template<int EPI>
__global__ __launch_bounds__(512, 1)
void mm_mfma256(const unsigned short* __restrict__ A,
                const unsigned short* __restrict__ BT,
                const float* __restrict__ bias,
                void* __restrict__ Cout, int M, int N, int K, int nbx) {
    extern __shared__ unsigned short LDS[];
    const int tid = threadIdx.x;
    const int w = tid >> 6, lane = tid & 63;
    const int wr = w >> 2, wc = w & 3;
    const int nwg = gridDim.x, bid = blockIdx.x;
    const int swz = (bid & 7) * (nwg >> 3) + (bid >> 3);
    const int bm = (swz / nbx) * 256, bn = (swz % nbx) * 256;

    f32x4 acc[8][4];
    #pragma unroll
    for (int m = 0; m < 8; ++m)
        #pragma unroll
        for (int n = 0; n < 4; ++n)
            acc[m][n] = (f32x4){0.f, 0.f, 0.f, 0.f};

    const int fr = lane & 15, kg = lane >> 4;
    const int rd0 = 8 * (kg ^ (lane & 7)), rd1 = 8 * ((kg + 4) ^ (lane & 7));
    const int stgch = 8 * ((lane & 7) ^ (lane >> 3));
    const int srow = w * 8 + (lane >> 3);
    unsigned short* const lAp[2] = { LDS + wr * 8192, LDS + (2 + wr) * 8192 };
    unsigned short* const lBp[2] = { LDS + 32768 + (wc >> 1) * 8192,
                                     LDS + 32768 + (2 + (wc >> 1)) * 8192 };
    bf16x8 bfr[8];

    STG_B(0, 0); STG_B(0, 1); STG_A(0, 0); STG_A(0, 1); STG_B(1, 0); STG_B(1, 1);
    asm volatile("s_waitcnt vmcnt(4)" ::: "memory");
    __builtin_amdgcn_sched_barrier(0);
    __builtin_amdgcn_s_barrier();

    const int T = K >> 7;
    for (int t = 0; t < T; ++t) {
        const int s = 2 * t;
        const bool nl = (t < T - 1);
        PHASE(0, 0, STG_A(s + 1, 0), );
        PHASE(1, 0, STG_A(s + 1, 1), );
        PHASE(2, 0, if (nl) STG_B(s + 2, 0), );
        PHASE(3, 0, if (nl) STG_B(s + 2, 1),
              if (nl) { asm volatile("s_waitcnt vmcnt(4)" ::: "memory"); } else { asm volatile("s_waitcnt vmcnt(0)" ::: "memory"); } __builtin_amdgcn_sched_barrier(0); );
        PHASE(4, 1, if (nl) STG_A(s + 2, 0), );
        PHASE(5, 1, if (nl) STG_A(s + 2, 1), );
        PHASE(6, 1, if (nl) STG_B(s + 3, 0), );
        PHASE(7, 1, if (nl) STG_B(s + 3, 1),
              if (nl) { asm volatile("s_waitcnt vmcnt(4)" ::: "memory"); __builtin_amdgcn_sched_barrier(0); } );
    }

    const int r0 = (lane >> 4) * 4;
    #pragma unroll
    for (int n = 0; n < 4; ++n) {
        int colb = bn + wc * 64 + n * 16;
        float bv = bias[colb + fr];
        #pragma unroll
        for (int m = 0; m < 8; ++m) {
            int rowb = bm + wr * 128 + m * 16 + r0;
            if (EPI == 3) {
                unsigned short* qkvB = (unsigned short*)Cout;
                int which = colb >> 10, hh = (colb & 1023) >> 6, dbase = colb & 63;
                int b_ = rowb >> 11, s_ = rowb & 2047;
                long bh2 = b_ * 16 + hh;
                float v[4];
                #pragma unroll
                for (int r = 0; r < 4; ++r) v[r] = acc[m][n][r] + bv;
                if (which == 2) {
                    ushort4v pk;
                    #pragma unroll
                    for (int r = 0; r < 4; ++r) pk[r] = f2bs(v[r]);
                    *(ushort4v*)&qkvB[8388608L + (bh2 * 64 + dbase + fr) * 2048 + s_] = pk;
                } else {
                    unsigned short* dst = qkvB + (long)which * 4194304L +
                                          (bh2 * 2048 + s_) * 64 + dbase + fr;
                    #pragma unroll
                    for (int r = 0; r < 4; ++r) dst[r * 64] = f2bs(v[r]);
                }
            } else {
                #pragma unroll
                for (int r = 0; r < 4; ++r) {
                    long row = rowb + r, col = colb + fr;
                    float v = acc[m][n][r] + bv;
                    v = 0.5f * v * (1.0f + erff(v * 0.70710678118f));
                    ((__hip_bfloat16*)Cout)[row * N + col] = __float2bfloat16(v);
                }
            }
        }
    }
}

// ---------------- n64 GEMM body (2-phase dbuf), dynamic smem 24KB ----------------
__device__ void n64_body(char* smem, int bx, int by,
                         const unsigned short* __restrict__ A,
                         const unsigned short* __restrict__ BT,
                         const float* __restrict__ bias, const float* __restrict__ R,
                         float* __restrict__ Cout, int M, int N, int K) {
    unsigned short* As = (unsigned short*)smem;          // [2][128*32]
    unsigned short* Bs = As + 2 * 128 * 32;              // [2][64*32]
    const int tid = threadIdx.x;
    const int w = tid >> 6, lane = tid & 63;
    const int bm = by * 128, bn = bx * 64;
    const int wr = (w >> 1) * 64, wc = (w & 1) * 32;

    f32x4 acc[4][2];
    #pragma unroll
    for (int m = 0; m < 4; ++m)
        #pragma unroll
        for (int n = 0; n < 2; ++n)
            acc[m][n] = (f32x4){0.f, 0.f, 0.f, 0.f};

    const int lrow = lane >> 2;
    const int lcol = (lane & 3) * 8;
    const unsigned short* gA = A + (long)(bm + w * 32 + lrow) * K + lcol;
    const unsigned short* gB = BT + (long)(bn + w * 16 + lrow) * K + lcol;

#define N64_STAGE(K0, BB) do { \
    gl_lds16(gA + (K0),          &As[(BB) * 4096 + (w * 32) * 32]); \
    gl_lds16(gA + (K0) + 16 * K, &As[(BB) * 4096 + (w * 32 + 16) * 32]); \
    gl_lds16(gB + (K0),          &Bs[(BB) * 2048 + (w * 16) * 32]); \
} while (0)

    N64_STAGE(0, 0);
    asm volatile("s_waitcnt vmcnt(0)" ::: "memory");
    __builtin_amdgcn_sched_barrier(0);
    __builtin_amdgcn_s_barrier();

    const int T = K >> 5;
    for (int t = 0; t < T; ++t) {
        const int buf = t & 1;
        if (t + 1 < T) N64_STAGE((t + 1) * 32, buf ^ 1);

        bf16x8 a[4], b[2];
        #pragma unroll
        for (int m = 0; m < 4; ++m)
            a[m] = *(const bf16x8*)&As[buf * 4096 + (wr + m * 16 + (lane & 15)) * 32 + (lane >> 4) * 8];
        #pragma unroll
        for (int n = 0; n < 2; ++n)
            b[n] = *(const bf16x8*)&Bs[buf * 2048 + (wc + n * 16 + (lane & 15)) * 32 + (lane >> 4) * 8];
        #pragma unroll
        for (int m = 0; m < 4; ++m)
            #pragma unroll
            for (int n = 0; n < 2; ++n)
                acc[m][n] = __builtin_amdgcn_mfma_f32_16x16x32_bf16(a[m], b[n], acc[m][n], 0, 0, 0);

        asm volatile("s_waitcnt vmcnt(0)" ::: "memory");
        __builtin_amdgcn_sched_barrier(0);
        __builtin_amdgcn_s_barrier();
    }
#undef N64_STAGE

    const int r0 = (lane >> 4) * 4, cc = lane & 15;
    #pragma unroll
    for (int n = 0; n < 2; ++n) {
        int colb = bn + wc + n * 16;
        float bv = bias[colb + cc];
        #pragma unroll
        for (int m = 0; m < 4; ++m) {
            int rowb = bm + wr + m * 16 + r0;
            #pragma unroll
            for (int r = 0; r < 4; ++r) {
                long row = rowb + r, col = colb + cc;
                float v = acc[m][n][r] + bv + R[row * N + col];
                Cout[row * N + col] = v;
            }
        }
    }
}

// ---------------- MFMA flash attention body, QBLK=128, KVBLK=128, 8 waves ----------------
// smem: Ks[128][64] 16K | Vs[64][128] 16K | Ps 8x[16][128] 32K = 64K
__device__ void attn_body(char* smem, int bh, int qb,
                          const unsigned short* __restrict__ qB,
                          const unsigned short* __restrict__ kB,
                          const unsigned short* __restrict__ vT,
                          __hip_bfloat16* __restrict__ z) {
    const int tid = threadIdx.x, w = tid >> 6, lane = tid & 63;
    const int arow = lane & 15, kg = lane >> 4;
    unsigned short* Ks = (unsigned short*)smem;
    unsigned short* Vs = Ks + 128 * 64;
    unsigned short* Ps = Vs + 64 * 128 + w * 16 * 128;

    const long kvbase = (long)bh * (2048 * 64);

    bf16x8 qa[2];
    {
        const unsigned short* q0 = qB + kvbase + (long)(qb + w * 16 + arow) * 64 + kg * 8;
        qa[0] = *(const bf16x8*)(q0);
        qa[1] = *(const bf16x8*)(q0 + 32);
    }

    f32x4 po[4];
    float mrow[4], lrow[4];
    #pragma unroll
    for (int i = 0; i < 4; ++i) {
        po[i] = (f32x4){0.f, 0.f, 0.f, 0.f};
        mrow[i] = -1e30f; lrow[i] = 0.f;
    }

    const int ksrow = lane >> 3;
    const int kschunk = (lane & 7) ^ ksrow;
    const int vsr = lane >> 4;
    const int cmax = qb >> 7;

    for (int c = 0; c <= cmax; ++c) {
        {
            const unsigned short* ks0 = kB + kvbase +
                (long)(c * 128 + w * 16 + ksrow) * 64 + kschunk * 8;
            #pragma unroll
            for (int i = 0; i < 2; ++i)
                gl_lds16(ks0 + (long)i * 8 * 64, &Ks[(w * 16 + i * 8) * 64]);
            #pragma unroll
            for (int i = 0; i < 2; ++i) {
                int d = w * 8 + i * 4 + vsr;
                int sch = (lane & 15) ^ (d & 7);
                gl_lds16(vT + kvbase + (long)d * 2048 + c * 128 + sch * 8,
                         &Vs[(w * 8 + i * 4) * 128]);
            }
        }
        __syncthreads();

        f32x4 s[8];
        #pragma unroll
        for (int n = 0; n < 8; ++n) {
            s[n] = (f32x4){0.f, 0.f, 0.f, 0.f};
            int row = n * 16 + arow, sw = row & 7;
            bf16x8 kb0 = *(const bf16x8*)&Ks[row * 64 + (kg ^ sw) * 8];
            bf16x8 kb1 = *(const bf16x8*)&Ks[row * 64 + ((4 + kg) ^ sw) * 8];
            s[n] = __builtin_amdgcn_mfma_f32_16x16x32_bf16(qa[0], kb0, s[n], 0, 0, 0);
            s[n] = __builtin_amdgcn_mfma_f32_16x16x32_bf16(qa[1], kb1, s[n], 0, 0, 0);
        }

        const bool diag = (c == cmax);
        #pragma unroll
        for (int n = 0; n < 8; ++n)
            #pragma unroll
            for (int r = 0; r < 4; ++r) {
                float v = s[n][r] * 0.125f;
                if (diag) {
                    int key = c * 128 + n * 16 + arow;
                    int qrow = qb + w * 16 + kg * 4 + r;
                    if (key > qrow) v = -1e30f;
                }
                s[n][r] = v;
            }

        #pragma unroll
        for (int r = 0; r < 4; ++r) {
            float rm = s[0][r];
            #pragma unroll
            for (int n = 1; n < 8; ++n) rm = fmaxf(rm, s[n][r]);
            #pragma unroll
            for (int off = 1; off < 16; off <<= 1)
                rm = fmaxf(rm, __shfl_xor(rm, off));
            float mnew = fmaxf(mrow[r], rm);
            float esc = expf(mrow[r] - mnew);
            float rs = 0.f;
            #pragma unroll
            for (int n = 0; n < 8; ++n) {
                float p = expf(s[n][r] - mnew);
                s[n][r] = p;
                rs += p;
            }
            #pragma unroll
            for (int off = 1; off < 16; off <<= 1)
                rs += __shfl_xor(rs, off);
            lrow[r] = lrow[r] * esc + rs;
            #pragma unroll
            for (int dt = 0; dt < 4; ++dt) po[dt][r] *= esc;
            mrow[r] = mnew;
        }

        #pragma unroll
        for (int n = 0; n < 8; ++n) {
            int col = n * 16 + arow;
            int chunk = col >> 3, cw = col & 7;
            #pragma unroll
            for (int r = 0; r < 4; ++r) {
                int row = kg * 4 + r;
                Ps[row * 128 + ((chunk ^ (row & 7)) * 8 + cw)] = f2bs(s[n][r]);
            }
        }

        bf16x8 pa[4];
        #pragma unroll
        for (int ks = 0; ks < 4; ++ks)
            pa[ks] = *(const bf16x8*)&Ps[arow * 128 + (((ks * 4 + kg) ^ (arow & 7)) * 8)];
        #pragma unroll
        for (int dt = 0; dt < 4; ++dt) {
            int vrow = dt * 16 + arow, sw = vrow & 7;
            #pragma unroll
            for (int ks = 0; ks < 4; ++ks) {
                bf16x8 vb = *(const bf16x8*)&Vs[vrow * 128 + (((ks * 4 + kg) ^ sw) * 8)];
                po[dt] = __builtin_amdgcn_mfma_f32_16x16x32_bf16(pa[ks], vb, po[dt], 0, 0, 0);
            }
        }
        __syncthreads();
    }

    const int b_ = bh >> 4, hofs = (bh & 15) * 64;
    #pragma unroll
    for (int dt = 0; dt < 4; ++dt)
        #pragma unroll
        for (int r = 0; r < 4; ++r) {
            long row = (long)b_ * 2048 + qb + w * 16 + kg * 4 + r;
            z[row * 1024 + hofs + dt * 16 + arow] = __float2bfloat16(po[dt][r] / lrow[r]);
        }
}

// ---------------- fused kernels ----------------
__global__ __launch_bounds__(256)
void fused_embed_convT(const int* __restrict__ x, const float* __restrict__ wte,
                       const float* __restrict__ wpe, float* __restrict__ h,
                       const float* __restrict__ W, unsigned short* __restrict__ WT,
                       int K, int N, int nEmb) {
    extern __shared__ char smem[];
    int bid = blockIdx.x;
    if (bid < nEmb) {
        embed_body(bid, x, wte, wpe, h);
    } else {
        int r = bid - nEmb, kt = K >> 6;
        convT_body(smem, r % kt, r / kt, W, WT, K, N);
    }
}

// attn QBLK=128 heavy-first (nAttn) + convT proj -> WT1 (n1) + convT cp -> WT2; 512 thr
__global__ __launch_bounds__(512)
void fused_attn_convT2(const unsigned short* __restrict__ qB,
                       const unsigned short* __restrict__ kB,
                       const unsigned short* __restrict__ vT,
                       __hip_bfloat16* __restrict__ z,
                       const float* __restrict__ W1, unsigned short* __restrict__ WT1,
                       int K1, int N1, int n1,
                       const float* __restrict__ W2, unsigned short* __restrict__ WT2,
                       int K2, int N2, int nAttn) {
    extern __shared__ char smem[];
    int bid = blockIdx.x;
    if (bid < nAttn) {
        int bh = bid & 31;
        int qblk = 15 - (bid >> 5);           // heavy-first
        attn_body(smem, bh, qblk * 128, qB, kB, vT, z);
    } else if (bid < nAttn + n1) {
        int r = bid - nAttn, kt = K1 >> 6;
        convT_body512(smem, r % kt, r / kt, W1, WT1, K1, N1);
    } else {
        int r = bid - nAttn - n1, kt = K2 >> 6;
        convT_body512(smem, r % kt, r / kt, W2, WT2, K2, N2);
    }
}

// n64 GEMM (nMM, bx=bid%nbx) + optional convT -> WT2 (nConv blocks)
__global__ __launch_bounds__(256)
void fused_n64_convT(const unsigned short* __restrict__ A,
                     const unsigned short* __restrict__ BT,
                     const float* __restrict__ bias, const float* __restrict__ R,
                     float* __restrict__ Cout, int M, int N, int K, int nbx,
                     const float* __restrict__ W2, unsigned short* __restrict__ WT2,
                     int K2, int N2, int nMM) {
    extern __shared__ char smem[];
    int bid = blockIdx.x;
    if (bid < nMM) {
        n64_body(smem, bid % nbx, bid / nbx, A, BT, bias, R, Cout, M, N, K);
    } else {
        int r = bid - nMM, kt = K2 >> 6;
        convT_body(smem, r % kt, r / kt, W2, WT2, K2, N2);
    }
}

// ---------------- head ----------------
__global__ void head_kernel(const float* __restrict__ hl, const float* __restrict__ W,
                            float* __restrict__ out) {
    __shared__ float hs[2 * DMODEL];
    int tid = threadIdx.x;
    #pragma unroll
    for (int i = 0; i < 8; ++i) hs[tid + i * 256] = hl[tid + i * 256];
    __syncthreads();
    int v = blockIdx.x * 256 + tid;
    if (v >= VOCAB) return;
    float a0 = 0.f, a1 = 0.f;
    for (int d = 0; d < DMODEL; ++d) {
        float wv = W[(long)d * VOCAB + v];
        a0 += hs[d] * wv;
        a1 += hs[DMODEL + d] * wv;
    }
    out[v] = a0;
    out[VOCAB + v] = a1;
}

extern "C" void kernel_launch(void* const* d_in, const int* in_sizes, int n_in,
                              void* d_out, int out_size, void* d_ws, size_t ws_size,
                              hipStream_t stream) {
    const int*   x      = (const int*)  d_in[0];
    const float* wte    = (const float*)d_in[1];
    const float* wpe    = (const float*)d_in[2];
    const float* ln1_g  = (const float*)d_in[3];
    const float* ln1_b  = (const float*)d_in[4];
    const float* w_qkv  = (const float*)d_in[5];
    const float* b_qkv  = (const float*)d_in[6];
    const float* w_proj = (const float*)d_in[7];
    const float* b_proj = (const float*)d_in[8];
    const float* ln2_g  = (const float*)d_in[9];
    const float* ln2_b  = (const float*)d_in[10];
    const float* w_fc   = (const float*)d_in[11];
    const float* b_fc   = (const float*)d_in[12];
    const float* w_cp   = (const float*)d_in[13];
    const float* b_cp   = (const float*)d_in[14];
    const float* lnf_g  = (const float*)d_in[15];
    const float* lnf_b  = (const float*)d_in[16];
    const float* w_head = (const float*)d_in[17];
    float* out = (float*)d_out;

    char* ws = (char*)d_ws;
    float*          h     = (float*)ws;                             // 16 MB
    unsigned short* qkvB  = (unsigned short*)(ws + (16L << 20));    // 24 MB
    unsigned short* y_bf  = (unsigned short*)(ws + (40L << 20));    // 8 MB
    __hip_bfloat16* z_bf  = (__hip_bfloat16*)(ws + (48L << 20));    // 8 MB
    unsigned short* fc_bf = (unsigned short*)(ws + (56L << 20));    // 32 MB
    unsigned short* wT_a  = (unsigned short*)(ws + (88L << 20));    // 8 MB (fc)
    unsigned short* wT_b  = (unsigned short*)(ws + (97L << 20));    // 8 MB (proj)
    unsigned short* wT_c  = (unsigned short*)(ws + (106L << 20));   // 8 MB (cp)
    unsigned short* wT_q  = (unsigned short*)(ws + (115L << 20));   // 8 MB (qkv)
    float*          hl    = (float*)(ws + (124L << 20));            // 8 KB

    const int SM_CONV = 16640;   // 64*65*4
    const int SM_ATTN = 65536;   // Ks 16K + Vs 16K + Ps 32K
    const int SM_N64  = 24576;   // As(16K)+Bs(8K), >= SM_CONV

    // P: embed (4096) + convT qkv layer 0 (768) -> wT_q
    fused_embed_convT<<<4096 + 768, 256, SM_CONV, stream>>>(
        x, wte, wpe, h, w_qkv, wT_q, 1024, 3072, 4096);

    for (int l = 0; l < NLAYER; ++l) {
        // A: LN1 (wave-per-row)
        ln_wave<<<NTOK / 4, 256, 0, stream>>>(h, y_bf, ln1_g + l * DMODEL, ln1_b + l * DMODEL);

        // B: qkv GEMM (reads wT_q produced by P or previous G)
        mm_mfma256<3><<<192, 512, 131072, stream>>>(
            y_bf, wT_q, b_qkv + l * 3072, qkvB, NTOK, 3072, 1024, 12);

        // C: attn QBLK=128 (512) + convT proj -> wT_b (256) + convT cp -> wT_c (1024)
        fused_attn_convT2<<<512 + 256 + 1024, 512, SM_ATTN, stream>>>(
            qkvB, qkvB + 4194304L, qkvB + 8388608L, z_bf,
            w_proj + (long)l * DMODEL * DMODEL, wT_b, 1024, 1024, 256,
            w_cp + (long)l * 4096 * DMODEL, wT_c, 4096, 1024, 512);

        // D: proj GEMM (+residual) + convT fc -> wT_a (1024)
        fused_n64_convT<<<512 + 1024, 256, SM_N64, stream>>>(
            (const unsigned short*)z_bf, wT_b, b_proj + l * DMODEL, h, h,
            NTOK, 1024, 1024, 16,
            w_fc + (long)l * DMODEL * 4096, wT_a, 1024, 4096, 512);

        // E: LN2 (wave-per-row)
        ln_wave<<<NTOK / 4, 256, 0, stream>>>(h, y_bf, ln2_g + l * DMODEL, ln2_b + l * DMODEL);

        // F: fc GEMM (256^2 8-phase, gelu; reads wT_a)
        mm_mfma256<2><<<256, 512, 131072, stream>>>(
            y_bf, wT_a, b_fc + l * 4096, fc_bf, NTOK, 4096, 1024, 16);

        // G: cp GEMM (+residual) + convT qkv(l+1) -> wT_q (768; none on last layer)
        int nConv = (l + 1 < NLAYER) ? 768 : 0;
        fused_n64_convT<<<512 + nConv, 256, SM_N64, stream>>>(
            fc_bf, wT_c, b_cp + l * DMODEL, h, h, NTOK, 1024, 4096, 16,
            w_qkv + (long)(l + 1) * DMODEL * 3072, wT_q, 1024, 3072, 512);
    }

    ln_final<<<BATCH, 256, 0, stream>>>(h + (long)(SEQ - 1) * DMODEL, hl,
                                        lnf_g, lnf_b, (long)SEQ * DMODEL);
    head_kernel<<<(VOCAB + 255) / 256, 256, 0, stream>>>(hl, w_head, out);
}

// Round 16
// 2275.479 us; speedup vs baseline: 1.3855x; 1.0336x over previous
//
#include <hip/hip_runtime.h>
#include <hip/hip_bf16.h>
#include <math.h>

#define VOCAB 50257
#define CTX 2048
#define DMODEL 1024
#define NHEAD 16
#define NLAYER 8
#define DHEAD 64
#define BATCH 2
#define SEQ 2048
#define NTOK (BATCH * SEQ)   // 4096

typedef __bf16 bf16x8 __attribute__((ext_vector_type(8)));
typedef float  f32x4  __attribute__((ext_vector_type(4)));
typedef unsigned short ushort4v __attribute__((ext_vector_type(4)));
typedef unsigned short ushort8v __attribute__((ext_vector_type(8)));

__device__ inline void gl_lds16(const void* g, void* l) {
    __builtin_amdgcn_global_load_lds(
        (const __attribute__((address_space(1))) unsigned int*)g,
        (__attribute__((address_space(3))) unsigned int*)l, 16, 0, 0);
}

__device__ inline unsigned short f2bs(float v) {
    __hip_bfloat16 t = __float2bfloat16(v);
    return *(unsigned short*)&t;
}

// ---------------- embedding body ----------------
__device__ void embed_body(int t, const int* __restrict__ x,
                           const float* __restrict__ wte,
                           const float* __restrict__ wpe,
                           float* __restrict__ h) {
    int s = t & (SEQ - 1);
    int tok = x[t];
    const float* pe = wpe + (long)s * DMODEL;
    const float* te = wte + (long)tok * DMODEL;
    float* ph = h + (long)t * DMODEL;
    for (int d = threadIdx.x; d < DMODEL; d += 256)
        ph[d] = te[d] + pe[d];
}

// ---------------- layernorm ----------------
__device__ inline float wave_sum(float v) {
    for (int off = 32; off; off >>= 1) v += __shfl_xor(v, off);
    return v;
}

// wave-per-row LN: 4 waves/block, each owns one row; no barriers, vector loads
__global__ void ln_wave(const float* __restrict__ in, unsigned short* __restrict__ out,
                        const float* __restrict__ g, const float* __restrict__ b) {
    const int w = threadIdx.x >> 6, lane = threadIdx.x & 63;
    const int row = blockIdx.x * 4 + w;
    const float* px = in + (long)row * DMODEL;
    f32x4 x[4];
    float s = 0.f;
    #pragma unroll
    for (int i = 0; i < 4; ++i) {
        x[i] = *(const f32x4*)&px[i * 256 + lane * 4];
        s += x[i][0] + x[i][1] + x[i][2] + x[i][3];
    }
    s = wave_sum(s);
    const float mean = s * (1.0f / DMODEL);
    float s2 = 0.f;
    #pragma unroll
    for (int i = 0; i < 4; ++i)
        #pragma unroll
        for (int j = 0; j < 4; ++j) { float d = x[i][j] - mean; s2 += d * d; }
    s2 = wave_sum(s2);
    const float r = 1.0f / sqrtf(s2 * (1.0f / DMODEL) + 1e-5f);
    unsigned short* po = out + (long)row * DMODEL;
    #pragma unroll
    for (int i = 0; i < 4; ++i) {
        const int d0 = i * 256 + lane * 4;
        f32x4 gv = *(const f32x4*)&g[d0];
        f32x4 bv = *(const f32x4*)&b[d0];
        ushort4v pk;
        #pragma unroll
        for (int j = 0; j < 4; ++j)
            pk[j] = f2bs((x[i][j] - mean) * r * gv[j] + bv[j]);
        *(ushort4v*)&po[d0] = pk;
    }
}

__global__ void ln_final(const float* __restrict__ in, float* __restrict__ out,
                         const float* __restrict__ g, const float* __restrict__ b,
                         long row_stride) {
    __shared__ float red[4], red2[4];
    int row = blockIdx.x;
    const float* px = in + (long)row * row_stride;
    float* po = out + (long)row * DMODEL;
    int tid = threadIdx.x;
    int wid = tid >> 6, lane = tid & 63;
    float x[4];
    float s = 0.f;
    #pragma unroll
    for (int i = 0; i < 4; ++i) { x[i] = px[tid + i * 256]; s += x[i]; }
    s = wave_sum(s);
    if (lane == 0) red[wid] = s;
    __syncthreads();
    float mean = (red[0] + red[1] + red[2] + red[3]) * (1.0f / DMODEL);
    float s2 = 0.f;
    #pragma unroll
    for (int i = 0; i < 4; ++i) { float d = x[i] - mean; s2 += d * d; }
    s2 = wave_sum(s2);
    if (lane == 0) red2[wid] = s2;
    __syncthreads();
    float var = (red2[0] + red2[1] + red2[2] + red2[3]) * (1.0f / DMODEL);
    float r = 1.0f / sqrtf(var + 1e-5f);
    #pragma unroll
    for (int i = 0; i < 4; ++i) {
        int d = tid + i * 256;
        po[d] = (x[i] - mean) * r * g[d] + b[d];
    }
}

// ------------- transpose+convert bodies: W f32 [K][N] -> WT bf16 [N][K] -------------
__device__ void convT_body(char* smem, int kx, int ny, const float* __restrict__ W,
                           unsigned short* __restrict__ WT, int K, int N) {
    float (*t)[65] = (float(*)[65])smem;
    const int k0 = kx * 64, n0 = ny * 64;
    const int tid = threadIdx.x;
    {
        const int krow = tid >> 4, c4 = (tid & 15) * 4;
        #pragma unroll
        for (int p = 0; p < 4; ++p) {
            f32x4 gv = *(const f32x4*)&W[(long)(k0 + p * 16 + krow) * N + n0 + c4];
            #pragma unroll
            for (int j = 0; j < 4; ++j) t[p * 16 + krow][c4 + j] = gv[j];
        }
    }
    __syncthreads();
    {
        const int n = tid >> 3, kl = (tid & 7) * 8;
        #pragma unroll
        for (int p = 0; p < 2; ++p) {
            ushort8v pk;
            #pragma unroll
            for (int j = 0; j < 8; ++j) pk[j] = f2bs(t[kl + j][p * 32 + n]);
            *(ushort8v*)&WT[(long)(n0 + p * 32 + n) * K + k0 + kl] = pk;
        }
    }
}

// 512-thread variant (for the 512-thread fused attention kernel)
__device__ void convT_body512(char* smem, int kx, int ny, const float* __restrict__ W,
                              unsigned short* __restrict__ WT, int K, int N) {
    float (*t)[65] = (float(*)[65])smem;
    const int k0 = kx * 64, n0 = ny * 64;
    const int tid = threadIdx.x;
    {
        const int krow = tid >> 4, c4 = (tid & 15) * 4;   // krow 0..31
        #pragma unroll
        for (int p = 0; p < 2; ++p) {
            f32x4 gv = *(const f32x4*)&W[(long)(k0 + p * 32 + krow) * N + n0 + c4];
            #pragma unroll
            for (int j = 0; j < 4; ++j) t[p * 32 + krow][c4 + j] = gv[j];
        }
    }
    __syncthreads();
    {
        const int n = tid >> 3, kl = (tid & 7) * 8;       // n 0..63
        ushort8v pk;
        #pragma unroll
        for (int j = 0; j < 8; ++j) pk[j] = f2bs(t[kl + j][n]);
        *(ushort8v*)&WT[(long)(n0 + n) * K + k0 + kl] = pk;
    }
}

// ---------------- 256^2 8-phase bf16 MFMA GEMM ----------------
#define STG_A(KS, H) do { \
    const unsigned short* g_ = A + (long)(bm + (H) * 128 + srow) * K + (KS) * 64 + stgch; \
    unsigned short* s_ = LDS + (((KS) & 1) * 2 + (H)) * 8192 + (w * 8) * 64; \
    gl_lds16(g_, s_); gl_lds16(g_ + 64L * K, s_ + 4096); \
} while (0)
#define STG_B(KS, H) do { \
    const unsigned short* g_ = BT + (long)(bn + (H) * 128 + srow) * K + (KS) * 64 + stgch; \
    unsigned short* s_ = LDS + 32768 + (((KS) & 1) * 2 + (H)) * 8192 + (w * 8) * 64; \
    gl_lds16(g_, s_); gl_lds16(g_ + 64L * K, s_ + 4096); \
} while (0)
#define MM2(M_, x0, x1) do { \
    acc[M_][0] = __builtin_amdgcn_mfma_f32_16x16x32_bf16(x0, bfr[0], acc[M_][0], 0, 0, 0); \
    acc[M_][0] = __builtin_amdgcn_mfma_f32_16x16x32_bf16(x1, bfr[1], acc[M_][0], 0, 0, 0); \
    acc[M_][1] = __builtin_amdgcn_mfma_f32_16x16x32_bf16(x0, bfr[2], acc[M_][1], 0, 0, 0); \
    acc[M_][1] = __builtin_amdgcn_mfma_f32_16x16x32_bf16(x1, bfr[3], acc[M_][1], 0, 0, 0); \
    acc[M_][2] = __builtin_amdgcn_mfma_f32_16x16x32_bf16(x0, bfr[4], acc[M_][2], 0, 0, 0); \
    acc[M_][2] = __builtin_amdgcn_mfma_f32_16x16x32_bf16(x1, bfr[5], acc[M_][2], 0, 0, 0); \
    acc[M_][3] = __builtin_amdgcn_mfma_f32_16x16x32_bf16(x0, bfr[6], acc[M_][3], 0, 0, 0); \
    acc[M_][3] = __builtin_amdgcn_mfma_f32_16x16x32_bf16(x1, bfr[7], acc[M_][3], 0, 0, 0); \
} while (0)
#define PHASE(Q, SPAR, STAGE_STMT, TAIL_STMT) do { \
    bf16x8 a00, a01, a10, a11; \
    if (((Q) & 3) == 0) { \
        const unsigned short* Bb_ = lBp[SPAR] + ((wc & 1) * 64 + fr) * 64; \
        bfr[0] = *(const bf16x8*)(Bb_ + rd0);        bfr[1] = *(const bf16x8*)(Bb_ + rd1); \
        bfr[2] = *(const bf16x8*)(Bb_ + 1024 + rd0); bfr[3] = *(const bf16x8*)(Bb_ + 1024 + rd1); \
        bfr[4] = *(const bf16x8*)(Bb_ + 2048 + rd0); bfr[5] = *(const bf16x8*)(Bb_ + 2048 + rd1); \
        bfr[6] = *(const bf16x8*)(Bb_ + 3072 + rd0); bfr[7] = *(const bf16x8*)(Bb_ + 3072 + rd1); \
    } \
    { const unsigned short* Ab_ = lAp[SPAR] + fr * 64; \
      a00 = *(const bf16x8*)(Ab_ + (((Q) & 3) * 2) * 1024 + rd0); \
      a01 = *(const bf16x8*)(Ab_ + (((Q) & 3) * 2) * 1024 + rd1); \
      a10 = *(const bf16x8*)(Ab_ + (((Q) & 3) * 2 + 1) * 1024 + rd0); \
      a11 = *(const bf16x8*)(Ab_ + (((Q) & 3) * 2 + 1) * 1024 + rd1); } \
    STAGE_STMT; \
    __builtin_amdgcn_s_barrier(); \
    asm volatile("s_waitcnt lgkmcnt(0)" ::: "memory"); \
    __builtin_amdgcn_sched_barrier(0); \
    __builtin_amdgcn_s_setprio(1); \
    MM2(((Q) & 3) * 2, a00, a01); \
    MM2(((Q) & 3) * 2 + 1, a10, a11); \
    __builtin_amdgcn_s_setprio(0); \
    TAIL_STMT; \
    __builtin_amdgcn_s_barrier(); \
} while (0)

template<int EPI>
__global__ __launch_bounds__(512, 1)
void mm_mfma256(const unsigned short* __restrict__ A,
                const unsigned short* __restrict__ BT,
                const float* __restrict__ bias,
                void* __restrict__ Cout, int M, int N, int K, int nbx) {
    extern __shared__ unsigned short LDS[];
    const int tid = threadIdx.x;
    const int w = tid >> 6, lane = tid & 63;
    const int wr = w >> 2, wc = w & 3;
    const int nwg = gridDim.x, bid = blockIdx.x;
    const int swz = (bid & 7) * (nwg >> 3) + (bid >> 3);
    const int bm = (swz / nbx) * 256, bn = (swz % nbx) * 256;

    f32x4 acc[8][4];
    #pragma unroll
    for (int m = 0; m < 8; ++m)
        #pragma unroll
        for (int n = 0; n < 4; ++n)
            acc[m][n] = (f32x4){0.f, 0.f, 0.f, 0.f};

    const int fr = lane & 15, kg = lane >> 4;
    const int rd0 = 8 * (kg ^ (lane & 7)), rd1 = 8 * ((kg + 4) ^ (lane & 7));
    const int stgch = 8 * ((lane & 7) ^ (lane >> 3));
    const int srow = w * 8 + (lane >> 3);
    unsigned short* const lAp[2] = { LDS + wr * 8192, LDS + (2 + wr) * 8192 };
    unsigned short* const lBp[2] = { LDS + 32768 + (wc >> 1) * 8192,
                                     LDS + 32768 + (2 + (wc >> 1)) * 8192 };
    bf16x8 bfr[8];

    STG_B(0, 0); STG_B(0, 1); STG_A(0, 0); STG_A(0, 1); STG_B(1, 0); STG_B(1, 1);
    asm volatile("s_waitcnt vmcnt(4)" ::: "memory");
    __builtin_amdgcn_sched_barrier(0);
    __builtin_amdgcn_s_barrier();

    const int T = K >> 7;
    for (int t = 0; t < T; ++t) {
        const int s = 2 * t;
        const bool nl = (t < T - 1);
        PHASE(0, 0, STG_A(s + 1, 0), );
        PHASE(1, 0, STG_A(s + 1, 1), );
        PHASE(2, 0, if (nl) STG_B(s + 2, 0), );
        PHASE(3, 0, if (nl) STG_B(s + 2, 1),
              if (nl) { asm volatile("s_waitcnt vmcnt(4)" ::: "memory"); } else { asm volatile("s_waitcnt vmcnt(0)" ::: "memory"); } __builtin_amdgcn_sched_barrier(0); );
        PHASE(4, 1, if (nl) STG_A(s + 2, 0), );
        PHASE(5, 1, if (nl) STG_A(s + 2, 1), );
        PHASE(6, 1, if (nl) STG_B(s + 3, 0), );
        PHASE(7, 1, if (nl) STG_B(s + 3, 1),
              if (nl) { asm volatile("s_waitcnt vmcnt(4)" ::: "memory"); __builtin_amdgcn_sched_barrier(0); } );
    }

    const int r0 = (lane >> 4) * 4;
    #pragma unroll
    for (int n = 0; n < 4; ++n) {
        int colb = bn + wc * 64 + n * 16;
        float bv = bias[colb + fr];
        #pragma unroll
        for (int m = 0; m < 8; ++m) {
            int rowb = bm + wr * 128 + m * 16 + r0;
            if (EPI == 3) {
                unsigned short* qkvB = (unsigned short*)Cout;
                int which = colb >> 10, hh = (colb & 1023) >> 6, dbase = colb & 63;
                int b_ = rowb >> 11, s_ = rowb & 2047;
                long bh2 = b_ * 16 + hh;
                float v[4];
                #pragma unroll
                for (int r = 0; r < 4; ++r) v[r] = acc[m][n][r] + bv;
                if (which == 2) {
                    ushort4v pk;
                    #pragma unroll
                    for (int r = 0; r < 4; ++r) pk[r] = f2bs(v[r]);
                    *(ushort4v*)&qkvB[8388608L + (bh2 * 64 + dbase + fr) * 2048 + s_] = pk;
                } else {
                    unsigned short* dst = qkvB + (long)which * 4194304L +
                                          (bh2 * 2048 + s_) * 64 + dbase + fr;
                    #pragma unroll
                    for (int r = 0; r < 4; ++r) dst[r * 64] = f2bs(v[r]);
                }
            } else {
                #pragma unroll
                for (int r = 0; r < 4; ++r) {
                    long row = rowb + r, col = colb + fr;
                    float v = acc[m][n][r] + bv;
                    v = 0.5f * v * (1.0f + erff(v * 0.70710678118f));
                    ((__hip_bfloat16*)Cout)[row * N + col] = __float2bfloat16(v);
                }
            }
        }
    }
}

// ---------------- n64 GEMM body (2-phase, counted vmcnt(3)), dynamic smem 24KB ----------------
// T4 schedule: stage(t+1) issued, then vmcnt(3) (waits t's loads only; t+1's
// 3 loads stay in flight across the barrier and hide under MFMA of tile t).
__device__ void n64_body(char* smem, int bx, int by,
                         const unsigned short* __restrict__ A,
                         const unsigned short* __restrict__ BT,
                         const float* __restrict__ bias, const float* __restrict__ R,
                         float* __restrict__ Cout, int M, int N, int K) {
    unsigned short* As = (unsigned short*)smem;          // [2][128*32]
    unsigned short* Bs = As + 2 * 128 * 32;              // [2][64*32]
    const int tid = threadIdx.x;
    const int w = tid >> 6, lane = tid & 63;
    const int bm = by * 128, bn = bx * 64;
    const int wr = (w >> 1) * 64, wc = (w & 1) * 32;

    f32x4 acc[4][2];
    #pragma unroll
    for (int m = 0; m < 4; ++m)
        #pragma unroll
        for (int n = 0; n < 2; ++n)
            acc[m][n] = (f32x4){0.f, 0.f, 0.f, 0.f};

    const int lrow = lane >> 2;
    const int lcol = (lane & 3) * 8;
    const unsigned short* gA = A + (long)(bm + w * 32 + lrow) * K + lcol;
    const unsigned short* gB = BT + (long)(bn + w * 16 + lrow) * K + lcol;

#define N64_STAGE(K0, BB) do { \
    gl_lds16(gA + (K0),          &As[(BB) * 4096 + (w * 32) * 32]); \
    gl_lds16(gA + (K0) + 16 * K, &As[(BB) * 4096 + (w * 32 + 16) * 32]); \
    gl_lds16(gB + (K0),          &Bs[(BB) * 2048 + (w * 16) * 32]); \
} while (0)

    N64_STAGE(0, 0);

    const int T = K >> 5;
    for (int t = 0; t < T; ++t) {
        const int buf = t & 1;
        if (t + 1 < T) {
            N64_STAGE((t + 1) * 32, buf ^ 1);
            asm volatile("s_waitcnt vmcnt(3)" ::: "memory");   // t's 3 loads landed
        } else {
            asm volatile("s_waitcnt vmcnt(0)" ::: "memory");
        }
        __builtin_amdgcn_sched_barrier(0);
        __builtin_amdgcn_s_barrier();

        bf16x8 a[4], b[2];
        #pragma unroll
        for (int m = 0; m < 4; ++m)
            a[m] = *(const bf16x8*)&As[buf * 4096 + (wr + m * 16 + (lane & 15)) * 32 + (lane >> 4) * 8];
        #pragma unroll
        for (int n = 0; n < 2; ++n)
            b[n] = *(const bf16x8*)&Bs[buf * 2048 + (wc + n * 16 + (lane & 15)) * 32 + (lane >> 4) * 8];
        #pragma unroll
        for (int m = 0; m < 4; ++m)
            #pragma unroll
            for (int n = 0; n < 2; ++n)
                acc[m][n] = __builtin_amdgcn_mfma_f32_16x16x32_bf16(a[m], b[n], acc[m][n], 0, 0, 0);

        __builtin_amdgcn_s_barrier();   // buf t free for stage(t+2) next iter
    }
#undef N64_STAGE

    const int r0 = (lane >> 4) * 4, cc = lane & 15;
    #pragma unroll
    for (int n = 0; n < 2; ++n) {
        int colb = bn + wc + n * 16;
        float bv = bias[colb + cc];
        #pragma unroll
        for (int m = 0; m < 4; ++m) {
            int rowb = bm + wr + m * 16 + r0;
            #pragma unroll
            for (int r = 0; r < 4; ++r) {
                long row = rowb + r, col = colb + cc;
                float v = acc[m][n][r] + bv + R[row * N + col];
                Cout[row * N + col] = v;
            }
        }
    }
}

// ---------------- MFMA flash attention body, QBLK=128, KVBLK=128, 8 waves ----------------
// smem: Ks[128][64] 16K | Vs[64][128] 16K | Ps 8x[16][128] 32K = 64K
__device__ void attn_body(char* smem, int bh, int qb,
                          const unsigned short* __restrict__ qB,
                          const unsigned short* __restrict__ kB,
                          const unsigned short* __restrict__ vT,
                          __hip_bfloat16* __restrict__ z) {
    const int tid = threadIdx.x, w = tid >> 6, lane = tid & 63;
    const int arow = lane & 15, kg = lane >> 4;
    unsigned short* Ks = (unsigned short*)smem;
    unsigned short* Vs = Ks + 128 * 64;
    unsigned short* Ps = Vs + 64 * 128 + w * 16 * 128;

    const long kvbase = (long)bh * (2048 * 64);

    bf16x8 qa[2];
    {
        const unsigned short* q0 = qB + kvbase + (long)(qb + w * 16 + arow) * 64 + kg * 8;
        qa[0] = *(const bf16x8*)(q0);
        qa[1] = *(const bf16x8*)(q0 + 32);
    }

    f32x4 po[4];
    float mrow[4], lrow[4];
    #pragma unroll
    for (int i = 0; i < 4; ++i) {
        po[i] = (f32x4){0.f, 0.f, 0.f, 0.f};
        mrow[i] = -1e30f; lrow[i] = 0.f;
    }

    const int ksrow = lane >> 3;
    const int kschunk = (lane & 7) ^ ksrow;
    const int vsr = lane >> 4;
    const int cmax = qb >> 7;

    for (int c = 0; c <= cmax; ++c) {
        {
            const unsigned short* ks0 = kB + kvbase +
                (long)(c * 128 + w * 16 + ksrow) * 64 + kschunk * 8;
            #pragma unroll
            for (int i = 0; i < 2; ++i)
                gl_lds16(ks0 + (long)i * 8 * 64, &Ks[(w * 16 + i * 8) * 64]);
            #pragma unroll
            for (int i = 0; i < 2; ++i) {
                int d = w * 8 + i * 4 + vsr;
                int sch = (lane & 15) ^ (d & 7);
                gl_lds16(vT + kvbase + (long)d * 2048 + c * 128 + sch * 8,
                         &Vs[(w * 8 + i * 4) * 128]);
            }
        }
        __syncthreads();

        f32x4 s[8];
        #pragma unroll
        for (int n = 0; n < 8; ++n) {
            s[n] = (f32x4){0.f, 0.f, 0.f, 0.f};
            int row = n * 16 + arow, sw = row & 7;
            bf16x8 kb0 = *(const bf16x8*)&Ks[row * 64 + (kg ^ sw) * 8];
            bf16x8 kb1 = *(const bf16x8*)&Ks[row * 64 + ((4 + kg) ^ sw) * 8];
            s[n] = __builtin_amdgcn_mfma_f32_16x16x32_bf16(qa[0], kb0, s[n], 0, 0, 0);
            s[n] = __builtin_amdgcn_mfma_f32_16x16x32_bf16(qa[1], kb1, s[n], 0, 0, 0);
        }

        const bool diag = (c == cmax);
        #pragma unroll
        for (int n = 0; n < 8; ++n)
            #pragma unroll
            for (int r = 0; r < 4; ++r) {
                float v = s[n][r] * 0.125f;
                if (diag) {
                    int key = c * 128 + n * 16 + arow;
                    int qrow = qb + w * 16 + kg * 4 + r;
                    if (key > qrow) v = -1e30f;
                }
                s[n][r] = v;
            }

        #pragma unroll
        for (int r = 0; r < 4; ++r) {
            float rm = s[0][r];
            #pragma unroll
            for (int n = 1; n < 8; ++n) rm = fmaxf(rm, s[n][r]);
            #pragma unroll
            for (int off = 1; off < 16; off <<= 1)
                rm = fmaxf(rm, __shfl_xor(rm, off));
            float mnew = fmaxf(mrow[r], rm);
            float esc = expf(mrow[r] - mnew);
            float rs = 0.f;
            #pragma unroll
            for (int n = 0; n < 8; ++n) {
                float p = expf(s[n][r] - mnew);
                s[n][r] = p;
                rs += p;
            }
            #pragma unroll
            for (int off = 1; off < 16; off <<= 1)
                rs += __shfl_xor(rs, off);
            lrow[r] = lrow[r] * esc + rs;
            #pragma unroll
            for (int dt = 0; dt < 4; ++dt) po[dt][r] *= esc;
            mrow[r] = mnew;
        }

        #pragma unroll
        for (int n = 0; n < 8; ++n) {
            int col = n * 16 + arow;
            int chunk = col >> 3, cw = col & 7;
            #pragma unroll
            for (int r = 0; r < 4; ++r) {
                int row = kg * 4 + r;
                Ps[row * 128 + ((chunk ^ (row & 7)) * 8 + cw)] = f2bs(s[n][r]);
            }
        }

        bf16x8 pa[4];
        #pragma unroll
        for (int ks = 0; ks < 4; ++ks)
            pa[ks] = *(const bf16x8*)&Ps[arow * 128 + (((ks * 4 + kg) ^ (arow & 7)) * 8)];
        #pragma unroll
        for (int dt = 0; dt < 4; ++dt) {
            int vrow = dt * 16 + arow, sw = vrow & 7;
            #pragma unroll
            for (int ks = 0; ks < 4; ++ks) {
                bf16x8 vb = *(const bf16x8*)&Vs[vrow * 128 + (((ks * 4 + kg) ^ sw) * 8)];
                po[dt] = __builtin_amdgcn_mfma_f32_16x16x32_bf16(pa[ks], vb, po[dt], 0, 0, 0);
            }
        }
        __syncthreads();
    }

    const int b_ = bh >> 4, hofs = (bh & 15) * 64;
    #pragma unroll
    for (int dt = 0; dt < 4; ++dt)
        #pragma unroll
        for (int r = 0; r < 4; ++r) {
            long row = (long)b_ * 2048 + qb + w * 16 + kg * 4 + r;
            z[row * 1024 + hofs + dt * 16 + arow] = __float2bfloat16(po[dt][r] / lrow[r]);
        }
}

// ---------------- fused kernels ----------------
__global__ __launch_bounds__(256)
void fused_embed_convT(const int* __restrict__ x, const float* __restrict__ wte,
                       const float* __restrict__ wpe, float* __restrict__ h,
                       const float* __restrict__ W, unsigned short* __restrict__ WT,
                       int K, int N, int nEmb) {
    extern __shared__ char smem[];
    int bid = blockIdx.x;
    if (bid < nEmb) {
        embed_body(bid, x, wte, wpe, h);
    } else {
        int r = bid - nEmb, kt = K >> 6;
        convT_body(smem, r % kt, r / kt, W, WT, K, N);
    }
}

// attn QBLK=128 heavy-first (nAttn) + convT proj -> WT1 (n1) + convT cp -> WT2; 512 thr
__global__ __launch_bounds__(512)
void fused_attn_convT2(const unsigned short* __restrict__ qB,
                       const unsigned short* __restrict__ kB,
                       const unsigned short* __restrict__ vT,
                       __hip_bfloat16* __restrict__ z,
                       const float* __restrict__ W1, unsigned short* __restrict__ WT1,
                       int K1, int N1, int n1,
                       const float* __restrict__ W2, unsigned short* __restrict__ WT2,
                       int K2, int N2, int nAttn) {
    extern __shared__ char smem[];
    int bid = blockIdx.x;
    if (bid < nAttn) {
        int bh = bid & 31;
        int qblk = 15 - (bid >> 5);           // heavy-first
        attn_body(smem, bh, qblk * 128, qB, kB, vT, z);
    } else if (bid < nAttn + n1) {
        int r = bid - nAttn, kt = K1 >> 6;
        convT_body512(smem, r % kt, r / kt, W1, WT1, K1, N1);
    } else {
        int r = bid - nAttn - n1, kt = K2 >> 6;
        convT_body512(smem, r % kt, r / kt, W2, WT2, K2, N2);
    }
}

// n64 GEMM (nMM, bx=bid%nbx) + optional convT -> WT2 (nConv blocks)
__global__ __launch_bounds__(256)
void fused_n64_convT(const unsigned short* __restrict__ A,
                     const unsigned short* __restrict__ BT,
                     const float* __restrict__ bias, const float* __restrict__ R,
                     float* __restrict__ Cout, int M, int N, int K, int nbx,
                     const float* __restrict__ W2, unsigned short* __restrict__ WT2,
                     int K2, int N2, int nMM) {
    extern __shared__ char smem[];
    int bid = blockIdx.x;
    if (bid < nMM) {
        n64_body(smem, bid % nbx, bid / nbx, A, BT, bias, R, Cout, M, N, K);
    } else {
        int r = bid - nMM, kt = K2 >> 6;
        convT_body(smem, r % kt, r / kt, W2, WT2, K2, N2);
    }
}

// ---------------- head ----------------
__global__ void head_kernel(const float* __restrict__ hl, const float* __restrict__ W,
                            float* __restrict__ out) {
    __shared__ float hs[2 * DMODEL];
    int tid = threadIdx.x;
    #pragma unroll
    for (int i = 0; i < 8; ++i) hs[tid + i * 256] = hl[tid + i * 256];
    __syncthreads();
    int v = blockIdx.x * 256 + tid;
    if (v >= VOCAB) return;
    float a0 = 0.f, a1 = 0.f;
    for (int d = 0; d < DMODEL; ++d) {
        float wv = W[(long)d * VOCAB + v];
        a0 += hs[d] * wv;
        a1 += hs[DMODEL + d] * wv;
    }
    out[v] = a0;
    out[VOCAB + v] = a1;
}

extern "C" void kernel_launch(void* const* d_in, const int* in_sizes, int n_in,
                              void* d_out, int out_size, void* d_ws, size_t ws_size,
                              hipStream_t stream) {
    const int*   x      = (const int*)  d_in[0];
    const float* wte    = (const float*)d_in[1];
    const float* wpe    = (const float*)d_in[2];
    const float* ln1_g  = (const float*)d_in[3];
    const float* ln1_b  = (const float*)d_in[4];
    const float* w_qkv  = (const float*)d_in[5];
    const float* b_qkv  = (const float*)d_in[6];
    const float* w_proj = (const float*)d_in[7];
    const float* b_proj = (const float*)d_in[8];
    const float* ln2_g  = (const float*)d_in[9];
    const float* ln2_b  = (const float*)d_in[10];
    const float* w_fc   = (const float*)d_in[11];
    const float* b_fc   = (const float*)d_in[12];
    const float* w_cp   = (const float*)d_in[13];
    const float* b_cp   = (const float*)d_in[14];
    const float* lnf_g  = (const float*)d_in[15];
    const float* lnf_b  = (const float*)d_in[16];
    const float* w_head = (const float*)d_in[17];
    float* out = (float*)d_out;

    char* ws = (char*)d_ws;
    float*          h     = (float*)ws;                             // 16 MB
    unsigned short* qkvB  = (unsigned short*)(ws + (16L << 20));    // 24 MB
    unsigned short* y_bf  = (unsigned short*)(ws + (40L << 20));    // 8 MB
    __hip_bfloat16* z_bf  = (__hip_bfloat16*)(ws + (48L << 20));    // 8 MB
    unsigned short* fc_bf = (unsigned short*)(ws + (56L << 20));    // 32 MB
    unsigned short* wT_a  = (unsigned short*)(ws + (88L << 20));    // 8 MB (fc)
    unsigned short* wT_b  = (unsigned short*)(ws + (97L << 20));    // 8 MB (proj)
    unsigned short* wT_c  = (unsigned short*)(ws + (106L << 20));   // 8 MB (cp)
    unsigned short* wT_q  = (unsigned short*)(ws + (115L << 20));   // 8 MB (qkv)
    float*          hl    = (float*)(ws + (124L << 20));            // 8 KB

    const int SM_CONV = 16640;   // 64*65*4
    const int SM_ATTN = 65536;   // Ks 16K + Vs 16K + Ps 32K
    const int SM_N64  = 24576;   // As(16K)+Bs(8K), >= SM_CONV

    // P: embed (4096) + convT qkv layer 0 (768) -> wT_q
    fused_embed_convT<<<4096 + 768, 256, SM_CONV, stream>>>(
        x, wte, wpe, h, w_qkv, wT_q, 1024, 3072, 4096);

    for (int l = 0; l < NLAYER; ++l) {
        // A: LN1 (wave-per-row)
        ln_wave<<<NTOK / 4, 256, 0, stream>>>(h, y_bf, ln1_g + l * DMODEL, ln1_b + l * DMODEL);

        // B: qkv GEMM (reads wT_q produced by P or previous G)
        mm_mfma256<3><<<192, 512, 131072, stream>>>(
            y_bf, wT_q, b_qkv + l * 3072, qkvB, NTOK, 3072, 1024, 12);

        // C: attn QBLK=128 (512) + convT proj -> wT_b (256) + convT cp -> wT_c (1024)
        fused_attn_convT2<<<512 + 256 + 1024, 512, SM_ATTN, stream>>>(
            qkvB, qkvB + 4194304L, qkvB + 8388608L, z_bf,
            w_proj + (long)l * DMODEL * DMODEL, wT_b, 1024, 1024, 256,
            w_cp + (long)l * 4096 * DMODEL, wT_c, 4096, 1024, 512);

        // D: proj GEMM (+residual) + convT fc -> wT_a (1024)
        fused_n64_convT<<<512 + 1024, 256, SM_N64, stream>>>(
            (const unsigned short*)z_bf, wT_b, b_proj + l * DMODEL, h, h,
            NTOK, 1024, 1024, 16,
            w_fc + (long)l * DMODEL * 4096, wT_a, 1024, 4096, 512);

        // E: LN2 (wave-per-row)
        ln_wave<<<NTOK / 4, 256, 0, stream>>>(h, y_bf, ln2_g + l * DMODEL, ln2_b + l * DMODEL);

        // F: fc GEMM (256^2 8-phase, gelu; reads wT_a)
        mm_mfma256<2><<<256, 512, 131072, stream>>>(
            y_bf, wT_a, b_fc + l * 4096, fc_bf, NTOK, 4096, 1024, 16);

        // G: cp GEMM (+residual) + convT qkv(l+1) -> wT_q (768; none on last layer)
        int nConv = (l + 1 < NLAYER) ? 768 : 0;
        fused_n64_convT<<<512 + nConv, 256, SM_N64, stream>>>(
            fc_bf, wT_c, b_cp + l * DMODEL, h, h, NTOK, 1024, 4096, 16,
            w_qkv + (long)(l + 1) * DMODEL * 3072, wT_q, 1024, 3072, 512);
    }

    ln_final<<<BATCH, 256, 0, stream>>>(h + (long)(SEQ - 1) * DMODEL, hl,
                                        lnf_g, lnf_b, (long)SEQ * DMODEL);
    head_kernel<<<(VOCAB + 255) / 256, 256, 0, stream>>>(hl, w_head, out);
}

// Round 18
// 2269.481 us; speedup vs baseline: 1.3892x; 1.0026x over previous
//
#include <hip/hip_runtime.h>
#include <hip/hip_bf16.h>
#include <math.h>

#define VOCAB 50257
#define CTX 2048
#define DMODEL 1024
#define NHEAD 16
#define NLAYER 8
#define DHEAD 64
#define BATCH 2
#define SEQ 2048
#define NTOK (BATCH * SEQ)   // 4096

typedef __bf16 bf16x8 __attribute__((ext_vector_type(8)));
typedef float  f32x4  __attribute__((ext_vector_type(4)));
typedef unsigned short ushort4v __attribute__((ext_vector_type(4)));
typedef unsigned short ushort8v __attribute__((ext_vector_type(8)));

__device__ inline void gl_lds16(const void* g, void* l) {
    __builtin_amdgcn_global_load_lds(
        (const __attribute__((address_space(1))) unsigned int*)g,
        (__attribute__((address_space(3))) unsigned int*)l, 16, 0, 0);
}

__device__ inline unsigned short f2bs(float v) {
    __hip_bfloat16 t = __float2bfloat16(v);
    return *(unsigned short*)&t;
}

// ---------------- embedding body ----------------
__device__ void embed_body(int t, const int* __restrict__ x,
                           const float* __restrict__ wte,
                           const float* __restrict__ wpe,
                           float* __restrict__ h) {
    int s = t & (SEQ - 1);
    int tok = x[t];
    const float* pe = wpe + (long)s * DMODEL;
    const float* te = wte + (long)tok * DMODEL;
    float* ph = h + (long)t * DMODEL;
    for (int d = threadIdx.x; d < DMODEL; d += 256)
        ph[d] = te[d] + pe[d];
}

// ---------------- layernorm ----------------
__device__ inline float wave_sum(float v) {
    for (int off = 32; off; off >>= 1) v += __shfl_xor(v, off);
    return v;
}

__global__ void ln_wave(const float* __restrict__ in, unsigned short* __restrict__ out,
                        const float* __restrict__ g, const float* __restrict__ b) {
    const int w = threadIdx.x >> 6, lane = threadIdx.x & 63;
    const int row = blockIdx.x * 4 + w;
    const float* px = in + (long)row * DMODEL;
    f32x4 x[4];
    float s = 0.f;
    #pragma unroll
    for (int i = 0; i < 4; ++i) {
        x[i] = *(const f32x4*)&px[i * 256 + lane * 4];
        s += x[i][0] + x[i][1] + x[i][2] + x[i][3];
    }
    s = wave_sum(s);
    const float mean = s * (1.0f / DMODEL);
    float s2 = 0.f;
    #pragma unroll
    for (int i = 0; i < 4; ++i)
        #pragma unroll
        for (int j = 0; j < 4; ++j) { float d = x[i][j] - mean; s2 += d * d; }
    s2 = wave_sum(s2);
    const float r = 1.0f / sqrtf(s2 * (1.0f / DMODEL) + 1e-5f);
    unsigned short* po = out + (long)row * DMODEL;
    #pragma unroll
    for (int i = 0; i < 4; ++i) {
        const int d0 = i * 256 + lane * 4;
        f32x4 gv = *(const f32x4*)&g[d0];
        f32x4 bv = *(const f32x4*)&b[d0];
        ushort4v pk;
        #pragma unroll
        for (int j = 0; j < 4; ++j)
            pk[j] = f2bs((x[i][j] - mean) * r * gv[j] + bv[j]);
        *(ushort4v*)&po[d0] = pk;
    }
}

__global__ void ln_final(const float* __restrict__ in, float* __restrict__ out,
                         const float* __restrict__ g, const float* __restrict__ b,
                         long row_stride) {
    __shared__ float red[4], red2[4];
    int row = blockIdx.x;
    const float* px = in + (long)row * row_stride;
    float* po = out + (long)row * DMODEL;
    int tid = threadIdx.x;
    int wid = tid >> 6, lane = tid & 63;
    float x[4];
    float s = 0.f;
    #pragma unroll
    for (int i = 0; i < 4; ++i) { x[i] = px[tid + i * 256]; s += x[i]; }
    s = wave_sum(s);
    if (lane == 0) red[wid] = s;
    __syncthreads();
    float mean = (red[0] + red[1] + red[2] + red[3]) * (1.0f / DMODEL);
    float s2 = 0.f;
    #pragma unroll
    for (int i = 0; i < 4; ++i) { float d = x[i] - mean; s2 += d * d; }
    s2 = wave_sum(s2);
    if (lane == 0) red2[wid] = s2;
    __syncthreads();
    float var = (red2[0] + red2[1] + red2[2] + red2[3]) * (1.0f / DMODEL);
    float r = 1.0f / sqrtf(var + 1e-5f);
    #pragma unroll
    for (int i = 0; i < 4; ++i) {
        int d = tid + i * 256;
        po[d] = (x[i] - mean) * r * g[d] + b[d];
    }
}

// ------------- transpose+convert bodies: W f32 [K][N] -> WT bf16 [N][K] -------------
__device__ void convT_body(char* smem, int kx, int ny, const float* __restrict__ W,
                           unsigned short* __restrict__ WT, int K, int N) {
    float (*t)[65] = (float(*)[65])smem;
    const int k0 = kx * 64, n0 = ny * 64;
    const int tid = threadIdx.x;
    {
        const int krow = tid >> 4, c4 = (tid & 15) * 4;
        #pragma unroll
        for (int p = 0; p < 4; ++p) {
            f32x4 gv = *(const f32x4*)&W[(long)(k0 + p * 16 + krow) * N + n0 + c4];
            #pragma unroll
            for (int j = 0; j < 4; ++j) t[p * 16 + krow][c4 + j] = gv[j];
        }
    }
    __syncthreads();
    {
        const int n = tid >> 3, kl = (tid & 7) * 8;
        #pragma unroll
        for (int p = 0; p < 2; ++p) {
            ushort8v pk;
            #pragma unroll
            for (int j = 0; j < 8; ++j) pk[j] = f2bs(t[kl + j][p * 32 + n]);
            *(ushort8v*)&WT[(long)(n0 + p * 32 + n) * K + k0 + kl] = pk;
        }
    }
}

// 512-thread variant
__device__ void convT_body512(char* smem, int kx, int ny, const float* __restrict__ W,
                              unsigned short* __restrict__ WT, int K, int N) {
    float (*t)[65] = (float(*)[65])smem;
    const int k0 = kx * 64, n0 = ny * 64;
    const int tid = threadIdx.x;
    {
        const int krow = tid >> 4, c4 = (tid & 15) * 4;   // krow 0..31
        #pragma unroll
        for (int p = 0; p < 2; ++p) {
            f32x4 gv = *(const f32x4*)&W[(long)(k0 + p * 32 + krow) * N + n0 + c4];
            #pragma unroll
            for (int j = 0; j < 4; ++j) t[p * 32 + krow][c4 + j] = gv[j];
        }
    }
    __syncthreads();
    {
        const int n = tid >> 3, kl = (tid & 7) * 8;       // n 0..63
        ushort8v pk;
        #pragma unroll
        for (int j = 0; j < 8; ++j) pk[j] = f2bs(t[kl + j][n]);
        *(ushort8v*)&WT[(long)(n0 + n) * K + k0 + kl] = pk;
    }
}

// ---------------- 256^2 8-phase bf16 MFMA GEMM body ----------------
#define STG_A(KS, H) do { \
    const unsigned short* g_ = A + (long)(bm + (H) * 128 + srow) * K + (KS) * 64 + stgch; \
    unsigned short* s_ = LDS + (((KS) & 1) * 2 + (H)) * 8192 + (w * 8) * 64; \
    gl_lds16(g_, s_); gl_lds16(g_ + 64L * K, s_ + 4096); \
} while (0)
#define STG_B(KS, H) do { \
    const unsigned short* g_ = BT + (long)(bn + (H) * 128 + srow) * K + (KS) * 64 + stgch; \
    unsigned short* s_ = LDS + 32768 + (((KS) & 1) * 2 + (H)) * 8192 + (w * 8) * 64; \
    gl_lds16(g_, s_); gl_lds16(g_ + 64L * K, s_ + 4096); \
} while (0)
#define MM2(M_, x0, x1) do { \
    acc[M_][0] = __builtin_amdgcn_mfma_f32_16x16x32_bf16(x0, bfr[0], acc[M_][0], 0, 0, 0); \
    acc[M_][0] = __builtin_amdgcn_mfma_f32_16x16x32_bf16(x1, bfr[1], acc[M_][0], 0, 0, 0); \
    acc[M_][1] = __builtin_amdgcn_mfma_f32_16x16x32_bf16(x0, bfr[2], acc[M_][1], 0, 0, 0); \
    acc[M_][1] = __builtin_amdgcn_mfma_f32_16x16x32_bf16(x1, bfr[3], acc[M_][1], 0, 0, 0); \
    acc[M_][2] = __builtin_amdgcn_mfma_f32_16x16x32_bf16(x0, bfr[4], acc[M_][2], 0, 0, 0); \
    acc[M_][2] = __builtin_amdgcn_mfma_f32_16x16x32_bf16(x1, bfr[5], acc[M_][2], 0, 0, 0); \
    acc[M_][3] = __builtin_amdgcn_mfma_f32_16x16x32_bf16(x0, bfr[6], acc[M_][3], 0, 0, 0); \
    acc[M_][3] = __builtin_amdgcn_mfma_f32_16x16x32_bf16(x1, bfr[7], acc[M_][3], 0, 0, 0); \
} while (0)
#define PHASE(Q, SPAR, STAGE_STMT, TAIL_STMT) do { \
    bf16x8 a00, a01, a10, a11; \
    if (((Q) & 3) == 0) { \
        const unsigned short* Bb_ = lBp[SPAR] + ((wc & 1) * 64 + fr) * 64; \
        bfr[0] = *(const bf16x8*)(Bb_ + rd0);        bfr[1] = *(const bf16x8*)(Bb_ + rd1); \
        bfr[2] = *(const bf16x8*)(Bb_ + 1024 + rd0); bfr[3] = *(const bf16x8*)(Bb_ + 1024 + rd1); \
        bfr[4] = *(const bf16x8*)(Bb_ + 2048 + rd0); bfr[5] = *(const bf16x8*)(Bb_ + 2048 + rd1); \
        bfr[6] = *(const bf16x8*)(Bb_ + 3072 + rd0); bfr[7] = *(const bf16x8*)(Bb_ + 3072 + rd1); \
    } \
    { const unsigned short* Ab_ = lAp[SPAR] + fr * 64; \
      a00 = *(const bf16x8*)(Ab_ + (((Q) & 3) * 2) * 1024 + rd0); \
      a01 = *(const bf16x8*)(Ab_ + (((Q) & 3) * 2) * 1024 + rd1); \
      a10 = *(const bf16x8*)(Ab_ + (((Q) & 3) * 2 + 1) * 1024 + rd0); \
      a11 = *(const bf16x8*)(Ab_ + (((Q) & 3) * 2 + 1) * 1024 + rd1); } \
    STAGE_STMT; \
    __builtin_amdgcn_s_barrier(); \
    asm volatile("s_waitcnt lgkmcnt(0)" ::: "memory"); \
    __builtin_amdgcn_sched_barrier(0); \
    __builtin_amdgcn_s_setprio(1); \
    MM2(((Q) & 3) * 2, a00, a01); \
    MM2(((Q) & 3) * 2 + 1, a10, a11); \
    __builtin_amdgcn_s_setprio(0); \
    TAIL_STMT; \
    __builtin_amdgcn_s_barrier(); \
} while (0)

template<int EPI>
__device__ void mm256_body(unsigned short* LDS, int bid, int nwg,
                           const unsigned short* __restrict__ A,
                           const unsigned short* __restrict__ BT,
                           const float* __restrict__ bias,
                           void* __restrict__ Cout, int M, int N, int K, int nbx) {
    const int tid = threadIdx.x;
    const int w = tid >> 6, lane = tid & 63;
    const int wr = w >> 2, wc = w & 3;
    const int swz = (bid & 7) * (nwg >> 3) + (bid >> 3);
    const int bm = (swz / nbx) * 256, bn = (swz % nbx) * 256;

    f32x4 acc[8][4];
    #pragma unroll
    for (int m = 0; m < 8; ++m)
        #pragma unroll
        for (int n = 0; n < 4; ++n)
            acc[m][n] = (f32x4){0.f, 0.f, 0.f, 0.f};

    const int fr = lane & 15, kg = lane >> 4;
    const int rd0 = 8 * (kg ^ (lane & 7)), rd1 = 8 * ((kg + 4) ^ (lane & 7));
    const int stgch = 8 * ((lane & 7) ^ (lane >> 3));
    const int srow = w * 8 + (lane >> 3);
    unsigned short* const lAp[2] = { LDS + wr * 8192, LDS + (2 + wr) * 8192 };
    unsigned short* const lBp[2] = { LDS + 32768 + (wc >> 1) * 8192,
                                     LDS + 32768 + (2 + (wc >> 1)) * 8192 };
    bf16x8 bfr[8];

    STG_B(0, 0); STG_B(0, 1); STG_A(0, 0); STG_A(0, 1); STG_B(1, 0); STG_B(1, 1);
    asm volatile("s_waitcnt vmcnt(4)" ::: "memory");
    __builtin_amdgcn_sched_barrier(0);
    __builtin_amdgcn_s_barrier();

    const int T = K >> 7;
    for (int t = 0; t < T; ++t) {
        const int s = 2 * t;
        const bool nl = (t < T - 1);
        PHASE(0, 0, STG_A(s + 1, 0), );
        PHASE(1, 0, STG_A(s + 1, 1), );
        PHASE(2, 0, if (nl) STG_B(s + 2, 0), );
        PHASE(3, 0, if (nl) STG_B(s + 2, 1),
              if (nl) { asm volatile("s_waitcnt vmcnt(4)" ::: "memory"); } else { asm volatile("s_waitcnt vmcnt(0)" ::: "memory"); } __builtin_amdgcn_sched_barrier(0); );
        PHASE(4, 1, if (nl) STG_A(s + 2, 0), );
        PHASE(5, 1, if (nl) STG_A(s + 2, 1), );
        PHASE(6, 1, if (nl) STG_B(s + 3, 0), );
        PHASE(7, 1, if (nl) STG_B(s + 3, 1),
              if (nl) { asm volatile("s_waitcnt vmcnt(4)" ::: "memory"); __builtin_amdgcn_sched_barrier(0); } );
    }

    const int r0 = (lane >> 4) * 4;
    #pragma unroll
    for (int n = 0; n < 4; ++n) {
        int colb = bn + wc * 64 + n * 16;
        float bv = bias[colb + fr];
        #pragma unroll
        for (int m = 0; m < 8; ++m) {
            int rowb = bm + wr * 128 + m * 16 + r0;
            if (EPI == 3) {
                unsigned short* qkvB = (unsigned short*)Cout;
                int which = colb >> 10, hh = (colb & 1023) >> 6, dbase = colb & 63;
                int b_ = rowb >> 11, s_ = rowb & 2047;
                long bh2 = b_ * 16 + hh;
                float v[4];
                #pragma unroll
                for (int r = 0; r < 4; ++r) v[r] = acc[m][n][r] + bv;
                if (which == 2) {
                    ushort4v pk;
                    #pragma unroll
                    for (int r = 0; r < 4; ++r) pk[r] = f2bs(v[r]);
                    *(ushort4v*)&qkvB[8388608L + (bh2 * 64 + dbase + fr) * 2048 + s_] = pk;
                } else {
                    unsigned short* dst = qkvB + (long)which * 4194304L +
                                          (bh2 * 2048 + s_) * 64 + dbase + fr;
                    #pragma unroll
                    for (int r = 0; r < 4; ++r) dst[r * 64] = f2bs(v[r]);
                }
            } else {
                #pragma unroll
                for (int r = 0; r < 4; ++r) {
                    long row = rowb + r, col = colb + fr;
                    float v = acc[m][n][r] + bv;
                    v = 0.5f * v * (1.0f + erff(v * 0.70710678118f));
                    ((__hip_bfloat16*)Cout)[row * N + col] = __float2bfloat16(v);
                }
            }
        }
    }
}

template<int EPI>
__global__ __launch_bounds__(512, 1)
void mm_mfma256(const unsigned short* __restrict__ A,
                const unsigned short* __restrict__ BT,
                const float* __restrict__ bias,
                void* __restrict__ Cout, int M, int N, int K, int nbx) {
    extern __shared__ unsigned short LDS[];
    mm256_body<EPI>(LDS, blockIdx.x, gridDim.x, A, BT, bias, Cout, M, N, K, nbx);
}

// 256^2 GEMM (nMM blocks) + convT -> WT2 (remaining blocks), 512 thr
template<int EPI>
__global__ __launch_bounds__(512, 1)
void fused_mm256_convT(const unsigned short* __restrict__ A,
                       const unsigned short* __restrict__ BT,
                       const float* __restrict__ bias,
                       void* __restrict__ Cout, int M, int N, int K, int nbx,
                       const float* __restrict__ W2, unsigned short* __restrict__ WT2,
                       int K2, int N2, int nMM) {
    extern __shared__ unsigned short LDS[];
    int bid = blockIdx.x;
    if (bid < nMM) {
        mm256_body<EPI>(LDS, bid, nMM, A, BT, bias, Cout, M, N, K, nbx);
    } else {
        int r = bid - nMM, kt = K2 >> 6;
        convT_body512((char*)LDS, r % kt, r / kt, W2, WT2, K2, N2);
    }
}

// ---------------- n64 GEMM body (3-buffer, 2-deep prefetch, vmcnt(6)) ----------------
// smem: As[3][128*32] 24K + Bs[3][64*32] 12K = 36K
__device__ void n64_body(char* smem, int bx, int by,
                         const unsigned short* __restrict__ A,
                         const unsigned short* __restrict__ BT,
                         const float* __restrict__ bias, const float* __restrict__ R,
                         float* __restrict__ Cout, int M, int N, int K) {
    unsigned short* As = (unsigned short*)smem;
    unsigned short* Bs = As + 3 * 128 * 32;
    const int tid = threadIdx.x;
    const int w = tid >> 6, lane = tid & 63;
    const int bm = by * 128, bn = bx * 64;
    const int wr = (w >> 1) * 64, wc = (w & 1) * 32;

    f32x4 acc[4][2];
    #pragma unroll
    for (int m = 0; m < 4; ++m)
        #pragma unroll
        for (int n = 0; n < 2; ++n)
            acc[m][n] = (f32x4){0.f, 0.f, 0.f, 0.f};

    const int lrow = lane >> 2;
    const int lcol = (lane & 3) * 8;
    const unsigned short* gA = A + (long)(bm + w * 32 + lrow) * K + lcol;
    const unsigned short* gB = BT + (long)(bn + w * 16 + lrow) * K + lcol;

#define N64_STAGE(K0, BB) do { \
    gl_lds16(gA + (K0),          &As[(BB) * 4096 + (w * 32) * 32]); \
    gl_lds16(gA + (K0) + 16 * K, &As[(BB) * 4096 + (w * 32 + 16) * 32]); \
    gl_lds16(gB + (K0),          &Bs[(BB) * 2048 + (w * 16) * 32]); \
} while (0)

    const int T = K >> 5;
    N64_STAGE(0, 0);
    if (T > 1) N64_STAGE(32, 1);

    for (int t = 0; t < T; ++t) {
        const int buf = t % 3;
        if (t + 2 < T) {
            N64_STAGE((t + 2) * 32, (t + 2) % 3);
            asm volatile("s_waitcnt vmcnt(6)" ::: "memory");   // t's 3 loads landed
        } else if (t + 1 < T) {
            asm volatile("s_waitcnt vmcnt(3)" ::: "memory");
        } else {
            asm volatile("s_waitcnt vmcnt(0)" ::: "memory");
        }
        __builtin_amdgcn_sched_barrier(0);
        __builtin_amdgcn_s_barrier();

        bf16x8 a[4], b[2];
        #pragma unroll
        for (int m = 0; m < 4; ++m)
            a[m] = *(const bf16x8*)&As[buf * 4096 + (wr + m * 16 + (lane & 15)) * 32 + (lane >> 4) * 8];
        #pragma unroll
        for (int n = 0; n < 2; ++n)
            b[n] = *(const bf16x8*)&Bs[buf * 2048 + (wc + n * 16 + (lane & 15)) * 32 + (lane >> 4) * 8];
        #pragma unroll
        for (int m = 0; m < 4; ++m)
            #pragma unroll
            for (int n = 0; n < 2; ++n)
                acc[m][n] = __builtin_amdgcn_mfma_f32_16x16x32_bf16(a[m], b[n], acc[m][n], 0, 0, 0);

        __builtin_amdgcn_s_barrier();   // buf t free for stage(t+3)
    }
#undef N64_STAGE

    const int r0 = (lane >> 4) * 4, cc = lane & 15;
    #pragma unroll
    for (int n = 0; n < 2; ++n) {
        int colb = bn + wc + n * 16;
        float bv = bias[colb + cc];
        #pragma unroll
        for (int m = 0; m < 4; ++m) {
            int rowb = bm + wr + m * 16 + r0;
            #pragma unroll
            for (int r = 0; r < 4; ++r) {
                long row = rowb + r, col = colb + cc;
                float v = acc[m][n][r] + bv + R[row * N + col];
                Cout[row * N + col] = v;
            }
        }
    }
}

// ---------------- MFMA flash attention body, QBLK=128, KVBLK=128, 8 waves ----------------
__device__ void attn_body(char* smem, int bh, int qb,
                          const unsigned short* __restrict__ qB,
                          const unsigned short* __restrict__ kB,
                          const unsigned short* __restrict__ vT,
                          __hip_bfloat16* __restrict__ z) {
    const int tid = threadIdx.x, w = tid >> 6, lane = tid & 63;
    const int arow = lane & 15, kg = lane >> 4;
    unsigned short* Ks = (unsigned short*)smem;
    unsigned short* Vs = Ks + 128 * 64;
    unsigned short* Ps = Vs + 64 * 128 + w * 16 * 128;

    const long kvbase = (long)bh * (2048 * 64);

    bf16x8 qa[2];
    {
        const unsigned short* q0 = qB + kvbase + (long)(qb + w * 16 + arow) * 64 + kg * 8;
        qa[0] = *(const bf16x8*)(q0);
        qa[1] = *(const bf16x8*)(q0 + 32);
    }

    f32x4 po[4];
    float mrow[4], lrow[4];
    #pragma unroll
    for (int i = 0; i < 4; ++i) {
        po[i] = (f32x4){0.f, 0.f, 0.f, 0.f};
        mrow[i] = -1e30f; lrow[i] = 0.f;
    }

    const int ksrow = lane >> 3;
    const int kschunk = (lane & 7) ^ ksrow;
    const int vsr = lane >> 4;
    const int cmax = qb >> 7;

    for (int c = 0; c <= cmax; ++c) {
        {
            const unsigned short* ks0 = kB + kvbase +
                (long)(c * 128 + w * 16 + ksrow) * 64 + kschunk * 8;
            #pragma unroll
            for (int i = 0; i < 2; ++i)
                gl_lds16(ks0 + (long)i * 8 * 64, &Ks[(w * 16 + i * 8) * 64]);
            #pragma unroll
            for (int i = 0; i < 2; ++i) {
                int d = w * 8 + i * 4 + vsr;
                int sch = (lane & 15) ^ (d & 7);
                gl_lds16(vT + kvbase + (long)d * 2048 + c * 128 + sch * 8,
                         &Vs[(w * 8 + i * 4) * 128]);
            }
        }
        __syncthreads();

        f32x4 s[8];
        #pragma unroll
        for (int n = 0; n < 8; ++n) {
            s[n] = (f32x4){0.f, 0.f, 0.f, 0.f};
            int row = n * 16 + arow, sw = row & 7;
            bf16x8 kb0 = *(const bf16x8*)&Ks[row * 64 + (kg ^ sw) * 8];
            bf16x8 kb1 = *(const bf16x8*)&Ks[row * 64 + ((4 + kg) ^ sw) * 8];
            s[n] = __builtin_amdgcn_mfma_f32_16x16x32_bf16(qa[0], kb0, s[n], 0, 0, 0);
            s[n] = __builtin_amdgcn_mfma_f32_16x16x32_bf16(qa[1], kb1, s[n], 0, 0, 0);
        }

        const bool diag = (c == cmax);
        #pragma unroll
        for (int n = 0; n < 8; ++n)
            #pragma unroll
            for (int r = 0; r < 4; ++r) {
                float v = s[n][r] * 0.125f;
                if (diag) {
                    int key = c * 128 + n * 16 + arow;
                    int qrow = qb + w * 16 + kg * 4 + r;
                    if (key > qrow) v = -1e30f;
                }
                s[n][r] = v;
            }

        #pragma unroll
        for (int r = 0; r < 4; ++r) {
            float rm = s[0][r];
            #pragma unroll
            for (int n = 1; n < 8; ++n) rm = fmaxf(rm, s[n][r]);
            #pragma unroll
            for (int off = 1; off < 16; off <<= 1)
                rm = fmaxf(rm, __shfl_xor(rm, off));
            float mnew = fmaxf(mrow[r], rm);
            float esc = expf(mrow[r] - mnew);
            float rs = 0.f;
            #pragma unroll
            for (int n = 0; n < 8; ++n) {
                float p = expf(s[n][r] - mnew);
                s[n][r] = p;
                rs += p;
            }
            #pragma unroll
            for (int off = 1; off < 16; off <<= 1)
                rs += __shfl_xor(rs, off);
            lrow[r] = lrow[r] * esc + rs;
            #pragma unroll
            for (int dt = 0; dt < 4; ++dt) po[dt][r] *= esc;
            mrow[r] = mnew;
        }

        #pragma unroll
        for (int n = 0; n < 8; ++n) {
            int col = n * 16 + arow;
            int chunk = col >> 3, cw = col & 7;
            #pragma unroll
            for (int r = 0; r < 4; ++r) {
                int row = kg * 4 + r;
                Ps[row * 128 + ((chunk ^ (row & 7)) * 8 + cw)] = f2bs(s[n][r]);
            }
        }

        bf16x8 pa[4];
        #pragma unroll
        for (int ks = 0; ks < 4; ++ks)
            pa[ks] = *(const bf16x8*)&Ps[arow * 128 + (((ks * 4 + kg) ^ (arow & 7)) * 8)];
        #pragma unroll
        for (int dt = 0; dt < 4; ++dt) {
            int vrow = dt * 16 + arow, sw = vrow & 7;
            #pragma unroll
            for (int ks = 0; ks < 4; ++ks) {
                bf16x8 vb = *(const bf16x8*)&Vs[vrow * 128 + (((ks * 4 + kg) ^ sw) * 8)];
                po[dt] = __builtin_amdgcn_mfma_f32_16x16x32_bf16(pa[ks], vb, po[dt], 0, 0, 0);
            }
        }
        __syncthreads();
    }

    const int b_ = bh >> 4, hofs = (bh & 15) * 64;
    #pragma unroll
    for (int dt = 0; dt < 4; ++dt)
        #pragma unroll
        for (int r = 0; r < 4; ++r) {
            long row = (long)b_ * 2048 + qb + w * 16 + kg * 4 + r;
            z[row * 1024 + hofs + dt * 16 + arow] = __float2bfloat16(po[dt][r] / lrow[r]);
        }
}

// ---------------- fused kernels ----------------
__global__ __launch_bounds__(256)
void fused_embed_convT(const int* __restrict__ x, const float* __restrict__ wte,
                       const float* __restrict__ wpe, float* __restrict__ h,
                       const float* __restrict__ W, unsigned short* __restrict__ WT,
                       int K, int N, int nEmb) {
    extern __shared__ char smem[];
    int bid = blockIdx.x;
    if (bid < nEmb) {
        embed_body(bid, x, wte, wpe, h);
    } else {
        int r = bid - nEmb, kt = K >> 6;
        convT_body(smem, r % kt, r / kt, W, WT, K, N);
    }
}

// attn QBLK=128 heavy-first (nAttn) + convT -> WT2; 512 thr
__global__ __launch_bounds__(512)
void fused_attn_convT(const unsigned short* __restrict__ qB,
                      const unsigned short* __restrict__ kB,
                      const unsigned short* __restrict__ vT,
                      __hip_bfloat16* __restrict__ z,
                      const float* __restrict__ W2, unsigned short* __restrict__ WT2,
                      int K2, int N2, int nAttn) {
    extern __shared__ char smem[];
    int bid = blockIdx.x;
    if (bid < nAttn) {
        int bh = bid & 31;
        int qblk = 15 - (bid >> 5);           // heavy-first
        attn_body(smem, bh, qblk * 128, qB, kB, vT, z);
    } else {
        int r = bid - nAttn, kt = K2 >> 6;
        convT_body512(smem, r % kt, r / kt, W2, WT2, K2, N2);
    }
}

// n64 GEMM (nMM, bx=bid%nbx) + optional convT -> WT2 (nConv blocks)
__global__ __launch_bounds__(256)
void fused_n64_convT(const unsigned short* __restrict__ A,
                     const unsigned short* __restrict__ BT,
                     const float* __restrict__ bias, const float* __restrict__ R,
                     float* __restrict__ Cout, int M, int N, int K, int nbx,
                     const float* __restrict__ W2, unsigned short* __restrict__ WT2,
                     int K2, int N2, int nMM) {
    extern __shared__ char smem[];
    int bid = blockIdx.x;
    if (bid < nMM) {
        n64_body(smem, bid % nbx, bid / nbx, A, BT, bias, R, Cout, M, N, K);
    } else {
        int r = bid - nMM, kt = K2 >> 6;
        convT_body(smem, r % kt, r / kt, W2, WT2, K2, N2);
    }
}

// ---------------- head ----------------
__global__ void head_kernel(const float* __restrict__ hl, const float* __restrict__ W,
                            float* __restrict__ out) {
    __shared__ float hs[2 * DMODEL];
    int tid = threadIdx.x;
    #pragma unroll
    for (int i = 0; i < 8; ++i) hs[tid + i * 256] = hl[tid + i * 256];
    __syncthreads();
    int v = blockIdx.x * 256 + tid;
    if (v >= VOCAB) return;
    float a0 = 0.f, a1 = 0.f;
    for (int d = 0; d < DMODEL; ++d) {
        float wv = W[(long)d * VOCAB + v];
        a0 += hs[d] * wv;
        a1 += hs[DMODEL + d] * wv;
    }
    out[v] = a0;
    out[VOCAB + v] = a1;
}

extern "C" void kernel_launch(void* const* d_in, const int* in_sizes, int n_in,
                              void* d_out, int out_size, void* d_ws, size_t ws_size,
                              hipStream_t stream) {
    const int*   x      = (const int*)  d_in[0];
    const float* wte    = (const float*)d_in[1];
    const float* wpe    = (const float*)d_in[2];
    const float* ln1_g  = (const float*)d_in[3];
    const float* ln1_b  = (const float*)d_in[4];
    const float* w_qkv  = (const float*)d_in[5];
    const float* b_qkv  = (const float*)d_in[6];
    const float* w_proj = (const float*)d_in[7];
    const float* b_proj = (const float*)d_in[8];
    const float* ln2_g  = (const float*)d_in[9];
    const float* ln2_b  = (const float*)d_in[10];
    const float* w_fc   = (const float*)d_in[11];
    const float* b_fc   = (const float*)d_in[12];
    const float* w_cp   = (const float*)d_in[13];
    const float* b_cp   = (const float*)d_in[14];
    const float* lnf_g  = (const float*)d_in[15];
    const float* lnf_b  = (const float*)d_in[16];
    const float* w_head = (const float*)d_in[17];
    float* out = (float*)d_out;

    char* ws = (char*)d_ws;
    float*          h     = (float*)ws;                             // 16 MB
    unsigned short* qkvB  = (unsigned short*)(ws + (16L << 20));    // 24 MB
    unsigned short* y_bf  = (unsigned short*)(ws + (40L << 20));    // 8 MB
    __hip_bfloat16* z_bf  = (__hip_bfloat16*)(ws + (48L << 20));    // 8 MB
    unsigned short* fc_bf = (unsigned short*)(ws + (56L << 20));    // 32 MB
    unsigned short* wT_a  = (unsigned short*)(ws + (88L << 20));    // 8 MB (fc)
    unsigned short* wT_b  = (unsigned short*)(ws + (97L << 20));    // 8 MB (proj)
    unsigned short* wT_c  = (unsigned short*)(ws + (106L << 20));   // 8 MB (cp)
    unsigned short* wT_q  = (unsigned short*)(ws + (115L << 20));   // 8 MB (qkv)
    float*          hl    = (float*)(ws + (124L << 20));            // 8 KB

    const int SM_CONV = 16640;   // 64*65*4
    const int SM_ATTN = 65536;   // Ks 16K + Vs 16K + Ps 32K
    const int SM_N64  = 36864;   // As(24K)+Bs(12K), >= SM_CONV

    // P: embed (4096) + convT qkv layer 0 (768) -> wT_q
    fused_embed_convT<<<4096 + 768, 256, SM_CONV, stream>>>(
        x, wte, wpe, h, w_qkv, wT_q, 1024, 3072, 4096);

    for (int l = 0; l < NLAYER; ++l) {
        // A: LN1 (wave-per-row)
        ln_wave<<<NTOK / 4, 256, 0, stream>>>(h, y_bf, ln1_g + l * DMODEL, ln1_b + l * DMODEL);

        // B: qkv GEMM (192) + convT proj -> wT_b (256; fills the 64 idle CUs)
        fused_mm256_convT<3><<<192 + 256, 512, 131072, stream>>>(
            y_bf, wT_q, b_qkv + l * 3072, qkvB, NTOK, 3072, 1024, 12,
            w_proj + (long)l * DMODEL * DMODEL, wT_b, 1024, 1024, 192);

        // C: attn QBLK=128 (512) + convT cp -> wT_c (1024 tiles: 64 k x 16 n)
        fused_attn_convT<<<512 + 1024, 512, SM_ATTN, stream>>>(
            qkvB, qkvB + 4194304L, qkvB + 8388608L, z_bf,
            w_cp + (long)l * 4096 * DMODEL, wT_c, 4096, 1024, 512);

        // D: proj GEMM (+residual) + convT fc -> wT_a (1024)
        fused_n64_convT<<<512 + 1024, 256, SM_N64, stream>>>(
            (const unsigned short*)z_bf, wT_b, b_proj + l * DMODEL, h, h,
            NTOK, 1024, 1024, 16,
            w_fc + (long)l * DMODEL * 4096, wT_a, 1024, 4096, 512);

        // E: LN2 (wave-per-row)
        ln_wave<<<NTOK / 4, 256, 0, stream>>>(h, y_bf, ln2_g + l * DMODEL, ln2_b + l * DMODEL);

        // F: fc GEMM (256^2 8-phase, gelu; reads wT_a)
        mm_mfma256<2><<<256, 512, 131072, stream>>>(
            y_bf, wT_a, b_fc + l * 4096, fc_bf, NTOK, 4096, 1024, 16);

        // G: cp GEMM (+residual) + convT qkv(l+1) -> wT_q (768; none on last layer)
        int nConv = (l + 1 < NLAYER) ? 768 : 0;
        fused_n64_convT<<<512 + nConv, 256, SM_N64, stream>>>(
            fc_bf, wT_c, b_cp + l * DMODEL, h, h, NTOK, 1024, 4096, 16,
            w_qkv + (long)(l + 1) * DMODEL * 3072, wT_q, 1024, 3072, 512);
    }

    ln_final<<<BATCH, 256, 0, stream>>>(h + (long)(SEQ - 1) * DMODEL, hl,
                                        lnf_g, lnf_b, (long)SEQ * DMODEL);
    head_kernel<<<(VOCAB + 255) / 256, 256, 0, stream>>>(hl, w_head, out);
}

// Round 19
// 2235.190 us; speedup vs baseline: 1.4105x; 1.0153x over previous
//
#include <hip/hip_runtime.h>
#include <hip/hip_bf16.h>
#include <math.h>

#define VOCAB 50257
#define CTX 2048
#define DMODEL 1024
#define NHEAD 16
#define NLAYER 8
#define DHEAD 64
#define BATCH 2
#define SEQ 2048
#define NTOK (BATCH * SEQ)   // 4096

typedef __bf16 bf16x8 __attribute__((ext_vector_type(8)));
typedef float  f32x4  __attribute__((ext_vector_type(4)));
typedef unsigned short ushort4v __attribute__((ext_vector_type(4)));
typedef unsigned short ushort8v __attribute__((ext_vector_type(8)));

__device__ inline void gl_lds16(const void* g, void* l) {
    __builtin_amdgcn_global_load_lds(
        (const __attribute__((address_space(1))) unsigned int*)g,
        (__attribute__((address_space(3))) unsigned int*)l, 16, 0, 0);
}

__device__ inline unsigned short f2bs(float v) {
    __hip_bfloat16 t = __float2bfloat16(v);
    return *(unsigned short*)&t;
}

// ---------------- embedding body ----------------
__device__ void embed_body(int t, const int* __restrict__ x,
                           const float* __restrict__ wte,
                           const float* __restrict__ wpe,
                           float* __restrict__ h) {
    int s = t & (SEQ - 1);
    int tok = x[t];
    const float* pe = wpe + (long)s * DMODEL;
    const float* te = wte + (long)tok * DMODEL;
    float* ph = h + (long)t * DMODEL;
    for (int d = threadIdx.x; d < DMODEL; d += 256)
        ph[d] = te[d] + pe[d];
}

// ---------------- layernorm ----------------
__device__ inline float wave_sum(float v) {
    for (int off = 32; off; off >>= 1) v += __shfl_xor(v, off);
    return v;
}

__global__ void ln_wave(const float* __restrict__ in, unsigned short* __restrict__ out,
                        const float* __restrict__ g, const float* __restrict__ b) {
    const int w = threadIdx.x >> 6, lane = threadIdx.x & 63;
    const int row = blockIdx.x * 4 + w;
    const float* px = in + (long)row * DMODEL;
    f32x4 x[4];
    float s = 0.f;
    #pragma unroll
    for (int i = 0; i < 4; ++i) {
        x[i] = *(const f32x4*)&px[i * 256 + lane * 4];
        s += x[i][0] + x[i][1] + x[i][2] + x[i][3];
    }
    s = wave_sum(s);
    const float mean = s * (1.0f / DMODEL);
    float s2 = 0.f;
    #pragma unroll
    for (int i = 0; i < 4; ++i)
        #pragma unroll
        for (int j = 0; j < 4; ++j) { float d = x[i][j] - mean; s2 += d * d; }
    s2 = wave_sum(s2);
    const float r = 1.0f / sqrtf(s2 * (1.0f / DMODEL) + 1e-5f);
    unsigned short* po = out + (long)row * DMODEL;
    #pragma unroll
    for (int i = 0; i < 4; ++i) {
        const int d0 = i * 256 + lane * 4;
        f32x4 gv = *(const f32x4*)&g[d0];
        f32x4 bv = *(const f32x4*)&b[d0];
        ushort4v pk;
        #pragma unroll
        for (int j = 0; j < 4; ++j)
            pk[j] = f2bs((x[i][j] - mean) * r * gv[j] + bv[j]);
        *(ushort4v*)&po[d0] = pk;
    }
}

__global__ void ln_final(const float* __restrict__ in, float* __restrict__ out,
                         const float* __restrict__ g, const float* __restrict__ b,
                         long row_stride) {
    __shared__ float red[4], red2[4];
    int row = blockIdx.x;
    const float* px = in + (long)row * row_stride;
    float* po = out + (long)row * DMODEL;
    int tid = threadIdx.x;
    int wid = tid >> 6, lane = tid & 63;
    float x[4];
    float s = 0.f;
    #pragma unroll
    for (int i = 0; i < 4; ++i) { x[i] = px[tid + i * 256]; s += x[i]; }
    s = wave_sum(s);
    if (lane == 0) red[wid] = s;
    __syncthreads();
    float mean = (red[0] + red[1] + red[2] + red[3]) * (1.0f / DMODEL);
    float s2 = 0.f;
    #pragma unroll
    for (int i = 0; i < 4; ++i) { float d = x[i] - mean; s2 += d * d; }
    s2 = wave_sum(s2);
    if (lane == 0) red2[wid] = s2;
    __syncthreads();
    float var = (red2[0] + red2[1] + red2[2] + red2[3]) * (1.0f / DMODEL);
    float r = 1.0f / sqrtf(var + 1e-5f);
    #pragma unroll
    for (int i = 0; i < 4; ++i) {
        int d = tid + i * 256;
        po[d] = (x[i] - mean) * r * g[d] + b[d];
    }
}

// ------------- transpose+convert bodies: W f32 [K][N] -> WT bf16 [N][K] -------------
__device__ void convT_body(char* smem, int kx, int ny, const float* __restrict__ W,
                           unsigned short* __restrict__ WT, int K, int N) {
    float (*t)[65] = (float(*)[65])smem;
    const int k0 = kx * 64, n0 = ny * 64;
    const int tid = threadIdx.x;
    {
        const int krow = tid >> 4, c4 = (tid & 15) * 4;
        #pragma unroll
        for (int p = 0; p < 4; ++p) {
            f32x4 gv = *(const f32x4*)&W[(long)(k0 + p * 16 + krow) * N + n0 + c4];
            #pragma unroll
            for (int j = 0; j < 4; ++j) t[p * 16 + krow][c4 + j] = gv[j];
        }
    }
    __syncthreads();
    {
        const int n = tid >> 3, kl = (tid & 7) * 8;
        #pragma unroll
        for (int p = 0; p < 2; ++p) {
            ushort8v pk;
            #pragma unroll
            for (int j = 0; j < 8; ++j) pk[j] = f2bs(t[kl + j][p * 32 + n]);
            *(ushort8v*)&WT[(long)(n0 + p * 32 + n) * K + k0 + kl] = pk;
        }
    }
}

// 512-thread variant
__device__ void convT_body512(char* smem, int kx, int ny, const float* __restrict__ W,
                              unsigned short* __restrict__ WT, int K, int N) {
    float (*t)[65] = (float(*)[65])smem;
    const int k0 = kx * 64, n0 = ny * 64;
    const int tid = threadIdx.x;
    {
        const int krow = tid >> 4, c4 = (tid & 15) * 4;   // krow 0..31
        #pragma unroll
        for (int p = 0; p < 2; ++p) {
            f32x4 gv = *(const f32x4*)&W[(long)(k0 + p * 32 + krow) * N + n0 + c4];
            #pragma unroll
            for (int j = 0; j < 4; ++j) t[p * 32 + krow][c4 + j] = gv[j];
        }
    }
    __syncthreads();
    {
        const int n = tid >> 3, kl = (tid & 7) * 8;       // n 0..63
        ushort8v pk;
        #pragma unroll
        for (int j = 0; j < 8; ++j) pk[j] = f2bs(t[kl + j][n]);
        *(ushort8v*)&WT[(long)(n0 + n) * K + k0 + kl] = pk;
    }
}

// ---------------- 256^2 8-phase bf16 MFMA GEMM body ----------------
#define STG_A(KS, H) do { \
    const unsigned short* g_ = A + (long)(bm + (H) * 128 + srow) * K + (KS) * 64 + stgch; \
    unsigned short* s_ = LDS + (((KS) & 1) * 2 + (H)) * 8192 + (w * 8) * 64; \
    gl_lds16(g_, s_); gl_lds16(g_ + 64L * K, s_ + 4096); \
} while (0)
#define STG_B(KS, H) do { \
    const unsigned short* g_ = BT + (long)(bn + (H) * 128 + srow) * K + (KS) * 64 + stgch; \
    unsigned short* s_ = LDS + 32768 + (((KS) & 1) * 2 + (H)) * 8192 + (w * 8) * 64; \
    gl_lds16(g_, s_); gl_lds16(g_ + 64L * K, s_ + 4096); \
} while (0)
#define MM2(M_, x0, x1) do { \
    acc[M_][0] = __builtin_amdgcn_mfma_f32_16x16x32_bf16(x0, bfr[0], acc[M_][0], 0, 0, 0); \
    acc[M_][0] = __builtin_amdgcn_mfma_f32_16x16x32_bf16(x1, bfr[1], acc[M_][0], 0, 0, 0); \
    acc[M_][1] = __builtin_amdgcn_mfma_f32_16x16x32_bf16(x0, bfr[2], acc[M_][1], 0, 0, 0); \
    acc[M_][1] = __builtin_amdgcn_mfma_f32_16x16x32_bf16(x1, bfr[3], acc[M_][1], 0, 0, 0); \
    acc[M_][2] = __builtin_amdgcn_mfma_f32_16x16x32_bf16(x0, bfr[4], acc[M_][2], 0, 0, 0); \
    acc[M_][2] = __builtin_amdgcn_mfma_f32_16x16x32_bf16(x1, bfr[5], acc[M_][2], 0, 0, 0); \
    acc[M_][3] = __builtin_amdgcn_mfma_f32_16x16x32_bf16(x0, bfr[6], acc[M_][3], 0, 0, 0); \
    acc[M_][3] = __builtin_amdgcn_mfma_f32_16x16x32_bf16(x1, bfr[7], acc[M_][3], 0, 0, 0); \
} while (0)
#define PHASE(Q, SPAR, STAGE_STMT, TAIL_STMT) do { \
    bf16x8 a00, a01, a10, a11; \
    if (((Q) & 3) == 0) { \
        const unsigned short* Bb_ = lBp[SPAR] + ((wc & 1) * 64 + fr) * 64; \
        bfr[0] = *(const bf16x8*)(Bb_ + rd0);        bfr[1] = *(const bf16x8*)(Bb_ + rd1); \
        bfr[2] = *(const bf16x8*)(Bb_ + 1024 + rd0); bfr[3] = *(const bf16x8*)(Bb_ + 1024 + rd1); \
        bfr[4] = *(const bf16x8*)(Bb_ + 2048 + rd0); bfr[5] = *(const bf16x8*)(Bb_ + 2048 + rd1); \
        bfr[6] = *(const bf16x8*)(Bb_ + 3072 + rd0); bfr[7] = *(const bf16x8*)(Bb_ + 3072 + rd1); \
    } \
    { const unsigned short* Ab_ = lAp[SPAR] + fr * 64; \
      a00 = *(const bf16x8*)(Ab_ + (((Q) & 3) * 2) * 1024 + rd0); \
      a01 = *(const bf16x8*)(Ab_ + (((Q) & 3) * 2) * 1024 + rd1); \
      a10 = *(const bf16x8*)(Ab_ + (((Q) & 3) * 2 + 1) * 1024 + rd0); \
      a11 = *(const bf16x8*)(Ab_ + (((Q) & 3) * 2 + 1) * 1024 + rd1); } \
    STAGE_STMT; \
    __builtin_amdgcn_s_barrier(); \
    asm volatile("s_waitcnt lgkmcnt(0)" ::: "memory"); \
    __builtin_amdgcn_sched_barrier(0); \
    __builtin_amdgcn_s_setprio(1); \
    MM2(((Q) & 3) * 2, a00, a01); \
    MM2(((Q) & 3) * 2 + 1, a10, a11); \
    __builtin_amdgcn_s_setprio(0); \
    TAIL_STMT; \
    __builtin_amdgcn_s_barrier(); \
} while (0)

template<int EPI>
__device__ void mm256_body(unsigned short* LDS, int bid, int nwg,
                           const unsigned short* __restrict__ A,
                           const unsigned short* __restrict__ BT,
                           const float* __restrict__ bias,
                           void* __restrict__ Cout, int M, int N, int K, int nbx) {
    const int tid = threadIdx.x;
    const int w = tid >> 6, lane = tid & 63;
    const int wr = w >> 2, wc = w & 3;
    const int swz = (bid & 7) * (nwg >> 3) + (bid >> 3);
    const int bm = (swz / nbx) * 256, bn = (swz % nbx) * 256;

    f32x4 acc[8][4];
    #pragma unroll
    for (int m = 0; m < 8; ++m)
        #pragma unroll
        for (int n = 0; n < 4; ++n)
            acc[m][n] = (f32x4){0.f, 0.f, 0.f, 0.f};

    const int fr = lane & 15, kg = lane >> 4;
    const int rd0 = 8 * (kg ^ (lane & 7)), rd1 = 8 * ((kg + 4) ^ (lane & 7));
    const int stgch = 8 * ((lane & 7) ^ (lane >> 3));
    const int srow = w * 8 + (lane >> 3);
    unsigned short* const lAp[2] = { LDS + wr * 8192, LDS + (2 + wr) * 8192 };
    unsigned short* const lBp[2] = { LDS + 32768 + (wc >> 1) * 8192,
                                     LDS + 32768 + (2 + (wc >> 1)) * 8192 };
    bf16x8 bfr[8];

    STG_B(0, 0); STG_B(0, 1); STG_A(0, 0); STG_A(0, 1); STG_B(1, 0); STG_B(1, 1);
    asm volatile("s_waitcnt vmcnt(4)" ::: "memory");
    __builtin_amdgcn_sched_barrier(0);
    __builtin_amdgcn_s_barrier();

    const int T = K >> 7;
    for (int t = 0; t < T; ++t) {
        const int s = 2 * t;
        const bool nl = (t < T - 1);
        PHASE(0, 0, STG_A(s + 1, 0), );
        PHASE(1, 0, STG_A(s + 1, 1), );
        PHASE(2, 0, if (nl) STG_B(s + 2, 0), );
        PHASE(3, 0, if (nl) STG_B(s + 2, 1),
              if (nl) { asm volatile("s_waitcnt vmcnt(4)" ::: "memory"); } else { asm volatile("s_waitcnt vmcnt(0)" ::: "memory"); } __builtin_amdgcn_sched_barrier(0); );
        PHASE(4, 1, if (nl) STG_A(s + 2, 0), );
        PHASE(5, 1, if (nl) STG_A(s + 2, 1), );
        PHASE(6, 1, if (nl) STG_B(s + 3, 0), );
        PHASE(7, 1, if (nl) STG_B(s + 3, 1),
              if (nl) { asm volatile("s_waitcnt vmcnt(4)" ::: "memory"); __builtin_amdgcn_sched_barrier(0); } );
    }

    const int r0 = (lane >> 4) * 4;
    #pragma unroll
    for (int n = 0; n < 4; ++n) {
        int colb = bn + wc * 64 + n * 16;
        float bv = bias[colb + fr];
        #pragma unroll
        for (int m = 0; m < 8; ++m) {
            int rowb = bm + wr * 128 + m * 16 + r0;
            if (EPI == 3) {
                unsigned short* qkvB = (unsigned short*)Cout;
                int which = colb >> 10, hh = (colb & 1023) >> 6, dbase = colb & 63;
                int b_ = rowb >> 11, s_ = rowb & 2047;
                long bh2 = b_ * 16 + hh;
                float v[4];
                #pragma unroll
                for (int r = 0; r < 4; ++r) v[r] = acc[m][n][r] + bv;
                if (which == 2) {
                    ushort4v pk;
                    #pragma unroll
                    for (int r = 0; r < 4; ++r) pk[r] = f2bs(v[r]);
                    *(ushort4v*)&qkvB[8388608L + (bh2 * 64 + dbase + fr) * 2048 + s_] = pk;
                } else {
                    unsigned short* dst = qkvB + (long)which * 4194304L +
                                          (bh2 * 2048 + s_) * 64 + dbase + fr;
                    #pragma unroll
                    for (int r = 0; r < 4; ++r) dst[r * 64] = f2bs(v[r]);
                }
            } else {
                #pragma unroll
                for (int r = 0; r < 4; ++r) {
                    long row = rowb + r, col = colb + fr;
                    float v = acc[m][n][r] + bv;
                    v = 0.5f * v * (1.0f + erff(v * 0.70710678118f));
                    ((__hip_bfloat16*)Cout)[row * N + col] = __float2bfloat16(v);
                }
            }
        }
    }
}

template<int EPI>
__global__ __launch_bounds__(512, 1)
void mm_mfma256(const unsigned short* __restrict__ A,
                const unsigned short* __restrict__ BT,
                const float* __restrict__ bias,
                void* __restrict__ Cout, int M, int N, int K, int nbx) {
    extern __shared__ unsigned short LDS[];
    mm256_body<EPI>(LDS, blockIdx.x, gridDim.x, A, BT, bias, Cout, M, N, K, nbx);
}

// 256^2 GEMM (nMM blocks) + convT -> WT2 (remaining blocks), 512 thr
template<int EPI>
__global__ __launch_bounds__(512, 1)
void fused_mm256_convT(const unsigned short* __restrict__ A,
                       const unsigned short* __restrict__ BT,
                       const float* __restrict__ bias,
                       void* __restrict__ Cout, int M, int N, int K, int nbx,
                       const float* __restrict__ W2, unsigned short* __restrict__ WT2,
                       int K2, int N2, int nMM) {
    extern __shared__ unsigned short LDS[];
    int bid = blockIdx.x;
    if (bid < nMM) {
        mm256_body<EPI>(LDS, bid, nMM, A, BT, bias, Cout, M, N, K, nbx);
    } else {
        int r = bid - nMM, kt = K2 >> 6;
        convT_body512((char*)LDS, r % kt, r / kt, W2, WT2, K2, N2);
    }
}

// ---------------- n64 GEMM body (3-buffer, 2-deep prefetch, vmcnt(6)) ----------------
__device__ void n64_body(char* smem, int bx, int by,
                         const unsigned short* __restrict__ A,
                         const unsigned short* __restrict__ BT,
                         const float* __restrict__ bias, const float* __restrict__ R,
                         float* __restrict__ Cout, int M, int N, int K) {
    unsigned short* As = (unsigned short*)smem;
    unsigned short* Bs = As + 3 * 128 * 32;
    const int tid = threadIdx.x;
    const int w = tid >> 6, lane = tid & 63;
    const int bm = by * 128, bn = bx * 64;
    const int wr = (w >> 1) * 64, wc = (w & 1) * 32;

    f32x4 acc[4][2];
    #pragma unroll
    for (int m = 0; m < 4; ++m)
        #pragma unroll
        for (int n = 0; n < 2; ++n)
            acc[m][n] = (f32x4){0.f, 0.f, 0.f, 0.f};

    const int lrow = lane >> 2;
    const int lcol = (lane & 3) * 8;
    const unsigned short* gA = A + (long)(bm + w * 32 + lrow) * K + lcol;
    const unsigned short* gB = BT + (long)(bn + w * 16 + lrow) * K + lcol;

#define N64_STAGE(K0, BB) do { \
    gl_lds16(gA + (K0),          &As[(BB) * 4096 + (w * 32) * 32]); \
    gl_lds16(gA + (K0) + 16 * K, &As[(BB) * 4096 + (w * 32 + 16) * 32]); \
    gl_lds16(gB + (K0),          &Bs[(BB) * 2048 + (w * 16) * 32]); \
} while (0)

    const int T = K >> 5;
    N64_STAGE(0, 0);
    if (T > 1) N64_STAGE(32, 1);

    for (int t = 0; t < T; ++t) {
        const int buf = t % 3;
        if (t + 2 < T) {
            N64_STAGE((t + 2) * 32, (t + 2) % 3);
            asm volatile("s_waitcnt vmcnt(6)" ::: "memory");
        } else if (t + 1 < T) {
            asm volatile("s_waitcnt vmcnt(3)" ::: "memory");
        } else {
            asm volatile("s_waitcnt vmcnt(0)" ::: "memory");
        }
        __builtin_amdgcn_sched_barrier(0);
        __builtin_amdgcn_s_barrier();

        bf16x8 a[4], b[2];
        #pragma unroll
        for (int m = 0; m < 4; ++m)
            a[m] = *(const bf16x8*)&As[buf * 4096 + (wr + m * 16 + (lane & 15)) * 32 + (lane >> 4) * 8];
        #pragma unroll
        for (int n = 0; n < 2; ++n)
            b[n] = *(const bf16x8*)&Bs[buf * 2048 + (wc + n * 16 + (lane & 15)) * 32 + (lane >> 4) * 8];
        #pragma unroll
        for (int m = 0; m < 4; ++m)
            #pragma unroll
            for (int n = 0; n < 2; ++n)
                acc[m][n] = __builtin_amdgcn_mfma_f32_16x16x32_bf16(a[m], b[n], acc[m][n], 0, 0, 0);

        __builtin_amdgcn_s_barrier();
    }
#undef N64_STAGE

    const int r0 = (lane >> 4) * 4, cc = lane & 15;
    #pragma unroll
    for (int n = 0; n < 2; ++n) {
        int colb = bn + wc + n * 16;
        float bv = bias[colb + cc];
        #pragma unroll
        for (int m = 0; m < 4; ++m) {
            int rowb = bm + wr + m * 16 + r0;
            #pragma unroll
            for (int r = 0; r < 4; ++r) {
                long row = rowb + r, col = colb + cc;
                float v = acc[m][n][r] + bv + R[row * N + col];
                Cout[row * N + col] = v;
            }
        }
    }
}

// ---------------- MFMA flash attention body, QBLK=128, KVBLK=128, 8 waves ----------------
// K double-buffered + counted vmcnt (T4): smem KB[2][128][64] 32K | Vs[64][128] 16K | Ps 32K = 80K
__device__ void attn_body(char* smem, int bh, int qb,
                          const unsigned short* __restrict__ qB,
                          const unsigned short* __restrict__ kB,
                          const unsigned short* __restrict__ vT,
                          __hip_bfloat16* __restrict__ z) {
    const int tid = threadIdx.x, w = tid >> 6, lane = tid & 63;
    const int arow = lane & 15, kg = lane >> 4;
    unsigned short* KB0 = (unsigned short*)smem;
    unsigned short* KB1 = KB0 + 128 * 64;
    unsigned short* Vs  = KB1 + 128 * 64;
    unsigned short* Ps  = Vs + 64 * 128 + w * 16 * 128;

    const long kvbase = (long)bh * (2048 * 64);

    bf16x8 qa[2];
    {
        const unsigned short* q0 = qB + kvbase + (long)(qb + w * 16 + arow) * 64 + kg * 8;
        qa[0] = *(const bf16x8*)(q0);
        qa[1] = *(const bf16x8*)(q0 + 32);
    }

    f32x4 po[4];
    float mrow[4], lrow[4];
    #pragma unroll
    for (int i = 0; i < 4; ++i) {
        po[i] = (f32x4){0.f, 0.f, 0.f, 0.f};
        mrow[i] = -1e30f; lrow[i] = 0.f;
    }

    const int ksrow = lane >> 3;                  // 0..7
    const int kschunk = (lane & 7) ^ ksrow;       // pre-swizzled source (rule #21)
    const int vsr = lane >> 4;                    // 0..3
    const int cmax = qb >> 7;

    const unsigned short* kSrc = kB + kvbase + (long)(w * 16 + ksrow) * 64 + kschunk * 8;

#define STAGE_K(c, KBp) do { \
    gl_lds16(kSrc + (long)(c) * 128 * 64,          &(KBp)[(w * 16) * 64]); \
    gl_lds16(kSrc + (long)(c) * 128 * 64 + 8 * 64, &(KBp)[(w * 16 + 8) * 64]); \
} while (0)
#define STAGE_V(c) do { \
    _Pragma("unroll") \
    for (int i_ = 0; i_ < 2; ++i_) { \
        int d_ = w * 8 + i_ * 4 + vsr; \
        int sch_ = (lane & 15) ^ (d_ & 7); \
        gl_lds16(vT + kvbase + (long)d_ * 2048 + (c) * 128 + sch_ * 8, \
                 &Vs[(w * 8 + i_ * 4) * 128]); \
    } \
} while (0)

    // prologue: K(0) -> KB0, V(0) -> Vs
    STAGE_K(0, KB0);
    STAGE_V(0);

    for (int c = 0; c <= cmax; ++c) {
        unsigned short* KBcur = (c & 1) ? KB1 : KB0;
        if (c < cmax) {
            STAGE_K(c + 1, (c & 1) ? KB0 : KB1);
            // outstanding: K(c+1)'s 2 loads (newest). V(c), K(c) drained by vmcnt(2).
            asm volatile("s_waitcnt vmcnt(2)" ::: "memory");
        } else {
            asm volatile("s_waitcnt vmcnt(0)" ::: "memory");
        }
        __builtin_amdgcn_sched_barrier(0);
        __builtin_amdgcn_s_barrier();
        __builtin_amdgcn_sched_barrier(0);

        // S = Q @ K^T
        f32x4 s[8];
        #pragma unroll
        for (int n = 0; n < 8; ++n) {
            s[n] = (f32x4){0.f, 0.f, 0.f, 0.f};
            int row = n * 16 + arow, sw = row & 7;
            bf16x8 kb0 = *(const bf16x8*)&KBcur[row * 64 + (kg ^ sw) * 8];
            bf16x8 kb1 = *(const bf16x8*)&KBcur[row * 64 + ((4 + kg) ^ sw) * 8];
            s[n] = __builtin_amdgcn_mfma_f32_16x16x32_bf16(qa[0], kb0, s[n], 0, 0, 0);
            s[n] = __builtin_amdgcn_mfma_f32_16x16x32_bf16(qa[1], kb1, s[n], 0, 0, 0);
        }

        const bool diag = (c == cmax);
        #pragma unroll
        for (int n = 0; n < 8; ++n)
            #pragma unroll
            for (int r = 0; r < 4; ++r) {
                float v = s[n][r] * 0.125f;
                if (diag) {
                    int key = c * 128 + n * 16 + arow;
                    int qrow = qb + w * 16 + kg * 4 + r;
                    if (key > qrow) v = -1e30f;
                }
                s[n][r] = v;
            }

        #pragma unroll
        for (int r = 0; r < 4; ++r) {
            float rm = s[0][r];
            #pragma unroll
            for (int n = 1; n < 8; ++n) rm = fmaxf(rm, s[n][r]);
            #pragma unroll
            for (int off = 1; off < 16; off <<= 1)
                rm = fmaxf(rm, __shfl_xor(rm, off));
            float mnew = fmaxf(mrow[r], rm);
            float esc = expf(mrow[r] - mnew);
            float rs = 0.f;
            #pragma unroll
            for (int n = 0; n < 8; ++n) {
                float p = expf(s[n][r] - mnew);
                s[n][r] = p;
                rs += p;
            }
            #pragma unroll
            for (int off = 1; off < 16; off <<= 1)
                rs += __shfl_xor(rs, off);
            lrow[r] = lrow[r] * esc + rs;
            #pragma unroll
            for (int dt = 0; dt < 4; ++dt) po[dt][r] *= esc;
            mrow[r] = mnew;
        }

        #pragma unroll
        for (int n = 0; n < 8; ++n) {
            int col = n * 16 + arow;
            int chunk = col >> 3, cw = col & 7;
            #pragma unroll
            for (int r = 0; r < 4; ++r) {
                int row = kg * 4 + r;
                Ps[row * 128 + ((chunk ^ (row & 7)) * 8 + cw)] = f2bs(s[n][r]);
            }
        }

        bf16x8 pa[4];
        #pragma unroll
        for (int ks = 0; ks < 4; ++ks)
            pa[ks] = *(const bf16x8*)&Ps[arow * 128 + (((ks * 4 + kg) ^ (arow & 7)) * 8)];
        #pragma unroll
        for (int dt = 0; dt < 4; ++dt) {
            int vrow = dt * 16 + arow, sw = vrow & 7;
            #pragma unroll
            for (int ks = 0; ks < 4; ++ks) {
                bf16x8 vb = *(const bf16x8*)&Vs[vrow * 128 + (((ks * 4 + kg) ^ sw) * 8)];
                po[dt] = __builtin_amdgcn_mfma_f32_16x16x32_bf16(pa[ks], vb, po[dt], 0, 0, 0);
            }
        }
        __builtin_amdgcn_sched_barrier(0);
        __builtin_amdgcn_s_barrier();     // all reads of Vs/KBcur complete
        __builtin_amdgcn_sched_barrier(0);
        if (c < cmax) STAGE_V(c + 1);     // safe: Vs readers done; drained at next top
    }
#undef STAGE_K
#undef STAGE_V

    const int b_ = bh >> 4, hofs = (bh & 15) * 64;
    #pragma unroll
    for (int dt = 0; dt < 4; ++dt)
        #pragma unroll
        for (int r = 0; r < 4; ++r) {
            long row = (long)b_ * 2048 + qb + w * 16 + kg * 4 + r;
            z[row * 1024 + hofs + dt * 16 + arow] = __float2bfloat16(po[dt][r] / lrow[r]);
        }
}

// ---------------- fused kernels ----------------
__global__ __launch_bounds__(256)
void fused_embed_convT(const int* __restrict__ x, const float* __restrict__ wte,
                       const float* __restrict__ wpe, float* __restrict__ h,
                       const float* __restrict__ W, unsigned short* __restrict__ WT,
                       int K, int N, int nEmb) {
    extern __shared__ char smem[];
    int bid = blockIdx.x;
    if (bid < nEmb) {
        embed_body(bid, x, wte, wpe, h);
    } else {
        int r = bid - nEmb, kt = K >> 6;
        convT_body(smem, r % kt, r / kt, W, WT, K, N);
    }
}

// attn QBLK=128 heavy-first (nAttn) + convT -> WT2; 512 thr
__global__ __launch_bounds__(512)
void fused_attn_convT(const unsigned short* __restrict__ qB,
                      const unsigned short* __restrict__ kB,
                      const unsigned short* __restrict__ vT,
                      __hip_bfloat16* __restrict__ z,
                      const float* __restrict__ W2, unsigned short* __restrict__ WT2,
                      int K2, int N2, int nAttn) {
    extern __shared__ char smem[];
    int bid = blockIdx.x;
    if (bid < nAttn) {
        int bh = bid & 31;
        int qblk = 15 - (bid >> 5);           // heavy-first
        attn_body(smem, bh, qblk * 128, qB, kB, vT, z);
    } else {
        int r = bid - nAttn, kt = K2 >> 6;
        convT_body512(smem, r % kt, r / kt, W2, WT2, K2, N2);
    }
}

// n64 GEMM (nMM, bx=bid%nbx) + optional convT -> WT2 (nConv blocks)
__global__ __launch_bounds__(256)
void fused_n64_convT(const unsigned short* __restrict__ A,
                     const unsigned short* __restrict__ BT,
                     const float* __restrict__ bias, const float* __restrict__ R,
                     float* __restrict__ Cout, int M, int N, int K, int nbx,
                     const float* __restrict__ W2, unsigned short* __restrict__ WT2,
                     int K2, int N2, int nMM) {
    extern __shared__ char smem[];
    int bid = blockIdx.x;
    if (bid < nMM) {
        n64_body(smem, bid % nbx, bid / nbx, A, BT, bias, R, Cout, M, N, K);
    } else {
        int r = bid - nMM, kt = K2 >> 6;
        convT_body(smem, r % kt, r / kt, W2, WT2, K2, N2);
    }
}

// ---------------- head ----------------
__global__ void head_kernel(const float* __restrict__ hl, const float* __restrict__ W,
                            float* __restrict__ out) {
    __shared__ float hs[2 * DMODEL];
    int tid = threadIdx.x;
    #pragma unroll
    for (int i = 0; i < 8; ++i) hs[tid + i * 256] = hl[tid + i * 256];
    __syncthreads();
    int v = blockIdx.x * 256 + tid;
    if (v >= VOCAB) return;
    float a0 = 0.f, a1 = 0.f;
    for (int d = 0; d < DMODEL; ++d) {
        float wv = W[(long)d * VOCAB + v];
        a0 += hs[d] * wv;
        a1 += hs[DMODEL + d] * wv;
    }
    out[v] = a0;
    out[VOCAB + v] = a1;
}

extern "C" void kernel_launch(void* const* d_in, const int* in_sizes, int n_in,
                              void* d_out, int out_size, void* d_ws, size_t ws_size,
                              hipStream_t stream) {
    const int*   x      = (const int*)  d_in[0];
    const float* wte    = (const float*)d_in[1];
    const float* wpe    = (const float*)d_in[2];
    const float* ln1_g  = (const float*)d_in[3];
    const float* ln1_b  = (const float*)d_in[4];
    const float* w_qkv  = (const float*)d_in[5];
    const float* b_qkv  = (const float*)d_in[6];
    const float* w_proj = (const float*)d_in[7];
    const float* b_proj = (const float*)d_in[8];
    const float* ln2_g  = (const float*)d_in[9];
    const float* ln2_b  = (const float*)d_in[10];
    const float* w_fc   = (const float*)d_in[11];
    const float* b_fc   = (const float*)d_in[12];
    const float* w_cp   = (const float*)d_in[13];
    const float* b_cp   = (const float*)d_in[14];
    const float* lnf_g  = (const float*)d_in[15];
    const float* lnf_b  = (const float*)d_in[16];
    const float* w_head = (const float*)d_in[17];
    float* out = (float*)d_out;

    char* ws = (char*)d_ws;
    float*          h     = (float*)ws;                             // 16 MB
    unsigned short* qkvB  = (unsigned short*)(ws + (16L << 20));    // 24 MB
    unsigned short* y_bf  = (unsigned short*)(ws + (40L << 20));    // 8 MB
    __hip_bfloat16* z_bf  = (__hip_bfloat16*)(ws + (48L << 20));    // 8 MB
    unsigned short* fc_bf = (unsigned short*)(ws + (56L << 20));    // 32 MB
    unsigned short* wT_a  = (unsigned short*)(ws + (88L << 20));    // 8 MB (fc)
    unsigned short* wT_b  = (unsigned short*)(ws + (97L << 20));    // 8 MB (proj)
    unsigned short* wT_c  = (unsigned short*)(ws + (106L << 20));   // 8 MB (cp)
    unsigned short* wT_q  = (unsigned short*)(ws + (115L << 20));   // 8 MB (qkv)
    float*          hl    = (float*)(ws + (124L << 20));            // 8 KB

    const int SM_CONV = 16640;   // 64*65*4
    const int SM_ATTN = 81920;   // KB 2x16K + Vs 16K + Ps 32K
    const int SM_N64  = 36864;   // As(24K)+Bs(12K)

    // P: embed (4096) + convT qkv layer 0 (768) -> wT_q
    fused_embed_convT<<<4096 + 768, 256, SM_CONV, stream>>>(
        x, wte, wpe, h, w_qkv, wT_q, 1024, 3072, 4096);

    for (int l = 0; l < NLAYER; ++l) {
        // A: LN1 (wave-per-row)
        ln_wave<<<NTOK / 4, 256, 0, stream>>>(h, y_bf, ln1_g + l * DMODEL, ln1_b + l * DMODEL);

        // B: qkv GEMM (192) + convT proj -> wT_b (256)
        fused_mm256_convT<3><<<192 + 256, 512, 131072, stream>>>(
            y_bf, wT_q, b_qkv + l * 3072, qkvB, NTOK, 3072, 1024, 12,
            w_proj + (long)l * DMODEL * DMODEL, wT_b, 1024, 1024, 192);

        // C: attn QBLK=128 (512) + convT cp -> wT_c (1024)
        fused_attn_convT<<<512 + 1024, 512, SM_ATTN, stream>>>(
            qkvB, qkvB + 4194304L, qkvB + 8388608L, z_bf,
            w_cp + (long)l * 4096 * DMODEL, wT_c, 4096, 1024, 512);

        // D: proj GEMM (+residual) + convT fc -> wT_a (1024)
        fused_n64_convT<<<512 + 1024, 256, SM_N64, stream>>>(
            (const unsigned short*)z_bf, wT_b, b_proj + l * DMODEL, h, h,
            NTOK, 1024, 1024, 16,
            w_fc + (long)l * DMODEL * 4096, wT_a, 1024, 4096, 512);

        // E: LN2 (wave-per-row)
        ln_wave<<<NTOK / 4, 256, 0, stream>>>(h, y_bf, ln2_g + l * DMODEL, ln2_b + l * DMODEL);

        // F: fc GEMM (256^2 8-phase, gelu; reads wT_a)
        mm_mfma256<2><<<256, 512, 131072, stream>>>(
            y_bf, wT_a, b_fc + l * 4096, fc_bf, NTOK, 4096, 1024, 16);

        // G: cp GEMM (+residual) + convT qkv(l+1) -> wT_q (768; none on last layer)
        int nConv = (l + 1 < NLAYER) ? 768 : 0;
        fused_n64_convT<<<512 + nConv, 256, SM_N64, stream>>>(
            fc_bf, wT_c, b_cp + l * DMODEL, h, h, NTOK, 1024, 4096, 16,
            w_qkv + (long)(l + 1) * DMODEL * 3072, wT_q, 1024, 3072, 512);
    }

    ln_final<<<BATCH, 256, 0, stream>>>(h + (long)(SEQ - 1) * DMODEL, hl,
                                        lnf_g, lnf_b, (long)SEQ * DMODEL);
    head_kernel<<<(VOCAB + 255) / 256, 256, 0, stream>>>(hl, w_head, out);
}

// Round 20
// 2222.130 us; speedup vs baseline: 1.4188x; 1.0059x over previous
//
#include <hip/hip_runtime.h>
#include <hip/hip_bf16.h>
#include <math.h>

#define VOCAB 50257
#define CTX 2048
#define DMODEL 1024
#define NHEAD 16
#define NLAYER 8
#define DHEAD 64
#define BATCH 2
#define SEQ 2048
#define NTOK (BATCH * SEQ)   // 4096

typedef __bf16 bf16x8 __attribute__((ext_vector_type(8)));
typedef float  f32x4  __attribute__((ext_vector_type(4)));
typedef unsigned short ushort4v __attribute__((ext_vector_type(4)));
typedef unsigned short ushort8v __attribute__((ext_vector_type(8)));

__device__ inline void gl_lds16(const void* g, void* l) {
    __builtin_amdgcn_global_load_lds(
        (const __attribute__((address_space(1))) unsigned int*)g,
        (__attribute__((address_space(3))) unsigned int*)l, 16, 0, 0);
}

__device__ inline unsigned short f2bs(float v) {
    __hip_bfloat16 t = __float2bfloat16(v);
    return *(unsigned short*)&t;
}
__device__ inline float bs2f(unsigned short u) {
    return __uint_as_float(((unsigned)u) << 16);
}

// ---------------- embedding body: h (bf16) = wte[x] + wpe[pos] ----------------
__device__ void embed_body(int t, const int* __restrict__ x,
                           const float* __restrict__ wte,
                           const float* __restrict__ wpe,
                           unsigned short* __restrict__ h) {
    int s = t & (SEQ - 1);
    int tok = x[t];
    const float* pe = wpe + (long)s * DMODEL;
    const float* te = wte + (long)tok * DMODEL;
    unsigned short* ph = h + (long)t * DMODEL;
    int d = threadIdx.x * 4;
    f32x4 t4 = *(const f32x4*)&te[d];
    f32x4 p4 = *(const f32x4*)&pe[d];
    ushort4v o;
    #pragma unroll
    for (int j = 0; j < 4; ++j) o[j] = f2bs(t4[j] + p4[j]);
    *(ushort4v*)&ph[d] = o;
}

// ---------------- layernorm ----------------
__device__ inline float wave_sum(float v) {
    for (int off = 32; off; off >>= 1) v += __shfl_xor(v, off);
    return v;
}

// wave-per-row LN, bf16 in -> bf16 out
__global__ void ln_wave(const unsigned short* __restrict__ in,
                        unsigned short* __restrict__ out,
                        const float* __restrict__ g, const float* __restrict__ b) {
    const int w = threadIdx.x >> 6, lane = threadIdx.x & 63;
    const int row = blockIdx.x * 4 + w;
    const unsigned short* px = in + (long)row * DMODEL;
    ushort8v u[2];
    u[0] = *(const ushort8v*)&px[lane * 16];
    u[1] = *(const ushort8v*)&px[lane * 16 + 8];
    float x[16];
    float s = 0.f;
    #pragma unroll
    for (int i = 0; i < 16; ++i) { x[i] = bs2f(u[i >> 3][i & 7]); s += x[i]; }
    s = wave_sum(s);
    const float mean = s * (1.0f / DMODEL);
    float s2 = 0.f;
    #pragma unroll
    for (int i = 0; i < 16; ++i) { float d = x[i] - mean; s2 += d * d; }
    s2 = wave_sum(s2);
    const float r = 1.0f / sqrtf(s2 * (1.0f / DMODEL) + 1e-5f);
    unsigned short* po = out + (long)row * DMODEL;
    const int d0 = lane * 16;
    #pragma unroll
    for (int p = 0; p < 2; ++p) {
        ushort8v pk;
        #pragma unroll
        for (int j = 0; j < 8; ++j) {
            int d = d0 + p * 8 + j;
            pk[j] = f2bs((x[p * 8 + j] - mean) * r * g[d] + b[d]);
        }
        *(ushort8v*)&po[d0 + p * 8] = pk;
    }
}

// final LN: bf16 in -> f32 out (2 rows)
__global__ void ln_final(const unsigned short* __restrict__ in, float* __restrict__ out,
                         const float* __restrict__ g, const float* __restrict__ b,
                         long row_stride) {
    __shared__ float red[4], red2[4];
    int row = blockIdx.x;
    const unsigned short* px = in + (long)row * row_stride;
    float* po = out + (long)row * DMODEL;
    int tid = threadIdx.x;
    int wid = tid >> 6, lane = tid & 63;
    float x[4];
    float s = 0.f;
    #pragma unroll
    for (int i = 0; i < 4; ++i) { x[i] = bs2f(px[tid + i * 256]); s += x[i]; }
    s = wave_sum(s);
    if (lane == 0) red[wid] = s;
    __syncthreads();
    float mean = (red[0] + red[1] + red[2] + red[3]) * (1.0f / DMODEL);
    float s2 = 0.f;
    #pragma unroll
    for (int i = 0; i < 4; ++i) { float d = x[i] - mean; s2 += d * d; }
    s2 = wave_sum(s2);
    if (lane == 0) red2[wid] = s2;
    __syncthreads();
    float var = (red2[0] + red2[1] + red2[2] + red2[3]) * (1.0f / DMODEL);
    float r = 1.0f / sqrtf(var + 1e-5f);
    #pragma unroll
    for (int i = 0; i < 4; ++i) {
        int d = tid + i * 256;
        po[d] = (x[i] - mean) * r * g[d] + b[d];
    }
}

// ------------- transpose+convert bodies: W f32 [K][N] -> WT bf16 [N][K] -------------
__device__ void convT_body(char* smem, int kx, int ny, const float* __restrict__ W,
                           unsigned short* __restrict__ WT, int K, int N) {
    float (*t)[65] = (float(*)[65])smem;
    const int k0 = kx * 64, n0 = ny * 64;
    const int tid = threadIdx.x;
    {
        const int krow = tid >> 4, c4 = (tid & 15) * 4;
        #pragma unroll
        for (int p = 0; p < 4; ++p) {
            f32x4 gv = *(const f32x4*)&W[(long)(k0 + p * 16 + krow) * N + n0 + c4];
            #pragma unroll
            for (int j = 0; j < 4; ++j) t[p * 16 + krow][c4 + j] = gv[j];
        }
    }
    __syncthreads();
    {
        const int n = tid >> 3, kl = (tid & 7) * 8;
        #pragma unroll
        for (int p = 0; p < 2; ++p) {
            ushort8v pk;
            #pragma unroll
            for (int j = 0; j < 8; ++j) pk[j] = f2bs(t[kl + j][p * 32 + n]);
            *(ushort8v*)&WT[(long)(n0 + p * 32 + n) * K + k0 + kl] = pk;
        }
    }
}

// 512-thread variant
__device__ void convT_body512(char* smem, int kx, int ny, const float* __restrict__ W,
                              unsigned short* __restrict__ WT, int K, int N) {
    float (*t)[65] = (float(*)[65])smem;
    const int k0 = kx * 64, n0 = ny * 64;
    const int tid = threadIdx.x;
    {
        const int krow = tid >> 4, c4 = (tid & 15) * 4;   // krow 0..31
        #pragma unroll
        for (int p = 0; p < 2; ++p) {
            f32x4 gv = *(const f32x4*)&W[(long)(k0 + p * 32 + krow) * N + n0 + c4];
            #pragma unroll
            for (int j = 0; j < 4; ++j) t[p * 32 + krow][c4 + j] = gv[j];
        }
    }
    __syncthreads();
    {
        const int n = tid >> 3, kl = (tid & 7) * 8;       // n 0..63
        ushort8v pk;
        #pragma unroll
        for (int j = 0; j < 8; ++j) pk[j] = f2bs(t[kl + j][n]);
        *(ushort8v*)&WT[(long)(n0 + n) * K + k0 + kl] = pk;
    }
}

// ---------------- 256^2 8-phase bf16 MFMA GEMM body ----------------
#define STG_A(KS, H) do { \
    const unsigned short* g_ = A + (long)(bm + (H) * 128 + srow) * K + (KS) * 64 + stgch; \
    unsigned short* s_ = LDS + (((KS) & 1) * 2 + (H)) * 8192 + (w * 8) * 64; \
    gl_lds16(g_, s_); gl_lds16(g_ + 64L * K, s_ + 4096); \
} while (0)
#define STG_B(KS, H) do { \
    const unsigned short* g_ = BT + (long)(bn + (H) * 128 + srow) * K + (KS) * 64 + stgch; \
    unsigned short* s_ = LDS + 32768 + (((KS) & 1) * 2 + (H)) * 8192 + (w * 8) * 64; \
    gl_lds16(g_, s_); gl_lds16(g_ + 64L * K, s_ + 4096); \
} while (0)
#define MM2(M_, x0, x1) do { \
    acc[M_][0] = __builtin_amdgcn_mfma_f32_16x16x32_bf16(x0, bfr[0], acc[M_][0], 0, 0, 0); \
    acc[M_][0] = __builtin_amdgcn_mfma_f32_16x16x32_bf16(x1, bfr[1], acc[M_][0], 0, 0, 0); \
    acc[M_][1] = __builtin_amdgcn_mfma_f32_16x16x32_bf16(x0, bfr[2], acc[M_][1], 0, 0, 0); \
    acc[M_][1] = __builtin_amdgcn_mfma_f32_16x16x32_bf16(x1, bfr[3], acc[M_][1], 0, 0, 0); \
    acc[M_][2] = __builtin_amdgcn_mfma_f32_16x16x32_bf16(x0, bfr[4], acc[M_][2], 0, 0, 0); \
    acc[M_][2] = __builtin_amdgcn_mfma_f32_16x16x32_bf16(x1, bfr[5], acc[M_][2], 0, 0, 0); \
    acc[M_][3] = __builtin_amdgcn_mfma_f32_16x16x32_bf16(x0, bfr[6], acc[M_][3], 0, 0, 0); \
    acc[M_][3] = __builtin_amdgcn_mfma_f32_16x16x32_bf16(x1, bfr[7], acc[M_][3], 0, 0, 0); \
} while (0)
#define PHASE(Q, SPAR, STAGE_STMT, TAIL_STMT) do { \
    bf16x8 a00, a01, a10, a11; \
    if (((Q) & 3) == 0) { \
        const unsigned short* Bb_ = lBp[SPAR] + ((wc & 1) * 64 + fr) * 64; \
        bfr[0] = *(const bf16x8*)(Bb_ + rd0);        bfr[1] = *(const bf16x8*)(Bb_ + rd1); \
        bfr[2] = *(const bf16x8*)(Bb_ + 1024 + rd0); bfr[3] = *(const bf16x8*)(Bb_ + 1024 + rd1); \
        bfr[4] = *(const bf16x8*)(Bb_ + 2048 + rd0); bfr[5] = *(const bf16x8*)(Bb_ + 2048 + rd1); \
        bfr[6] = *(const bf16x8*)(Bb_ + 3072 + rd0); bfr[7] = *(const bf16x8*)(Bb_ + 3072 + rd1); \
    } \
    { const unsigned short* Ab_ = lAp[SPAR] + fr * 64; \
      a00 = *(const bf16x8*)(Ab_ + (((Q) & 3) * 2) * 1024 + rd0); \
      a01 = *(const bf16x8*)(Ab_ + (((Q) & 3) * 2) * 1024 + rd1); \
      a10 = *(const bf16x8*)(Ab_ + (((Q) & 3) * 2 + 1) * 1024 + rd0); \
      a11 = *(const bf16x8*)(Ab_ + (((Q) & 3) * 2 + 1) * 1024 + rd1); } \
    STAGE_STMT; \
    __builtin_amdgcn_s_barrier(); \
    asm volatile("s_waitcnt lgkmcnt(0)" ::: "memory"); \
    __builtin_amdgcn_sched_barrier(0); \
    __builtin_amdgcn_s_setprio(1); \
    MM2(((Q) & 3) * 2, a00, a01); \
    MM2(((Q) & 3) * 2 + 1, a10, a11); \
    __builtin_amdgcn_s_setprio(0); \
    TAIL_STMT; \
    __builtin_amdgcn_s_barrier(); \
} while (0)

template<int EPI>
__device__ void mm256_body(unsigned short* LDS, int bid, int nwg,
                           const unsigned short* __restrict__ A,
                           const unsigned short* __restrict__ BT,
                           const float* __restrict__ bias,
                           void* __restrict__ Cout, int M, int N, int K, int nbx) {
    const int tid = threadIdx.x;
    const int w = tid >> 6, lane = tid & 63;
    const int wr = w >> 2, wc = w & 3;
    const int swz = (bid & 7) * (nwg >> 3) + (bid >> 3);
    const int bm = (swz / nbx) * 256, bn = (swz % nbx) * 256;

    f32x4 acc[8][4];
    #pragma unroll
    for (int m = 0; m < 8; ++m)
        #pragma unroll
        for (int n = 0; n < 4; ++n)
            acc[m][n] = (f32x4){0.f, 0.f, 0.f, 0.f};

    const int fr = lane & 15, kg = lane >> 4;
    const int rd0 = 8 * (kg ^ (lane & 7)), rd1 = 8 * ((kg + 4) ^ (lane & 7));
    const int stgch = 8 * ((lane & 7) ^ (lane >> 3));
    const int srow = w * 8 + (lane >> 3);
    unsigned short* const lAp[2] = { LDS + wr * 8192, LDS + (2 + wr) * 8192 };
    unsigned short* const lBp[2] = { LDS + 32768 + (wc >> 1) * 8192,
                                     LDS + 32768 + (2 + (wc >> 1)) * 8192 };
    bf16x8 bfr[8];

    STG_B(0, 0); STG_B(0, 1); STG_A(0, 0); STG_A(0, 1); STG_B(1, 0); STG_B(1, 1);
    asm volatile("s_waitcnt vmcnt(4)" ::: "memory");
    __builtin_amdgcn_sched_barrier(0);
    __builtin_amdgcn_s_barrier();

    const int T = K >> 7;
    for (int t = 0; t < T; ++t) {
        const int s = 2 * t;
        const bool nl = (t < T - 1);
        PHASE(0, 0, STG_A(s + 1, 0), );
        PHASE(1, 0, STG_A(s + 1, 1), );
        PHASE(2, 0, if (nl) STG_B(s + 2, 0), );
        PHASE(3, 0, if (nl) STG_B(s + 2, 1),
              if (nl) { asm volatile("s_waitcnt vmcnt(4)" ::: "memory"); } else { asm volatile("s_waitcnt vmcnt(0)" ::: "memory"); } __builtin_amdgcn_sched_barrier(0); );
        PHASE(4, 1, if (nl) STG_A(s + 2, 0), );
        PHASE(5, 1, if (nl) STG_A(s + 2, 1), );
        PHASE(6, 1, if (nl) STG_B(s + 3, 0), );
        PHASE(7, 1, if (nl) STG_B(s + 3, 1),
              if (nl) { asm volatile("s_waitcnt vmcnt(4)" ::: "memory"); __builtin_amdgcn_sched_barrier(0); } );
    }

    const int r0 = (lane >> 4) * 4;
    #pragma unroll
    for (int n = 0; n < 4; ++n) {
        int colb = bn + wc * 64 + n * 16;
        float bv = bias[colb + fr];
        #pragma unroll
        for (int m = 0; m < 8; ++m) {
            int rowb = bm + wr * 128 + m * 16 + r0;
            if (EPI == 3) {
                unsigned short* qkvB = (unsigned short*)Cout;
                int which = colb >> 10, hh = (colb & 1023) >> 6, dbase = colb & 63;
                int b_ = rowb >> 11, s_ = rowb & 2047;
                long bh2 = b_ * 16 + hh;
                float v[4];
                #pragma unroll
                for (int r = 0; r < 4; ++r) v[r] = acc[m][n][r] + bv;
                if (which == 2) {
                    ushort4v pk;
                    #pragma unroll
                    for (int r = 0; r < 4; ++r) pk[r] = f2bs(v[r]);
                    *(ushort4v*)&qkvB[8388608L + (bh2 * 64 + dbase + fr) * 2048 + s_] = pk;
                } else {
                    unsigned short* dst = qkvB + (long)which * 4194304L +
                                          (bh2 * 2048 + s_) * 64 + dbase + fr;
                    #pragma unroll
                    for (int r = 0; r < 4; ++r) dst[r * 64] = f2bs(v[r]);
                }
            } else {
                #pragma unroll
                for (int r = 0; r < 4; ++r) {
                    long row = rowb + r, col = colb + fr;
                    float v = acc[m][n][r] + bv;
                    v = 0.5f * v * (1.0f + erff(v * 0.70710678118f));
                    ((__hip_bfloat16*)Cout)[row * N + col] = __float2bfloat16(v);
                }
            }
        }
    }
}

template<int EPI>
__global__ __launch_bounds__(512, 1)
void mm_mfma256(const unsigned short* __restrict__ A,
                const unsigned short* __restrict__ BT,
                const float* __restrict__ bias,
                void* __restrict__ Cout, int M, int N, int K, int nbx) {
    extern __shared__ unsigned short LDS[];
    mm256_body<EPI>(LDS, blockIdx.x, gridDim.x, A, BT, bias, Cout, M, N, K, nbx);
}

// 256^2 GEMM (nMM blocks) + convT -> WT2 (remaining blocks), 512 thr
template<int EPI>
__global__ __launch_bounds__(512, 1)
void fused_mm256_convT(const unsigned short* __restrict__ A,
                       const unsigned short* __restrict__ BT,
                       const float* __restrict__ bias,
                       void* __restrict__ Cout, int M, int N, int K, int nbx,
                       const float* __restrict__ W2, unsigned short* __restrict__ WT2,
                       int K2, int N2, int nMM) {
    extern __shared__ unsigned short LDS[];
    int bid = blockIdx.x;
    if (bid < nMM) {
        mm256_body<EPI>(LDS, bid, nMM, A, BT, bias, Cout, M, N, K, nbx);
    } else {
        int r = bid - nMM, kt = K2 >> 6;
        convT_body512((char*)LDS, r % kt, r / kt, W2, WT2, K2, N2);
    }
}

// ---------------- n64 GEMM body (3-buffer, 2-deep prefetch, vmcnt(6)); bf16 residual ----------------
__device__ void n64_body(char* smem, int bx, int by,
                         const unsigned short* __restrict__ A,
                         const unsigned short* __restrict__ BT,
                         const float* __restrict__ bias,
                         const unsigned short* __restrict__ R,
                         unsigned short* __restrict__ Cout, int M, int N, int K) {
    unsigned short* As = (unsigned short*)smem;
    unsigned short* Bs = As + 3 * 128 * 32;
    const int tid = threadIdx.x;
    const int w = tid >> 6, lane = tid & 63;
    const int bm = by * 128, bn = bx * 64;
    const int wr = (w >> 1) * 64, wc = (w & 1) * 32;

    f32x4 acc[4][2];
    #pragma unroll
    for (int m = 0; m < 4; ++m)
        #pragma unroll
        for (int n = 0; n < 2; ++n)
            acc[m][n] = (f32x4){0.f, 0.f, 0.f, 0.f};

    const int lrow = lane >> 2;
    const int lcol = (lane & 3) * 8;
    const unsigned short* gA = A + (long)(bm + w * 32 + lrow) * K + lcol;
    const unsigned short* gB = BT + (long)(bn + w * 16 + lrow) * K + lcol;

#define N64_STAGE(K0, BB) do { \
    gl_lds16(gA + (K0),          &As[(BB) * 4096 + (w * 32) * 32]); \
    gl_lds16(gA + (K0) + 16 * K, &As[(BB) * 4096 + (w * 32 + 16) * 32]); \
    gl_lds16(gB + (K0),          &Bs[(BB) * 2048 + (w * 16) * 32]); \
} while (0)

    const int T = K >> 5;
    N64_STAGE(0, 0);
    if (T > 1) N64_STAGE(32, 1);

    for (int t = 0; t < T; ++t) {
        const int buf = t % 3;
        if (t + 2 < T) {
            N64_STAGE((t + 2) * 32, (t + 2) % 3);
            asm volatile("s_waitcnt vmcnt(6)" ::: "memory");
        } else if (t + 1 < T) {
            asm volatile("s_waitcnt vmcnt(3)" ::: "memory");
        } else {
            asm volatile("s_waitcnt vmcnt(0)" ::: "memory");
        }
        __builtin_amdgcn_sched_barrier(0);
        __builtin_amdgcn_s_barrier();

        bf16x8 a[4], b[2];
        #pragma unroll
        for (int m = 0; m < 4; ++m)
            a[m] = *(const bf16x8*)&As[buf * 4096 + (wr + m * 16 + (lane & 15)) * 32 + (lane >> 4) * 8];
        #pragma unroll
        for (int n = 0; n < 2; ++n)
            b[n] = *(const bf16x8*)&Bs[buf * 2048 + (wc + n * 16 + (lane & 15)) * 32 + (lane >> 4) * 8];
        #pragma unroll
        for (int m = 0; m < 4; ++m)
            #pragma unroll
            for (int n = 0; n < 2; ++n)
                acc[m][n] = __builtin_amdgcn_mfma_f32_16x16x32_bf16(a[m], b[n], acc[m][n], 0, 0, 0);

        __builtin_amdgcn_s_barrier();
    }
#undef N64_STAGE

    const int r0 = (lane >> 4) * 4, cc = lane & 15;
    #pragma unroll
    for (int n = 0; n < 2; ++n) {
        int colb = bn + wc + n * 16;
        float bv = bias[colb + cc];
        #pragma unroll
        for (int m = 0; m < 4; ++m) {
            int rowb = bm + wr + m * 16 + r0;
            #pragma unroll
            for (int r = 0; r < 4; ++r) {
                long row = rowb + r, col = colb + cc;
                float v = acc[m][n][r] + bv + bs2f(R[row * N + col]);
                Cout[row * N + col] = f2bs(v);
            }
        }
    }
}

// ---------------- MFMA flash attention body, QBLK=128, KVBLK=128, 8 waves ----------------
// K double-buffered + counted vmcnt: smem KB[2][128][64] 32K | Vs[64][128] 16K | Ps 32K = 80K
__device__ void attn_body(char* smem, int bh, int qb,
                          const unsigned short* __restrict__ qB,
                          const unsigned short* __restrict__ kB,
                          const unsigned short* __restrict__ vT,
                          __hip_bfloat16* __restrict__ z) {
    const int tid = threadIdx.x, w = tid >> 6, lane = tid & 63;
    const int arow = lane & 15, kg = lane >> 4;
    unsigned short* KB0 = (unsigned short*)smem;
    unsigned short* KB1 = KB0 + 128 * 64;
    unsigned short* Vs  = KB1 + 128 * 64;
    unsigned short* Ps  = Vs + 64 * 128 + w * 16 * 128;

    const long kvbase = (long)bh * (2048 * 64);

    bf16x8 qa[2];
    {
        const unsigned short* q0 = qB + kvbase + (long)(qb + w * 16 + arow) * 64 + kg * 8;
        qa[0] = *(const bf16x8*)(q0);
        qa[1] = *(const bf16x8*)(q0 + 32);
    }

    f32x4 po[4];
    float mrow[4], lrow[4];
    #pragma unroll
    for (int i = 0; i < 4; ++i) {
        po[i] = (f32x4){0.f, 0.f, 0.f, 0.f};
        mrow[i] = -1e30f; lrow[i] = 0.f;
    }

    const int ksrow = lane >> 3;
    const int kschunk = (lane & 7) ^ ksrow;
    const int vsr = lane >> 4;
    const int cmax = qb >> 7;

    const unsigned short* kSrc = kB + kvbase + (long)(w * 16 + ksrow) * 64 + kschunk * 8;

#define STAGE_K(c, KBp) do { \
    gl_lds16(kSrc + (long)(c) * 128 * 64,          &(KBp)[(w * 16) * 64]); \
    gl_lds16(kSrc + (long)(c) * 128 * 64 + 8 * 64, &(KBp)[(w * 16 + 8) * 64]); \
} while (0)
#define STAGE_V(c) do { \
    _Pragma("unroll") \
    for (int i_ = 0; i_ < 2; ++i_) { \
        int d_ = w * 8 + i_ * 4 + vsr; \
        int sch_ = (lane & 15) ^ (d_ & 7); \
        gl_lds16(vT + kvbase + (long)d_ * 2048 + (c) * 128 + sch_ * 8, \
                 &Vs[(w * 8 + i_ * 4) * 128]); \
    } \
} while (0)

    STAGE_K(0, KB0);
    STAGE_V(0);

    for (int c = 0; c <= cmax; ++c) {
        unsigned short* KBcur = (c & 1) ? KB1 : KB0;
        if (c < cmax) {
            STAGE_K(c + 1, (c & 1) ? KB0 : KB1);
            asm volatile("s_waitcnt vmcnt(2)" ::: "memory");
        } else {
            asm volatile("s_waitcnt vmcnt(0)" ::: "memory");
        }
        __builtin_amdgcn_sched_barrier(0);
        __builtin_amdgcn_s_barrier();
        __builtin_amdgcn_sched_barrier(0);

        f32x4 s[8];
        #pragma unroll
        for (int n = 0; n < 8; ++n) {
            s[n] = (f32x4){0.f, 0.f, 0.f, 0.f};
            int row = n * 16 + arow, sw = row & 7;
            bf16x8 kb0 = *(const bf16x8*)&KBcur[row * 64 + (kg ^ sw) * 8];
            bf16x8 kb1 = *(const bf16x8*)&KBcur[row * 64 + ((4 + kg) ^ sw) * 8];
            s[n] = __builtin_amdgcn_mfma_f32_16x16x32_bf16(qa[0], kb0, s[n], 0, 0, 0);
            s[n] = __builtin_amdgcn_mfma_f32_16x16x32_bf16(qa[1], kb1, s[n], 0, 0, 0);
        }

        const bool diag = (c == cmax);
        #pragma unroll
        for (int n = 0; n < 8; ++n)
            #pragma unroll
            for (int r = 0; r < 4; ++r) {
                float v = s[n][r] * 0.125f;
                if (diag) {
                    int key = c * 128 + n * 16 + arow;
                    int qrow = qb + w * 16 + kg * 4 + r;
                    if (key > qrow) v = -1e30f;
                }
                s[n][r] = v;
            }

        #pragma unroll
        for (int r = 0; r < 4; ++r) {
            float rm = s[0][r];
            #pragma unroll
            for (int n = 1; n < 8; ++n) rm = fmaxf(rm, s[n][r]);
            #pragma unroll
            for (int off = 1; off < 16; off <<= 1)
                rm = fmaxf(rm, __shfl_xor(rm, off));
            float mnew = fmaxf(mrow[r], rm);
            float esc = expf(mrow[r] - mnew);
            float rs = 0.f;
            #pragma unroll
            for (int n = 0; n < 8; ++n) {
                float p = expf(s[n][r] - mnew);
                s[n][r] = p;
                rs += p;
            }
            #pragma unroll
            for (int off = 1; off < 16; off <<= 1)
                rs += __shfl_xor(rs, off);
            lrow[r] = lrow[r] * esc + rs;
            #pragma unroll
            for (int dt = 0; dt < 4; ++dt) po[dt][r] *= esc;
            mrow[r] = mnew;
        }

        #pragma unroll
        for (int n = 0; n < 8; ++n) {
            int col = n * 16 + arow;
            int chunk = col >> 3, cw = col & 7;
            #pragma unroll
            for (int r = 0; r < 4; ++r) {
                int row = kg * 4 + r;
                Ps[row * 128 + ((chunk ^ (row & 7)) * 8 + cw)] = f2bs(s[n][r]);
            }
        }

        bf16x8 pa[4];
        #pragma unroll
        for (int ks = 0; ks < 4; ++ks)
            pa[ks] = *(const bf16x8*)&Ps[arow * 128 + (((ks * 4 + kg) ^ (arow & 7)) * 8)];
        #pragma unroll
        for (int dt = 0; dt < 4; ++dt) {
            int vrow = dt * 16 + arow, sw = vrow & 7;
            #pragma unroll
            for (int ks = 0; ks < 4; ++ks) {
                bf16x8 vb = *(const bf16x8*)&Vs[vrow * 128 + (((ks * 4 + kg) ^ sw) * 8)];
                po[dt] = __builtin_amdgcn_mfma_f32_16x16x32_bf16(pa[ks], vb, po[dt], 0, 0, 0);
            }
        }
        __builtin_amdgcn_sched_barrier(0);
        __builtin_amdgcn_s_barrier();
        __builtin_amdgcn_sched_barrier(0);
        if (c < cmax) STAGE_V(c + 1);
    }
#undef STAGE_K
#undef STAGE_V

    const int b_ = bh >> 4, hofs = (bh & 15) * 64;
    #pragma unroll
    for (int dt = 0; dt < 4; ++dt)
        #pragma unroll
        for (int r = 0; r < 4; ++r) {
            long row = (long)b_ * 2048 + qb + w * 16 + kg * 4 + r;
            z[row * 1024 + hofs + dt * 16 + arow] = __float2bfloat16(po[dt][r] / lrow[r]);
        }
}

// ---------------- fused kernels ----------------
__global__ __launch_bounds__(256)
void fused_embed_convT(const int* __restrict__ x, const float* __restrict__ wte,
                       const float* __restrict__ wpe, unsigned short* __restrict__ h,
                       const float* __restrict__ W, unsigned short* __restrict__ WT,
                       int K, int N, int nEmb) {
    extern __shared__ char smem[];
    int bid = blockIdx.x;
    if (bid < nEmb) {
        embed_body(bid, x, wte, wpe, h);
    } else {
        int r = bid - nEmb, kt = K >> 6;
        convT_body(smem, r % kt, r / kt, W, WT, K, N);
    }
}

// attn QBLK=128 heavy-first (nAttn) + convT -> WT2; 512 thr
__global__ __launch_bounds__(512)
void fused_attn_convT(const unsigned short* __restrict__ qB,
                      const unsigned short* __restrict__ kB,
                      const unsigned short* __restrict__ vT,
                      __hip_bfloat16* __restrict__ z,
                      const float* __restrict__ W2, unsigned short* __restrict__ WT2,
                      int K2, int N2, int nAttn) {
    extern __shared__ char smem[];
    int bid = blockIdx.x;
    if (bid < nAttn) {
        int bh = bid & 31;
        int qblk = 15 - (bid >> 5);           // heavy-first
        attn_body(smem, bh, qblk * 128, qB, kB, vT, z);
    } else {
        int r = bid - nAttn, kt = K2 >> 6;
        convT_body512(smem, r % kt, r / kt, W2, WT2, K2, N2);
    }
}

// n64 GEMM (nMM, bx=bid%nbx) + optional convT -> WT2 (nConv blocks)
__global__ __launch_bounds__(256)
void fused_n64_convT(const unsigned short* __restrict__ A,
                     const unsigned short* __restrict__ BT,
                     const float* __restrict__ bias, const unsigned short* __restrict__ R,
                     unsigned short* __restrict__ Cout, int M, int N, int K, int nbx,
                     const float* __restrict__ W2, unsigned short* __restrict__ WT2,
                     int K2, int N2, int nMM) {
    extern __shared__ char smem[];
    int bid = blockIdx.x;
    if (bid < nMM) {
        n64_body(smem, bid % nbx, bid / nbx, A, BT, bias, R, Cout, M, N, K);
    } else {
        int r = bid - nMM, kt = K2 >> 6;
        convT_body(smem, r % kt, r / kt, W2, WT2, K2, N2);
    }
}

// ---------------- head ----------------
__global__ void head_kernel(const float* __restrict__ hl, const float* __restrict__ W,
                            float* __restrict__ out) {
    __shared__ float hs[2 * DMODEL];
    int tid = threadIdx.x;
    #pragma unroll
    for (int i = 0; i < 8; ++i) hs[tid + i * 256] = hl[tid + i * 256];
    __syncthreads();
    int v = blockIdx.x * 256 + tid;
    if (v >= VOCAB) return;
    float a0 = 0.f, a1 = 0.f;
    for (int d = 0; d < DMODEL; ++d) {
        float wv = W[(long)d * VOCAB + v];
        a0 += hs[d] * wv;
        a1 += hs[DMODEL + d] * wv;
    }
    out[v] = a0;
    out[VOCAB + v] = a1;
}

extern "C" void kernel_launch(void* const* d_in, const int* in_sizes, int n_in,
                              void* d_out, int out_size, void* d_ws, size_t ws_size,
                              hipStream_t stream) {
    const int*   x      = (const int*)  d_in[0];
    const float* wte    = (const float*)d_in[1];
    const float* wpe    = (const float*)d_in[2];
    const float* ln1_g  = (const float*)d_in[3];
    const float* ln1_b  = (const float*)d_in[4];
    const float* w_qkv  = (const float*)d_in[5];
    const float* b_qkv  = (const float*)d_in[6];
    const float* w_proj = (const float*)d_in[7];
    const float* b_proj = (const float*)d_in[8];
    const float* ln2_g  = (const float*)d_in[9];
    const float* ln2_b  = (const float*)d_in[10];
    const float* w_fc   = (const float*)d_in[11];
    const float* b_fc   = (const float*)d_in[12];
    const float* w_cp   = (const float*)d_in[13];
    const float* b_cp   = (const float*)d_in[14];
    const float* lnf_g  = (const float*)d_in[15];
    const float* lnf_b  = (const float*)d_in[16];
    const float* w_head = (const float*)d_in[17];
    float* out = (float*)d_out;

    char* ws = (char*)d_ws;
    unsigned short* h     = (unsigned short*)ws;                    // 8 MB (bf16)
    unsigned short* qkvB  = (unsigned short*)(ws + (8L << 20));     // 24 MB
    unsigned short* y_bf  = (unsigned short*)(ws + (32L << 20));    // 8 MB
    __hip_bfloat16* z_bf  = (__hip_bfloat16*)(ws + (40L << 20));    // 8 MB
    unsigned short* fc_bf = (unsigned short*)(ws + (48L << 20));    // 32 MB
    unsigned short* wT_a  = (unsigned short*)(ws + (80L << 20));    // 8 MB (fc)
    unsigned short* wT_b  = (unsigned short*)(ws + (89L << 20));    // 8 MB (proj)
    unsigned short* wT_c  = (unsigned short*)(ws + (98L << 20));    // 8 MB (cp)
    unsigned short* wT_q  = (unsigned short*)(ws + (107L << 20));   // 8 MB (qkv)
    float*          hl    = (float*)(ws + (116L << 20));            // 8 KB

    const int SM_CONV = 16640;   // 64*65*4
    const int SM_ATTN = 81920;   // KB 2x16K + Vs 16K + Ps 32K
    const int SM_N64  = 36864;   // As(24K)+Bs(12K)

    // P: embed (4096) + convT qkv layer 0 (768) -> wT_q
    fused_embed_convT<<<4096 + 768, 256, SM_CONV, stream>>>(
        x, wte, wpe, h, w_qkv, wT_q, 1024, 3072, 4096);

    for (int l = 0; l < NLAYER; ++l) {
        // A: LN1 (wave-per-row, bf16 in/out)
        ln_wave<<<NTOK / 4, 256, 0, stream>>>(h, y_bf, ln1_g + l * DMODEL, ln1_b + l * DMODEL);

        // B: qkv GEMM (192) + convT proj -> wT_b (256)
        fused_mm256_convT<3><<<192 + 256, 512, 131072, stream>>>(
            y_bf, wT_q, b_qkv + l * 3072, qkvB, NTOK, 3072, 1024, 12,
            w_proj + (long)l * DMODEL * DMODEL, wT_b, 1024, 1024, 192);

        // C: attn QBLK=128 (512) + convT cp -> wT_c (1024)
        fused_attn_convT<<<512 + 1024, 512, SM_ATTN, stream>>>(
            qkvB, qkvB + 4194304L, qkvB + 8388608L, z_bf,
            w_cp + (long)l * 4096 * DMODEL, wT_c, 4096, 1024, 512);

        // D: proj GEMM (+bf16 residual) + convT fc -> wT_a (1024)
        fused_n64_convT<<<512 + 1024, 256, SM_N64, stream>>>(
            (const unsigned short*)z_bf, wT_b, b_proj + l * DMODEL, h, h,
            NTOK, 1024, 1024, 16,
            w_fc + (long)l * DMODEL * 4096, wT_a, 1024, 4096, 512);

        // E: LN2 (wave-per-row)
        ln_wave<<<NTOK / 4, 256, 0, stream>>>(h, y_bf, ln2_g + l * DMODEL, ln2_b + l * DMODEL);

        // F: fc GEMM (256^2 8-phase, gelu; reads wT_a)
        mm_mfma256<2><<<256, 512, 131072, stream>>>(
            y_bf, wT_a, b_fc + l * 4096, fc_bf, NTOK, 4096, 1024, 16);

        // G: cp GEMM (+bf16 residual) + convT qkv(l+1) -> wT_q (768; none on last layer)
        int nConv = (l + 1 < NLAYER) ? 768 : 0;
        fused_n64_convT<<<512 + nConv, 256, SM_N64, stream>>>(
            fc_bf, wT_c, b_cp + l * DMODEL, h, h, NTOK, 1024, 4096, 16,
            w_qkv + (long)(l + 1) * DMODEL * 3072, wT_q, 1024, 3072, 512);
    }

    ln_final<<<BATCH, 256, 0, stream>>>(h + (long)(SEQ - 1) * DMODEL, hl,
                                        lnf_g, lnf_b, (long)SEQ * DMODEL);
    head_kernel<<<(VOCAB + 255) / 256, 256, 0, stream>>>(hl, w_head, out);
}